// Round 4
// baseline (22245.956 us; speedup 1.0000x reference)
//
#include <hip/hip_runtime.h>
#include <hip/hip_bf16.h>
#include <math.h>

// Problem constants
#define Bc 2
#define Tc 4096
#define Dc 1024
#define Hc 16
#define DKc 64
#define DVc 128
#define KDIMc 1024   // H*DK
#define VDIMc 2048   // H*DV
#define Mrows (Bc*Tc) // 8192
#define CC 64        // scan chunk size
#define NCH (Tc/CC)  // 64 chunks

__device__ __forceinline__ float siluf(float x) {
    return x / (1.f + expf(-x));
}

// ---------------------------------------------------------------------------
// Generic tiled f32 GEMM: C[M,N] = A[M,K] @ B[K,N], all row-major.
// ---------------------------------------------------------------------------
#define GBM 64
#define GBN 64
#define GBK 16
__global__ void __launch_bounds__(256) gemm_f32(
    const float* __restrict__ A, const float* __restrict__ B,
    float* __restrict__ C, int M, int N, int K) {
    __shared__ float As[GBK][GBM + 4];
    __shared__ float Bs[GBK][GBN];
    const int tid = threadIdx.x;
    const int nbx = N / GBN;
    const int bx = blockIdx.x % nbx;
    const int by = blockIdx.x / nbx;
    const int row0 = by * GBM, col0 = bx * GBN;
    const int ty = tid >> 4, tx = tid & 15;
    const int ar = tid >> 2, ak = (tid & 3) * 4;
    const int bc = tid & 63, bk0 = (tid >> 6) * 4;

    float acc[4][4];
#pragma unroll
    for (int i = 0; i < 4; i++)
#pragma unroll
        for (int j = 0; j < 4; j++) acc[i][j] = 0.f;

    for (int k0 = 0; k0 < K; k0 += GBK) {
        float4 av = *(const float4*)&A[(size_t)(row0 + ar) * K + k0 + ak];
        As[ak + 0][ar] = av.x;
        As[ak + 1][ar] = av.y;
        As[ak + 2][ar] = av.z;
        As[ak + 3][ar] = av.w;
#pragma unroll
        for (int i = 0; i < 4; i++)
            Bs[bk0 + i][bc] = B[(size_t)(k0 + bk0 + i) * N + col0 + bc];
        __syncthreads();
#pragma unroll
        for (int kk = 0; kk < GBK; kk++) {
            float a[4], b[4];
            *(float4*)a = *(const float4*)&As[kk][ty * 4];
            *(float4*)b = *(const float4*)&Bs[kk][tx * 4];
#pragma unroll
            for (int i = 0; i < 4; i++)
#pragma unroll
                for (int j = 0; j < 4; j++) acc[i][j] += a[i] * b[j];
        }
        __syncthreads();
    }
#pragma unroll
    for (int i = 0; i < 4; i++) {
        float4 v = make_float4(acc[i][0], acc[i][1], acc[i][2], acc[i][3]);
        *(float4*)&C[(size_t)(row0 + ty * 4 + i) * N + col0 + tx * 4] = v;
    }
}

// ---------------------------------------------------------------------------
// a/b projections (N=16 each) fused with softplus/sigmoid -> g, beta.
// ---------------------------------------------------------------------------
__global__ void __launch_bounds__(256) ab_proj(
    const float* __restrict__ x, const float* __restrict__ w_a,
    const float* __restrict__ w_b, const float* __restrict__ A_log,
    const float* __restrict__ dt_bias, float* __restrict__ g_out,
    float* __restrict__ beta_out) {
    const int row = blockIdx.x * 4 + (threadIdx.x >> 6);
    const int lane = threadIdx.x & 63;
    const int h = lane >> 2;
    const int kg = lane & 3;
    const float* xr = x + (size_t)row * Dc;
    float pa = 0.f, pb = 0.f;
    const int kbeg = kg * 256, kend = kbeg + 256;
    for (int k = kbeg; k < kend; k++) {
        float xv = xr[k];
        pa += xv * w_a[k * Hc + h];
        pb += xv * w_b[k * Hc + h];
    }
    pa += __shfl_xor(pa, 1, 64);
    pa += __shfl_xor(pa, 2, 64);
    pb += __shfl_xor(pb, 1, 64);
    pb += __shfl_xor(pb, 2, 64);
    if (kg == 0) {
        float arg = pa + dt_bias[h];
        float sp = fmaxf(arg, 0.f) + log1pf(expf(-fabsf(arg)));
        g_out[(size_t)row * Hc + h] = -expf(A_log[h]) * sp;
        beta_out[(size_t)row * Hc + h] = 2.f / (1.f + expf(-pb));
    }
}

// ---------------------------------------------------------------------------
// Save 3-row halos at 64-step chunk boundaries (for in-place conv).
// ---------------------------------------------------------------------------
template <int C>
__global__ void __launch_bounds__(256) save_halo(
    const float* __restrict__ in, float* __restrict__ halo) {
    const int g = blockIdx.x * 256 + threadIdx.x;
    const int total = Bc * (Tc / 64 - 1) * 3 * C;
    if (g >= total) return;
    const int c = g % C;
    int r = g / C;
    const int j = r % 3;
    r /= 3;
    const int chunk = r % (Tc / 64 - 1) + 1;
    const int b = r / (Tc / 64 - 1);
    halo[((size_t)(b * 64 + chunk) * 3 + j) * C + c] =
        in[((size_t)b * Tc + chunk * 64 - 3 + j) * C + c];
}

// ---------------------------------------------------------------------------
// Depthwise causal conv1d (K=4) + SiLU (+ optional l2norm), IN PLACE.
// ---------------------------------------------------------------------------
template <int C, bool L2N>
__global__ void __launch_bounds__(256) conv_silu_inplace(
    float* __restrict__ buf, const float* __restrict__ w,
    const float* __restrict__ halo) {
    constexpr int CB = C / 256;
    const int bidx = blockIdx.x;
    const int cb = bidx % CB;
    const int tchunk = (bidx / CB) % (Tc / 64);
    const int b = bidx / (CB * (Tc / 64));
    const int c = cb * 256 + threadIdx.x;
    const int t0 = tchunk * 64;
    const float w0 = w[c * 4 + 0], w1 = w[c * 4 + 1], w2 = w[c * 4 + 2],
                w3 = w[c * 4 + 3];
    float xm3 = 0.f, xm2 = 0.f, xm1 = 0.f;
    if (tchunk > 0) {
        const float* hp = halo + (size_t)(b * 64 + tchunk) * 3 * C + c;
        xm3 = hp[0];
        xm2 = hp[C];
        xm1 = hp[2 * C];
    }
    float* p = buf + (size_t)b * Tc * C + c;
#pragma unroll 4
    for (int i = 0; i < 64; i++) {
        float xt = p[(size_t)(t0 + i) * C];
        float y = w0 * xm3 + w1 * xm2 + w2 * xm1 + w3 * xt;
        y = siluf(y);
        if (L2N) {
            float ss = y * y;
#pragma unroll
            for (int m = 1; m < 64; m <<= 1) ss += __shfl_xor(ss, m, 64);
            y *= rsqrtf(ss + 1e-6f);
        }
        p[(size_t)(t0 + i) * C] = y;
        xm3 = xm2;
        xm2 = xm1;
        xm1 = xt;
    }
}

// ---------------------------------------------------------------------------
// Chunked gated delta rule (WY form), one WG of 512 per (b,h).
//   A[t,s] = beta_t exp(c_t-c_s) (k_t.k_s)   (s<t)
//   RHS    = beta*(V - Gamma*(K S_in))        (Gamma_t = exp(c_t))
//   (I+A) delta = RHS   -> forward substitution (lane-parallel, spill-free)
//   O      = scale*Gamma*(Q S_in) + M delta,  M[t,s]=scale exp(c_t-c_s)(q_t.k_s)
//   S_out  = exp(c_end) S_in + sum_s exp(c_end-c_s) k_s delta_s^T
// Thread (dv=tid>>2, qd=tid&3) owns S[qd*16+j][dv], j=0..15 (registers).
// ---------------------------------------------------------------------------
__global__ void __launch_bounds__(512) chunk_scan(
    const float* __restrict__ qc, const float* __restrict__ kc,
    const float* __restrict__ vc, const float* __restrict__ g,
    const float* __restrict__ beta, float* __restrict__ o) {
    const int bh = blockIdx.x;
    const int b = bh >> 4, h = bh & 15;
    const int tid = threadIdx.x;
    const int dv = tid >> 2, qd = tid & 3;

    __shared__ float kL[CC][DKc + 4];   // k rows (never rescaled)
    __shared__ float qL[CC][DKc + 4];
    __shared__ float kT[DKc][CC + 4];   // transposes for A/M dot products
    __shared__ float qT[DKc][CC + 4];
    __shared__ float AtL[CC][CC + 4];   // A^T (zeros on/above diag)
    __shared__ float ML[CC][CC + 4];    // M   (zeros above diag)
    __shared__ float vL[CC][DVc + 5];   // v -> RHS -> delta (stride 133)
    __shared__ float cL[CC], gamL[CC], egL[CC], betaL[CC];

    float S[16];
#pragma unroll
    for (int j = 0; j < 16; j++) S[j] = 0.f;

    const size_t qk0 = (size_t)b * Tc * KDIMc + h * DKc;
    const size_t v0 = (size_t)b * Tc * VDIMc + h * DVc;
    const size_t gb0 = (size_t)b * Tc * Hc + h;

#pragma unroll 1
    for (int ch = 0; ch < NCH; ch++) {
        const int t0 = ch * CC;
        __syncthreads();  // previous chunk done reading LDS

        // ---- P0: stage k,q (64x64) + transposes, v (64x128)
#pragma unroll
        for (int i = 0; i < 2; i++) {
            int e = tid + i * 512;
            int r = e >> 4, c4 = (e & 15) << 2;
            float4 kv = *(const float4*)&kc[qk0 + (size_t)(t0 + r) * KDIMc + c4];
            float4 qv = *(const float4*)&qc[qk0 + (size_t)(t0 + r) * KDIMc + c4];
            *(float4*)&kL[r][c4] = kv;
            *(float4*)&qL[r][c4] = qv;
            kT[c4 + 0][r] = kv.x; kT[c4 + 1][r] = kv.y;
            kT[c4 + 2][r] = kv.z; kT[c4 + 3][r] = kv.w;
            qT[c4 + 0][r] = qv.x; qT[c4 + 1][r] = qv.y;
            qT[c4 + 2][r] = qv.z; qT[c4 + 3][r] = qv.w;
        }
#pragma unroll
        for (int i = 0; i < 4; i++) {
            int e = tid + i * 512;
            int r = e >> 5, c4 = (e & 31) << 2;
            float4 vv = *(const float4*)&vc[v0 + (size_t)(t0 + r) * VDIMc + c4];
            vL[r][c4 + 0] = vv.x; vL[r][c4 + 1] = vv.y;
            vL[r][c4 + 2] = vv.z; vL[r][c4 + 3] = vv.w;
        }
        // ---- P1: wave 0: cumsum(g), decay factors, beta
        if (tid < 64) {
            float gv = g[gb0 + (size_t)(t0 + tid) * Hc];
            float cv = gv;
#pragma unroll
            for (int d = 1; d < 64; d <<= 1) {
                float nb = __shfl_up(cv, d, 64);
                if (tid >= d) cv += nb;
            }
            cL[tid] = cv;
            gamL[tid] = expf(cv);
            float cend = __shfl(cv, 63, 64);
            egL[tid] = expf(cend - cv);
            betaL[tid] = beta[gb0 + (size_t)(t0 + tid) * Hc];
        }
        __syncthreads();

        // ---- P2a: A (threads 0..255) and M (threads 256..511), 4x4 tiles
        {
            const int half = tid >> 8;
            const int tt2 = tid & 255;
            const int tIdx = tt2 >> 4, sIdx = tt2 & 15;
            float dot[4][4];
#pragma unroll
            for (int i = 0; i < 4; i++)
#pragma unroll
                for (int j = 0; j < 4; j++) dot[i][j] = 0.f;
            const float(*TA)[CC + 4] = half ? qT : kT;
#pragma unroll
            for (int d = 0; d < 64; d++) {
                float4 ta = *(const float4*)&TA[d][tIdx * 4];
                float4 sa = *(const float4*)&kT[d][sIdx * 4];
                dot[0][0] += ta.x * sa.x; dot[0][1] += ta.x * sa.y;
                dot[0][2] += ta.x * sa.z; dot[0][3] += ta.x * sa.w;
                dot[1][0] += ta.y * sa.x; dot[1][1] += ta.y * sa.y;
                dot[1][2] += ta.y * sa.z; dot[1][3] += ta.y * sa.w;
                dot[2][0] += ta.z * sa.x; dot[2][1] += ta.z * sa.y;
                dot[2][2] += ta.z * sa.z; dot[2][3] += ta.z * sa.w;
                dot[3][0] += ta.w * sa.x; dot[3][1] += ta.w * sa.y;
                dot[3][2] += ta.w * sa.z; dot[3][3] += ta.w * sa.w;
            }
#pragma unroll
            for (int it = 0; it < 4; it++)
#pragma unroll
                for (int is = 0; is < 4; is++) {
                    int t = tIdx * 4 + it, s = sIdx * 4 + is;
                    if (half == 0) {
                        float v = (s < t) ? betaL[t] * expf(cL[t] - cL[s]) *
                                                dot[it][is]
                                          : 0.f;
                        AtL[s][t] = v;
                    } else {
                        float v = (s <= t) ? 0.125f * expf(cL[t] - cL[s]) *
                                                 dot[it][is]
                                           : 0.f;
                        ML[t][s] = v;
                    }
                }
        }
        // ---- P2b: RHS = beta*(v - Gamma*(k.S_in))  (in place over vL)
#pragma unroll 8
        for (int t = 0; t < 64; t++) {
            float p = 0.f;
#pragma unroll
            for (int j4 = 0; j4 < 4; j4++) {
                float4 kk = *(const float4*)&kL[t][qd * 16 + j4 * 4];
                p += kk.x * S[j4 * 4 + 0] + kk.y * S[j4 * 4 + 1] +
                     kk.z * S[j4 * 4 + 2] + kk.w * S[j4 * 4 + 3];
            }
            p += __shfl_xor(p, 1, 64);
            p += __shfl_xor(p, 2, 64);
            if (qd == 0) vL[t][dv] = betaL[t] * (vL[t][dv] - gamL[t] * p);
        }
        __syncthreads();

        // ---- P3: lane-parallel forward substitution, spill-free.
        // Wave w owns 16 delta-columns d = w*16+di; lane t holds row t.
        // Step s: delta_s comes from lane s via shuffle; AtL[s][lane]=0 for
        // lane<=s keeps finalized rows untouched.
        {
            const int w = tid >> 6, lane = tid & 63;
            const int d0 = w * 16;
            float acc[16];
#pragma unroll
            for (int di = 0; di < 16; di++) acc[di] = vL[lane][d0 + di];
#pragma unroll 4
            for (int s = 0; s < 64; s++) {
                float a = AtL[s][lane];
#pragma unroll
                for (int di = 0; di < 16; di++) {
                    float ds = __shfl(acc[di], s, 64);
                    acc[di] -= a * ds;
                }
            }
#pragma unroll
            for (int di = 0; di < 16; di++) vL[lane][d0 + di] = acc[di];
        }
        __syncthreads();

        // ---- P6: O = scale*Gamma*(q.S_in) + M delta
        const float gend = gamL[63];
#pragma unroll 4
        for (int t = 0; t < 64; t++) {
            float p1 = 0.f, p2 = 0.f;
#pragma unroll
            for (int j4 = 0; j4 < 4; j4++) {
                float4 qq = *(const float4*)&qL[t][qd * 16 + j4 * 4];
                p1 += qq.x * S[j4 * 4 + 0] + qq.y * S[j4 * 4 + 1] +
                      qq.z * S[j4 * 4 + 2] + qq.w * S[j4 * 4 + 3];
                float4 mm = *(const float4*)&ML[t][qd * 16 + j4 * 4];
                int s0 = qd * 16 + j4 * 4;
                p2 += mm.x * vL[s0 + 0][dv] + mm.y * vL[s0 + 1][dv] +
                      mm.z * vL[s0 + 2][dv] + mm.w * vL[s0 + 3][dv];
            }
            float p = 0.125f * gamL[t] * p1 + p2;
            p += __shfl_xor(p, 1, 64);
            p += __shfl_xor(p, 2, 64);
            if (qd == 0)
                o[((size_t)b * Tc + t0 + t) * VDIMc + h * DVc + dv] = p;
        }
        // ---- P7: S = exp(c_end) S + sum_s exp(c_end-c_s) k_s delta_s
        // (egL folded into the delta scalar; kL stays unscaled)
#pragma unroll
        for (int j = 0; j < 16; j++) S[j] *= gend;
#pragma unroll 8
        for (int s = 0; s < 64; s++) {
            float d0 = egL[s] * vL[s][dv];
#pragma unroll
            for (int j4 = 0; j4 < 4; j4++) {
                float4 kk = *(const float4*)&kL[s][qd * 16 + j4 * 4];
                S[j4 * 4 + 0] += kk.x * d0;
                S[j4 * 4 + 1] += kk.y * d0;
                S[j4 * 4 + 2] += kk.z * d0;
                S[j4 * 4 + 3] += kk.w * d0;
            }
        }
    }
}

// ---------------------------------------------------------------------------
// Gated RMSNorm: one wave per (b,t,h) row of 128; in-place on o.
// ---------------------------------------------------------------------------
__global__ void __launch_bounds__(256) rms_gate(
    float* __restrict__ o, const float* __restrict__ gg,
    const float* __restrict__ norm_w) {
    const int row = blockIdx.x * 4 + (threadIdx.x >> 6);
    const int lane = threadIdx.x & 63;
    const size_t base = (size_t)row * DVc;
    float2 ov = *(const float2*)&o[base + lane * 2];
    float ss = ov.x * ov.x + ov.y * ov.y;
#pragma unroll
    for (int m = 1; m < 64; m <<= 1) ss += __shfl_xor(ss, m, 64);
    const float f = rsqrtf(ss * (1.f / 128.f) + 1e-5f);
    float2 gv = *(const float2*)&gg[base + lane * 2];
    const float nw0 = norm_w[lane * 2], nw1 = norm_w[lane * 2 + 1];
    float y0 = ov.x * f * nw0 * siluf(gv.x);
    float y1 = ov.y * f * nw1 * siluf(gv.y);
    *(float2*)&o[base + lane * 2] = make_float2(y0, y1);
}

// ---------------------------------------------------------------------------
// Workspace: qb 8.4M + kb 8.4M + vb 16.8M + obuf 16.8M + gbuf/bbuf 0.26M
//            + halo 0.79M  = 51.4M floats = 205.5 MB
// ---------------------------------------------------------------------------
extern "C" void kernel_launch(void* const* d_in, const int* in_sizes, int n_in,
                              void* d_out, int out_size, void* d_ws,
                              size_t ws_size, hipStream_t stream) {
    const float* x = (const float*)d_in[0];
    const float* w_q = (const float*)d_in[1];
    const float* w_k = (const float*)d_in[2];
    const float* w_v = (const float*)d_in[3];
    const float* w_a = (const float*)d_in[4];
    const float* w_b = (const float*)d_in[5];
    const float* w_g = (const float*)d_in[6];
    const float* w_out = (const float*)d_in[7];
    const float* A_log = (const float*)d_in[8];
    const float* dt_bias = (const float*)d_in[9];
    const float* conv_q = (const float*)d_in[10];
    const float* conv_k = (const float*)d_in[11];
    const float* conv_v = (const float*)d_in[12];
    const float* norm_w = (const float*)d_in[13];

    float* ws = (float*)d_ws;
    const size_t M = Mrows;
    float* qb = ws;
    float* kb = qb + M * KDIMc;
    float* vb = kb + M * KDIMc;
    float* obuf = vb + M * VDIMc;
    float* gbuf = obuf + M * VDIMc;
    float* bbuf = gbuf + M * Hc;
    float* halo = bbuf + M * Hc;
    float* gg = qb;  // aliased AFTER the scan (qb+kb contiguous)

    // 1) q/k/v projections
    gemm_f32<<<dim3((M / GBM) * (KDIMc / GBN)), 256, 0, stream>>>(
        x, w_q, qb, M, KDIMc, Dc);
    gemm_f32<<<dim3((M / GBM) * (KDIMc / GBN)), 256, 0, stream>>>(
        x, w_k, kb, M, KDIMc, Dc);
    gemm_f32<<<dim3((M / GBM) * (VDIMc / GBN)), 256, 0, stream>>>(
        x, w_v, vb, M, VDIMc, Dc);

    // 2) a/b projections fused with activation -> g, beta
    ab_proj<<<dim3(M / 4), 256, 0, stream>>>(x, w_a, w_b, A_log, dt_bias, gbuf,
                                             bbuf);

    // 3) conv + silu (+ l2norm for q,k), in place with halo save
    {
        const int nqk = Bc * (Tc / 64 - 1) * 3 * KDIMc;
        const int nv = Bc * (Tc / 64 - 1) * 3 * VDIMc;
        save_halo<KDIMc><<<dim3((nqk + 255) / 256), 256, 0, stream>>>(qb, halo);
        conv_silu_inplace<KDIMc, true>
            <<<dim3(Bc * (Tc / 64) * (KDIMc / 256)), 256, 0, stream>>>(
                qb, conv_q, halo);
        save_halo<KDIMc><<<dim3((nqk + 255) / 256), 256, 0, stream>>>(kb, halo);
        conv_silu_inplace<KDIMc, true>
            <<<dim3(Bc * (Tc / 64) * (KDIMc / 256)), 256, 0, stream>>>(
                kb, conv_k, halo);
        save_halo<VDIMc><<<dim3((nv + 255) / 256), 256, 0, stream>>>(vb, halo);
        conv_silu_inplace<VDIMc, false>
            <<<dim3(Bc * (Tc / 64) * (VDIMc / 256)), 256, 0, stream>>>(
                vb, conv_v, halo);
    }

    // 4) chunked gated delta-rule (WY form)
    chunk_scan<<<dim3(Bc * Hc), 512, 0, stream>>>(qb, kb, vb, gbuf, bbuf,
                                                  obuf);

    // 5) gate projection (after scan so it can alias qb+kb)
    gemm_f32<<<dim3((M / GBM) * (VDIMc / GBN)), 256, 0, stream>>>(
        x, w_g, gg, M, VDIMc, Dc);

    // 6) gated RMSNorm (in place on obuf)
    rms_gate<<<dim3(M * Hc / 4), 256, 0, stream>>>(obuf, gg, norm_w);

    // 7) output projection -> d_out
    gemm_f32<<<dim3((M / GBM) * (Dc / GBN)), 256, 0, stream>>>(
        obuf, w_out, (float*)d_out, M, Dc, VDIMc);
}

// Round 5
// 6290.417 us; speedup vs baseline: 3.5365x; 3.5365x over previous
//
#include <hip/hip_runtime.h>
#include <hip/hip_bf16.h>
#include <math.h>

// Problem constants
#define Bc 2
#define Tc 4096
#define Dc 1024
#define Hc 16
#define DKc 64
#define DVc 128
#define KDIMc 1024   // H*DK
#define VDIMc 2048   // H*DV
#define Mrows (Bc*Tc) // 8192
#define CC 64        // scan chunk size
#define NCH (Tc/CC)  // 64 chunks

__device__ __forceinline__ float siluf(float x) {
    return x / (1.f + expf(-x));
}

// ---------------------------------------------------------------------------
// Generic tiled f32 GEMM: C[M,N] = A[M,K] @ B[K,N], all row-major.
// ---------------------------------------------------------------------------
#define GBM 64
#define GBN 64
#define GBK 16
__global__ void __launch_bounds__(256) gemm_f32(
    const float* __restrict__ A, const float* __restrict__ B,
    float* __restrict__ C, int M, int N, int K) {
    __shared__ float As[GBK][GBM + 4];
    __shared__ float Bs[GBK][GBN];
    const int tid = threadIdx.x;
    const int nbx = N / GBN;
    const int bx = blockIdx.x % nbx;
    const int by = blockIdx.x / nbx;
    const int row0 = by * GBM, col0 = bx * GBN;
    const int ty = tid >> 4, tx = tid & 15;
    const int ar = tid >> 2, ak = (tid & 3) * 4;
    const int bc = tid & 63, bk0 = (tid >> 6) * 4;

    float acc[4][4];
#pragma unroll
    for (int i = 0; i < 4; i++)
#pragma unroll
        for (int j = 0; j < 4; j++) acc[i][j] = 0.f;

    for (int k0 = 0; k0 < K; k0 += GBK) {
        float4 av = *(const float4*)&A[(size_t)(row0 + ar) * K + k0 + ak];
        As[ak + 0][ar] = av.x;
        As[ak + 1][ar] = av.y;
        As[ak + 2][ar] = av.z;
        As[ak + 3][ar] = av.w;
#pragma unroll
        for (int i = 0; i < 4; i++)
            Bs[bk0 + i][bc] = B[(size_t)(k0 + bk0 + i) * N + col0 + bc];
        __syncthreads();
#pragma unroll
        for (int kk = 0; kk < GBK; kk++) {
            float a[4], b[4];
            *(float4*)a = *(const float4*)&As[kk][ty * 4];
            *(float4*)b = *(const float4*)&Bs[kk][tx * 4];
#pragma unroll
            for (int i = 0; i < 4; i++)
#pragma unroll
                for (int j = 0; j < 4; j++) acc[i][j] += a[i] * b[j];
        }
        __syncthreads();
    }
#pragma unroll
    for (int i = 0; i < 4; i++) {
        float4 v = make_float4(acc[i][0], acc[i][1], acc[i][2], acc[i][3]);
        *(float4*)&C[(size_t)(row0 + ty * 4 + i) * N + col0 + tx * 4] = v;
    }
}

// ---------------------------------------------------------------------------
// a/b projections (N=16 each) fused with softplus/sigmoid -> g, beta.
// ---------------------------------------------------------------------------
__global__ void __launch_bounds__(256) ab_proj(
    const float* __restrict__ x, const float* __restrict__ w_a,
    const float* __restrict__ w_b, const float* __restrict__ A_log,
    const float* __restrict__ dt_bias, float* __restrict__ g_out,
    float* __restrict__ beta_out) {
    const int row = blockIdx.x * 4 + (threadIdx.x >> 6);
    const int lane = threadIdx.x & 63;
    const int h = lane >> 2;
    const int kg = lane & 3;
    const float* xr = x + (size_t)row * Dc;
    float pa = 0.f, pb = 0.f;
    const int kbeg = kg * 256, kend = kbeg + 256;
    for (int k = kbeg; k < kend; k++) {
        float xv = xr[k];
        pa += xv * w_a[k * Hc + h];
        pb += xv * w_b[k * Hc + h];
    }
    pa += __shfl_xor(pa, 1, 64);
    pa += __shfl_xor(pa, 2, 64);
    pb += __shfl_xor(pb, 1, 64);
    pb += __shfl_xor(pb, 2, 64);
    if (kg == 0) {
        float arg = pa + dt_bias[h];
        float sp = fmaxf(arg, 0.f) + log1pf(expf(-fabsf(arg)));
        g_out[(size_t)row * Hc + h] = -expf(A_log[h]) * sp;
        beta_out[(size_t)row * Hc + h] = 2.f / (1.f + expf(-pb));
    }
}

// ---------------------------------------------------------------------------
// Save 3-row halos at 64-step chunk boundaries (for in-place conv).
// ---------------------------------------------------------------------------
template <int C>
__global__ void __launch_bounds__(256) save_halo(
    const float* __restrict__ in, float* __restrict__ halo) {
    const int g = blockIdx.x * 256 + threadIdx.x;
    const int total = Bc * (Tc / 64 - 1) * 3 * C;
    if (g >= total) return;
    const int c = g % C;
    int r = g / C;
    const int j = r % 3;
    r /= 3;
    const int chunk = r % (Tc / 64 - 1) + 1;
    const int b = r / (Tc / 64 - 1);
    halo[((size_t)(b * 64 + chunk) * 3 + j) * C + c] =
        in[((size_t)b * Tc + chunk * 64 - 3 + j) * C + c];
}

// ---------------------------------------------------------------------------
// Depthwise causal conv1d (K=4) + SiLU (+ optional l2norm), IN PLACE.
// ---------------------------------------------------------------------------
template <int C, bool L2N>
__global__ void __launch_bounds__(256) conv_silu_inplace(
    float* __restrict__ buf, const float* __restrict__ w,
    const float* __restrict__ halo) {
    constexpr int CB = C / 256;
    const int bidx = blockIdx.x;
    const int cb = bidx % CB;
    const int tchunk = (bidx / CB) % (Tc / 64);
    const int b = bidx / (CB * (Tc / 64));
    const int c = cb * 256 + threadIdx.x;
    const int t0 = tchunk * 64;
    const float w0 = w[c * 4 + 0], w1 = w[c * 4 + 1], w2 = w[c * 4 + 2],
                w3 = w[c * 4 + 3];
    float xm3 = 0.f, xm2 = 0.f, xm1 = 0.f;
    if (tchunk > 0) {
        const float* hp = halo + (size_t)(b * 64 + tchunk) * 3 * C + c;
        xm3 = hp[0];
        xm2 = hp[C];
        xm1 = hp[2 * C];
    }
    float* p = buf + (size_t)b * Tc * C + c;
#pragma unroll 4
    for (int i = 0; i < 64; i++) {
        float xt = p[(size_t)(t0 + i) * C];
        float y = w0 * xm3 + w1 * xm2 + w2 * xm1 + w3 * xt;
        y = siluf(y);
        if (L2N) {
            float ss = y * y;
#pragma unroll
            for (int m = 1; m < 64; m <<= 1) ss += __shfl_xor(ss, m, 64);
            y *= rsqrtf(ss + 1e-6f);
        }
        p[(size_t)(t0 + i) * C] = y;
        xm3 = xm2;
        xm2 = xm1;
        xm1 = xt;
    }
}

// ---------------------------------------------------------------------------
// Chunked gated delta rule (WY form), one WG of 512 per (b,h).
//   A[t,s] = beta_t exp(c_t-c_s) (k_t.k_s)   (s<t)
//   RHS    = beta*(V - Gamma*(K S_in))        (Gamma_t = exp(c_t))
//   (I+A) delta = RHS   -> forward substitution (lane-parallel)
//   O      = scale*Gamma*(Q S_in) + M delta,  M[t,s]=scale exp(c_t-c_s)(q_t.k_s)
//   S_out  = exp(c_end) S_in + sum_s exp(c_end-c_s) k_s delta_s^T
// Thread (dv=tid>>2, qd=tid&3) owns S[qd*16+j][dv], j=0..15 (registers).
// launch_bounds(512,2): exactly 1 WG/CU (LDS-limited anyway) -> 256 VGPR cap,
// plus reduced unrolls, to eliminate spill scratch traffic (R4 WRITE_SIZE
// was ~1.2 GB vs ~70 MB of real stores).
// ---------------------------------------------------------------------------
__global__ void __launch_bounds__(512, 2) chunk_scan(
    const float* __restrict__ qc, const float* __restrict__ kc,
    const float* __restrict__ vc, const float* __restrict__ g,
    const float* __restrict__ beta, float* __restrict__ o) {
    const int bh = blockIdx.x;
    const int b = bh >> 4, h = bh & 15;
    const int tid = threadIdx.x;
    const int dv = tid >> 2, qd = tid & 3;

    __shared__ float kL[CC][DKc + 4];   // k rows (never rescaled)
    __shared__ float qL[CC][DKc + 4];
    __shared__ float kT[DKc][CC + 4];   // transposes for A/M dot products
    __shared__ float qT[DKc][CC + 4];
    __shared__ float AtL[CC][CC + 4];   // A^T (zeros on/above diag)
    __shared__ float ML[CC][CC + 4];    // M   (zeros above diag)
    __shared__ float vL[CC][DVc + 5];   // v -> RHS -> delta (stride 133)
    __shared__ float cL[CC], gamL[CC], egL[CC], betaL[CC];

    float S[16];
#pragma unroll
    for (int j = 0; j < 16; j++) S[j] = 0.f;

    const size_t qk0 = (size_t)b * Tc * KDIMc + h * DKc;
    const size_t v0 = (size_t)b * Tc * VDIMc + h * DVc;
    const size_t gb0 = (size_t)b * Tc * Hc + h;

#pragma unroll 1
    for (int ch = 0; ch < NCH; ch++) {
        const int t0 = ch * CC;
        __syncthreads();  // previous chunk done reading LDS

        // ---- P0: stage k,q (64x64) + transposes, v (64x128)
#pragma unroll
        for (int i = 0; i < 2; i++) {
            int e = tid + i * 512;
            int r = e >> 4, c4 = (e & 15) << 2;
            float4 kv = *(const float4*)&kc[qk0 + (size_t)(t0 + r) * KDIMc + c4];
            float4 qv = *(const float4*)&qc[qk0 + (size_t)(t0 + r) * KDIMc + c4];
            *(float4*)&kL[r][c4] = kv;
            *(float4*)&qL[r][c4] = qv;
            kT[c4 + 0][r] = kv.x; kT[c4 + 1][r] = kv.y;
            kT[c4 + 2][r] = kv.z; kT[c4 + 3][r] = kv.w;
            qT[c4 + 0][r] = qv.x; qT[c4 + 1][r] = qv.y;
            qT[c4 + 2][r] = qv.z; qT[c4 + 3][r] = qv.w;
        }
#pragma unroll
        for (int i = 0; i < 4; i++) {
            int e = tid + i * 512;
            int r = e >> 5, c4 = (e & 31) << 2;
            float4 vv = *(const float4*)&vc[v0 + (size_t)(t0 + r) * VDIMc + c4];
            vL[r][c4 + 0] = vv.x; vL[r][c4 + 1] = vv.y;
            vL[r][c4 + 2] = vv.z; vL[r][c4 + 3] = vv.w;
        }
        // ---- P1: wave 0: cumsum(g), decay factors, beta
        if (tid < 64) {
            float gv = g[gb0 + (size_t)(t0 + tid) * Hc];
            float cv = gv;
#pragma unroll
            for (int d = 1; d < 64; d <<= 1) {
                float nb = __shfl_up(cv, d, 64);
                if (tid >= d) cv += nb;
            }
            cL[tid] = cv;
            gamL[tid] = expf(cv);
            float cend = __shfl(cv, 63, 64);
            egL[tid] = expf(cend - cv);
            betaL[tid] = beta[gb0 + (size_t)(t0 + tid) * Hc];
        }
        __syncthreads();

        // ---- P2a: A (threads 0..255) and M (threads 256..511), 4x4 tiles
        {
            const int half = tid >> 8;
            const int tt2 = tid & 255;
            const int tIdx = tt2 >> 4, sIdx = tt2 & 15;
            float dot[4][4];
#pragma unroll
            for (int i = 0; i < 4; i++)
#pragma unroll
                for (int j = 0; j < 4; j++) dot[i][j] = 0.f;
            const float(*TA)[CC + 4] = half ? qT : kT;
#pragma unroll 8
            for (int d = 0; d < 64; d++) {
                float4 ta = *(const float4*)&TA[d][tIdx * 4];
                float4 sa = *(const float4*)&kT[d][sIdx * 4];
                dot[0][0] += ta.x * sa.x; dot[0][1] += ta.x * sa.y;
                dot[0][2] += ta.x * sa.z; dot[0][3] += ta.x * sa.w;
                dot[1][0] += ta.y * sa.x; dot[1][1] += ta.y * sa.y;
                dot[1][2] += ta.y * sa.z; dot[1][3] += ta.y * sa.w;
                dot[2][0] += ta.z * sa.x; dot[2][1] += ta.z * sa.y;
                dot[2][2] += ta.z * sa.z; dot[2][3] += ta.z * sa.w;
                dot[3][0] += ta.w * sa.x; dot[3][1] += ta.w * sa.y;
                dot[3][2] += ta.w * sa.z; dot[3][3] += ta.w * sa.w;
            }
#pragma unroll
            for (int it = 0; it < 4; it++)
#pragma unroll
                for (int is = 0; is < 4; is++) {
                    int t = tIdx * 4 + it, s = sIdx * 4 + is;
                    if (half == 0) {
                        float v = (s < t) ? betaL[t] * expf(cL[t] - cL[s]) *
                                                dot[it][is]
                                          : 0.f;
                        AtL[s][t] = v;
                    } else {
                        float v = (s <= t) ? 0.125f * expf(cL[t] - cL[s]) *
                                                 dot[it][is]
                                           : 0.f;
                        ML[t][s] = v;
                    }
                }
        }
        // ---- P2b: RHS = beta*(v - Gamma*(k.S_in))  (in place over vL)
#pragma unroll 2
        for (int t = 0; t < 64; t++) {
            float p = 0.f;
#pragma unroll
            for (int j4 = 0; j4 < 4; j4++) {
                float4 kk = *(const float4*)&kL[t][qd * 16 + j4 * 4];
                p += kk.x * S[j4 * 4 + 0] + kk.y * S[j4 * 4 + 1] +
                     kk.z * S[j4 * 4 + 2] + kk.w * S[j4 * 4 + 3];
            }
            p += __shfl_xor(p, 1, 64);
            p += __shfl_xor(p, 2, 64);
            if (qd == 0) vL[t][dv] = betaL[t] * (vL[t][dv] - gamL[t] * p);
        }
        __syncthreads();

        // ---- P3: lane-parallel forward substitution, spill-free.
        // Wave w owns 16 delta-columns d = w*16+di; lane t holds row t.
        {
            const int w = tid >> 6, lane = tid & 63;
            const int d0 = w * 16;
            float acc[16];
#pragma unroll
            for (int di = 0; di < 16; di++) acc[di] = vL[lane][d0 + di];
#pragma unroll 4
            for (int s = 0; s < 64; s++) {
                float a = AtL[s][lane];
#pragma unroll
                for (int di = 0; di < 16; di++) {
                    float ds = __shfl(acc[di], s, 64);
                    acc[di] -= a * ds;
                }
            }
#pragma unroll
            for (int di = 0; di < 16; di++) vL[lane][d0 + di] = acc[di];
        }
        __syncthreads();

        // ---- P6: O = scale*Gamma*(q.S_in) + M delta
        const float gend = gamL[63];
#pragma unroll 2
        for (int t = 0; t < 64; t++) {
            float p1 = 0.f, p2 = 0.f;
#pragma unroll
            for (int j4 = 0; j4 < 4; j4++) {
                float4 qq = *(const float4*)&qL[t][qd * 16 + j4 * 4];
                p1 += qq.x * S[j4 * 4 + 0] + qq.y * S[j4 * 4 + 1] +
                      qq.z * S[j4 * 4 + 2] + qq.w * S[j4 * 4 + 3];
                float4 mm = *(const float4*)&ML[t][qd * 16 + j4 * 4];
                int s0 = qd * 16 + j4 * 4;
                p2 += mm.x * vL[s0 + 0][dv] + mm.y * vL[s0 + 1][dv] +
                      mm.z * vL[s0 + 2][dv] + mm.w * vL[s0 + 3][dv];
            }
            float p = 0.125f * gamL[t] * p1 + p2;
            p += __shfl_xor(p, 1, 64);
            p += __shfl_xor(p, 2, 64);
            if (qd == 0)
                o[((size_t)b * Tc + t0 + t) * VDIMc + h * DVc + dv] = p;
        }
        // ---- P7: S = exp(c_end) S + sum_s exp(c_end-c_s) k_s delta_s
#pragma unroll
        for (int j = 0; j < 16; j++) S[j] *= gend;
#pragma unroll 2
        for (int s = 0; s < 64; s++) {
            float d0 = egL[s] * vL[s][dv];
#pragma unroll
            for (int j4 = 0; j4 < 4; j4++) {
                float4 kk = *(const float4*)&kL[s][qd * 16 + j4 * 4];
                S[j4 * 4 + 0] += kk.x * d0;
                S[j4 * 4 + 1] += kk.y * d0;
                S[j4 * 4 + 2] += kk.z * d0;
                S[j4 * 4 + 3] += kk.w * d0;
            }
        }
    }
}

// ---------------------------------------------------------------------------
// Gated RMSNorm: one wave per (b,t,h) row of 128; in-place on o.
// ---------------------------------------------------------------------------
__global__ void __launch_bounds__(256) rms_gate(
    float* __restrict__ o, const float* __restrict__ gg,
    const float* __restrict__ norm_w) {
    const int row = blockIdx.x * 4 + (threadIdx.x >> 6);
    const int lane = threadIdx.x & 63;
    const size_t base = (size_t)row * DVc;
    float2 ov = *(const float2*)&o[base + lane * 2];
    float ss = ov.x * ov.x + ov.y * ov.y;
#pragma unroll
    for (int m = 1; m < 64; m <<= 1) ss += __shfl_xor(ss, m, 64);
    const float f = rsqrtf(ss * (1.f / 128.f) + 1e-5f);
    float2 gv = *(const float2*)&gg[base + lane * 2];
    const float nw0 = norm_w[lane * 2], nw1 = norm_w[lane * 2 + 1];
    float y0 = ov.x * f * nw0 * siluf(gv.x);
    float y1 = ov.y * f * nw1 * siluf(gv.y);
    *(float2*)&o[base + lane * 2] = make_float2(y0, y1);
}

// ---------------------------------------------------------------------------
// Workspace: qb 8.4M + kb 8.4M + vb 16.8M + obuf 16.8M + gbuf/bbuf 0.26M
//            + halo 0.79M  = 51.4M floats = 205.5 MB
// ---------------------------------------------------------------------------
extern "C" void kernel_launch(void* const* d_in, const int* in_sizes, int n_in,
                              void* d_out, int out_size, void* d_ws,
                              size_t ws_size, hipStream_t stream) {
    const float* x = (const float*)d_in[0];
    const float* w_q = (const float*)d_in[1];
    const float* w_k = (const float*)d_in[2];
    const float* w_v = (const float*)d_in[3];
    const float* w_a = (const float*)d_in[4];
    const float* w_b = (const float*)d_in[5];
    const float* w_g = (const float*)d_in[6];
    const float* w_out = (const float*)d_in[7];
    const float* A_log = (const float*)d_in[8];
    const float* dt_bias = (const float*)d_in[9];
    const float* conv_q = (const float*)d_in[10];
    const float* conv_k = (const float*)d_in[11];
    const float* conv_v = (const float*)d_in[12];
    const float* norm_w = (const float*)d_in[13];

    float* ws = (float*)d_ws;
    const size_t M = Mrows;
    float* qb = ws;
    float* kb = qb + M * KDIMc;
    float* vb = kb + M * KDIMc;
    float* obuf = vb + M * VDIMc;
    float* gbuf = obuf + M * VDIMc;
    float* bbuf = gbuf + M * Hc;
    float* halo = bbuf + M * Hc;
    float* gg = qb;  // aliased AFTER the scan (qb+kb contiguous)

    // 1) q/k/v projections
    gemm_f32<<<dim3((M / GBM) * (KDIMc / GBN)), 256, 0, stream>>>(
        x, w_q, qb, M, KDIMc, Dc);
    gemm_f32<<<dim3((M / GBM) * (KDIMc / GBN)), 256, 0, stream>>>(
        x, w_k, kb, M, KDIMc, Dc);
    gemm_f32<<<dim3((M / GBM) * (VDIMc / GBN)), 256, 0, stream>>>(
        x, w_v, vb, M, VDIMc, Dc);

    // 2) a/b projections fused with activation -> g, beta
    ab_proj<<<dim3(M / 4), 256, 0, stream>>>(x, w_a, w_b, A_log, dt_bias, gbuf,
                                             bbuf);

    // 3) conv + silu (+ l2norm for q,k), in place with halo save
    {
        const int nqk = Bc * (Tc / 64 - 1) * 3 * KDIMc;
        const int nv = Bc * (Tc / 64 - 1) * 3 * VDIMc;
        save_halo<KDIMc><<<dim3((nqk + 255) / 256), 256, 0, stream>>>(qb, halo);
        conv_silu_inplace<KDIMc, true>
            <<<dim3(Bc * (Tc / 64) * (KDIMc / 256)), 256, 0, stream>>>(
                qb, conv_q, halo);
        save_halo<KDIMc><<<dim3((nqk + 255) / 256), 256, 0, stream>>>(kb, halo);
        conv_silu_inplace<KDIMc, true>
            <<<dim3(Bc * (Tc / 64) * (KDIMc / 256)), 256, 0, stream>>>(
                kb, conv_k, halo);
        save_halo<VDIMc><<<dim3((nv + 255) / 256), 256, 0, stream>>>(vb, halo);
        conv_silu_inplace<VDIMc, false>
            <<<dim3(Bc * (Tc / 64) * (VDIMc / 256)), 256, 0, stream>>>(
                vb, conv_v, halo);
    }

    // 4) chunked gated delta-rule (WY form)
    chunk_scan<<<dim3(Bc * Hc), 512, 0, stream>>>(qb, kb, vb, gbuf, bbuf,
                                                  obuf);

    // 5) gate projection (after scan so it can alias qb+kb)
    gemm_f32<<<dim3((M / GBM) * (VDIMc / GBN)), 256, 0, stream>>>(
        x, w_g, gg, M, VDIMc, Dc);

    // 6) gated RMSNorm (in place on obuf)
    rms_gate<<<dim3(M * Hc / 4), 256, 0, stream>>>(obuf, gg, norm_w);

    // 7) output projection -> d_out
    gemm_f32<<<dim3((M / GBM) * (Dc / GBN)), 256, 0, stream>>>(
        obuf, w_out, (float*)d_out, M, Dc, VDIMc);
}

// Round 6
// 2856.715 us; speedup vs baseline: 7.7873x; 2.2020x over previous
//
#include <hip/hip_runtime.h>
#include <hip/hip_bf16.h>
#include <math.h>

// Problem constants
#define Bc 2
#define Tc 4096
#define Dc 1024
#define Hc 16
#define DKc 64
#define DVc 128
#define KDIMc 1024   // H*DK
#define VDIMc 2048   // H*DV
#define Mrows (Bc*Tc) // 8192
#define CC 64        // scan chunk size
#define NCH (Tc/CC)  // 64 chunks

__device__ __forceinline__ float siluf(float x) {
    return x / (1.f + expf(-x));
}
__device__ __forceinline__ float dot4(float4 a, float4 b) {
    return a.x * b.x + a.y * b.y + a.z * b.z + a.w * b.w;
}

// ---------------------------------------------------------------------------
// Generic tiled f32 GEMM: C[M,N] = A[M,K] @ B[K,N], all row-major.
// ---------------------------------------------------------------------------
#define GBM 64
#define GBN 64
#define GBK 16
__global__ void __launch_bounds__(256) gemm_f32(
    const float* __restrict__ A, const float* __restrict__ B,
    float* __restrict__ C, int M, int N, int K) {
    __shared__ float As[GBK][GBM + 4];
    __shared__ float Bs[GBK][GBN];
    const int tid = threadIdx.x;
    const int nbx = N / GBN;
    const int bx = blockIdx.x % nbx;
    const int by = blockIdx.x / nbx;
    const int row0 = by * GBM, col0 = bx * GBN;
    const int ty = tid >> 4, tx = tid & 15;
    const int ar = tid >> 2, ak = (tid & 3) * 4;
    const int bc = tid & 63, bk0 = (tid >> 6) * 4;

    float acc[4][4];
#pragma unroll
    for (int i = 0; i < 4; i++)
#pragma unroll
        for (int j = 0; j < 4; j++) acc[i][j] = 0.f;

    for (int k0 = 0; k0 < K; k0 += GBK) {
        float4 av = *(const float4*)&A[(size_t)(row0 + ar) * K + k0 + ak];
        As[ak + 0][ar] = av.x;
        As[ak + 1][ar] = av.y;
        As[ak + 2][ar] = av.z;
        As[ak + 3][ar] = av.w;
#pragma unroll
        for (int i = 0; i < 4; i++)
            Bs[bk0 + i][bc] = B[(size_t)(k0 + bk0 + i) * N + col0 + bc];
        __syncthreads();
#pragma unroll
        for (int kk = 0; kk < GBK; kk++) {
            float a[4], b[4];
            *(float4*)a = *(const float4*)&As[kk][ty * 4];
            *(float4*)b = *(const float4*)&Bs[kk][tx * 4];
#pragma unroll
            for (int i = 0; i < 4; i++)
#pragma unroll
                for (int j = 0; j < 4; j++) acc[i][j] += a[i] * b[j];
        }
        __syncthreads();
    }
#pragma unroll
    for (int i = 0; i < 4; i++) {
        float4 v = make_float4(acc[i][0], acc[i][1], acc[i][2], acc[i][3]);
        *(float4*)&C[(size_t)(row0 + ty * 4 + i) * N + col0 + tx * 4] = v;
    }
}

// ---------------------------------------------------------------------------
// a/b projections (N=16 each) fused with softplus/sigmoid -> g, beta.
// ---------------------------------------------------------------------------
__global__ void __launch_bounds__(256) ab_proj(
    const float* __restrict__ x, const float* __restrict__ w_a,
    const float* __restrict__ w_b, const float* __restrict__ A_log,
    const float* __restrict__ dt_bias, float* __restrict__ g_out,
    float* __restrict__ beta_out) {
    const int row = blockIdx.x * 4 + (threadIdx.x >> 6);
    const int lane = threadIdx.x & 63;
    const int h = lane >> 2;
    const int kg = lane & 3;
    const float* xr = x + (size_t)row * Dc;
    float pa = 0.f, pb = 0.f;
    const int kbeg = kg * 256, kend = kbeg + 256;
    for (int k = kbeg; k < kend; k++) {
        float xv = xr[k];
        pa += xv * w_a[k * Hc + h];
        pb += xv * w_b[k * Hc + h];
    }
    pa += __shfl_xor(pa, 1, 64);
    pa += __shfl_xor(pa, 2, 64);
    pb += __shfl_xor(pb, 1, 64);
    pb += __shfl_xor(pb, 2, 64);
    if (kg == 0) {
        float arg = pa + dt_bias[h];
        float sp = fmaxf(arg, 0.f) + log1pf(expf(-fabsf(arg)));
        g_out[(size_t)row * Hc + h] = -expf(A_log[h]) * sp;
        beta_out[(size_t)row * Hc + h] = 2.f / (1.f + expf(-pb));
    }
}

// ---------------------------------------------------------------------------
// Save 3-row halos at 64-step chunk boundaries (for in-place conv).
// ---------------------------------------------------------------------------
template <int C>
__global__ void __launch_bounds__(256) save_halo(
    const float* __restrict__ in, float* __restrict__ halo) {
    const int g = blockIdx.x * 256 + threadIdx.x;
    const int total = Bc * (Tc / 64 - 1) * 3 * C;
    if (g >= total) return;
    const int c = g % C;
    int r = g / C;
    const int j = r % 3;
    r /= 3;
    const int chunk = r % (Tc / 64 - 1) + 1;
    const int b = r / (Tc / 64 - 1);
    halo[((size_t)(b * 64 + chunk) * 3 + j) * C + c] =
        in[((size_t)b * Tc + chunk * 64 - 3 + j) * C + c];
}

// ---------------------------------------------------------------------------
// Depthwise causal conv1d (K=4) + SiLU (+ optional l2norm), IN PLACE.
// ---------------------------------------------------------------------------
template <int C, bool L2N>
__global__ void __launch_bounds__(256) conv_silu_inplace(
    float* __restrict__ buf, const float* __restrict__ w,
    const float* __restrict__ halo) {
    constexpr int CB = C / 256;
    const int bidx = blockIdx.x;
    const int cb = bidx % CB;
    const int tchunk = (bidx / CB) % (Tc / 64);
    const int b = bidx / (CB * (Tc / 64));
    const int c = cb * 256 + threadIdx.x;
    const int t0 = tchunk * 64;
    const float w0 = w[c * 4 + 0], w1 = w[c * 4 + 1], w2 = w[c * 4 + 2],
                w3 = w[c * 4 + 3];
    float xm3 = 0.f, xm2 = 0.f, xm1 = 0.f;
    if (tchunk > 0) {
        const float* hp = halo + (size_t)(b * 64 + tchunk) * 3 * C + c;
        xm3 = hp[0];
        xm2 = hp[C];
        xm1 = hp[2 * C];
    }
    float* p = buf + (size_t)b * Tc * C + c;
#pragma unroll 4
    for (int i = 0; i < 64; i++) {
        float xt = p[(size_t)(t0 + i) * C];
        float y = w0 * xm3 + w1 * xm2 + w2 * xm1 + w3 * xt;
        y = siluf(y);
        if (L2N) {
            float ss = y * y;
#pragma unroll
            for (int m = 1; m < 64; m <<= 1) ss += __shfl_xor(ss, m, 64);
            y *= rsqrtf(ss + 1e-6f);
        }
        p[(size_t)(t0 + i) * C] = y;
        xm3 = xm2;
        xm2 = xm1;
        xm1 = xt;
    }
}

// ---------------------------------------------------------------------------
// TM precompute: per (b,h,chunk) tile, compute
//   A[t][s] = beta_t exp(c_t-c_s)(k_t.k_s), s<t   (LDS only)
//   M[t][s] = 0.125 exp(c_t-c_s)(q_t.k_s), s<=t   -> tmM (row-major [t][s])
//   T = (I+A)^{-1} (unit lower triangular)        -> tmT (stored [col][row])
// Fully parallel: grid = B*H*NCH = 2048 WGs, 256 threads.
// ---------------------------------------------------------------------------
__global__ void __launch_bounds__(256) tm_precompute(
    const float* __restrict__ kc, const float* __restrict__ qc,
    const float* __restrict__ g, const float* __restrict__ beta,
    float* __restrict__ tmT, float* __restrict__ tmM) {
    const int bid = blockIdx.x;
    const int ch = bid & (NCH - 1);
    const int bh = bid >> 6;
    const int b = bh >> 4, h = bh & 15;
    const int tid = threadIdx.x;
    const int t0 = ch * CC;

    __shared__ __align__(16) float kL[CC][DKc + 4];
    __shared__ __align__(16) float qL[CC][DKc + 4];
    __shared__ __align__(16) float AtL[CC][DKc + 4];  // A^T: AtL[s][t]
    __shared__ float cL[CC], betaL[CC];

    const size_t qk0 = (size_t)b * Tc * KDIMc + h * DKc;
    const size_t gb0 = (size_t)b * Tc * Hc + h;
    const size_t tile = (size_t)(bh * NCH + ch) * 4096;

    // stage k, q
#pragma unroll
    for (int i = 0; i < 4; i++) {
        int e = tid + i * 256;
        int r = e >> 4, c4 = (e & 15) << 2;
        *(float4*)&kL[r][c4] =
            *(const float4*)&kc[qk0 + (size_t)(t0 + r) * KDIMc + c4];
        *(float4*)&qL[r][c4] =
            *(const float4*)&qc[qk0 + (size_t)(t0 + r) * KDIMc + c4];
    }
    // cumsum + beta (wave 0)
    if (tid < 64) {
        float gv = g[gb0 + (size_t)(t0 + tid) * Hc];
        float cv = gv;
#pragma unroll
        for (int d = 1; d < 64; d <<= 1) {
            float nb = __shfl_up(cv, d, 64);
            if (tid >= d) cv += nb;
        }
        cL[tid] = cv;
        betaL[tid] = beta[gb0 + (size_t)(t0 + tid) * Hc];
    }
    __syncthreads();

    // A and M, 4x4 tiles per thread
    {
        const int tIdx = tid >> 4, sIdx = tid & 15;
        float dka[4][4], dqa[4][4];
#pragma unroll
        for (int i = 0; i < 4; i++)
#pragma unroll
            for (int j = 0; j < 4; j++) { dka[i][j] = 0.f; dqa[i][j] = 0.f; }
#pragma unroll 4
        for (int d = 0; d < 64; d += 4) {
            float4 kb[4], qb_[4], sb[4];
#pragma unroll
            for (int i = 0; i < 4; i++) {
                kb[i] = *(const float4*)&kL[tIdx * 4 + i][d];
                qb_[i] = *(const float4*)&qL[tIdx * 4 + i][d];
                sb[i] = *(const float4*)&kL[sIdx * 4 + i][d];
            }
#pragma unroll
            for (int i = 0; i < 4; i++)
#pragma unroll
                for (int j = 0; j < 4; j++) {
                    dka[i][j] += dot4(kb[i], sb[j]);
                    dqa[i][j] += dot4(qb_[i], sb[j]);
                }
        }
#pragma unroll
        for (int i = 0; i < 4; i++) {
            float mrow[4];
#pragma unroll
            for (int j = 0; j < 4; j++) {
                int t = tIdx * 4 + i, s = sIdx * 4 + j;
                float E = expf(cL[t] - cL[s]);
                AtL[s][t] = (s < t) ? betaL[t] * E * dka[i][j] : 0.f;
                mrow[j] = (s <= t) ? 0.125f * E * dqa[i][j] : 0.f;
            }
            *(float4*)&tmM[tile + (size_t)(tIdx * 4 + i) * 64 + sIdx * 4] =
                make_float4(mrow[0], mrow[1], mrow[2], mrow[3]);
        }
    }
    __syncthreads();

    // T = (I+A)^{-1}: lane-parallel substitution, RHS = identity.
    // Wave w owns cols w*16+di; lane = row.
    {
        const int w = tid >> 6, lane = tid & 63;
        float acc[16];
#pragma unroll
        for (int di = 0; di < 16; di++)
            acc[di] = (lane == w * 16 + di) ? 1.f : 0.f;
#pragma unroll 4
        for (int s = 0; s < 64; s++) {
            float a = AtL[s][lane];
#pragma unroll
            for (int di = 0; di < 16; di++) {
                float ds = __shfl(acc[di], s, 64);
                acc[di] -= a * ds;
            }
        }
        // store T as [col][row] so lane-writes coalesce
#pragma unroll
        for (int di = 0; di < 16; di++)
            tmT[tile + (size_t)(w * 16 + di) * 64 + lane] = acc[di];
    }
}

// ---------------------------------------------------------------------------
// Sequential chunk scan, DV-split 8 ways: grid = B*H*8 = 256 WGs, 256 thr.
// WG (b,h,sl) owns S[64][16] slice (in LDS, stored transposed [dv][dk]).
// Per chunk: RHS = beta*(v - Gamma*(K.S)); delta = T*RHS (dense matmul);
//            O = 0.125*Gamma*(Q.S) + M*delta;  S = gend*S + K^T(eg*delta).
// O is written IN PLACE over v (same rows/cols, after v consumed).
// ---------------------------------------------------------------------------
__global__ void __launch_bounds__(256) delta_scan(
    const float* __restrict__ kc, const float* __restrict__ qc,
    float* vo,  // v input and O output (aliased)
    const float* __restrict__ g, const float* __restrict__ beta,
    const float* __restrict__ tmT, const float* __restrict__ tmM) {
    const int bid = blockIdx.x;
    const int sl = bid & 7;
    const int bh = bid >> 3;
    const int b = bh >> 4, h = bh & 15;
    const int tid = threadIdx.x;

    __shared__ __align__(16) float kL[CC][DKc + 4];
    __shared__ __align__(16) float kT[DKc][CC + 4];
    __shared__ __align__(16) float qL[CC][DKc + 4];
    __shared__ __align__(16) float TL[CC][CC + 4];
    __shared__ __align__(16) float ML[CC][CC + 4];
    __shared__ __align__(16) float ST[16][DKc + 4];  // S^T: [dv][dk]
    __shared__ __align__(16) float DT[16][CC + 4];   // RHS/delta^T: [dv][s]
    __shared__ __align__(16) float VL[CC][20];
    __shared__ __align__(16) float OL[CC][20];
    __shared__ __align__(16) float gamL[CC], egL[CC], betaL[CC];

    const size_t qk0 = (size_t)b * Tc * KDIMc + h * DKc;
    const size_t v0 = (size_t)b * Tc * VDIMc + h * DVc + sl * 16;
    const size_t gb0 = (size_t)b * Tc * Hc + h;
    const size_t tb0 = (size_t)(bh * NCH) * 4096;

    for (int i = tid; i < 16 * (DKc + 4); i += 256) ((float*)ST)[i] = 0.f;

    const int dv0 = tid >> 5, tt = tid & 31;        // P1-P3 blocking
    const int dvv = tid >> 4, dk4 = (tid & 15) << 2;  // P4 blocking

#pragma unroll 1
    for (int ch = 0; ch < NCH; ch++) {
        const int t0 = ch * CC;
        const size_t tile = tb0 + (size_t)ch * 4096;
        __syncthreads();  // prev chunk done with staging buffers / DT / ST

        // ---- P0: stage k (+transpose), q, T (transpose), M, v-slice
#pragma unroll
        for (int i = 0; i < 4; i++) {
            int e = tid + i * 256;
            int r = e >> 4, c4 = (e & 15) << 2;
            float4 kv = *(const float4*)&kc[qk0 + (size_t)(t0 + r) * KDIMc + c4];
            *(float4*)&kL[r][c4] = kv;
            kT[c4 + 0][r] = kv.x; kT[c4 + 1][r] = kv.y;
            kT[c4 + 2][r] = kv.z; kT[c4 + 3][r] = kv.w;
            *(float4*)&qL[r][c4] =
                *(const float4*)&qc[qk0 + (size_t)(t0 + r) * KDIMc + c4];
            // T stored [col][row]: scatter to TL[row][col]
            float4 tv = *(const float4*)&tmT[tile + (size_t)e * 4];
            int c = e >> 4, t4 = (e & 15) << 2;
            TL[t4 + 0][c] = tv.x; TL[t4 + 1][c] = tv.y;
            TL[t4 + 2][c] = tv.z; TL[t4 + 3][c] = tv.w;
            float4 mv = *(const float4*)&tmM[tile + (size_t)e * 4];
            *(float4*)&ML[r][c4] = mv;
        }
        {
            int r = tid >> 2, j4 = (tid & 3) << 2;
            *(float4*)&VL[r][j4] =
                *(const float4*)&vo[v0 + (size_t)(t0 + r) * VDIMc + j4];
        }
        if (tid < 64) {
            float gv = g[gb0 + (size_t)(t0 + tid) * Hc];
            float cv = gv;
#pragma unroll
            for (int d = 1; d < 64; d <<= 1) {
                float nb = __shfl_up(cv, d, 64);
                if (tid >= d) cv += nb;
            }
            gamL[tid] = expf(cv);
            float cend = __shfl(cv, 63, 64);
            egL[tid] = expf(cend - cv);
            betaL[tid] = beta[gb0 + (size_t)(t0 + tid) * Hc];
        }
        __syncthreads();

        // ---- P1: RHS[t][dv] = beta_t*(v - gam_t*(k_t . S[:,dv]))
        {
            float a00 = 0.f, a01 = 0.f, a10 = 0.f, a11 = 0.f;
#pragma unroll 4
            for (int dk = 0; dk < 64; dk += 4) {
                float4 k1 = *(const float4*)&kL[tt][dk];
                float4 k2 = *(const float4*)&kL[tt + 32][dk];
                float4 s1 = *(const float4*)&ST[dv0][dk];
                float4 s2 = *(const float4*)&ST[dv0 + 8][dk];
                a00 += dot4(k1, s1); a01 += dot4(k1, s2);
                a10 += dot4(k2, s1); a11 += dot4(k2, s2);
            }
            float b1 = betaL[tt], b2 = betaL[tt + 32];
            float g1 = gamL[tt], g2 = gamL[tt + 32];
            DT[dv0][tt] = b1 * (VL[tt][dv0] - g1 * a00);
            DT[dv0 + 8][tt] = b1 * (VL[tt][dv0 + 8] - g1 * a01);
            DT[dv0][tt + 32] = b2 * (VL[tt + 32][dv0] - g2 * a10);
            DT[dv0 + 8][tt + 32] = b2 * (VL[tt + 32][dv0 + 8] - g2 * a11);
        }
        __syncthreads();

        // ---- P2: delta = T * RHS (registers), then overwrite DT
        float d00 = 0.f, d01 = 0.f, d10 = 0.f, d11 = 0.f;
#pragma unroll 4
        for (int s = 0; s < 64; s += 4) {
            float4 t1 = *(const float4*)&TL[tt][s];
            float4 t2 = *(const float4*)&TL[tt + 32][s];
            float4 r1 = *(const float4*)&DT[dv0][s];
            float4 r2 = *(const float4*)&DT[dv0 + 8][s];
            d00 += dot4(t1, r1); d01 += dot4(t1, r2);
            d10 += dot4(t2, r1); d11 += dot4(t2, r2);
        }
        __syncthreads();
        DT[dv0][tt] = d00;
        DT[dv0 + 8][tt] = d01;
        DT[dv0][tt + 32] = d10;
        DT[dv0 + 8][tt + 32] = d11;
        __syncthreads();

        // ---- P3: O = 0.125*gam_t*(q_t.S) + sum_s M[t][s] delta[s]
        {
            float p00 = 0.f, p01 = 0.f, p10 = 0.f, p11 = 0.f;
            float m00 = 0.f, m01 = 0.f, m10 = 0.f, m11 = 0.f;
#pragma unroll 4
            for (int dk = 0; dk < 64; dk += 4) {
                float4 q1 = *(const float4*)&qL[tt][dk];
                float4 q2 = *(const float4*)&qL[tt + 32][dk];
                float4 s1 = *(const float4*)&ST[dv0][dk];
                float4 s2 = *(const float4*)&ST[dv0 + 8][dk];
                p00 += dot4(q1, s1); p01 += dot4(q1, s2);
                p10 += dot4(q2, s1); p11 += dot4(q2, s2);
            }
#pragma unroll 4
            for (int s = 0; s < 64; s += 4) {
                float4 m1 = *(const float4*)&ML[tt][s];
                float4 m2 = *(const float4*)&ML[tt + 32][s];
                float4 e1 = *(const float4*)&DT[dv0][s];
                float4 e2 = *(const float4*)&DT[dv0 + 8][s];
                m00 += dot4(m1, e1); m01 += dot4(m1, e2);
                m10 += dot4(m2, e1); m11 += dot4(m2, e2);
            }
            float f1 = 0.125f * gamL[tt], f2 = 0.125f * gamL[tt + 32];
            OL[tt][dv0] = f1 * p00 + m00;
            OL[tt][dv0 + 8] = f1 * p01 + m01;
            OL[tt + 32][dv0] = f2 * p10 + m10;
            OL[tt + 32][dv0 + 8] = f2 * p11 + m11;
        }
        __syncthreads();  // OL complete; ST reads done -> safe to update

        // O write (in place over v)
        {
            int r = tid >> 2, j4 = (tid & 3) << 2;
            *(float4*)&vo[v0 + (size_t)(t0 + r) * VDIMc + j4] =
                *(const float4*)&OL[r][j4];
        }
        // ---- P4: S = gend*S + sum_s eg[s]*k_s[dk]*delta[s][dv]
        {
            const float ge = gamL[63];
            float sacc[4];
            float4 sv = *(const float4*)&ST[dvv][dk4];
            sacc[0] = ge * sv.x; sacc[1] = ge * sv.y;
            sacc[2] = ge * sv.z; sacc[3] = ge * sv.w;
#pragma unroll 4
            for (int s = 0; s < 64; s += 4) {
                float4 dd = *(const float4*)&DT[dvv][s];
                float4 ee = *(const float4*)&egL[s];
                float e0 = ee.x * dd.x, e1 = ee.y * dd.y;
                float e2 = ee.z * dd.z, e3 = ee.w * dd.w;
#pragma unroll
                for (int n = 0; n < 4; n++) {
                    float4 kv = *(const float4*)&kT[dk4 + n][s];
                    sacc[n] += kv.x * e0 + kv.y * e1 + kv.z * e2 + kv.w * e3;
                }
            }
            *(float4*)&ST[dvv][dk4] =
                make_float4(sacc[0], sacc[1], sacc[2], sacc[3]);
        }
    }
}

// ---------------------------------------------------------------------------
// Gated RMSNorm: one wave per (b,t,h) row of 128; in-place on o.
// ---------------------------------------------------------------------------
__global__ void __launch_bounds__(256) rms_gate(
    float* __restrict__ o, const float* __restrict__ gg,
    const float* __restrict__ norm_w) {
    const int row = blockIdx.x * 4 + (threadIdx.x >> 6);
    const int lane = threadIdx.x & 63;
    const size_t base = (size_t)row * DVc;
    float2 ov = *(const float2*)&o[base + lane * 2];
    float ss = ov.x * ov.x + ov.y * ov.y;
#pragma unroll
    for (int m = 1; m < 64; m <<= 1) ss += __shfl_xor(ss, m, 64);
    const float f = rsqrtf(ss * (1.f / 128.f) + 1e-5f);
    float2 gv = *(const float2*)&gg[base + lane * 2];
    const float nw0 = norm_w[lane * 2], nw1 = norm_w[lane * 2 + 1];
    float y0 = ov.x * f * nw0 * siluf(gv.x);
    float y1 = ov.y * f * nw1 * siluf(gv.y);
    *(float2*)&o[base + lane * 2] = make_float2(y0, y1);
}

// ---------------------------------------------------------------------------
// Workspace (floats): qb 8.4M + kb 8.4M + vb 16.8M + tm 16.8M (T then M)
//   + gbuf 0.131M + bbuf 0.131M + halo 0.786M = 51.4M = 205.5 MB (proven fit).
// O overwrites vb in delta_scan; gg aliases qb+kb after the scan.
// ---------------------------------------------------------------------------
extern "C" void kernel_launch(void* const* d_in, const int* in_sizes, int n_in,
                              void* d_out, int out_size, void* d_ws,
                              size_t ws_size, hipStream_t stream) {
    const float* x = (const float*)d_in[0];
    const float* w_q = (const float*)d_in[1];
    const float* w_k = (const float*)d_in[2];
    const float* w_v = (const float*)d_in[3];
    const float* w_a = (const float*)d_in[4];
    const float* w_b = (const float*)d_in[5];
    const float* w_g = (const float*)d_in[6];
    const float* w_out = (const float*)d_in[7];
    const float* A_log = (const float*)d_in[8];
    const float* dt_bias = (const float*)d_in[9];
    const float* conv_q = (const float*)d_in[10];
    const float* conv_k = (const float*)d_in[11];
    const float* conv_v = (const float*)d_in[12];
    const float* norm_w = (const float*)d_in[13];

    float* ws = (float*)d_ws;
    const size_t M = Mrows;
    float* qb = ws;
    float* kb = qb + M * KDIMc;
    float* vb = kb + M * KDIMc;
    float* tm = vb + M * VDIMc;          // T (8.4M) then M (8.4M)
    float* gbuf = tm + M * VDIMc;
    float* bbuf = gbuf + M * Hc;
    float* halo = bbuf + M * Hc;
    float* tmT = tm;
    float* tmM = tm + (size_t)Bc * Hc * NCH * 4096;
    float* gg = qb;  // aliased AFTER the scan (qb+kb contiguous)

    // 1) q/k/v projections
    gemm_f32<<<dim3((M / GBM) * (KDIMc / GBN)), 256, 0, stream>>>(
        x, w_q, qb, M, KDIMc, Dc);
    gemm_f32<<<dim3((M / GBM) * (KDIMc / GBN)), 256, 0, stream>>>(
        x, w_k, kb, M, KDIMc, Dc);
    gemm_f32<<<dim3((M / GBM) * (VDIMc / GBN)), 256, 0, stream>>>(
        x, w_v, vb, M, VDIMc, Dc);

    // 2) a/b projections fused with activation -> g, beta
    ab_proj<<<dim3(M / 4), 256, 0, stream>>>(x, w_a, w_b, A_log, dt_bias, gbuf,
                                             bbuf);

    // 3) conv + silu (+ l2norm for q,k), in place with halo save
    {
        const int nqk = Bc * (Tc / 64 - 1) * 3 * KDIMc;
        const int nv = Bc * (Tc / 64 - 1) * 3 * VDIMc;
        save_halo<KDIMc><<<dim3((nqk + 255) / 256), 256, 0, stream>>>(qb, halo);
        conv_silu_inplace<KDIMc, true>
            <<<dim3(Bc * (Tc / 64) * (KDIMc / 256)), 256, 0, stream>>>(
                qb, conv_q, halo);
        save_halo<KDIMc><<<dim3((nqk + 255) / 256), 256, 0, stream>>>(kb, halo);
        conv_silu_inplace<KDIMc, true>
            <<<dim3(Bc * (Tc / 64) * (KDIMc / 256)), 256, 0, stream>>>(
                kb, conv_k, halo);
        save_halo<VDIMc><<<dim3((nv + 255) / 256), 256, 0, stream>>>(vb, halo);
        conv_silu_inplace<VDIMc, false>
            <<<dim3(Bc * (Tc / 64) * (VDIMc / 256)), 256, 0, stream>>>(
                vb, conv_v, halo);
    }

    // 4a) parallel precompute of T=(I+A)^{-1} and M per (b,h,chunk)
    tm_precompute<<<dim3(Bc * Hc * NCH), 256, 0, stream>>>(kb, qb, gbuf, bbuf,
                                                           tmT, tmM);
    // 4b) sequential scan, DV-split 8x; O overwrites vb
    delta_scan<<<dim3(Bc * Hc * 8), 256, 0, stream>>>(kb, qb, vb, gbuf, bbuf,
                                                      tmT, tmM);

    // 5) gate projection (after scan so it can alias qb+kb)
    gemm_f32<<<dim3((M / GBM) * (VDIMc / GBN)), 256, 0, stream>>>(
        x, w_g, gg, M, VDIMc, Dc);

    // 6) gated RMSNorm (in place on vb = O)
    rms_gate<<<dim3(M * Hc / 4), 256, 0, stream>>>(vb, gg, norm_w);

    // 7) output projection -> d_out
    gemm_f32<<<dim3((M / GBM) * (Dc / GBN)), 256, 0, stream>>>(
        vb, w_out, (float*)d_out, M, Dc, VDIMc);
}

// Round 7
// 1229.624 us; speedup vs baseline: 18.0917x; 2.3232x over previous
//
#include <hip/hip_runtime.h>
#include <hip/hip_bf16.h>
#include <math.h>

// Problem constants
#define Bc 2
#define Tc 4096
#define Dc 1024
#define Hc 16
#define DKc 64
#define DVc 128
#define KDIMc 1024   // H*DK
#define VDIMc 2048   // H*DV
#define Mrows (Bc*Tc) // 8192
#define CC 64        // scan chunk size
#define NCH (Tc/CC)  // 64 chunks

typedef short short8 __attribute__((ext_vector_type(8)));
typedef float f32x4 __attribute__((ext_vector_type(4)));

__device__ __forceinline__ float siluf(float x) {
    return x / (1.f + expf(-x));
}
__device__ __forceinline__ float dot4(float4 a, float4 b) {
    return a.x * b.x + a.y * b.y + a.z * b.z + a.w * b.w;
}
__device__ __forceinline__ unsigned short f2bf(float f) {
    unsigned int u = __float_as_uint(f);
    unsigned int r = (u + 0x7fffu + ((u >> 16) & 1u)) >> 16;
    return (unsigned short)r;
}

// ---------------------------------------------------------------------------
// x (f32) -> bf16, straight elementwise. 4 elems/thread.
// ---------------------------------------------------------------------------
__global__ void __launch_bounds__(256) convert_bf16(
    const float* __restrict__ in, unsigned short* __restrict__ out, int n4) {
    int g = blockIdx.x * 256 + threadIdx.x;
    if (g >= n4) return;
    float4 v = *(const float4*)&in[(size_t)g * 4];
    unsigned short h[4] = {f2bf(v.x), f2bf(v.y), f2bf(v.z), f2bf(v.w)};
    *(uint2*)&out[(size_t)g * 4] =
        make_uint2((unsigned)h[0] | ((unsigned)h[1] << 16),
                   (unsigned)h[2] | ((unsigned)h[3] << 16));
}

// ---------------------------------------------------------------------------
// Transpose + convert: in f32 [K][N] -> out bf16 [N][K]. 32x32 LDS tiles.
// grid = (N/32) * (K/32)
// ---------------------------------------------------------------------------
__global__ void __launch_bounds__(256) transp_bf16(
    const float* __restrict__ in, unsigned short* __restrict__ out, int K,
    int N) {
    __shared__ float t[32][33];
    const int nbx = N >> 5;
    const int n0 = (blockIdx.x % nbx) << 5;
    const int k0 = (blockIdx.x / nbx) << 5;
    const int c = threadIdx.x & 31, r4 = (threadIdx.x >> 5) << 2;
#pragma unroll
    for (int i = 0; i < 4; i++)
        t[r4 + i][c] = in[(size_t)(k0 + r4 + i) * N + n0 + c];
    __syncthreads();
#pragma unroll
    for (int i = 0; i < 4; i++)
        out[(size_t)(n0 + r4 + i) * K + k0 + c] = f2bf(t[c][r4 + i]);
}

// ---------------------------------------------------------------------------
// bf16 MFMA GEMM: C[M,N] f32 = A[M,K] bf16 (row-major) @ Bt[N,K] bf16.
// 128x128 tile, BK=32, 256 thr = 4 waves, each wave 64x64 via 4x4 frags of
// mfma_f32_16x16x32_bf16. LDS row stride 40 shorts = 80 B -> <=2-way banks.
// ---------------------------------------------------------------------------
__global__ void __launch_bounds__(256) gemm_bf16(
    const unsigned short* __restrict__ A, const unsigned short* __restrict__ Bt,
    float* __restrict__ C, int M, int N, int K) {
    __shared__ short As[128][40];
    __shared__ short Bs[128][40];
    const int tid = threadIdx.x;
    const int nbx = N >> 7;
    const int bx = blockIdx.x % nbx, by = blockIdx.x / nbx;
    const int m0 = by << 7, n0 = bx << 7;
    const int w = tid >> 6, lane = tid & 63;
    const int wr = (w >> 1) << 6, wc = (w & 1) << 6;
    const int fr = lane & 15, fk = (lane >> 4) << 3;
    const int srow = tid >> 1, skb = (tid & 1) << 4;

    f32x4 acc[4][4];
#pragma unroll
    for (int i = 0; i < 4; i++)
#pragma unroll
        for (int j = 0; j < 4; j++)
            acc[i][j] = (f32x4){0.f, 0.f, 0.f, 0.f};

    const int nkt = K >> 5;
    for (int kt = 0; kt < nkt; kt++) {
        __syncthreads();
        {
            const unsigned short* ap = &A[(size_t)(m0 + srow) * K + (kt << 5) + skb];
            const unsigned short* bp = &Bt[(size_t)(n0 + srow) * K + (kt << 5) + skb];
            *(short8*)&As[srow][skb] = *(const short8*)&ap[0];
            *(short8*)&As[srow][skb + 8] = *(const short8*)&ap[8];
            *(short8*)&Bs[srow][skb] = *(const short8*)&bp[0];
            *(short8*)&Bs[srow][skb + 8] = *(const short8*)&bp[8];
        }
        __syncthreads();
        short8 af[4], bfr[4];
#pragma unroll
        for (int i = 0; i < 4; i++)
            af[i] = *(const short8*)&As[wr + i * 16 + fr][fk];
#pragma unroll
        for (int j = 0; j < 4; j++)
            bfr[j] = *(const short8*)&Bs[wc + j * 16 + fr][fk];
#pragma unroll
        for (int i = 0; i < 4; i++)
#pragma unroll
            for (int j = 0; j < 4; j++)
                acc[i][j] = __builtin_amdgcn_mfma_f32_16x16x32_bf16(
                    af[i], bfr[j], acc[i][j], 0, 0, 0);
    }
    const int cr = (lane >> 4) << 2;
#pragma unroll
    for (int i = 0; i < 4; i++)
#pragma unroll
        for (int j = 0; j < 4; j++) {
#pragma unroll
            for (int r = 0; r < 4; r++) {
                C[(size_t)(m0 + wr + i * 16 + cr + r) * N + n0 + wc + j * 16 +
                  fr] = acc[i][j][r];
            }
        }
}

// ---------------------------------------------------------------------------
// a/b projections (N=16 each) fused with softplus/sigmoid -> g, beta.
// ---------------------------------------------------------------------------
__global__ void __launch_bounds__(256) ab_proj(
    const float* __restrict__ x, const float* __restrict__ w_a,
    const float* __restrict__ w_b, const float* __restrict__ A_log,
    const float* __restrict__ dt_bias, float* __restrict__ g_out,
    float* __restrict__ beta_out) {
    const int row = blockIdx.x * 4 + (threadIdx.x >> 6);
    const int lane = threadIdx.x & 63;
    const int h = lane >> 2;
    const int kg = lane & 3;
    const float* xr = x + (size_t)row * Dc;
    float pa = 0.f, pb = 0.f;
    const int kbeg = kg * 256, kend = kbeg + 256;
    for (int k = kbeg; k < kend; k++) {
        float xv = xr[k];
        pa += xv * w_a[k * Hc + h];
        pb += xv * w_b[k * Hc + h];
    }
    pa += __shfl_xor(pa, 1, 64);
    pa += __shfl_xor(pa, 2, 64);
    pb += __shfl_xor(pb, 1, 64);
    pb += __shfl_xor(pb, 2, 64);
    if (kg == 0) {
        float arg = pa + dt_bias[h];
        float sp = fmaxf(arg, 0.f) + log1pf(expf(-fabsf(arg)));
        g_out[(size_t)row * Hc + h] = -expf(A_log[h]) * sp;
        beta_out[(size_t)row * Hc + h] = 2.f / (1.f + expf(-pb));
    }
}

// ---------------------------------------------------------------------------
// Save 3-row halos at 64-step chunk boundaries (for in-place conv).
// ---------------------------------------------------------------------------
template <int C>
__global__ void __launch_bounds__(256) save_halo(
    const float* __restrict__ in, float* __restrict__ halo) {
    const int g = blockIdx.x * 256 + threadIdx.x;
    const int total = Bc * (Tc / 64 - 1) * 3 * C;
    if (g >= total) return;
    const int c = g % C;
    int r = g / C;
    const int j = r % 3;
    r /= 3;
    const int chunk = r % (Tc / 64 - 1) + 1;
    const int b = r / (Tc / 64 - 1);
    halo[((size_t)(b * 64 + chunk) * 3 + j) * C + c] =
        in[((size_t)b * Tc + chunk * 64 - 3 + j) * C + c];
}

// ---------------------------------------------------------------------------
// Depthwise causal conv1d (K=4) + SiLU (+ optional l2norm), IN PLACE.
// ---------------------------------------------------------------------------
template <int C, bool L2N>
__global__ void __launch_bounds__(256) conv_silu_inplace(
    float* __restrict__ buf, const float* __restrict__ w,
    const float* __restrict__ halo) {
    constexpr int CB = C / 256;
    const int bidx = blockIdx.x;
    const int cb = bidx % CB;
    const int tchunk = (bidx / CB) % (Tc / 64);
    const int b = bidx / (CB * (Tc / 64));
    const int c = cb * 256 + threadIdx.x;
    const int t0 = tchunk * 64;
    const float w0 = w[c * 4 + 0], w1 = w[c * 4 + 1], w2 = w[c * 4 + 2],
                w3 = w[c * 4 + 3];
    float xm3 = 0.f, xm2 = 0.f, xm1 = 0.f;
    if (tchunk > 0) {
        const float* hp = halo + (size_t)(b * 64 + tchunk) * 3 * C + c;
        xm3 = hp[0];
        xm2 = hp[C];
        xm1 = hp[2 * C];
    }
    float* p = buf + (size_t)b * Tc * C + c;
#pragma unroll 4
    for (int i = 0; i < 64; i++) {
        float xt = p[(size_t)(t0 + i) * C];
        float y = w0 * xm3 + w1 * xm2 + w2 * xm1 + w3 * xt;
        y = siluf(y);
        if (L2N) {
            float ss = y * y;
#pragma unroll
            for (int m = 1; m < 64; m <<= 1) ss += __shfl_xor(ss, m, 64);
            y *= rsqrtf(ss + 1e-6f);
        }
        p[(size_t)(t0 + i) * C] = y;
        xm3 = xm2;
        xm2 = xm1;
        xm1 = xt;
    }
}

// ---------------------------------------------------------------------------
// TM precompute: per (b,h,chunk) tile: A (LDS), M -> tmM, T=(I+A)^{-1} -> tmT.
// grid = B*H*NCH = 2048 WGs, 256 threads.
// ---------------------------------------------------------------------------
__global__ void __launch_bounds__(256) tm_precompute(
    const float* __restrict__ kc, const float* __restrict__ qc,
    const float* __restrict__ g, const float* __restrict__ beta,
    float* __restrict__ tmT, float* __restrict__ tmM) {
    const int bid = blockIdx.x;
    const int ch = bid & (NCH - 1);
    const int bh = bid >> 6;
    const int b = bh >> 4, h = bh & 15;
    const int tid = threadIdx.x;
    const int t0 = ch * CC;

    __shared__ __align__(16) float kL[CC][DKc + 4];
    __shared__ __align__(16) float qL[CC][DKc + 4];
    __shared__ __align__(16) float AtL[CC][DKc + 4];  // A^T: AtL[s][t]
    __shared__ float cL[CC], betaL[CC];

    const size_t qk0 = (size_t)b * Tc * KDIMc + h * DKc;
    const size_t gb0 = (size_t)b * Tc * Hc + h;
    const size_t tile = (size_t)(bh * NCH + ch) * 4096;

#pragma unroll
    for (int i = 0; i < 4; i++) {
        int e = tid + i * 256;
        int r = e >> 4, c4 = (e & 15) << 2;
        *(float4*)&kL[r][c4] =
            *(const float4*)&kc[qk0 + (size_t)(t0 + r) * KDIMc + c4];
        *(float4*)&qL[r][c4] =
            *(const float4*)&qc[qk0 + (size_t)(t0 + r) * KDIMc + c4];
    }
    if (tid < 64) {
        float gv = g[gb0 + (size_t)(t0 + tid) * Hc];
        float cv = gv;
#pragma unroll
        for (int d = 1; d < 64; d <<= 1) {
            float nb = __shfl_up(cv, d, 64);
            if (tid >= d) cv += nb;
        }
        cL[tid] = cv;
        betaL[tid] = beta[gb0 + (size_t)(t0 + tid) * Hc];
    }
    __syncthreads();

    {
        const int tIdx = tid >> 4, sIdx = tid & 15;
        float dka[4][4], dqa[4][4];
#pragma unroll
        for (int i = 0; i < 4; i++)
#pragma unroll
            for (int j = 0; j < 4; j++) { dka[i][j] = 0.f; dqa[i][j] = 0.f; }
#pragma unroll 4
        for (int d = 0; d < 64; d += 4) {
            float4 kb[4], qb_[4], sb[4];
#pragma unroll
            for (int i = 0; i < 4; i++) {
                kb[i] = *(const float4*)&kL[tIdx * 4 + i][d];
                qb_[i] = *(const float4*)&qL[tIdx * 4 + i][d];
                sb[i] = *(const float4*)&kL[sIdx * 4 + i][d];
            }
#pragma unroll
            for (int i = 0; i < 4; i++)
#pragma unroll
                for (int j = 0; j < 4; j++) {
                    dka[i][j] += dot4(kb[i], sb[j]);
                    dqa[i][j] += dot4(qb_[i], sb[j]);
                }
        }
#pragma unroll
        for (int i = 0; i < 4; i++) {
            float mrow[4];
#pragma unroll
            for (int j = 0; j < 4; j++) {
                int t = tIdx * 4 + i, s = sIdx * 4 + j;
                float E = expf(cL[t] - cL[s]);
                AtL[s][t] = (s < t) ? betaL[t] * E * dka[i][j] : 0.f;
                mrow[j] = (s <= t) ? 0.125f * E * dqa[i][j] : 0.f;
            }
            *(float4*)&tmM[tile + (size_t)(tIdx * 4 + i) * 64 + sIdx * 4] =
                make_float4(mrow[0], mrow[1], mrow[2], mrow[3]);
        }
    }
    __syncthreads();

    {
        const int w = tid >> 6, lane = tid & 63;
        float acc[16];
#pragma unroll
        for (int di = 0; di < 16; di++)
            acc[di] = (lane == w * 16 + di) ? 1.f : 0.f;
#pragma unroll 4
        for (int s = 0; s < 64; s++) {
            float a = AtL[s][lane];
#pragma unroll
            for (int di = 0; di < 16; di++) {
                float ds = __shfl(acc[di], s, 64);
                acc[di] -= a * ds;
            }
        }
#pragma unroll
        for (int di = 0; di < 16; di++)
            tmT[tile + (size_t)(w * 16 + di) * 64 + lane] = acc[di];
    }
}

// ---------------------------------------------------------------------------
// Sequential chunk scan, DV-split 8 ways; XCD-swizzled decode so all 8
// slices of one (b,h) land on the same XCD (bid%8 == bh%8) and share L2
// for k/q/T/M (R6 showed 594 MB FETCH = staging-bound).
// ---------------------------------------------------------------------------
__global__ void __launch_bounds__(256) delta_scan(
    const float* __restrict__ kc, const float* __restrict__ qc,
    float* vo, const float* __restrict__ g, const float* __restrict__ beta,
    const float* __restrict__ tmT, const float* __restrict__ tmM) {
    const int bid = blockIdx.x;
    const int sl = bid >> 5;   // 0..7   (was bid&7)
    const int bh = bid & 31;   // 0..31  -> XCD = bid%8 = bh%8
    const int b = bh >> 4, h = bh & 15;
    const int tid = threadIdx.x;

    __shared__ __align__(16) float kL[CC][DKc + 4];
    __shared__ __align__(16) float kT[DKc][CC + 4];
    __shared__ __align__(16) float qL[CC][DKc + 4];
    __shared__ __align__(16) float TL[CC][CC + 4];
    __shared__ __align__(16) float ML[CC][CC + 4];
    __shared__ __align__(16) float ST[16][DKc + 4];  // S^T: [dv][dk]
    __shared__ __align__(16) float DT[16][CC + 4];   // RHS/delta^T: [dv][s]
    __shared__ __align__(16) float VL[CC][20];
    __shared__ __align__(16) float OL[CC][20];
    __shared__ __align__(16) float gamL[CC], egL[CC], betaL[CC];

    const size_t qk0 = (size_t)b * Tc * KDIMc + h * DKc;
    const size_t v0 = (size_t)b * Tc * VDIMc + h * DVc + sl * 16;
    const size_t gb0 = (size_t)b * Tc * Hc + h;
    const size_t tb0 = (size_t)(bh * NCH) * 4096;

    for (int i = tid; i < 16 * (DKc + 4); i += 256) ((float*)ST)[i] = 0.f;

    const int dv0 = tid >> 5, tt = tid & 31;
    const int dvv = tid >> 4, dk4 = (tid & 15) << 2;

#pragma unroll 1
    for (int ch = 0; ch < NCH; ch++) {
        const int t0 = ch * CC;
        const size_t tile = tb0 + (size_t)ch * 4096;
        __syncthreads();

#pragma unroll
        for (int i = 0; i < 4; i++) {
            int e = tid + i * 256;
            int r = e >> 4, c4 = (e & 15) << 2;
            float4 kv = *(const float4*)&kc[qk0 + (size_t)(t0 + r) * KDIMc + c4];
            *(float4*)&kL[r][c4] = kv;
            kT[c4 + 0][r] = kv.x; kT[c4 + 1][r] = kv.y;
            kT[c4 + 2][r] = kv.z; kT[c4 + 3][r] = kv.w;
            *(float4*)&qL[r][c4] =
                *(const float4*)&qc[qk0 + (size_t)(t0 + r) * KDIMc + c4];
            float4 tv = *(const float4*)&tmT[tile + (size_t)e * 4];
            int c = e >> 4, t4 = (e & 15) << 2;
            TL[t4 + 0][c] = tv.x; TL[t4 + 1][c] = tv.y;
            TL[t4 + 2][c] = tv.z; TL[t4 + 3][c] = tv.w;
            float4 mv = *(const float4*)&tmM[tile + (size_t)e * 4];
            *(float4*)&ML[r][c4] = mv;
        }
        {
            int r = tid >> 2, j4 = (tid & 3) << 2;
            *(float4*)&VL[r][j4] =
                *(const float4*)&vo[v0 + (size_t)(t0 + r) * VDIMc + j4];
        }
        if (tid < 64) {
            float gv = g[gb0 + (size_t)(t0 + tid) * Hc];
            float cv = gv;
#pragma unroll
            for (int d = 1; d < 64; d <<= 1) {
                float nb = __shfl_up(cv, d, 64);
                if (tid >= d) cv += nb;
            }
            gamL[tid] = expf(cv);
            float cend = __shfl(cv, 63, 64);
            egL[tid] = expf(cend - cv);
            betaL[tid] = beta[gb0 + (size_t)(t0 + tid) * Hc];
        }
        __syncthreads();

        // P1: RHS
        {
            float a00 = 0.f, a01 = 0.f, a10 = 0.f, a11 = 0.f;
#pragma unroll 4
            for (int dk = 0; dk < 64; dk += 4) {
                float4 k1 = *(const float4*)&kL[tt][dk];
                float4 k2 = *(const float4*)&kL[tt + 32][dk];
                float4 s1 = *(const float4*)&ST[dv0][dk];
                float4 s2 = *(const float4*)&ST[dv0 + 8][dk];
                a00 += dot4(k1, s1); a01 += dot4(k1, s2);
                a10 += dot4(k2, s1); a11 += dot4(k2, s2);
            }
            float b1 = betaL[tt], b2 = betaL[tt + 32];
            float g1 = gamL[tt], g2 = gamL[tt + 32];
            DT[dv0][tt] = b1 * (VL[tt][dv0] - g1 * a00);
            DT[dv0 + 8][tt] = b1 * (VL[tt][dv0 + 8] - g1 * a01);
            DT[dv0][tt + 32] = b2 * (VL[tt + 32][dv0] - g2 * a10);
            DT[dv0 + 8][tt + 32] = b2 * (VL[tt + 32][dv0 + 8] - g2 * a11);
        }
        __syncthreads();

        // P2: delta = T * RHS
        float d00 = 0.f, d01 = 0.f, d10 = 0.f, d11 = 0.f;
#pragma unroll 4
        for (int s = 0; s < 64; s += 4) {
            float4 t1 = *(const float4*)&TL[tt][s];
            float4 t2 = *(const float4*)&TL[tt + 32][s];
            float4 r1 = *(const float4*)&DT[dv0][s];
            float4 r2 = *(const float4*)&DT[dv0 + 8][s];
            d00 += dot4(t1, r1); d01 += dot4(t1, r2);
            d10 += dot4(t2, r1); d11 += dot4(t2, r2);
        }
        __syncthreads();
        DT[dv0][tt] = d00;
        DT[dv0 + 8][tt] = d01;
        DT[dv0][tt + 32] = d10;
        DT[dv0 + 8][tt + 32] = d11;
        __syncthreads();

        // P3: O
        {
            float p00 = 0.f, p01 = 0.f, p10 = 0.f, p11 = 0.f;
            float m00 = 0.f, m01 = 0.f, m10 = 0.f, m11 = 0.f;
#pragma unroll 4
            for (int dk = 0; dk < 64; dk += 4) {
                float4 q1 = *(const float4*)&qL[tt][dk];
                float4 q2 = *(const float4*)&qL[tt + 32][dk];
                float4 s1 = *(const float4*)&ST[dv0][dk];
                float4 s2 = *(const float4*)&ST[dv0 + 8][dk];
                p00 += dot4(q1, s1); p01 += dot4(q1, s2);
                p10 += dot4(q2, s1); p11 += dot4(q2, s2);
            }
#pragma unroll 4
            for (int s = 0; s < 64; s += 4) {
                float4 m1 = *(const float4*)&ML[tt][s];
                float4 m2 = *(const float4*)&ML[tt + 32][s];
                float4 e1 = *(const float4*)&DT[dv0][s];
                float4 e2 = *(const float4*)&DT[dv0 + 8][s];
                m00 += dot4(m1, e1); m01 += dot4(m1, e2);
                m10 += dot4(m2, e1); m11 += dot4(m2, e2);
            }
            float f1 = 0.125f * gamL[tt], f2 = 0.125f * gamL[tt + 32];
            OL[tt][dv0] = f1 * p00 + m00;
            OL[tt][dv0 + 8] = f1 * p01 + m01;
            OL[tt + 32][dv0] = f2 * p10 + m10;
            OL[tt + 32][dv0 + 8] = f2 * p11 + m11;
        }
        __syncthreads();

        {
            int r = tid >> 2, j4 = (tid & 3) << 2;
            *(float4*)&vo[v0 + (size_t)(t0 + r) * VDIMc + j4] =
                *(const float4*)&OL[r][j4];
        }
        // P4: S update
        {
            const float ge = gamL[63];
            float sacc[4];
            float4 sv = *(const float4*)&ST[dvv][dk4];
            sacc[0] = ge * sv.x; sacc[1] = ge * sv.y;
            sacc[2] = ge * sv.z; sacc[3] = ge * sv.w;
#pragma unroll 4
            for (int s = 0; s < 64; s += 4) {
                float4 dd = *(const float4*)&DT[dvv][s];
                float4 ee = *(const float4*)&egL[s];
                float e0 = ee.x * dd.x, e1 = ee.y * dd.y;
                float e2 = ee.z * dd.z, e3 = ee.w * dd.w;
#pragma unroll
                for (int n = 0; n < 4; n++) {
                    float4 kv = *(const float4*)&kT[dk4 + n][s];
                    sacc[n] += kv.x * e0 + kv.y * e1 + kv.z * e2 + kv.w * e3;
                }
            }
            *(float4*)&ST[dvv][dk4] =
                make_float4(sacc[0], sacc[1], sacc[2], sacc[3]);
        }
    }
}

// ---------------------------------------------------------------------------
// Gated RMSNorm -> bf16 output buffer (for the MFMA output GEMM).
// ---------------------------------------------------------------------------
__global__ void __launch_bounds__(256) rms_gate_bf16(
    const float* __restrict__ o, const float* __restrict__ gg,
    const float* __restrict__ norm_w, unsigned short* __restrict__ out) {
    const int row = blockIdx.x * 4 + (threadIdx.x >> 6);
    const int lane = threadIdx.x & 63;
    const size_t base = (size_t)row * DVc;
    float2 ov = *(const float2*)&o[base + lane * 2];
    float ss = ov.x * ov.x + ov.y * ov.y;
#pragma unroll
    for (int m = 1; m < 64; m <<= 1) ss += __shfl_xor(ss, m, 64);
    const float f = rsqrtf(ss * (1.f / 128.f) + 1e-5f);
    float2 gv = *(const float2*)&gg[base + lane * 2];
    const float nw0 = norm_w[lane * 2], nw1 = norm_w[lane * 2 + 1];
    float y0 = ov.x * f * nw0 * siluf(gv.x);
    float y1 = ov.y * f * nw1 * siluf(gv.y);
    unsigned int packed = (unsigned)f2bf(y0) | ((unsigned)f2bf(y1) << 16);
    *(unsigned int*)&out[base + lane * 2] = packed;
}

// ---------------------------------------------------------------------------
// Workspace (floats):
//   qb 8.39M | kb 8.39M | vb 16.78M | tm 16.78M | gbuf .131M | bbuf .131M |
//   xb 4.19M (bf16 x) | wT 4.19M (bf16 wqT,wkT,wvT,wgT,woT)
// total 58.98M floats = 235.9 MB. halo + obb alias tm (disjoint lifetimes);
// gg aliases qb+kb after the scan.
// ---------------------------------------------------------------------------
extern "C" void kernel_launch(void* const* d_in, const int* in_sizes, int n_in,
                              void* d_out, int out_size, void* d_ws,
                              size_t ws_size, hipStream_t stream) {
    const float* x = (const float*)d_in[0];
    const float* w_q = (const float*)d_in[1];
    const float* w_k = (const float*)d_in[2];
    const float* w_v = (const float*)d_in[3];
    const float* w_a = (const float*)d_in[4];
    const float* w_b = (const float*)d_in[5];
    const float* w_g = (const float*)d_in[6];
    const float* w_out = (const float*)d_in[7];
    const float* A_log = (const float*)d_in[8];
    const float* dt_bias = (const float*)d_in[9];
    const float* conv_q = (const float*)d_in[10];
    const float* conv_k = (const float*)d_in[11];
    const float* conv_v = (const float*)d_in[12];
    const float* norm_w = (const float*)d_in[13];

    float* ws = (float*)d_ws;
    const size_t M = Mrows;
    float* qb = ws;
    float* kb = qb + M * KDIMc;
    float* vb = kb + M * KDIMc;
    float* tm = vb + M * VDIMc;          // T (8.4M) + M (8.4M)
    float* gbuf = tm + M * VDIMc;
    float* bbuf = gbuf + M * Hc;
    float* xtra = bbuf + M * Hc;
    float* tmT = tm;
    float* tmM = tm + (size_t)Bc * Hc * NCH * 4096;
    float* halo = tm;                     // alias: dead before tm_precompute
    unsigned short* obb = (unsigned short*)tm;  // alias: after scan, tm dead
    float* gg = qb;                       // alias: after scan

    unsigned short* xb = (unsigned short*)xtra;                  // 8.39M bf16
    unsigned short* wqT = xb + M * KDIMc;                        // 1M
    unsigned short* wkT = wqT + (size_t)KDIMc * Dc;              // 1M
    unsigned short* wvT = wkT + (size_t)KDIMc * Dc;              // 2M
    unsigned short* wgT = wvT + (size_t)VDIMc * Dc;              // 2M
    unsigned short* woT = wgT + (size_t)VDIMc * Dc;              // 2M

    // 0) conversions
    convert_bf16<<<dim3(M * Dc / 4 / 256), 256, 0, stream>>>(x, xb, M * Dc / 4);
    transp_bf16<<<dim3((KDIMc / 32) * (Dc / 32)), 256, 0, stream>>>(w_q, wqT,
                                                                    Dc, KDIMc);
    transp_bf16<<<dim3((KDIMc / 32) * (Dc / 32)), 256, 0, stream>>>(w_k, wkT,
                                                                    Dc, KDIMc);
    transp_bf16<<<dim3((VDIMc / 32) * (Dc / 32)), 256, 0, stream>>>(w_v, wvT,
                                                                    Dc, VDIMc);
    transp_bf16<<<dim3((VDIMc / 32) * (Dc / 32)), 256, 0, stream>>>(w_g, wgT,
                                                                    Dc, VDIMc);
    transp_bf16<<<dim3((Dc / 32) * (VDIMc / 32)), 256, 0, stream>>>(
        w_out, woT, VDIMc, Dc);

    // 1) q/k/v projections (bf16 MFMA)
    gemm_bf16<<<dim3((M / 128) * (KDIMc / 128)), 256, 0, stream>>>(
        xb, wqT, qb, M, KDIMc, Dc);
    gemm_bf16<<<dim3((M / 128) * (KDIMc / 128)), 256, 0, stream>>>(
        xb, wkT, kb, M, KDIMc, Dc);
    gemm_bf16<<<dim3((M / 128) * (VDIMc / 128)), 256, 0, stream>>>(
        xb, wvT, vb, M, VDIMc, Dc);

    // 2) a/b projections fused with activation -> g, beta
    ab_proj<<<dim3(M / 4), 256, 0, stream>>>(x, w_a, w_b, A_log, dt_bias, gbuf,
                                             bbuf);

    // 3) conv + silu (+ l2norm for q,k), in place with halo save
    {
        const int nqk = Bc * (Tc / 64 - 1) * 3 * KDIMc;
        const int nv = Bc * (Tc / 64 - 1) * 3 * VDIMc;
        save_halo<KDIMc><<<dim3((nqk + 255) / 256), 256, 0, stream>>>(qb, halo);
        conv_silu_inplace<KDIMc, true>
            <<<dim3(Bc * (Tc / 64) * (KDIMc / 256)), 256, 0, stream>>>(
                qb, conv_q, halo);
        save_halo<KDIMc><<<dim3((nqk + 255) / 256), 256, 0, stream>>>(kb, halo);
        conv_silu_inplace<KDIMc, true>
            <<<dim3(Bc * (Tc / 64) * (KDIMc / 256)), 256, 0, stream>>>(
                kb, conv_k, halo);
        save_halo<VDIMc><<<dim3((nv + 255) / 256), 256, 0, stream>>>(vb, halo);
        conv_silu_inplace<VDIMc, false>
            <<<dim3(Bc * (Tc / 64) * (VDIMc / 256)), 256, 0, stream>>>(
                vb, conv_v, halo);
    }

    // 4a) parallel precompute of T=(I+A)^{-1} and M per (b,h,chunk)
    tm_precompute<<<dim3(Bc * Hc * NCH), 256, 0, stream>>>(kb, qb, gbuf, bbuf,
                                                           tmT, tmM);
    // 4b) sequential scan, DV-split 8x, XCD-swizzled; O overwrites vb
    delta_scan<<<dim3(Bc * Hc * 8), 256, 0, stream>>>(kb, qb, vb, gbuf, bbuf,
                                                      tmT, tmM);

    // 5) gate projection (bf16 MFMA; gg aliases qb+kb)
    gemm_bf16<<<dim3((M / 128) * (VDIMc / 128)), 256, 0, stream>>>(
        xb, wgT, gg, M, VDIMc, Dc);

    // 6) gated RMSNorm -> bf16 obb (aliases tm)
    rms_gate_bf16<<<dim3(M * Hc / 4), 256, 0, stream>>>(vb, gg, norm_w, obb);

    // 7) output projection (bf16 MFMA) -> d_out
    gemm_bf16<<<dim3((M / 128) * (Dc / 128)), 256, 0, stream>>>(
        obb, woT, (float*)d_out, M, Dc, VDIMc);
}

// Round 8
// 1135.668 us; speedup vs baseline: 19.5884x; 1.0827x over previous
//
#include <hip/hip_runtime.h>
#include <hip/hip_bf16.h>
#include <math.h>

// Problem constants
#define Bc 2
#define Tc 4096
#define Dc 1024
#define Hc 16
#define DKc 64
#define DVc 128
#define KDIMc 1024   // H*DK
#define VDIMc 2048   // H*DV
#define Mrows (Bc*Tc) // 8192
#define CC 64        // scan chunk size
#define NCH (Tc/CC)  // 64 chunks

typedef short short8 __attribute__((ext_vector_type(8)));
typedef float f32x4 __attribute__((ext_vector_type(4)));

__device__ __forceinline__ float siluf(float x) {
    return x / (1.f + expf(-x));
}
__device__ __forceinline__ float dot4(float4 a, float4 b) {
    return a.x * b.x + a.y * b.y + a.z * b.z + a.w * b.w;
}
__device__ __forceinline__ unsigned short f2bf(float f) {
    unsigned int u = __float_as_uint(f);
    unsigned int r = (u + 0x7fffu + ((u >> 16) & 1u)) >> 16;
    return (unsigned short)r;
}

// ---------------------------------------------------------------------------
// x (f32) -> bf16, straight elementwise. 4 elems/thread.
// ---------------------------------------------------------------------------
__global__ void __launch_bounds__(256) convert_bf16(
    const float* __restrict__ in, unsigned short* __restrict__ out, int n4) {
    int g = blockIdx.x * 256 + threadIdx.x;
    if (g >= n4) return;
    float4 v = *(const float4*)&in[(size_t)g * 4];
    unsigned short h[4] = {f2bf(v.x), f2bf(v.y), f2bf(v.z), f2bf(v.w)};
    *(uint2*)&out[(size_t)g * 4] =
        make_uint2((unsigned)h[0] | ((unsigned)h[1] << 16),
                   (unsigned)h[2] | ((unsigned)h[3] << 16));
}

// ---------------------------------------------------------------------------
// Transpose + convert: in f32 [K][N] -> out bf16 [N][K]. 32x32 LDS tiles.
// ---------------------------------------------------------------------------
__global__ void __launch_bounds__(256) transp_bf16(
    const float* __restrict__ in, unsigned short* __restrict__ out, int K,
    int N) {
    __shared__ float t[32][33];
    const int nbx = N >> 5;
    const int n0 = (blockIdx.x % nbx) << 5;
    const int k0 = (blockIdx.x / nbx) << 5;
    const int c = threadIdx.x & 31, r4 = (threadIdx.x >> 5) << 2;
#pragma unroll
    for (int i = 0; i < 4; i++)
        t[r4 + i][c] = in[(size_t)(k0 + r4 + i) * N + n0 + c];
    __syncthreads();
#pragma unroll
    for (int i = 0; i < 4; i++)
        out[(size_t)(n0 + r4 + i) * K + k0 + c] = f2bf(t[c][r4 + i]);
}

// ---------------------------------------------------------------------------
// bf16 MFMA GEMM: C[M,N] f32 = A[M,K] bf16 (row-major) @ Bt[N,K] bf16.
// ---------------------------------------------------------------------------
__global__ void __launch_bounds__(256) gemm_bf16(
    const unsigned short* __restrict__ A, const unsigned short* __restrict__ Bt,
    float* __restrict__ C, int M, int N, int K) {
    __shared__ short As[128][40];
    __shared__ short Bs[128][40];
    const int tid = threadIdx.x;
    const int nbx = N >> 7;
    const int bx = blockIdx.x % nbx, by = blockIdx.x / nbx;
    const int m0 = by << 7, n0 = bx << 7;
    const int w = tid >> 6, lane = tid & 63;
    const int wr = (w >> 1) << 6, wc = (w & 1) << 6;
    const int fr = lane & 15, fk = (lane >> 4) << 3;
    const int srow = tid >> 1, skb = (tid & 1) << 4;

    f32x4 acc[4][4];
#pragma unroll
    for (int i = 0; i < 4; i++)
#pragma unroll
        for (int j = 0; j < 4; j++)
            acc[i][j] = (f32x4){0.f, 0.f, 0.f, 0.f};

    const int nkt = K >> 5;
    for (int kt = 0; kt < nkt; kt++) {
        __syncthreads();
        {
            const unsigned short* ap = &A[(size_t)(m0 + srow) * K + (kt << 5) + skb];
            const unsigned short* bp = &Bt[(size_t)(n0 + srow) * K + (kt << 5) + skb];
            *(short8*)&As[srow][skb] = *(const short8*)&ap[0];
            *(short8*)&As[srow][skb + 8] = *(const short8*)&ap[8];
            *(short8*)&Bs[srow][skb] = *(const short8*)&bp[0];
            *(short8*)&Bs[srow][skb + 8] = *(const short8*)&bp[8];
        }
        __syncthreads();
        short8 af[4], bfr[4];
#pragma unroll
        for (int i = 0; i < 4; i++)
            af[i] = *(const short8*)&As[wr + i * 16 + fr][fk];
#pragma unroll
        for (int j = 0; j < 4; j++)
            bfr[j] = *(const short8*)&Bs[wc + j * 16 + fr][fk];
#pragma unroll
        for (int i = 0; i < 4; i++)
#pragma unroll
            for (int j = 0; j < 4; j++)
                acc[i][j] = __builtin_amdgcn_mfma_f32_16x16x32_bf16(
                    af[i], bfr[j], acc[i][j], 0, 0, 0);
    }
    const int cr = (lane >> 4) << 2;
#pragma unroll
    for (int i = 0; i < 4; i++)
#pragma unroll
        for (int j = 0; j < 4; j++) {
#pragma unroll
            for (int r = 0; r < 4; r++) {
                C[(size_t)(m0 + wr + i * 16 + cr + r) * N + n0 + wc + j * 16 +
                  fr] = acc[i][j][r];
            }
        }
}

// ---------------------------------------------------------------------------
// a/b projections (N=16 each) fused with softplus/sigmoid -> g, beta.
// ---------------------------------------------------------------------------
__global__ void __launch_bounds__(256) ab_proj(
    const float* __restrict__ x, const float* __restrict__ w_a,
    const float* __restrict__ w_b, const float* __restrict__ A_log,
    const float* __restrict__ dt_bias, float* __restrict__ g_out,
    float* __restrict__ beta_out) {
    const int row = blockIdx.x * 4 + (threadIdx.x >> 6);
    const int lane = threadIdx.x & 63;
    const int h = lane >> 2;
    const int kg = lane & 3;
    const float* xr = x + (size_t)row * Dc;
    float pa = 0.f, pb = 0.f;
    const int kbeg = kg * 256, kend = kbeg + 256;
    for (int k = kbeg; k < kend; k++) {
        float xv = xr[k];
        pa += xv * w_a[k * Hc + h];
        pb += xv * w_b[k * Hc + h];
    }
    pa += __shfl_xor(pa, 1, 64);
    pa += __shfl_xor(pa, 2, 64);
    pb += __shfl_xor(pb, 1, 64);
    pb += __shfl_xor(pb, 2, 64);
    if (kg == 0) {
        float arg = pa + dt_bias[h];
        float sp = fmaxf(arg, 0.f) + log1pf(expf(-fabsf(arg)));
        g_out[(size_t)row * Hc + h] = -expf(A_log[h]) * sp;
        beta_out[(size_t)row * Hc + h] = 2.f / (1.f + expf(-pb));
    }
}

// ---------------------------------------------------------------------------
// Save 3-row halos at 64-step chunk boundaries (for in-place conv).
// ---------------------------------------------------------------------------
template <int C>
__global__ void __launch_bounds__(256) save_halo(
    const float* __restrict__ in, float* __restrict__ halo) {
    const int g = blockIdx.x * 256 + threadIdx.x;
    const int total = Bc * (Tc / 64 - 1) * 3 * C;
    if (g >= total) return;
    const int c = g % C;
    int r = g / C;
    const int j = r % 3;
    r /= 3;
    const int chunk = r % (Tc / 64 - 1) + 1;
    const int b = r / (Tc / 64 - 1);
    halo[((size_t)(b * 64 + chunk) * 3 + j) * C + c] =
        in[((size_t)b * Tc + chunk * 64 - 3 + j) * C + c];
}

// ---------------------------------------------------------------------------
// Depthwise causal conv1d (K=4) + SiLU (+ optional l2norm), IN PLACE.
// ---------------------------------------------------------------------------
template <int C, bool L2N>
__global__ void __launch_bounds__(256) conv_silu_inplace(
    float* __restrict__ buf, const float* __restrict__ w,
    const float* __restrict__ halo) {
    constexpr int CB = C / 256;
    const int bidx = blockIdx.x;
    const int cb = bidx % CB;
    const int tchunk = (bidx / CB) % (Tc / 64);
    const int b = bidx / (CB * (Tc / 64));
    const int c = cb * 256 + threadIdx.x;
    const int t0 = tchunk * 64;
    const float w0 = w[c * 4 + 0], w1 = w[c * 4 + 1], w2 = w[c * 4 + 2],
                w3 = w[c * 4 + 3];
    float xm3 = 0.f, xm2 = 0.f, xm1 = 0.f;
    if (tchunk > 0) {
        const float* hp = halo + (size_t)(b * 64 + tchunk) * 3 * C + c;
        xm3 = hp[0];
        xm2 = hp[C];
        xm1 = hp[2 * C];
    }
    float* p = buf + (size_t)b * Tc * C + c;
#pragma unroll 4
    for (int i = 0; i < 64; i++) {
        float xt = p[(size_t)(t0 + i) * C];
        float y = w0 * xm3 + w1 * xm2 + w2 * xm1 + w3 * xt;
        y = siluf(y);
        if (L2N) {
            float ss = y * y;
#pragma unroll
            for (int m = 1; m < 64; m <<= 1) ss += __shfl_xor(ss, m, 64);
            y *= rsqrtf(ss + 1e-6f);
        }
        p[(size_t)(t0 + i) * C] = y;
        xm3 = xm2;
        xm2 = xm1;
        xm1 = xt;
    }
}

// ---------------------------------------------------------------------------
// TM precompute: per (b,h,chunk) tile: A (LDS), M -> tmM, T=(I+A)^{-1} -> tmT.
// ---------------------------------------------------------------------------
__global__ void __launch_bounds__(256) tm_precompute(
    const float* __restrict__ kc, const float* __restrict__ qc,
    const float* __restrict__ g, const float* __restrict__ beta,
    float* __restrict__ tmT, float* __restrict__ tmM) {
    const int bid = blockIdx.x;
    const int ch = bid & (NCH - 1);
    const int bh = bid >> 6;
    const int b = bh >> 4, h = bh & 15;
    const int tid = threadIdx.x;
    const int t0 = ch * CC;

    __shared__ __align__(16) float kL[CC][DKc + 4];
    __shared__ __align__(16) float qL[CC][DKc + 4];
    __shared__ __align__(16) float AtL[CC][DKc + 4];  // A^T: AtL[s][t]
    __shared__ float cL[CC], betaL[CC];

    const size_t qk0 = (size_t)b * Tc * KDIMc + h * DKc;
    const size_t gb0 = (size_t)b * Tc * Hc + h;
    const size_t tile = (size_t)(bh * NCH + ch) * 4096;

#pragma unroll
    for (int i = 0; i < 4; i++) {
        int e = tid + i * 256;
        int r = e >> 4, c4 = (e & 15) << 2;
        *(float4*)&kL[r][c4] =
            *(const float4*)&kc[qk0 + (size_t)(t0 + r) * KDIMc + c4];
        *(float4*)&qL[r][c4] =
            *(const float4*)&qc[qk0 + (size_t)(t0 + r) * KDIMc + c4];
    }
    if (tid < 64) {
        float gv = g[gb0 + (size_t)(t0 + tid) * Hc];
        float cv = gv;
#pragma unroll
        for (int d = 1; d < 64; d <<= 1) {
            float nb = __shfl_up(cv, d, 64);
            if (tid >= d) cv += nb;
        }
        cL[tid] = cv;
        betaL[tid] = beta[gb0 + (size_t)(t0 + tid) * Hc];
    }
    __syncthreads();

    {
        const int tIdx = tid >> 4, sIdx = tid & 15;
        float dka[4][4], dqa[4][4];
#pragma unroll
        for (int i = 0; i < 4; i++)
#pragma unroll
            for (int j = 0; j < 4; j++) { dka[i][j] = 0.f; dqa[i][j] = 0.f; }
#pragma unroll 4
        for (int d = 0; d < 64; d += 4) {
            float4 kb[4], qb_[4], sb[4];
#pragma unroll
            for (int i = 0; i < 4; i++) {
                kb[i] = *(const float4*)&kL[tIdx * 4 + i][d];
                qb_[i] = *(const float4*)&qL[tIdx * 4 + i][d];
                sb[i] = *(const float4*)&kL[sIdx * 4 + i][d];
            }
#pragma unroll
            for (int i = 0; i < 4; i++)
#pragma unroll
                for (int j = 0; j < 4; j++) {
                    dka[i][j] += dot4(kb[i], sb[j]);
                    dqa[i][j] += dot4(qb_[i], sb[j]);
                }
        }
#pragma unroll
        for (int i = 0; i < 4; i++) {
            float mrow[4];
#pragma unroll
            for (int j = 0; j < 4; j++) {
                int t = tIdx * 4 + i, s = sIdx * 4 + j;
                float E = expf(cL[t] - cL[s]);
                AtL[s][t] = (s < t) ? betaL[t] * E * dka[i][j] : 0.f;
                mrow[j] = (s <= t) ? 0.125f * E * dqa[i][j] : 0.f;
            }
            *(float4*)&tmM[tile + (size_t)(tIdx * 4 + i) * 64 + sIdx * 4] =
                make_float4(mrow[0], mrow[1], mrow[2], mrow[3]);
        }
    }
    __syncthreads();

    {
        const int w = tid >> 6, lane = tid & 63;
        float acc[16];
#pragma unroll
        for (int di = 0; di < 16; di++)
            acc[di] = (lane == w * 16 + di) ? 1.f : 0.f;
#pragma unroll 4
        for (int s = 0; s < 64; s++) {
            float a = AtL[s][lane];
#pragma unroll
            for (int di = 0; di < 16; di++) {
                float ds = __shfl(acc[di], s, 64);
                acc[di] -= a * ds;
            }
        }
#pragma unroll
        for (int di = 0; di < 16; di++)
            tmT[tile + (size_t)(w * 16 + di) * 64 + lane] = acc[di];
    }
}

// ---------------------------------------------------------------------------
// Sequential chunk scan v2: 512 threads (8 waves/CU), wave-blocked compute
// (wave w owns t-rows w*8..w*8+7; lane = 8*(t&7)+dv_base), register prefetch
// of chunk ch+1 (T14), DT2 double-buffer (5 barriers/chunk).
// Grid 256, XCD-swizzled decode (all 8 dv-slices of a (b,h) share an XCD).
// ---------------------------------------------------------------------------
__global__ void __launch_bounds__(512, 2) delta_scan(
    const float* __restrict__ kc, const float* __restrict__ qc,
    float* vo, const float* __restrict__ g, const float* __restrict__ beta,
    const float* __restrict__ tmT, const float* __restrict__ tmM) {
    const int bid = blockIdx.x;
    const int sl = bid >> 5;   // 0..7
    const int bh = bid & 31;   // 0..31 -> XCD = bh%8
    const int b = bh >> 4, h = bh & 15;
    const int tid = threadIdx.x;

    __shared__ __align__(16) float kL[CC][DKc + 4];
    __shared__ __align__(16) float kT[DKc][CC + 4];
    __shared__ __align__(16) float qL[CC][DKc + 4];
    __shared__ __align__(16) float TL[CC][CC + 4];
    __shared__ __align__(16) float ML[CC][CC + 4];
    __shared__ __align__(16) float ST[16][DKc + 4];   // S^T: [dv][dk]
    __shared__ __align__(16) float DT[16][CC + 4];    // RHS^T: [dv][t]
    __shared__ __align__(16) float DT2[16][CC + 4];   // delta^T
    __shared__ __align__(16) float VL[CC][20];
    __shared__ __align__(16) float OL[CC][20];
    __shared__ __align__(16) float gamL[CC], egL[CC], betaL[CC];

    const size_t qk0 = (size_t)b * Tc * KDIMc + h * DKc;
    const size_t v0 = (size_t)b * Tc * VDIMc + h * DVc + sl * 16;
    const size_t gb0 = (size_t)b * Tc * Hc + h;
    const size_t tb0 = (size_t)(bh * NCH) * 4096;

    for (int i = tid; i < 16 * (DKc + 4); i += 512) ((float*)ST)[i] = 0.f;

    // staging coords (512 threads, 1024 float4 per 64x64 array)
    const int r0 = tid >> 4, c40 = (tid & 15) << 2;  // rows 0..31
    const int r1 = r0 + 32;                          // rows 32..63
    const int cc0 = tid >> 4, t40 = (tid & 15) << 2; // TL scatter
    // compute coords
    const int wid = tid >> 6, lane = tid & 63;
    const int tb = (wid << 3) | (lane >> 3);  // t (or dk) index 0..63
    const int dvb = lane & 7;                 // dv base (pair: dvb, dvb+8)

    float4 kv0, kv1, qv0, qv1, tv0, tv1, mv0, mv1, vv0;
    float gvr = 0.f, bvr = 0.f;

#define LOADREGS(CH)                                                          \
    {                                                                         \
        const size_t tK = qk0 + (size_t)(CH) * CC * KDIMc;                    \
        const size_t tile_ = tb0 + (size_t)(CH) * 4096;                       \
        kv0 = *(const float4*)&kc[tK + (size_t)r0 * KDIMc + c40];             \
        kv1 = *(const float4*)&kc[tK + (size_t)r1 * KDIMc + c40];             \
        qv0 = *(const float4*)&qc[tK + (size_t)r0 * KDIMc + c40];             \
        qv1 = *(const float4*)&qc[tK + (size_t)r1 * KDIMc + c40];             \
        tv0 = *(const float4*)&tmT[tile_ + (size_t)tid * 4];                  \
        tv1 = *(const float4*)&tmT[tile_ + (size_t)(tid + 512) * 4];          \
        mv0 = *(const float4*)&tmM[tile_ + (size_t)tid * 4];                  \
        mv1 = *(const float4*)&tmM[tile_ + (size_t)(tid + 512) * 4];          \
        if (tid < 256)                                                        \
            vv0 = *(const float4*)&vo[v0 +                                    \
                                      (size_t)((CH) * CC + (tid >> 2)) *     \
                                          VDIMc +                             \
                                      ((tid & 3) << 2)];                      \
        if (tid < 64) {                                                       \
            gvr = g[gb0 + (size_t)((CH) * CC + tid) * Hc];                    \
            bvr = beta[gb0 + (size_t)((CH) * CC + tid) * Hc];                 \
        }                                                                     \
    }

    LOADREGS(0);

#pragma unroll 1
    for (int ch = 0; ch < NCH; ch++) {
        __syncthreads();  // prev chunk compute done reading LDS

        // ---- stage regs -> LDS
        {
            float* kp0 = (float*)&kv0;
            float* kp1 = (float*)&kv1;
            float* tp0 = (float*)&tv0;
            float* tp1 = (float*)&tv1;
            *(float4*)&kL[r0][c40] = kv0;
            *(float4*)&kL[r1][c40] = kv1;
#pragma unroll
            for (int i = 0; i < 4; i++) {
                kT[c40 + i][r0] = kp0[i];
                kT[c40 + i][r1] = kp1[i];
                TL[t40 + i][cc0] = tp0[i];
                TL[t40 + i][cc0 + 32] = tp1[i];
            }
            *(float4*)&qL[r0][c40] = qv0;
            *(float4*)&qL[r1][c40] = qv1;
            *(float4*)&ML[r0][c40] = mv0;
            *(float4*)&ML[r1][c40] = mv1;
            if (tid < 256) *(float4*)&VL[tid >> 2][(tid & 3) << 2] = vv0;
            if (tid < 64) {
                float cv = gvr;
#pragma unroll
                for (int d = 1; d < 64; d <<= 1) {
                    float nb = __shfl_up(cv, d, 64);
                    if (tid >= d) cv += nb;
                }
                gamL[tid] = expf(cv);
                float cend = __shfl(cv, 63, 64);
                egL[tid] = expf(cend - cv);
                betaL[tid] = bvr;
            }
        }
        // issue next chunk's loads early (latency hides under P1-P4)
        if (ch + 1 < NCH) LOADREGS(ch + 1);
        __syncthreads();  // stage visible

        // ---- P1: DT[dv][t] = beta_t*(v[t][dv] - gam_t*(k_t . S[:,dv]))
        {
            float a0 = 0.f, a1 = 0.f;
#pragma unroll 4
            for (int dk = 0; dk < 64; dk += 4) {
                float4 kk = *(const float4*)&kL[tb][dk];
                float4 s0 = *(const float4*)&ST[dvb][dk];
                float4 s1 = *(const float4*)&ST[dvb + 8][dk];
                a0 += dot4(kk, s0);
                a1 += dot4(kk, s1);
            }
            float bt = betaL[tb], gm = gamL[tb];
            DT[dvb][tb] = bt * (VL[tb][dvb] - gm * a0);
            DT[dvb + 8][tb] = bt * (VL[tb][dvb + 8] - gm * a1);
        }
        __syncthreads();

        // ---- P2: delta = T * RHS
        {
            float d0 = 0.f, d1 = 0.f;
#pragma unroll 4
            for (int s = 0; s < 64; s += 4) {
                float4 t4 = *(const float4*)&TL[tb][s];
                float4 e0 = *(const float4*)&DT[dvb][s];
                float4 e1 = *(const float4*)&DT[dvb + 8][s];
                d0 += dot4(t4, e0);
                d1 += dot4(t4, e1);
            }
            DT2[dvb][tb] = d0;
            DT2[dvb + 8][tb] = d1;
        }
        __syncthreads();

        // ---- P3: O = 0.125*gam_t*(q_t.S) + M delta
        {
            float p0 = 0.f, p1 = 0.f, m0 = 0.f, m1 = 0.f;
#pragma unroll 4
            for (int dk = 0; dk < 64; dk += 4) {
                float4 q4 = *(const float4*)&qL[tb][dk];
                float4 s0 = *(const float4*)&ST[dvb][dk];
                float4 s1 = *(const float4*)&ST[dvb + 8][dk];
                p0 += dot4(q4, s0);
                p1 += dot4(q4, s1);
            }
#pragma unroll 4
            for (int s = 0; s < 64; s += 4) {
                float4 m4 = *(const float4*)&ML[tb][s];
                float4 e0 = *(const float4*)&DT2[dvb][s];
                float4 e1 = *(const float4*)&DT2[dvb + 8][s];
                m0 += dot4(m4, e0);
                m1 += dot4(m4, e1);
            }
            float f = 0.125f * gamL[tb];
            OL[tb][dvb] = f * p0 + m0;
            OL[tb][dvb + 8] = f * p1 + m1;
        }
        __syncthreads();

        // ---- O write (in place over v) + P4: S update (disjoint threads ok)
        if (tid < 256) {
            int r = tid >> 2, j4 = (tid & 3) << 2;
            *(float4*)&vo[v0 + (size_t)(ch * CC + r) * VDIMc + j4] =
                *(const float4*)&OL[r][j4];
        }
        {
            const float ge = gamL[63];
            float s0 = ge * ST[dvb][tb];
            float s1 = ge * ST[dvb + 8][tb];
#pragma unroll 4
            for (int s = 0; s < 64; s += 4) {
                float4 k4 = *(const float4*)&kT[tb][s];
                float4 eg4 = *(const float4*)&egL[s];
                float4 e0 = *(const float4*)&DT2[dvb][s];
                float4 e1 = *(const float4*)&DT2[dvb + 8][s];
                s0 += k4.x * (eg4.x * e0.x) + k4.y * (eg4.y * e0.y) +
                      k4.z * (eg4.z * e0.z) + k4.w * (eg4.w * e0.w);
                s1 += k4.x * (eg4.x * e1.x) + k4.y * (eg4.y * e1.y) +
                      k4.z * (eg4.z * e1.z) + k4.w * (eg4.w * e1.w);
            }
            ST[dvb][tb] = s0;
            ST[dvb + 8][tb] = s1;
        }
    }
#undef LOADREGS
}

// ---------------------------------------------------------------------------
// Gated RMSNorm -> bf16 output buffer (for the MFMA output GEMM).
// ---------------------------------------------------------------------------
__global__ void __launch_bounds__(256) rms_gate_bf16(
    const float* __restrict__ o, const float* __restrict__ gg,
    const float* __restrict__ norm_w, unsigned short* __restrict__ out) {
    const int row = blockIdx.x * 4 + (threadIdx.x >> 6);
    const int lane = threadIdx.x & 63;
    const size_t base = (size_t)row * DVc;
    float2 ov = *(const float2*)&o[base + lane * 2];
    float ss = ov.x * ov.x + ov.y * ov.y;
#pragma unroll
    for (int m = 1; m < 64; m <<= 1) ss += __shfl_xor(ss, m, 64);
    const float f = rsqrtf(ss * (1.f / 128.f) + 1e-5f);
    float2 gv = *(const float2*)&gg[base + lane * 2];
    const float nw0 = norm_w[lane * 2], nw1 = norm_w[lane * 2 + 1];
    float y0 = ov.x * f * nw0 * siluf(gv.x);
    float y1 = ov.y * f * nw1 * siluf(gv.y);
    unsigned int packed = (unsigned)f2bf(y0) | ((unsigned)f2bf(y1) << 16);
    *(unsigned int*)&out[base + lane * 2] = packed;
}

// ---------------------------------------------------------------------------
// Workspace layout identical to R7 (235.9 MB, proven).
// ---------------------------------------------------------------------------
extern "C" void kernel_launch(void* const* d_in, const int* in_sizes, int n_in,
                              void* d_out, int out_size, void* d_ws,
                              size_t ws_size, hipStream_t stream) {
    const float* x = (const float*)d_in[0];
    const float* w_q = (const float*)d_in[1];
    const float* w_k = (const float*)d_in[2];
    const float* w_v = (const float*)d_in[3];
    const float* w_a = (const float*)d_in[4];
    const float* w_b = (const float*)d_in[5];
    const float* w_g = (const float*)d_in[6];
    const float* w_out = (const float*)d_in[7];
    const float* A_log = (const float*)d_in[8];
    const float* dt_bias = (const float*)d_in[9];
    const float* conv_q = (const float*)d_in[10];
    const float* conv_k = (const float*)d_in[11];
    const float* conv_v = (const float*)d_in[12];
    const float* norm_w = (const float*)d_in[13];

    float* ws = (float*)d_ws;
    const size_t M = Mrows;
    float* qb = ws;
    float* kb = qb + M * KDIMc;
    float* vb = kb + M * KDIMc;
    float* tm = vb + M * VDIMc;          // T (8.4M) + M (8.4M)
    float* gbuf = tm + M * VDIMc;
    float* bbuf = gbuf + M * Hc;
    float* xtra = bbuf + M * Hc;
    float* tmT = tm;
    float* tmM = tm + (size_t)Bc * Hc * NCH * 4096;
    float* halo = tm;                     // alias: dead before tm_precompute
    unsigned short* obb = (unsigned short*)tm;  // alias: after scan, tm dead
    float* gg = qb;                       // alias: after scan

    unsigned short* xb = (unsigned short*)xtra;
    unsigned short* wqT = xb + M * KDIMc;
    unsigned short* wkT = wqT + (size_t)KDIMc * Dc;
    unsigned short* wvT = wkT + (size_t)KDIMc * Dc;
    unsigned short* wgT = wvT + (size_t)VDIMc * Dc;
    unsigned short* woT = wgT + (size_t)VDIMc * Dc;

    // 0) conversions
    convert_bf16<<<dim3(M * Dc / 4 / 256), 256, 0, stream>>>(x, xb, M * Dc / 4);
    transp_bf16<<<dim3((KDIMc / 32) * (Dc / 32)), 256, 0, stream>>>(w_q, wqT,
                                                                    Dc, KDIMc);
    transp_bf16<<<dim3((KDIMc / 32) * (Dc / 32)), 256, 0, stream>>>(w_k, wkT,
                                                                    Dc, KDIMc);
    transp_bf16<<<dim3((VDIMc / 32) * (Dc / 32)), 256, 0, stream>>>(w_v, wvT,
                                                                    Dc, VDIMc);
    transp_bf16<<<dim3((VDIMc / 32) * (Dc / 32)), 256, 0, stream>>>(w_g, wgT,
                                                                    Dc, VDIMc);
    transp_bf16<<<dim3((Dc / 32) * (VDIMc / 32)), 256, 0, stream>>>(
        w_out, woT, VDIMc, Dc);

    // 1) q/k/v projections (bf16 MFMA)
    gemm_bf16<<<dim3((M / 128) * (KDIMc / 128)), 256, 0, stream>>>(
        xb, wqT, qb, M, KDIMc, Dc);
    gemm_bf16<<<dim3((M / 128) * (KDIMc / 128)), 256, 0, stream>>>(
        xb, wkT, kb, M, KDIMc, Dc);
    gemm_bf16<<<dim3((M / 128) * (VDIMc / 128)), 256, 0, stream>>>(
        xb, wvT, vb, M, VDIMc, Dc);

    // 2) a/b projections fused with activation -> g, beta
    ab_proj<<<dim3(M / 4), 256, 0, stream>>>(x, w_a, w_b, A_log, dt_bias, gbuf,
                                             bbuf);

    // 3) conv + silu (+ l2norm for q,k), in place with halo save
    {
        const int nqk = Bc * (Tc / 64 - 1) * 3 * KDIMc;
        const int nv = Bc * (Tc / 64 - 1) * 3 * VDIMc;
        save_halo<KDIMc><<<dim3((nqk + 255) / 256), 256, 0, stream>>>(qb, halo);
        conv_silu_inplace<KDIMc, true>
            <<<dim3(Bc * (Tc / 64) * (KDIMc / 256)), 256, 0, stream>>>(
                qb, conv_q, halo);
        save_halo<KDIMc><<<dim3((nqk + 255) / 256), 256, 0, stream>>>(kb, halo);
        conv_silu_inplace<KDIMc, true>
            <<<dim3(Bc * (Tc / 64) * (KDIMc / 256)), 256, 0, stream>>>(
                kb, conv_k, halo);
        save_halo<VDIMc><<<dim3((nv + 255) / 256), 256, 0, stream>>>(vb, halo);
        conv_silu_inplace<VDIMc, false>
            <<<dim3(Bc * (Tc / 64) * (VDIMc / 256)), 256, 0, stream>>>(
                vb, conv_v, halo);
    }

    // 4a) parallel precompute of T=(I+A)^{-1} and M per (b,h,chunk)
    tm_precompute<<<dim3(Bc * Hc * NCH), 256, 0, stream>>>(kb, qb, gbuf, bbuf,
                                                           tmT, tmM);
    // 4b) sequential scan v2 (512 thr, wave-blocked, prefetch)
    delta_scan<<<dim3(Bc * Hc * 8), 512, 0, stream>>>(kb, qb, vb, gbuf, bbuf,
                                                      tmT, tmM);

    // 5) gate projection (bf16 MFMA; gg aliases qb+kb)
    gemm_bf16<<<dim3((M / 128) * (VDIMc / 128)), 256, 0, stream>>>(
        xb, wgT, gg, M, VDIMc, Dc);

    // 6) gated RMSNorm -> bf16 obb (aliases tm)
    rms_gate_bf16<<<dim3(M * Hc / 4), 256, 0, stream>>>(vb, gg, norm_w, obb);

    // 7) output projection (bf16 MFMA) -> d_out
    gemm_bf16<<<dim3((M / 128) * (Dc / 128)), 256, 0, stream>>>(
        obb, woT, (float*)d_out, M, Dc, VDIMc);
}

// Round 9
// 877.717 us; speedup vs baseline: 25.3453x; 1.2939x over previous
//
#include <hip/hip_runtime.h>
#include <hip/hip_bf16.h>
#include <math.h>

// Problem constants
#define Bc 2
#define Tc 4096
#define Dc 1024
#define Hc 16
#define DKc 64
#define DVc 128
#define KDIMc 1024   // H*DK
#define VDIMc 2048   // H*DV
#define Mrows (Bc*Tc) // 8192
#define CC 64        // scan chunk size
#define NCH (Tc/CC)  // 64 chunks

typedef short short8 __attribute__((ext_vector_type(8)));
typedef float f32x4 __attribute__((ext_vector_type(4)));

__device__ __forceinline__ float siluf(float x) {
    return x / (1.f + expf(-x));
}
__device__ __forceinline__ float dot4(float4 a, float4 b) {
    return a.x * b.x + a.y * b.y + a.z * b.z + a.w * b.w;
}
__device__ __forceinline__ unsigned short f2bf(float f) {
    unsigned int u = __float_as_uint(f);
    unsigned int r = (u + 0x7fffu + ((u >> 16) & 1u)) >> 16;
    return (unsigned short)r;
}
__device__ __forceinline__ unsigned int pk2(float a, float b) {
    return (unsigned)f2bf(a) | ((unsigned)f2bf(b) << 16);
}

// ---------------------------------------------------------------------------
// x (f32) -> bf16, straight elementwise. 4 elems/thread.
// ---------------------------------------------------------------------------
__global__ void __launch_bounds__(256) convert_bf16(
    const float* __restrict__ in, unsigned short* __restrict__ out, int n4) {
    int g = blockIdx.x * 256 + threadIdx.x;
    if (g >= n4) return;
    float4 v = *(const float4*)&in[(size_t)g * 4];
    *(uint2*)&out[(size_t)g * 4] = make_uint2(pk2(v.x, v.y), pk2(v.z, v.w));
}

// ---------------------------------------------------------------------------
// Transpose + convert: in f32 [K][N] -> out bf16 [N][K]. 32x32 LDS tiles.
// ---------------------------------------------------------------------------
__global__ void __launch_bounds__(256) transp_bf16(
    const float* __restrict__ in, unsigned short* __restrict__ out, int K,
    int N) {
    __shared__ float t[32][33];
    const int nbx = N >> 5;
    const int n0 = (blockIdx.x % nbx) << 5;
    const int k0 = (blockIdx.x / nbx) << 5;
    const int c = threadIdx.x & 31, r4 = (threadIdx.x >> 5) << 2;
#pragma unroll
    for (int i = 0; i < 4; i++)
        t[r4 + i][c] = in[(size_t)(k0 + r4 + i) * N + n0 + c];
    __syncthreads();
#pragma unroll
    for (int i = 0; i < 4; i++)
        out[(size_t)(n0 + r4 + i) * K + k0 + c] = f2bf(t[c][r4 + i]);
}

// ---------------------------------------------------------------------------
// bf16 MFMA GEMM: C[M,N] f32 = A[M,K] bf16 (row-major) @ Bt[N,K] bf16.
// ---------------------------------------------------------------------------
__global__ void __launch_bounds__(256) gemm_bf16(
    const unsigned short* __restrict__ A, const unsigned short* __restrict__ Bt,
    float* __restrict__ C, int M, int N, int K) {
    __shared__ short As[128][40];
    __shared__ short Bs[128][40];
    const int tid = threadIdx.x;
    const int nbx = N >> 7;
    const int bx = blockIdx.x % nbx, by = blockIdx.x / nbx;
    const int m0 = by << 7, n0 = bx << 7;
    const int w = tid >> 6, lane = tid & 63;
    const int wr = (w >> 1) << 6, wc = (w & 1) << 6;
    const int fr = lane & 15, fk = (lane >> 4) << 3;
    const int srow = tid >> 1, skb = (tid & 1) << 4;

    f32x4 acc[4][4];
#pragma unroll
    for (int i = 0; i < 4; i++)
#pragma unroll
        for (int j = 0; j < 4; j++)
            acc[i][j] = (f32x4){0.f, 0.f, 0.f, 0.f};

    const int nkt = K >> 5;
    for (int kt = 0; kt < nkt; kt++) {
        __syncthreads();
        {
            const unsigned short* ap = &A[(size_t)(m0 + srow) * K + (kt << 5) + skb];
            const unsigned short* bp = &Bt[(size_t)(n0 + srow) * K + (kt << 5) + skb];
            *(short8*)&As[srow][skb] = *(const short8*)&ap[0];
            *(short8*)&As[srow][skb + 8] = *(const short8*)&ap[8];
            *(short8*)&Bs[srow][skb] = *(const short8*)&bp[0];
            *(short8*)&Bs[srow][skb + 8] = *(const short8*)&bp[8];
        }
        __syncthreads();
        short8 af[4], bfr[4];
#pragma unroll
        for (int i = 0; i < 4; i++)
            af[i] = *(const short8*)&As[wr + i * 16 + fr][fk];
#pragma unroll
        for (int j = 0; j < 4; j++)
            bfr[j] = *(const short8*)&Bs[wc + j * 16 + fr][fk];
#pragma unroll
        for (int i = 0; i < 4; i++)
#pragma unroll
            for (int j = 0; j < 4; j++)
                acc[i][j] = __builtin_amdgcn_mfma_f32_16x16x32_bf16(
                    af[i], bfr[j], acc[i][j], 0, 0, 0);
    }
    const int cr = (lane >> 4) << 2;
#pragma unroll
    for (int i = 0; i < 4; i++)
#pragma unroll
        for (int j = 0; j < 4; j++) {
#pragma unroll
            for (int r = 0; r < 4; r++) {
                C[(size_t)(m0 + wr + i * 16 + cr + r) * N + n0 + wc + j * 16 +
                  fr] = acc[i][j][r];
            }
        }
}

// ---------------------------------------------------------------------------
// a/b projections (N=16 each) fused with softplus/sigmoid -> g, beta.
// ---------------------------------------------------------------------------
__global__ void __launch_bounds__(256) ab_proj(
    const float* __restrict__ x, const float* __restrict__ w_a,
    const float* __restrict__ w_b, const float* __restrict__ A_log,
    const float* __restrict__ dt_bias, float* __restrict__ g_out,
    float* __restrict__ beta_out) {
    const int row = blockIdx.x * 4 + (threadIdx.x >> 6);
    const int lane = threadIdx.x & 63;
    const int h = lane >> 2;
    const int kg = lane & 3;
    const float* xr = x + (size_t)row * Dc;
    float pa = 0.f, pb = 0.f;
    const int kbeg = kg * 256, kend = kbeg + 256;
    for (int k = kbeg; k < kend; k++) {
        float xv = xr[k];
        pa += xv * w_a[k * Hc + h];
        pb += xv * w_b[k * Hc + h];
    }
    pa += __shfl_xor(pa, 1, 64);
    pa += __shfl_xor(pa, 2, 64);
    pb += __shfl_xor(pb, 1, 64);
    pb += __shfl_xor(pb, 2, 64);
    if (kg == 0) {
        float arg = pa + dt_bias[h];
        float sp = fmaxf(arg, 0.f) + log1pf(expf(-fabsf(arg)));
        g_out[(size_t)row * Hc + h] = -expf(A_log[h]) * sp;
        beta_out[(size_t)row * Hc + h] = 2.f / (1.f + expf(-pb));
    }
}

// ---------------------------------------------------------------------------
// Save 3-row halos at 64-step chunk boundaries (for in-place conv).
// ---------------------------------------------------------------------------
template <int C>
__global__ void __launch_bounds__(256) save_halo(
    const float* __restrict__ in, float* __restrict__ halo) {
    const int g = blockIdx.x * 256 + threadIdx.x;
    const int total = Bc * (Tc / 64 - 1) * 3 * C;
    if (g >= total) return;
    const int c = g % C;
    int r = g / C;
    const int j = r % 3;
    r /= 3;
    const int chunk = r % (Tc / 64 - 1) + 1;
    const int b = r / (Tc / 64 - 1);
    halo[((size_t)(b * 64 + chunk) * 3 + j) * C + c] =
        in[((size_t)b * Tc + chunk * 64 - 3 + j) * C + c];
}

// ---------------------------------------------------------------------------
// Depthwise causal conv1d (K=4) + SiLU (+ optional l2norm), IN PLACE.
// ---------------------------------------------------------------------------
template <int C, bool L2N>
__global__ void __launch_bounds__(256) conv_silu_inplace(
    float* __restrict__ buf, const float* __restrict__ w,
    const float* __restrict__ halo) {
    constexpr int CB = C / 256;
    const int bidx = blockIdx.x;
    const int cb = bidx % CB;
    const int tchunk = (bidx / CB) % (Tc / 64);
    const int b = bidx / (CB * (Tc / 64));
    const int c = cb * 256 + threadIdx.x;
    const int t0 = tchunk * 64;
    const float w0 = w[c * 4 + 0], w1 = w[c * 4 + 1], w2 = w[c * 4 + 2],
                w3 = w[c * 4 + 3];
    float xm3 = 0.f, xm2 = 0.f, xm1 = 0.f;
    if (tchunk > 0) {
        const float* hp = halo + (size_t)(b * 64 + tchunk) * 3 * C + c;
        xm3 = hp[0];
        xm2 = hp[C];
        xm1 = hp[2 * C];
    }
    float* p = buf + (size_t)b * Tc * C + c;
#pragma unroll 4
    for (int i = 0; i < 64; i++) {
        float xt = p[(size_t)(t0 + i) * C];
        float y = w0 * xm3 + w1 * xm2 + w2 * xm1 + w3 * xt;
        y = siluf(y);
        if (L2N) {
            float ss = y * y;
#pragma unroll
            for (int m = 1; m < 64; m <<= 1) ss += __shfl_xor(ss, m, 64);
            y *= rsqrtf(ss + 1e-6f);
        }
        p[(size_t)(t0 + i) * C] = y;
        xm3 = xm2;
        xm2 = xm1;
        xm1 = xt;
    }
}

// ---------------------------------------------------------------------------
// TM precompute: per (b,h,chunk) tile: A (LDS), M -> tmM (row-major [t][s]),
// T=(I+A)^{-1} -> tmT (NOW row-major [t][s] for direct bf16 staging).
// ---------------------------------------------------------------------------
__global__ void __launch_bounds__(256) tm_precompute(
    const float* __restrict__ kc, const float* __restrict__ qc,
    const float* __restrict__ g, const float* __restrict__ beta,
    float* __restrict__ tmT, float* __restrict__ tmM) {
    const int bid = blockIdx.x;
    const int ch = bid & (NCH - 1);
    const int bh = bid >> 6;
    const int b = bh >> 4, h = bh & 15;
    const int tid = threadIdx.x;
    const int t0 = ch * CC;

    __shared__ __align__(16) float kL[CC][DKc + 4];
    __shared__ __align__(16) float qL[CC][DKc + 4];
    __shared__ __align__(16) float AtL[CC][DKc + 4];  // A^T: AtL[s][t]
    __shared__ float cL[CC], betaL[CC];

    const size_t qk0 = (size_t)b * Tc * KDIMc + h * DKc;
    const size_t gb0 = (size_t)b * Tc * Hc + h;
    const size_t tile = (size_t)(bh * NCH + ch) * 4096;

#pragma unroll
    for (int i = 0; i < 4; i++) {
        int e = tid + i * 256;
        int r = e >> 4, c4 = (e & 15) << 2;
        *(float4*)&kL[r][c4] =
            *(const float4*)&kc[qk0 + (size_t)(t0 + r) * KDIMc + c4];
        *(float4*)&qL[r][c4] =
            *(const float4*)&qc[qk0 + (size_t)(t0 + r) * KDIMc + c4];
    }
    if (tid < 64) {
        float gv = g[gb0 + (size_t)(t0 + tid) * Hc];
        float cv = gv;
#pragma unroll
        for (int d = 1; d < 64; d <<= 1) {
            float nb = __shfl_up(cv, d, 64);
            if (tid >= d) cv += nb;
        }
        cL[tid] = cv;
        betaL[tid] = beta[gb0 + (size_t)(t0 + tid) * Hc];
    }
    __syncthreads();

    {
        const int tIdx = tid >> 4, sIdx = tid & 15;
        float dka[4][4], dqa[4][4];
#pragma unroll
        for (int i = 0; i < 4; i++)
#pragma unroll
            for (int j = 0; j < 4; j++) { dka[i][j] = 0.f; dqa[i][j] = 0.f; }
#pragma unroll 4
        for (int d = 0; d < 64; d += 4) {
            float4 kb[4], qb_[4], sb[4];
#pragma unroll
            for (int i = 0; i < 4; i++) {
                kb[i] = *(const float4*)&kL[tIdx * 4 + i][d];
                qb_[i] = *(const float4*)&qL[tIdx * 4 + i][d];
                sb[i] = *(const float4*)&kL[sIdx * 4 + i][d];
            }
#pragma unroll
            for (int i = 0; i < 4; i++)
#pragma unroll
                for (int j = 0; j < 4; j++) {
                    dka[i][j] += dot4(kb[i], sb[j]);
                    dqa[i][j] += dot4(qb_[i], sb[j]);
                }
        }
#pragma unroll
        for (int i = 0; i < 4; i++) {
            float mrow[4];
#pragma unroll
            for (int j = 0; j < 4; j++) {
                int t = tIdx * 4 + i, s = sIdx * 4 + j;
                float E = expf(cL[t] - cL[s]);
                AtL[s][t] = (s < t) ? betaL[t] * E * dka[i][j] : 0.f;
                mrow[j] = (s <= t) ? 0.125f * E * dqa[i][j] : 0.f;
            }
            *(float4*)&tmM[tile + (size_t)(tIdx * 4 + i) * 64 + sIdx * 4] =
                make_float4(mrow[0], mrow[1], mrow[2], mrow[3]);
        }
    }
    __syncthreads();

    {
        const int w = tid >> 6, lane = tid & 63;
        float acc[16];
#pragma unroll
        for (int di = 0; di < 16; di++)
            acc[di] = (lane == w * 16 + di) ? 1.f : 0.f;
#pragma unroll 4
        for (int s = 0; s < 64; s++) {
            float a = AtL[s][lane];
#pragma unroll
            for (int di = 0; di < 16; di++) {
                float ds = __shfl(acc[di], s, 64);
                acc[di] -= a * ds;
            }
        }
        // store T ROW-major: row = lane, cols w*16..w*16+15 (4 x float4)
#pragma unroll
        for (int p = 0; p < 4; p++) {
            float4 v4 = make_float4(acc[p * 4 + 0], acc[p * 4 + 1],
                                    acc[p * 4 + 2], acc[p * 4 + 3]);
            *(float4*)&tmT[tile + (size_t)lane * 64 + w * 16 + p * 4] = v4;
        }
    }
}

// ---------------------------------------------------------------------------
// Sequential chunk scan v3: MFMA (bf16 operands, f32 accum) for the KS/QS
// readouts, T*RHS solve and M*delta; S master update stays f32 (R8's P4).
// 512 thr, 8 waves; waves 0-3 own KS/delta, waves 4-7 own QS/O.
// Grid 256, XCD-swizzled; register prefetch of chunk ch+1.
// ---------------------------------------------------------------------------
__global__ void __launch_bounds__(512, 2) delta_scan(
    const float* __restrict__ kc, const float* __restrict__ qc,
    float* vo, const float* __restrict__ g, const float* __restrict__ beta,
    const float* __restrict__ tmT, const float* __restrict__ tmM) {
    const int bid = blockIdx.x;
    const int sl = bid >> 5;   // 0..7
    const int bh = bid & 31;   // 0..31 -> XCD = bh%8
    const int b = bh >> 4, h = bh & 15;
    const int tid = threadIdx.x;

    // f32 state + P4 operands
    __shared__ __align__(16) float kT[DKc][CC + 4];   // k^T for P4
    __shared__ __align__(16) float ST[16][DKc + 4];   // S^T master (f32)
    __shared__ __align__(16) float DT2[16][CC + 4];   // delta^T f32 (P4)
    __shared__ __align__(16) float VL[CC][20];
    __shared__ __align__(16) float OL[CC][20];
    __shared__ float gamL[CC], egL[CC], betaL[CC];
    // bf16 MFMA operands (row stride 72 shorts = 144B, 16B-aligned rows)
    __shared__ __align__(16) unsigned short kb16[CC][72];
    __shared__ __align__(16) unsigned short qb16[CC][72];
    __shared__ __align__(16) unsigned short Tb16[CC][72];
    __shared__ __align__(16) unsigned short Mb16[CC][72];
    __shared__ __align__(16) unsigned short STb16[16][72];
    __shared__ __align__(16) unsigned short DTb16[16][72];   // RHS bf16
    __shared__ __align__(16) unsigned short D2b16[16][72];   // delta bf16

    const size_t qk0 = (size_t)b * Tc * KDIMc + h * DKc;
    const size_t v0 = (size_t)b * Tc * VDIMc + h * DVc + sl * 16;
    const size_t gb0 = (size_t)b * Tc * Hc + h;
    const size_t tb0 = (size_t)(bh * NCH) * 4096;

    for (int i = tid; i < 16 * (DKc + 4); i += 512) ((float*)ST)[i] = 0.f;
    for (int i = tid; i < 16 * 72; i += 512) ((unsigned short*)STb16)[i] = 0;

    // staging coords
    const int r0 = tid >> 4, c40 = (tid & 15) << 2;
    const int r1 = r0 + 32;
    // MFMA frag coords (proven gemm_bf16 mapping)
    const int wid = tid >> 6, lane = tid & 63;
    const int fr = lane & 15;
    const int fk8 = (lane >> 4) << 3;
    const int rr = (lane >> 4) << 2;
    // P4 coords (R8)
    const int tb = (wid << 3) | (lane >> 3);
    const int dvb = lane & 7;

    float4 kv0, kv1, qv0, qv1, tv0, tv1, mv0, mv1, vv0;
    float gvr = 0.f, bvr = 0.f;

#define LOADREGS(CH)                                                          \
    {                                                                         \
        const size_t tK = qk0 + (size_t)(CH) * CC * KDIMc;                    \
        const size_t tile_ = tb0 + (size_t)(CH) * 4096;                       \
        kv0 = *(const float4*)&kc[tK + (size_t)r0 * KDIMc + c40];             \
        kv1 = *(const float4*)&kc[tK + (size_t)r1 * KDIMc + c40];             \
        qv0 = *(const float4*)&qc[tK + (size_t)r0 * KDIMc + c40];             \
        qv1 = *(const float4*)&qc[tK + (size_t)r1 * KDIMc + c40];             \
        tv0 = *(const float4*)&tmT[tile_ + (size_t)tid * 4];                  \
        tv1 = *(const float4*)&tmT[tile_ + (size_t)(tid + 512) * 4];          \
        mv0 = *(const float4*)&tmM[tile_ + (size_t)tid * 4];                  \
        mv1 = *(const float4*)&tmM[tile_ + (size_t)(tid + 512) * 4];          \
        if (tid < 256)                                                        \
            vv0 = *(const float4*)&vo[v0 +                                    \
                                      (size_t)((CH) * CC + (tid >> 2)) *     \
                                          VDIMc +                             \
                                      ((tid & 3) << 2)];                      \
        if (tid < 64) {                                                       \
            gvr = g[gb0 + (size_t)((CH) * CC + tid) * Hc];                    \
            bvr = beta[gb0 + (size_t)((CH) * CC + tid) * Hc];                 \
        }                                                                     \
    }

    LOADREGS(0);

#pragma unroll 1
    for (int ch = 0; ch < NCH; ch++) {
        __syncthreads();  // B0: prev chunk fully done (incl. P4 S writes)

        // ---- stage regs -> LDS (bf16 packed; kT f32 scatter; V; decay)
        {
            *(uint2*)&kb16[r0][c40] = make_uint2(pk2(kv0.x, kv0.y), pk2(kv0.z, kv0.w));
            *(uint2*)&kb16[r1][c40] = make_uint2(pk2(kv1.x, kv1.y), pk2(kv1.z, kv1.w));
            *(uint2*)&qb16[r0][c40] = make_uint2(pk2(qv0.x, qv0.y), pk2(qv0.z, qv0.w));
            *(uint2*)&qb16[r1][c40] = make_uint2(pk2(qv1.x, qv1.y), pk2(qv1.z, qv1.w));
            *(uint2*)&Tb16[r0][c40] = make_uint2(pk2(tv0.x, tv0.y), pk2(tv0.z, tv0.w));
            *(uint2*)&Tb16[r1][c40] = make_uint2(pk2(tv1.x, tv1.y), pk2(tv1.z, tv1.w));
            *(uint2*)&Mb16[r0][c40] = make_uint2(pk2(mv0.x, mv0.y), pk2(mv0.z, mv0.w));
            *(uint2*)&Mb16[r1][c40] = make_uint2(pk2(mv1.x, mv1.y), pk2(mv1.z, mv1.w));
            float* kp0 = (float*)&kv0;
            float* kp1 = (float*)&kv1;
#pragma unroll
            for (int i = 0; i < 4; i++) {
                kT[c40 + i][r0] = kp0[i];
                kT[c40 + i][r1] = kp1[i];
            }
            if (tid < 256) *(float4*)&VL[tid >> 2][(tid & 3) << 2] = vv0;
            if (tid < 64) {
                float cv = gvr;
#pragma unroll
                for (int d = 1; d < 64; d <<= 1) {
                    float nb = __shfl_up(cv, d, 64);
                    if (tid >= d) cv += nb;
                }
                gamL[tid] = expf(cv);
                float cend = __shfl(cv, 63, 64);
                egL[tid] = expf(cend - cv);
                betaL[tid] = bvr;
            }
        }
        if (ch + 1 < NCH) LOADREGS(ch + 1);
        __syncthreads();  // B1: stage visible

        // ---- phase 1: KS (waves 0-3) and QS (waves 4-7) via MFMA
        f32x4 acc1 = (f32x4){0.f, 0.f, 0.f, 0.f};
        {
            short8 bs0 = *(const short8*)&STb16[fr][fk8];
            short8 bs1 = *(const short8*)&STb16[fr][fk8 + 32];
            if (wid < 4) {
                const int m0 = wid << 4;
                short8 a0 = *(const short8*)&kb16[m0 + fr][fk8];
                short8 a1 = *(const short8*)&kb16[m0 + fr][fk8 + 32];
                acc1 = __builtin_amdgcn_mfma_f32_16x16x32_bf16(a0, bs0, acc1, 0, 0, 0);
                acc1 = __builtin_amdgcn_mfma_f32_16x16x32_bf16(a1, bs1, acc1, 0, 0, 0);
                // RHS = beta*(V - gam*KS) -> bf16
#pragma unroll
                for (int r = 0; r < 4; r++) {
                    int t = m0 + rr + r;
                    float rhs = betaL[t] * (VL[t][fr] - gamL[t] * acc1[r]);
                    DTb16[fr][t] = f2bf(rhs);
                }
            } else {
                const int m0 = (wid - 4) << 4;
                short8 a0 = *(const short8*)&qb16[m0 + fr][fk8];
                short8 a1 = *(const short8*)&qb16[m0 + fr][fk8 + 32];
                acc1 = __builtin_amdgcn_mfma_f32_16x16x32_bf16(a0, bs0, acc1, 0, 0, 0);
                acc1 = __builtin_amdgcn_mfma_f32_16x16x32_bf16(a1, bs1, acc1, 0, 0, 0);
                // pre-scale QS by 0.125*gam (becomes C-operand of M*delta)
#pragma unroll
                for (int r = 0; r < 4; r++) {
                    int t = m0 + rr + r;
                    acc1[r] *= 0.125f * gamL[t];
                }
            }
        }
        __syncthreads();  // B2: RHS ready

        // ---- phase 2: delta = T * RHS (waves 0-3); keep f32 + bf16 copies
        if (wid < 4) {
            const int m0 = wid << 4;
            short8 a0 = *(const short8*)&Tb16[m0 + fr][fk8];
            short8 a1 = *(const short8*)&Tb16[m0 + fr][fk8 + 32];
            short8 b0 = *(const short8*)&DTb16[fr][fk8];
            short8 b1 = *(const short8*)&DTb16[fr][fk8 + 32];
            f32x4 d = (f32x4){0.f, 0.f, 0.f, 0.f};
            d = __builtin_amdgcn_mfma_f32_16x16x32_bf16(a0, b0, d, 0, 0, 0);
            d = __builtin_amdgcn_mfma_f32_16x16x32_bf16(a1, b1, d, 0, 0, 0);
#pragma unroll
            for (int r = 0; r < 4; r++) {
                int t = m0 + rr + r;
                DT2[fr][t] = d[r];
                D2b16[fr][t] = f2bf(d[r]);
            }
        }
        __syncthreads();  // B3: delta ready

        // ---- phase 3: O = M*delta + scaledQS (waves 4-7)
        if (wid >= 4) {
            const int m0 = (wid - 4) << 4;
            short8 a0 = *(const short8*)&Mb16[m0 + fr][fk8];
            short8 a1 = *(const short8*)&Mb16[m0 + fr][fk8 + 32];
            short8 b0 = *(const short8*)&D2b16[fr][fk8];
            short8 b1 = *(const short8*)&D2b16[fr][fk8 + 32];
            f32x4 o = acc1;  // 0.125*gam*QS
            o = __builtin_amdgcn_mfma_f32_16x16x32_bf16(a0, b0, o, 0, 0, 0);
            o = __builtin_amdgcn_mfma_f32_16x16x32_bf16(a1, b1, o, 0, 0, 0);
#pragma unroll
            for (int r = 0; r < 4; r++) OL[m0 + rr + r][fr] = o[r];
        }
        __syncthreads();  // B4: OL ready

        // ---- O global write (tid<256) + P4 f32 S update (all threads)
        if (tid < 256) {
            int r = tid >> 2, j4 = (tid & 3) << 2;
            *(float4*)&vo[v0 + (size_t)(ch * CC + r) * VDIMc + j4] =
                *(const float4*)&OL[r][j4];
        }
        {
            const float ge = gamL[63];
            float s0 = ge * ST[dvb][tb];
            float s1 = ge * ST[dvb + 8][tb];
#pragma unroll 4
            for (int s = 0; s < 64; s += 4) {
                float4 k4 = *(const float4*)&kT[tb][s];
                float4 eg4 = *(const float4*)&egL[s];
                float4 e0 = *(const float4*)&DT2[dvb][s];
                float4 e1 = *(const float4*)&DT2[dvb + 8][s];
                s0 += k4.x * (eg4.x * e0.x) + k4.y * (eg4.y * e0.y) +
                      k4.z * (eg4.z * e0.z) + k4.w * (eg4.w * e0.w);
                s1 += k4.x * (eg4.x * e1.x) + k4.y * (eg4.y * e1.y) +
                      k4.z * (eg4.z * e1.z) + k4.w * (eg4.w * e1.w);
            }
            ST[dvb][tb] = s0;
            ST[dvb + 8][tb] = s1;
            STb16[dvb][tb] = f2bf(s0);
            STb16[dvb + 8][tb] = f2bf(s1);
        }
    }
#undef LOADREGS
}

// ---------------------------------------------------------------------------
// Gated RMSNorm -> bf16 output buffer (for the MFMA output GEMM).
// ---------------------------------------------------------------------------
__global__ void __launch_bounds__(256) rms_gate_bf16(
    const float* __restrict__ o, const float* __restrict__ gg,
    const float* __restrict__ norm_w, unsigned short* __restrict__ out) {
    const int row = blockIdx.x * 4 + (threadIdx.x >> 6);
    const int lane = threadIdx.x & 63;
    const size_t base = (size_t)row * DVc;
    float2 ov = *(const float2*)&o[base + lane * 2];
    float ss = ov.x * ov.x + ov.y * ov.y;
#pragma unroll
    for (int m = 1; m < 64; m <<= 1) ss += __shfl_xor(ss, m, 64);
    const float f = rsqrtf(ss * (1.f / 128.f) + 1e-5f);
    float2 gv = *(const float2*)&gg[base + lane * 2];
    const float nw0 = norm_w[lane * 2], nw1 = norm_w[lane * 2 + 1];
    float y0 = ov.x * f * nw0 * siluf(gv.x);
    float y1 = ov.y * f * nw1 * siluf(gv.y);
    *(unsigned int*)&out[base + lane * 2] = pk2(y0, y1);
}

// ---------------------------------------------------------------------------
// Workspace layout identical to R7/R8 (235.9 MB, proven).
// ---------------------------------------------------------------------------
extern "C" void kernel_launch(void* const* d_in, const int* in_sizes, int n_in,
                              void* d_out, int out_size, void* d_ws,
                              size_t ws_size, hipStream_t stream) {
    const float* x = (const float*)d_in[0];
    const float* w_q = (const float*)d_in[1];
    const float* w_k = (const float*)d_in[2];
    const float* w_v = (const float*)d_in[3];
    const float* w_a = (const float*)d_in[4];
    const float* w_b = (const float*)d_in[5];
    const float* w_g = (const float*)d_in[6];
    const float* w_out = (const float*)d_in[7];
    const float* A_log = (const float*)d_in[8];
    const float* dt_bias = (const float*)d_in[9];
    const float* conv_q = (const float*)d_in[10];
    const float* conv_k = (const float*)d_in[11];
    const float* conv_v = (const float*)d_in[12];
    const float* norm_w = (const float*)d_in[13];

    float* ws = (float*)d_ws;
    const size_t M = Mrows;
    float* qb = ws;
    float* kb = qb + M * KDIMc;
    float* vb = kb + M * KDIMc;
    float* tm = vb + M * VDIMc;          // T (8.4M) + M (8.4M)
    float* gbuf = tm + M * VDIMc;
    float* bbuf = gbuf + M * Hc;
    float* xtra = bbuf + M * Hc;
    float* tmT = tm;
    float* tmM = tm + (size_t)Bc * Hc * NCH * 4096;
    float* halo = tm;                     // alias: dead before tm_precompute
    unsigned short* obb = (unsigned short*)tm;  // alias: after scan, tm dead
    float* gg = qb;                       // alias: after scan

    unsigned short* xb = (unsigned short*)xtra;
    unsigned short* wqT = xb + M * KDIMc;
    unsigned short* wkT = wqT + (size_t)KDIMc * Dc;
    unsigned short* wvT = wkT + (size_t)KDIMc * Dc;
    unsigned short* wgT = wvT + (size_t)VDIMc * Dc;
    unsigned short* woT = wgT + (size_t)VDIMc * Dc;

    // 0) conversions
    convert_bf16<<<dim3(M * Dc / 4 / 256), 256, 0, stream>>>(x, xb, M * Dc / 4);
    transp_bf16<<<dim3((KDIMc / 32) * (Dc / 32)), 256, 0, stream>>>(w_q, wqT,
                                                                    Dc, KDIMc);
    transp_bf16<<<dim3((KDIMc / 32) * (Dc / 32)), 256, 0, stream>>>(w_k, wkT,
                                                                    Dc, KDIMc);
    transp_bf16<<<dim3((VDIMc / 32) * (Dc / 32)), 256, 0, stream>>>(w_v, wvT,
                                                                    Dc, VDIMc);
    transp_bf16<<<dim3((VDIMc / 32) * (Dc / 32)), 256, 0, stream>>>(w_g, wgT,
                                                                    Dc, VDIMc);
    transp_bf16<<<dim3((Dc / 32) * (VDIMc / 32)), 256, 0, stream>>>(
        w_out, woT, VDIMc, Dc);

    // 1) q/k/v projections (bf16 MFMA)
    gemm_bf16<<<dim3((M / 128) * (KDIMc / 128)), 256, 0, stream>>>(
        xb, wqT, qb, M, KDIMc, Dc);
    gemm_bf16<<<dim3((M / 128) * (KDIMc / 128)), 256, 0, stream>>>(
        xb, wkT, kb, M, KDIMc, Dc);
    gemm_bf16<<<dim3((M / 128) * (VDIMc / 128)), 256, 0, stream>>>(
        xb, wvT, vb, M, VDIMc, Dc);

    // 2) a/b projections fused with activation -> g, beta
    ab_proj<<<dim3(M / 4), 256, 0, stream>>>(x, w_a, w_b, A_log, dt_bias, gbuf,
                                             bbuf);

    // 3) conv + silu (+ l2norm for q,k), in place with halo save
    {
        const int nqk = Bc * (Tc / 64 - 1) * 3 * KDIMc;
        const int nv = Bc * (Tc / 64 - 1) * 3 * VDIMc;
        save_halo<KDIMc><<<dim3((nqk + 255) / 256), 256, 0, stream>>>(qb, halo);
        conv_silu_inplace<KDIMc, true>
            <<<dim3(Bc * (Tc / 64) * (KDIMc / 256)), 256, 0, stream>>>(
                qb, conv_q, halo);
        save_halo<KDIMc><<<dim3((nqk + 255) / 256), 256, 0, stream>>>(kb, halo);
        conv_silu_inplace<KDIMc, true>
            <<<dim3(Bc * (Tc / 64) * (KDIMc / 256)), 256, 0, stream>>>(
                kb, conv_k, halo);
        save_halo<VDIMc><<<dim3((nv + 255) / 256), 256, 0, stream>>>(vb, halo);
        conv_silu_inplace<VDIMc, false>
            <<<dim3(Bc * (Tc / 64) * (VDIMc / 256)), 256, 0, stream>>>(
                vb, conv_v, halo);
    }

    // 4a) parallel precompute of T=(I+A)^{-1} (row-major) and M
    tm_precompute<<<dim3(Bc * Hc * NCH), 256, 0, stream>>>(kb, qb, gbuf, bbuf,
                                                           tmT, tmM);
    // 4b) sequential scan v3 (MFMA readouts/solve, f32 S master)
    delta_scan<<<dim3(Bc * Hc * 8), 512, 0, stream>>>(kb, qb, vb, gbuf, bbuf,
                                                      tmT, tmM);

    // 5) gate projection (bf16 MFMA; gg aliases qb+kb)
    gemm_bf16<<<dim3((M / 128) * (VDIMc / 128)), 256, 0, stream>>>(
        xb, wgT, gg, M, VDIMc, Dc);

    // 6) gated RMSNorm -> bf16 obb (aliases tm)
    rms_gate_bf16<<<dim3(M * Hc / 4), 256, 0, stream>>>(vb, gg, norm_w, obb);

    // 7) output projection (bf16 MFMA) -> d_out
    gemm_bf16<<<dim3((M / 128) * (Dc / 128)), 256, 0, stream>>>(
        obb, woT, (float*)d_out, M, Dc, VDIMc);
}

// Round 10
// 839.829 us; speedup vs baseline: 26.4887x; 1.0451x over previous
//
#include <hip/hip_runtime.h>
#include <hip/hip_bf16.h>
#include <math.h>

// Problem constants
#define Bc 2
#define Tc 4096
#define Dc 1024
#define Hc 16
#define DKc 64
#define DVc 128
#define KDIMc 1024   // H*DK
#define VDIMc 2048   // H*DV
#define Mrows (Bc*Tc) // 8192
#define CC 64        // scan chunk size
#define NCH (Tc/CC)  // 64 chunks

typedef short short8 __attribute__((ext_vector_type(8)));
typedef float f32x4 __attribute__((ext_vector_type(4)));

__device__ __forceinline__ float siluf(float x) {
    return x / (1.f + expf(-x));
}
__device__ __forceinline__ unsigned short f2bf(float f) {
    unsigned int u = __float_as_uint(f);
    unsigned int r = (u + 0x7fffu + ((u >> 16) & 1u)) >> 16;
    return (unsigned short)r;
}
__device__ __forceinline__ unsigned int pk2(float a, float b) {
    return (unsigned)f2bf(a) | ((unsigned)f2bf(b) << 16);
}
// async global->LDS DMA, 16B per lane; lds base must be wave-uniform.
__device__ __forceinline__ void gload16(const unsigned short* g,
                                        unsigned short* l) {
    __builtin_amdgcn_global_load_lds(
        (const __attribute__((address_space(1))) unsigned int*)g,
        (__attribute__((address_space(3))) unsigned int*)l, 16, 0, 0);
}

// ---------------------------------------------------------------------------
// x (f32) -> bf16, straight elementwise. 4 elems/thread.
// ---------------------------------------------------------------------------
__global__ void __launch_bounds__(256) convert_bf16(
    const float* __restrict__ in, unsigned short* __restrict__ out, int n4) {
    int g = blockIdx.x * 256 + threadIdx.x;
    if (g >= n4) return;
    float4 v = *(const float4*)&in[(size_t)g * 4];
    *(uint2*)&out[(size_t)g * 4] = make_uint2(pk2(v.x, v.y), pk2(v.z, v.w));
}

// ---------------------------------------------------------------------------
// Transpose + convert: in f32 [K][N] -> out bf16 [N][K]. 32x32 LDS tiles.
// ---------------------------------------------------------------------------
__global__ void __launch_bounds__(256) transp_bf16(
    const float* __restrict__ in, unsigned short* __restrict__ out, int K,
    int N) {
    __shared__ float t[32][33];
    const int nbx = N >> 5;
    const int n0 = (blockIdx.x % nbx) << 5;
    const int k0 = (blockIdx.x / nbx) << 5;
    const int c = threadIdx.x & 31, r4 = (threadIdx.x >> 5) << 2;
#pragma unroll
    for (int i = 0; i < 4; i++)
        t[r4 + i][c] = in[(size_t)(k0 + r4 + i) * N + n0 + c];
    __syncthreads();
#pragma unroll
    for (int i = 0; i < 4; i++)
        out[(size_t)(n0 + r4 + i) * K + k0 + c] = f2bf(t[c][r4 + i]);
}

// ---------------------------------------------------------------------------
// bf16 MFMA GEMM: C[M,N] f32 = A[M,K] bf16 (row-major) @ Bt[N,K] bf16.
// 128x128 tile, BK=32, 4 waves. Staging via global_load_lds (linear LDS,
// [128][32] shorts; DMA = wave-uniform base + lane*16B).
// ---------------------------------------------------------------------------
__global__ void __launch_bounds__(256) gemm_bf16(
    const unsigned short* __restrict__ A, const unsigned short* __restrict__ Bt,
    float* __restrict__ C, int M, int N, int K) {
    __shared__ unsigned short As[128 * 32];
    __shared__ unsigned short Bs[128 * 32];
    const int tid = threadIdx.x;
    const int nbx = N >> 7;
    const int bx = blockIdx.x % nbx, by = blockIdx.x / nbx;
    const int m0 = by << 7, n0 = bx << 7;
    const int w = tid >> 6, lane = tid & 63;
    const int wr = (w >> 1) << 6, wc = (w & 1) << 6;
    const int fr = lane & 15, fk8 = (lane >> 4) << 3;
    const int grow = lane >> 2;        // 0..15 row within 16-row DMA group
    const int gcol = (lane & 3) << 3;  // 0/8/16/24 shorts

    f32x4 acc[4][4];
#pragma unroll
    for (int i = 0; i < 4; i++)
#pragma unroll
        for (int j = 0; j < 4; j++)
            acc[i][j] = (f32x4){0.f, 0.f, 0.f, 0.f};

    const int nkt = K >> 5;
    for (int kt = 0; kt < nkt; kt++) {
        __syncthreads();  // previous compute done reading LDS
        {
            const size_t kb = (size_t)(kt << 5) + gcol;
#pragma unroll
            for (int r = 0; r < 2; r++) {
                const int rows = r * 64 + w * 16;
                gload16(&A[(size_t)(m0 + rows + grow) * K + kb],
                        &As[rows * 32]);
                gload16(&Bt[(size_t)(n0 + rows + grow) * K + kb],
                        &Bs[rows * 32]);
            }
        }
        __syncthreads();  // DMA landed (compiler drains vmcnt before barrier)
        short8 af[4], bfr[4];
#pragma unroll
        for (int i = 0; i < 4; i++)
            af[i] = *(const short8*)&As[(wr + i * 16 + fr) * 32 + fk8];
#pragma unroll
        for (int j = 0; j < 4; j++)
            bfr[j] = *(const short8*)&Bs[(wc + j * 16 + fr) * 32 + fk8];
#pragma unroll
        for (int i = 0; i < 4; i++)
#pragma unroll
            for (int j = 0; j < 4; j++)
                acc[i][j] = __builtin_amdgcn_mfma_f32_16x16x32_bf16(
                    af[i], bfr[j], acc[i][j], 0, 0, 0);
    }
    const int cr = (lane >> 4) << 2;
#pragma unroll
    for (int i = 0; i < 4; i++)
#pragma unroll
        for (int j = 0; j < 4; j++) {
#pragma unroll
            for (int r = 0; r < 4; r++) {
                C[(size_t)(m0 + wr + i * 16 + cr + r) * N + n0 + wc + j * 16 +
                  fr] = acc[i][j][r];
            }
        }
}

// ---------------------------------------------------------------------------
// a/b projections (N=16 each) fused with softplus/sigmoid -> g, beta.
// ---------------------------------------------------------------------------
__global__ void __launch_bounds__(256) ab_proj(
    const float* __restrict__ x, const float* __restrict__ w_a,
    const float* __restrict__ w_b, const float* __restrict__ A_log,
    const float* __restrict__ dt_bias, float* __restrict__ g_out,
    float* __restrict__ beta_out) {
    const int row = blockIdx.x * 4 + (threadIdx.x >> 6);
    const int lane = threadIdx.x & 63;
    const int h = lane >> 2;
    const int kg = lane & 3;
    const float* xr = x + (size_t)row * Dc;
    float pa = 0.f, pb = 0.f;
    const int kbeg = kg * 256, kend = kbeg + 256;
    for (int k = kbeg; k < kend; k += 4) {
        float4 xv = *(const float4*)&xr[k];
        pa += xv.x * w_a[(k + 0) * Hc + h] + xv.y * w_a[(k + 1) * Hc + h] +
              xv.z * w_a[(k + 2) * Hc + h] + xv.w * w_a[(k + 3) * Hc + h];
        pb += xv.x * w_b[(k + 0) * Hc + h] + xv.y * w_b[(k + 1) * Hc + h] +
              xv.z * w_b[(k + 2) * Hc + h] + xv.w * w_b[(k + 3) * Hc + h];
    }
    pa += __shfl_xor(pa, 1, 64);
    pa += __shfl_xor(pa, 2, 64);
    pb += __shfl_xor(pb, 1, 64);
    pb += __shfl_xor(pb, 2, 64);
    if (kg == 0) {
        float arg = pa + dt_bias[h];
        float sp = fmaxf(arg, 0.f) + log1pf(expf(-fabsf(arg)));
        g_out[(size_t)row * Hc + h] = -expf(A_log[h]) * sp;
        beta_out[(size_t)row * Hc + h] = 2.f / (1.f + expf(-pb));
    }
}

// ---------------------------------------------------------------------------
// Save 3-row halos at 64-step chunk boundaries (for in-place conv).
// ---------------------------------------------------------------------------
template <int C>
__global__ void __launch_bounds__(256) save_halo(
    const float* __restrict__ in, float* __restrict__ halo) {
    const int g = blockIdx.x * 256 + threadIdx.x;
    const int total = Bc * (Tc / 64 - 1) * 3 * C;
    if (g >= total) return;
    const int c = g % C;
    int r = g / C;
    const int j = r % 3;
    r /= 3;
    const int chunk = r % (Tc / 64 - 1) + 1;
    const int b = r / (Tc / 64 - 1);
    halo[((size_t)(b * 64 + chunk) * 3 + j) * C + c] =
        in[((size_t)b * Tc + chunk * 64 - 3 + j) * C + c];
}

// ---------------------------------------------------------------------------
// Depthwise causal conv1d (K=4) + SiLU (+ optional l2norm), IN PLACE.
// ---------------------------------------------------------------------------
template <int C, bool L2N>
__global__ void __launch_bounds__(256) conv_silu_inplace(
    float* __restrict__ buf, const float* __restrict__ w,
    const float* __restrict__ halo) {
    constexpr int CB = C / 256;
    const int bidx = blockIdx.x;
    const int cb = bidx % CB;
    const int tchunk = (bidx / CB) % (Tc / 64);
    const int b = bidx / (CB * (Tc / 64));
    const int c = cb * 256 + threadIdx.x;
    const int t0 = tchunk * 64;
    const float w0 = w[c * 4 + 0], w1 = w[c * 4 + 1], w2 = w[c * 4 + 2],
                w3 = w[c * 4 + 3];
    float xm3 = 0.f, xm2 = 0.f, xm1 = 0.f;
    if (tchunk > 0) {
        const float* hp = halo + (size_t)(b * 64 + tchunk) * 3 * C + c;
        xm3 = hp[0];
        xm2 = hp[C];
        xm1 = hp[2 * C];
    }
    float* p = buf + (size_t)b * Tc * C + c;
#pragma unroll 4
    for (int i = 0; i < 64; i++) {
        float xt = p[(size_t)(t0 + i) * C];
        float y = w0 * xm3 + w1 * xm2 + w2 * xm1 + w3 * xt;
        y = siluf(y);
        if (L2N) {
            float ss = y * y;
#pragma unroll
            for (int m = 1; m < 64; m <<= 1) ss += __shfl_xor(ss, m, 64);
            y *= rsqrtf(ss + 1e-6f);
        }
        p[(size_t)(t0 + i) * C] = y;
        xm3 = xm2;
        xm2 = xm1;
        xm1 = xt;
    }
}

// ---------------------------------------------------------------------------
// TM precompute v2: Gram matrices KK^T / QK^T via bf16 MFMA (f32 accum),
// exp/beta epilogue; f32 lane-parallel solve for T=(I+A)^{-1}.
// M -> tmM row-major [t][s]; T -> tmT row-major [t][s].
// ---------------------------------------------------------------------------
__global__ void __launch_bounds__(256) tm_precompute(
    const float* __restrict__ kc, const float* __restrict__ qc,
    const float* __restrict__ g, const float* __restrict__ beta,
    float* __restrict__ tmT, float* __restrict__ tmM) {
    const int bid = blockIdx.x;
    const int ch = bid & (NCH - 1);
    const int bh = bid >> 6;
    const int b = bh >> 4, h = bh & 15;
    const int tid = threadIdx.x;
    const int t0 = ch * CC;

    __shared__ __align__(16) unsigned short kb16[CC][72];
    __shared__ __align__(16) unsigned short qb16[CC][72];
    __shared__ __align__(16) float AtL[CC][DKc + 4];  // A^T: AtL[s][t]
    __shared__ float cL[CC], betaL[CC];

    const size_t qk0 = (size_t)b * Tc * KDIMc + h * DKc;
    const size_t gb0 = (size_t)b * Tc * Hc + h;
    const size_t tile = (size_t)(bh * NCH + ch) * 4096;

#pragma unroll
    for (int i = 0; i < 4; i++) {
        int e = tid + i * 256;
        int r = e >> 4, c4 = (e & 15) << 2;
        float4 kv = *(const float4*)&kc[qk0 + (size_t)(t0 + r) * KDIMc + c4];
        float4 qv = *(const float4*)&qc[qk0 + (size_t)(t0 + r) * KDIMc + c4];
        *(uint2*)&kb16[r][c4] = make_uint2(pk2(kv.x, kv.y), pk2(kv.z, kv.w));
        *(uint2*)&qb16[r][c4] = make_uint2(pk2(qv.x, qv.y), pk2(qv.z, qv.w));
    }
    if (tid < 64) {
        float gv = g[gb0 + (size_t)(t0 + tid) * Hc];
        float cv = gv;
#pragma unroll
        for (int d = 1; d < 64; d <<= 1) {
            float nb = __shfl_up(cv, d, 64);
            if (tid >= d) cv += nb;
        }
        cL[tid] = cv;
        betaL[tid] = beta[gb0 + (size_t)(t0 + tid) * Hc];
    }
    __syncthreads();

    // Gram via MFMA: wave w owns t-strip w*16..w*16+15.
    {
        const int w = tid >> 6, lane = tid & 63;
        const int fr = lane & 15, fk8 = (lane >> 4) << 3;
        const int rr = (lane >> 4) << 2;
        short8 ak0 = *(const short8*)&kb16[w * 16 + fr][fk8];
        short8 ak1 = *(const short8*)&kb16[w * 16 + fr][fk8 + 32];
        short8 aq0 = *(const short8*)&qb16[w * 16 + fr][fk8];
        short8 aq1 = *(const short8*)&qb16[w * 16 + fr][fk8 + 32];
#pragma unroll
        for (int j = 0; j < 4; j++) {
            short8 b0 = *(const short8*)&kb16[j * 16 + fr][fk8];
            short8 b1 = *(const short8*)&kb16[j * 16 + fr][fk8 + 32];
            f32x4 kk = (f32x4){0.f, 0.f, 0.f, 0.f};
            f32x4 qk = (f32x4){0.f, 0.f, 0.f, 0.f};
            kk = __builtin_amdgcn_mfma_f32_16x16x32_bf16(ak0, b0, kk, 0, 0, 0);
            kk = __builtin_amdgcn_mfma_f32_16x16x32_bf16(ak1, b1, kk, 0, 0, 0);
            qk = __builtin_amdgcn_mfma_f32_16x16x32_bf16(aq0, b0, qk, 0, 0, 0);
            qk = __builtin_amdgcn_mfma_f32_16x16x32_bf16(aq1, b1, qk, 0, 0, 0);
#pragma unroll
            for (int r = 0; r < 4; r++) {
                int t = w * 16 + rr + r, s = j * 16 + fr;
                float E = expf(cL[t] - cL[s]);
                AtL[s][t] = (s < t) ? betaL[t] * E * kk[r] : 0.f;
                tmM[tile + (size_t)t * 64 + s] =
                    (s <= t) ? 0.125f * E * qk[r] : 0.f;
            }
        }
    }
    __syncthreads();

    {
        const int w = tid >> 6, lane = tid & 63;
        float acc[16];
#pragma unroll
        for (int di = 0; di < 16; di++)
            acc[di] = (lane == w * 16 + di) ? 1.f : 0.f;
#pragma unroll 4
        for (int s = 0; s < 64; s++) {
            float a = AtL[s][lane];
#pragma unroll
            for (int di = 0; di < 16; di++) {
                float ds = __shfl(acc[di], s, 64);
                acc[di] -= a * ds;
            }
        }
        // store T ROW-major: row = lane, cols w*16..w*16+15
#pragma unroll
        for (int p = 0; p < 4; p++) {
            float4 v4 = make_float4(acc[p * 4 + 0], acc[p * 4 + 1],
                                    acc[p * 4 + 2], acc[p * 4 + 3]);
            *(float4*)&tmT[tile + (size_t)lane * 64 + w * 16 + p * 4] = v4;
        }
    }
}

// ---------------------------------------------------------------------------
// Sequential chunk scan v4: MFMA phases, 4 barriers/chunk (O stored straight
// from the accumulator; waves 0-3 overlap P4 with waves 4-7's phase 3).
// ---------------------------------------------------------------------------
__global__ void __launch_bounds__(512, 2) delta_scan(
    const float* __restrict__ kc, const float* __restrict__ qc,
    float* vo, const float* __restrict__ g, const float* __restrict__ beta,
    const float* __restrict__ tmT, const float* __restrict__ tmM) {
    const int bid = blockIdx.x;
    const int sl = bid >> 5;   // 0..7
    const int bh = bid & 31;   // 0..31 -> XCD = bh%8
    const int b = bh >> 4, h = bh & 15;
    const int tid = threadIdx.x;

    __shared__ __align__(16) float kT[DKc][CC + 4];   // k^T for P4
    __shared__ __align__(16) float ST[16][DKc + 4];   // S^T master (f32)
    __shared__ __align__(16) float DT2[16][CC + 4];   // delta^T f32 (P4)
    __shared__ __align__(16) float VL[CC][20];
    __shared__ float gamL[CC], egL[CC], betaL[CC];
    __shared__ __align__(16) unsigned short kb16[CC][72];
    __shared__ __align__(16) unsigned short qb16[CC][72];
    __shared__ __align__(16) unsigned short Tb16[CC][72];
    __shared__ __align__(16) unsigned short Mb16[CC][72];
    __shared__ __align__(16) unsigned short STb16[16][72];
    __shared__ __align__(16) unsigned short DTb16[16][72];   // RHS bf16
    __shared__ __align__(16) unsigned short D2b16[16][72];   // delta bf16

    const size_t qk0 = (size_t)b * Tc * KDIMc + h * DKc;
    const size_t v0 = (size_t)b * Tc * VDIMc + h * DVc + sl * 16;
    const size_t gb0 = (size_t)b * Tc * Hc + h;
    const size_t tb0 = (size_t)(bh * NCH) * 4096;

    for (int i = tid; i < 16 * (DKc + 4); i += 512) ((float*)ST)[i] = 0.f;
    for (int i = tid; i < 16 * 72; i += 512) ((unsigned short*)STb16)[i] = 0;

    const int r0 = tid >> 4, c40 = (tid & 15) << 2;
    const int r1 = r0 + 32;
    const int wid = tid >> 6, lane = tid & 63;
    const int fr = lane & 15;
    const int fk8 = (lane >> 4) << 3;
    const int rr = (lane >> 4) << 2;
    const int tb = (wid << 3) | (lane >> 3);
    const int dvb = lane & 7;

    float4 kv0, kv1, qv0, qv1, tv0, tv1, mv0, mv1, vv0;
    float gvr = 0.f, bvr = 0.f;

#define LOADREGS(CH)                                                          \
    {                                                                         \
        const size_t tK = qk0 + (size_t)(CH) * CC * KDIMc;                    \
        const size_t tile_ = tb0 + (size_t)(CH) * 4096;                       \
        kv0 = *(const float4*)&kc[tK + (size_t)r0 * KDIMc + c40];             \
        kv1 = *(const float4*)&kc[tK + (size_t)r1 * KDIMc + c40];             \
        qv0 = *(const float4*)&qc[tK + (size_t)r0 * KDIMc + c40];             \
        qv1 = *(const float4*)&qc[tK + (size_t)r1 * KDIMc + c40];             \
        tv0 = *(const float4*)&tmT[tile_ + (size_t)tid * 4];                  \
        tv1 = *(const float4*)&tmT[tile_ + (size_t)(tid + 512) * 4];          \
        mv0 = *(const float4*)&tmM[tile_ + (size_t)tid * 4];                  \
        mv1 = *(const float4*)&tmM[tile_ + (size_t)(tid + 512) * 4];          \
        if (tid < 256)                                                        \
            vv0 = *(const float4*)&vo[v0 +                                    \
                                      (size_t)((CH) * CC + (tid >> 2)) *     \
                                          VDIMc +                             \
                                      ((tid & 3) << 2)];                      \
        if (tid < 64) {                                                       \
            gvr = g[gb0 + (size_t)((CH) * CC + tid) * Hc];                    \
            bvr = beta[gb0 + (size_t)((CH) * CC + tid) * Hc];                 \
        }                                                                     \
    }

    LOADREGS(0);

#pragma unroll 1
    for (int ch = 0; ch < NCH; ch++) {
        __syncthreads();  // B0: prev chunk fully done

        // ---- stage regs -> LDS
        {
            *(uint2*)&kb16[r0][c40] = make_uint2(pk2(kv0.x, kv0.y), pk2(kv0.z, kv0.w));
            *(uint2*)&kb16[r1][c40] = make_uint2(pk2(kv1.x, kv1.y), pk2(kv1.z, kv1.w));
            *(uint2*)&qb16[r0][c40] = make_uint2(pk2(qv0.x, qv0.y), pk2(qv0.z, qv0.w));
            *(uint2*)&qb16[r1][c40] = make_uint2(pk2(qv1.x, qv1.y), pk2(qv1.z, qv1.w));
            *(uint2*)&Tb16[r0][c40] = make_uint2(pk2(tv0.x, tv0.y), pk2(tv0.z, tv0.w));
            *(uint2*)&Tb16[r1][c40] = make_uint2(pk2(tv1.x, tv1.y), pk2(tv1.z, tv1.w));
            *(uint2*)&Mb16[r0][c40] = make_uint2(pk2(mv0.x, mv0.y), pk2(mv0.z, mv0.w));
            *(uint2*)&Mb16[r1][c40] = make_uint2(pk2(mv1.x, mv1.y), pk2(mv1.z, mv1.w));
            float* kp0 = (float*)&kv0;
            float* kp1 = (float*)&kv1;
#pragma unroll
            for (int i = 0; i < 4; i++) {
                kT[c40 + i][r0] = kp0[i];
                kT[c40 + i][r1] = kp1[i];
            }
            if (tid < 256) *(float4*)&VL[tid >> 2][(tid & 3) << 2] = vv0;
            if (tid < 64) {
                float cv = gvr;
#pragma unroll
                for (int d = 1; d < 64; d <<= 1) {
                    float nb = __shfl_up(cv, d, 64);
                    if (tid >= d) cv += nb;
                }
                gamL[tid] = expf(cv);
                float cend = __shfl(cv, 63, 64);
                egL[tid] = expf(cend - cv);
                betaL[tid] = bvr;
            }
        }
        if (ch + 1 < NCH) LOADREGS(ch + 1);
        __syncthreads();  // B1: stage visible

        // ---- phase 1: KS (waves 0-3) and QS (waves 4-7) via MFMA
        f32x4 acc1 = (f32x4){0.f, 0.f, 0.f, 0.f};
        {
            short8 bs0 = *(const short8*)&STb16[fr][fk8];
            short8 bs1 = *(const short8*)&STb16[fr][fk8 + 32];
            if (wid < 4) {
                const int m0 = wid << 4;
                short8 a0 = *(const short8*)&kb16[m0 + fr][fk8];
                short8 a1 = *(const short8*)&kb16[m0 + fr][fk8 + 32];
                acc1 = __builtin_amdgcn_mfma_f32_16x16x32_bf16(a0, bs0, acc1, 0, 0, 0);
                acc1 = __builtin_amdgcn_mfma_f32_16x16x32_bf16(a1, bs1, acc1, 0, 0, 0);
#pragma unroll
                for (int r = 0; r < 4; r++) {
                    int t = m0 + rr + r;
                    float rhs = betaL[t] * (VL[t][fr] - gamL[t] * acc1[r]);
                    DTb16[fr][t] = f2bf(rhs);
                }
            } else {
                const int m0 = (wid - 4) << 4;
                short8 a0 = *(const short8*)&qb16[m0 + fr][fk8];
                short8 a1 = *(const short8*)&qb16[m0 + fr][fk8 + 32];
                acc1 = __builtin_amdgcn_mfma_f32_16x16x32_bf16(a0, bs0, acc1, 0, 0, 0);
                acc1 = __builtin_amdgcn_mfma_f32_16x16x32_bf16(a1, bs1, acc1, 0, 0, 0);
#pragma unroll
                for (int r = 0; r < 4; r++) {
                    int t = m0 + rr + r;
                    acc1[r] *= 0.125f * gamL[t];
                }
            }
        }
        __syncthreads();  // B2: RHS ready

        // ---- phase 2: delta = T * RHS (waves 0-3)
        if (wid < 4) {
            const int m0 = wid << 4;
            short8 a0 = *(const short8*)&Tb16[m0 + fr][fk8];
            short8 a1 = *(const short8*)&Tb16[m0 + fr][fk8 + 32];
            short8 b0 = *(const short8*)&DTb16[fr][fk8];
            short8 b1 = *(const short8*)&DTb16[fr][fk8 + 32];
            f32x4 d = (f32x4){0.f, 0.f, 0.f, 0.f};
            d = __builtin_amdgcn_mfma_f32_16x16x32_bf16(a0, b0, d, 0, 0, 0);
            d = __builtin_amdgcn_mfma_f32_16x16x32_bf16(a1, b1, d, 0, 0, 0);
#pragma unroll
            for (int r = 0; r < 4; r++) {
                int t = m0 + rr + r;
                DT2[fr][t] = d[r];
                D2b16[fr][t] = f2bf(d[r]);
            }
        }
        __syncthreads();  // B3: delta ready

        // ---- phase 3: O = M*delta + scaledQS (waves 4-7), store direct;
        //      waves 0-3 fall straight through to P4 (overlap).
        if (wid >= 4) {
            const int m0 = (wid - 4) << 4;
            short8 a0 = *(const short8*)&Mb16[m0 + fr][fk8];
            short8 a1 = *(const short8*)&Mb16[m0 + fr][fk8 + 32];
            short8 b0 = *(const short8*)&D2b16[fr][fk8];
            short8 b1 = *(const short8*)&D2b16[fr][fk8 + 32];
            f32x4 o = acc1;  // 0.125*gam*QS
            o = __builtin_amdgcn_mfma_f32_16x16x32_bf16(a0, b0, o, 0, 0, 0);
            o = __builtin_amdgcn_mfma_f32_16x16x32_bf16(a1, b1, o, 0, 0, 0);
#pragma unroll
            for (int r = 0; r < 4; r++)
                vo[v0 + (size_t)(ch * CC + m0 + rr + r) * VDIMc + fr] = o[r];
        }
        // ---- P4: f32 S update (all threads; each owns its 2 elements)
        {
            const float ge = gamL[63];
            float s0 = ge * ST[dvb][tb];
            float s1 = ge * ST[dvb + 8][tb];
#pragma unroll 4
            for (int s = 0; s < 64; s += 4) {
                float4 k4 = *(const float4*)&kT[tb][s];
                float4 eg4 = *(const float4*)&egL[s];
                float4 e0 = *(const float4*)&DT2[dvb][s];
                float4 e1 = *(const float4*)&DT2[dvb + 8][s];
                s0 += k4.x * (eg4.x * e0.x) + k4.y * (eg4.y * e0.y) +
                      k4.z * (eg4.z * e0.z) + k4.w * (eg4.w * e0.w);
                s1 += k4.x * (eg4.x * e1.x) + k4.y * (eg4.y * e1.y) +
                      k4.z * (eg4.z * e1.z) + k4.w * (eg4.w * e1.w);
            }
            ST[dvb][tb] = s0;
            ST[dvb + 8][tb] = s1;
            STb16[dvb][tb] = f2bf(s0);
            STb16[dvb + 8][tb] = f2bf(s1);
        }
    }
#undef LOADREGS
}

// ---------------------------------------------------------------------------
// Gated RMSNorm -> bf16 output buffer (for the MFMA output GEMM).
// ---------------------------------------------------------------------------
__global__ void __launch_bounds__(256) rms_gate_bf16(
    const float* __restrict__ o, const float* __restrict__ gg,
    const float* __restrict__ norm_w, unsigned short* __restrict__ out) {
    const int row = blockIdx.x * 4 + (threadIdx.x >> 6);
    const int lane = threadIdx.x & 63;
    const size_t base = (size_t)row * DVc;
    float2 ov = *(const float2*)&o[base + lane * 2];
    float ss = ov.x * ov.x + ov.y * ov.y;
#pragma unroll
    for (int m = 1; m < 64; m <<= 1) ss += __shfl_xor(ss, m, 64);
    const float f = rsqrtf(ss * (1.f / 128.f) + 1e-5f);
    float2 gv = *(const float2*)&gg[base + lane * 2];
    const float nw0 = norm_w[lane * 2], nw1 = norm_w[lane * 2 + 1];
    float y0 = ov.x * f * nw0 * siluf(gv.x);
    float y1 = ov.y * f * nw1 * siluf(gv.y);
    *(unsigned int*)&out[base + lane * 2] = pk2(y0, y1);
}

// ---------------------------------------------------------------------------
// Workspace layout identical to R7-R9 (235.9 MB, proven).
// ---------------------------------------------------------------------------
extern "C" void kernel_launch(void* const* d_in, const int* in_sizes, int n_in,
                              void* d_out, int out_size, void* d_ws,
                              size_t ws_size, hipStream_t stream) {
    const float* x = (const float*)d_in[0];
    const float* w_q = (const float*)d_in[1];
    const float* w_k = (const float*)d_in[2];
    const float* w_v = (const float*)d_in[3];
    const float* w_a = (const float*)d_in[4];
    const float* w_b = (const float*)d_in[5];
    const float* w_g = (const float*)d_in[6];
    const float* w_out = (const float*)d_in[7];
    const float* A_log = (const float*)d_in[8];
    const float* dt_bias = (const float*)d_in[9];
    const float* conv_q = (const float*)d_in[10];
    const float* conv_k = (const float*)d_in[11];
    const float* conv_v = (const float*)d_in[12];
    const float* norm_w = (const float*)d_in[13];

    float* ws = (float*)d_ws;
    const size_t M = Mrows;
    float* qb = ws;
    float* kb = qb + M * KDIMc;
    float* vb = kb + M * KDIMc;
    float* tm = vb + M * VDIMc;          // T (8.4M) + M (8.4M)
    float* gbuf = tm + M * VDIMc;
    float* bbuf = gbuf + M * Hc;
    float* xtra = bbuf + M * Hc;
    float* tmT = tm;
    float* tmM = tm + (size_t)Bc * Hc * NCH * 4096;
    float* halo = tm;                     // alias: dead before tm_precompute
    unsigned short* obb = (unsigned short*)tm;  // alias: after scan, tm dead
    float* gg = qb;                       // alias: after scan

    unsigned short* xb = (unsigned short*)xtra;
    unsigned short* wqT = xb + M * KDIMc;
    unsigned short* wkT = wqT + (size_t)KDIMc * Dc;
    unsigned short* wvT = wkT + (size_t)KDIMc * Dc;
    unsigned short* wgT = wvT + (size_t)VDIMc * Dc;
    unsigned short* woT = wgT + (size_t)VDIMc * Dc;

    // 0) conversions
    convert_bf16<<<dim3(M * Dc / 4 / 256), 256, 0, stream>>>(x, xb, M * Dc / 4);
    transp_bf16<<<dim3((KDIMc / 32) * (Dc / 32)), 256, 0, stream>>>(w_q, wqT,
                                                                    Dc, KDIMc);
    transp_bf16<<<dim3((KDIMc / 32) * (Dc / 32)), 256, 0, stream>>>(w_k, wkT,
                                                                    Dc, KDIMc);
    transp_bf16<<<dim3((VDIMc / 32) * (Dc / 32)), 256, 0, stream>>>(w_v, wvT,
                                                                    Dc, VDIMc);
    transp_bf16<<<dim3((VDIMc / 32) * (Dc / 32)), 256, 0, stream>>>(w_g, wgT,
                                                                    Dc, VDIMc);
    transp_bf16<<<dim3((Dc / 32) * (VDIMc / 32)), 256, 0, stream>>>(
        w_out, woT, VDIMc, Dc);

    // 1) q/k/v projections (bf16 MFMA, global_load_lds staging)
    gemm_bf16<<<dim3((M / 128) * (KDIMc / 128)), 256, 0, stream>>>(
        xb, wqT, qb, M, KDIMc, Dc);
    gemm_bf16<<<dim3((M / 128) * (KDIMc / 128)), 256, 0, stream>>>(
        xb, wkT, kb, M, KDIMc, Dc);
    gemm_bf16<<<dim3((M / 128) * (VDIMc / 128)), 256, 0, stream>>>(
        xb, wvT, vb, M, VDIMc, Dc);

    // 2) a/b projections fused with activation -> g, beta
    ab_proj<<<dim3(M / 4), 256, 0, stream>>>(x, w_a, w_b, A_log, dt_bias, gbuf,
                                             bbuf);

    // 3) conv + silu (+ l2norm for q,k), in place with halo save
    {
        const int nqk = Bc * (Tc / 64 - 1) * 3 * KDIMc;
        const int nv = Bc * (Tc / 64 - 1) * 3 * VDIMc;
        save_halo<KDIMc><<<dim3((nqk + 255) / 256), 256, 0, stream>>>(qb, halo);
        conv_silu_inplace<KDIMc, true>
            <<<dim3(Bc * (Tc / 64) * (KDIMc / 256)), 256, 0, stream>>>(
                qb, conv_q, halo);
        save_halo<KDIMc><<<dim3((nqk + 255) / 256), 256, 0, stream>>>(kb, halo);
        conv_silu_inplace<KDIMc, true>
            <<<dim3(Bc * (Tc / 64) * (KDIMc / 256)), 256, 0, stream>>>(
                kb, conv_k, halo);
        save_halo<VDIMc><<<dim3((nv + 255) / 256), 256, 0, stream>>>(vb, halo);
        conv_silu_inplace<VDIMc, false>
            <<<dim3(Bc * (Tc / 64) * (VDIMc / 256)), 256, 0, stream>>>(
                vb, conv_v, halo);
    }

    // 4a) parallel precompute of T=(I+A)^{-1} and M (MFMA Gram)
    tm_precompute<<<dim3(Bc * Hc * NCH), 256, 0, stream>>>(kb, qb, gbuf, bbuf,
                                                           tmT, tmM);
    // 4b) sequential scan v4
    delta_scan<<<dim3(Bc * Hc * 8), 512, 0, stream>>>(kb, qb, vb, gbuf, bbuf,
                                                      tmT, tmM);

    // 5) gate projection (bf16 MFMA; gg aliases qb+kb)
    gemm_bf16<<<dim3((M / 128) * (VDIMc / 128)), 256, 0, stream>>>(
        xb, wgT, gg, M, VDIMc, Dc);

    // 6) gated RMSNorm -> bf16 obb (aliases tm)
    rms_gate_bf16<<<dim3(M * Hc / 4), 256, 0, stream>>>(vb, gg, norm_w, obb);

    // 7) output projection (bf16 MFMA) -> d_out
    gemm_bf16<<<dim3((M / 128) * (Dc / 128)), 256, 0, stream>>>(
        obb, woT, (float*)d_out, M, Dc, VDIMc);
}

// Round 11
// 766.807 us; speedup vs baseline: 29.0111x; 1.0952x over previous
//
#include <hip/hip_runtime.h>
#include <hip/hip_bf16.h>
#include <math.h>

// Problem constants
#define Bc 2
#define Tc 4096
#define Dc 1024
#define Hc 16
#define DKc 64
#define DVc 128
#define KDIMc 1024   // H*DK
#define VDIMc 2048   // H*DV
#define Mrows (Bc*Tc) // 8192
#define CC 64        // scan chunk size
#define NCH (Tc/CC)  // 64 chunks

typedef short short8 __attribute__((ext_vector_type(8)));
typedef float f32x4 __attribute__((ext_vector_type(4)));

__device__ __forceinline__ float siluf(float x) {
    return x / (1.f + expf(-x));
}
__device__ __forceinline__ unsigned short f2bf(float f) {
    unsigned int u = __float_as_uint(f);
    unsigned int r = (u + 0x7fffu + ((u >> 16) & 1u)) >> 16;
    return (unsigned short)r;
}
__device__ __forceinline__ unsigned int pk2(float a, float b) {
    return (unsigned)f2bf(a) | ((unsigned)f2bf(b) << 16);
}
// async global->LDS DMA, 16B per lane; lds base must be wave-uniform.
__device__ __forceinline__ void gload16(const unsigned short* g,
                                        unsigned short* l) {
    __builtin_amdgcn_global_load_lds(
        (const __attribute__((address_space(1))) unsigned int*)g,
        (__attribute__((address_space(3))) unsigned int*)l, 16, 0, 0);
}

// ---------------------------------------------------------------------------
// x (f32) -> bf16, straight elementwise. 4 elems/thread.
// ---------------------------------------------------------------------------
__global__ void __launch_bounds__(256) convert_bf16(
    const float* __restrict__ in, unsigned short* __restrict__ out, int n4) {
    int g = blockIdx.x * 256 + threadIdx.x;
    if (g >= n4) return;
    float4 v = *(const float4*)&in[(size_t)g * 4];
    *(uint2*)&out[(size_t)g * 4] = make_uint2(pk2(v.x, v.y), pk2(v.z, v.w));
}

// ---------------------------------------------------------------------------
// Transpose + convert: in f32 [K][N] -> out bf16 [N][K]. 32x32 LDS tiles.
// ---------------------------------------------------------------------------
__global__ void __launch_bounds__(256) transp_bf16(
    const float* __restrict__ in, unsigned short* __restrict__ out, int K,
    int N) {
    __shared__ float t[32][33];
    const int nbx = N >> 5;
    const int n0 = (blockIdx.x % nbx) << 5;
    const int k0 = (blockIdx.x / nbx) << 5;
    const int c = threadIdx.x & 31, r4 = (threadIdx.x >> 5) << 2;
#pragma unroll
    for (int i = 0; i < 4; i++)
        t[r4 + i][c] = in[(size_t)(k0 + r4 + i) * N + n0 + c];
    __syncthreads();
#pragma unroll
    for (int i = 0; i < 4; i++)
        out[(size_t)(n0 + r4 + i) * K + k0 + c] = f2bf(t[c][r4 + i]);
}

// ---------------------------------------------------------------------------
// bf16 MFMA GEMM: C[M,N] f32 = A[M,K] bf16 (row-major) @ Bt[N,K] bf16.
// 128x128 tile, BK=32, 4 waves, global_load_lds staging.
// ---------------------------------------------------------------------------
__global__ void __launch_bounds__(256) gemm_bf16(
    const unsigned short* __restrict__ A, const unsigned short* __restrict__ Bt,
    float* __restrict__ C, int M, int N, int K) {
    __shared__ unsigned short As[128 * 32];
    __shared__ unsigned short Bs[128 * 32];
    const int tid = threadIdx.x;
    const int nbx = N >> 7;
    const int bx = blockIdx.x % nbx, by = blockIdx.x / nbx;
    const int m0 = by << 7, n0 = bx << 7;
    const int w = tid >> 6, lane = tid & 63;
    const int wr = (w >> 1) << 6, wc = (w & 1) << 6;
    const int fr = lane & 15, fk8 = (lane >> 4) << 3;
    const int grow = lane >> 2;
    const int gcol = (lane & 3) << 3;

    f32x4 acc[4][4];
#pragma unroll
    for (int i = 0; i < 4; i++)
#pragma unroll
        for (int j = 0; j < 4; j++)
            acc[i][j] = (f32x4){0.f, 0.f, 0.f, 0.f};

    const int nkt = K >> 5;
    for (int kt = 0; kt < nkt; kt++) {
        __syncthreads();
        {
            const size_t kb = (size_t)(kt << 5) + gcol;
#pragma unroll
            for (int r = 0; r < 2; r++) {
                const int rows = r * 64 + w * 16;
                gload16(&A[(size_t)(m0 + rows + grow) * K + kb],
                        &As[rows * 32]);
                gload16(&Bt[(size_t)(n0 + rows + grow) * K + kb],
                        &Bs[rows * 32]);
            }
        }
        __syncthreads();
        short8 af[4], bfr[4];
#pragma unroll
        for (int i = 0; i < 4; i++)
            af[i] = *(const short8*)&As[(wr + i * 16 + fr) * 32 + fk8];
#pragma unroll
        for (int j = 0; j < 4; j++)
            bfr[j] = *(const short8*)&Bs[(wc + j * 16 + fr) * 32 + fk8];
#pragma unroll
        for (int i = 0; i < 4; i++)
#pragma unroll
            for (int j = 0; j < 4; j++)
                acc[i][j] = __builtin_amdgcn_mfma_f32_16x16x32_bf16(
                    af[i], bfr[j], acc[i][j], 0, 0, 0);
    }
    const int cr = (lane >> 4) << 2;
#pragma unroll
    for (int i = 0; i < 4; i++)
#pragma unroll
        for (int j = 0; j < 4; j++) {
#pragma unroll
            for (int r = 0; r < 4; r++) {
                C[(size_t)(m0 + wr + i * 16 + cr + r) * N + n0 + wc + j * 16 +
                  fr] = acc[i][j][r];
            }
        }
}

// ---------------------------------------------------------------------------
// Gate GEMM fused with gated RMSNorm epilogue: obb = rms(o)*w*silu(x@w_g).
// N=VDIM, col-tile 128 = exactly one head. rfac precomputed per (row,h).
// ---------------------------------------------------------------------------
__global__ void __launch_bounds__(256) gemm_gate_rms(
    const unsigned short* __restrict__ A, const unsigned short* __restrict__ Bt,
    const float* __restrict__ o, const float* __restrict__ rfac,
    const float* __restrict__ norm_w, unsigned short* __restrict__ out,
    int M, int N, int K) {
    __shared__ unsigned short As[128 * 32];
    __shared__ unsigned short Bs[128 * 32];
    const int tid = threadIdx.x;
    const int nbx = N >> 7;
    const int bx = blockIdx.x % nbx, by = blockIdx.x / nbx;
    const int m0 = by << 7, n0 = bx << 7;
    const int h = n0 >> 7;
    const int w = tid >> 6, lane = tid & 63;
    const int wr = (w >> 1) << 6, wc = (w & 1) << 6;
    const int fr = lane & 15, fk8 = (lane >> 4) << 3;
    const int grow = lane >> 2;
    const int gcol = (lane & 3) << 3;

    f32x4 acc[4][4];
#pragma unroll
    for (int i = 0; i < 4; i++)
#pragma unroll
        for (int j = 0; j < 4; j++)
            acc[i][j] = (f32x4){0.f, 0.f, 0.f, 0.f};

    const int nkt = K >> 5;
    for (int kt = 0; kt < nkt; kt++) {
        __syncthreads();
        {
            const size_t kb = (size_t)(kt << 5) + gcol;
#pragma unroll
            for (int r = 0; r < 2; r++) {
                const int rows = r * 64 + w * 16;
                gload16(&A[(size_t)(m0 + rows + grow) * K + kb],
                        &As[rows * 32]);
                gload16(&Bt[(size_t)(n0 + rows + grow) * K + kb],
                        &Bs[rows * 32]);
            }
        }
        __syncthreads();
        short8 af[4], bfr[4];
#pragma unroll
        for (int i = 0; i < 4; i++)
            af[i] = *(const short8*)&As[(wr + i * 16 + fr) * 32 + fk8];
#pragma unroll
        for (int j = 0; j < 4; j++)
            bfr[j] = *(const short8*)&Bs[(wc + j * 16 + fr) * 32 + fk8];
#pragma unroll
        for (int i = 0; i < 4; i++)
#pragma unroll
            for (int j = 0; j < 4; j++)
                acc[i][j] = __builtin_amdgcn_mfma_f32_16x16x32_bf16(
                    af[i], bfr[j], acc[i][j], 0, 0, 0);
    }
    const int cr = (lane >> 4) << 2;
#pragma unroll
    for (int i = 0; i < 4; i++)
#pragma unroll
        for (int j = 0; j < 4; j++) {
            const int colh = wc + j * 16 + fr;
            const float nw = norm_w[colh];
#pragma unroll
            for (int r = 0; r < 4; r++) {
                const int row = m0 + wr + i * 16 + cr + r;
                float ov = o[(size_t)row * VDIMc + n0 + colh];
                float f = rfac[(size_t)row * Hc + h];
                float y = ov * f * nw * siluf(acc[i][j][r]);
                out[(size_t)row * VDIMc + n0 + colh] = f2bf(y);
            }
        }
}

// ---------------------------------------------------------------------------
// Per-(row,h) RMS factor: rf = rsqrt(mean(o^2)+eps). One wave per 128-row.
// ---------------------------------------------------------------------------
__global__ void __launch_bounds__(256) rfac_kernel(
    const float* __restrict__ o, float* __restrict__ rf) {
    const int row = blockIdx.x * 4 + (threadIdx.x >> 6);
    const int lane = threadIdx.x & 63;
    const size_t base = (size_t)row * DVc;
    float2 ov = *(const float2*)&o[base + lane * 2];
    float ss = ov.x * ov.x + ov.y * ov.y;
#pragma unroll
    for (int m = 1; m < 64; m <<= 1) ss += __shfl_xor(ss, m, 64);
    if (lane == 0) rf[row] = rsqrtf(ss * (1.f / 128.f) + 1e-5f);
}

// ---------------------------------------------------------------------------
// a/b projections (N=16 each) fused with softplus/sigmoid -> g, beta.
// ---------------------------------------------------------------------------
__global__ void __launch_bounds__(256) ab_proj(
    const float* __restrict__ x, const float* __restrict__ w_a,
    const float* __restrict__ w_b, const float* __restrict__ A_log,
    const float* __restrict__ dt_bias, float* __restrict__ g_out,
    float* __restrict__ beta_out) {
    const int row = blockIdx.x * 4 + (threadIdx.x >> 6);
    const int lane = threadIdx.x & 63;
    const int h = lane >> 2;
    const int kg = lane & 3;
    const float* xr = x + (size_t)row * Dc;
    float pa = 0.f, pb = 0.f;
    const int kbeg = kg * 256, kend = kbeg + 256;
    for (int k = kbeg; k < kend; k += 4) {
        float4 xv = *(const float4*)&xr[k];
        pa += xv.x * w_a[(k + 0) * Hc + h] + xv.y * w_a[(k + 1) * Hc + h] +
              xv.z * w_a[(k + 2) * Hc + h] + xv.w * w_a[(k + 3) * Hc + h];
        pb += xv.x * w_b[(k + 0) * Hc + h] + xv.y * w_b[(k + 1) * Hc + h] +
              xv.z * w_b[(k + 2) * Hc + h] + xv.w * w_b[(k + 3) * Hc + h];
    }
    pa += __shfl_xor(pa, 1, 64);
    pa += __shfl_xor(pa, 2, 64);
    pb += __shfl_xor(pb, 1, 64);
    pb += __shfl_xor(pb, 2, 64);
    if (kg == 0) {
        float arg = pa + dt_bias[h];
        float sp = fmaxf(arg, 0.f) + log1pf(expf(-fabsf(arg)));
        g_out[(size_t)row * Hc + h] = -expf(A_log[h]) * sp;
        beta_out[(size_t)row * Hc + h] = 2.f / (1.f + expf(-pb));
    }
}

// ---------------------------------------------------------------------------
// Save 3-row halos at 64-step chunk boundaries (for in-place conv).
// ---------------------------------------------------------------------------
template <int C>
__global__ void __launch_bounds__(256) save_halo(
    const float* __restrict__ in, float* __restrict__ halo) {
    const int g = blockIdx.x * 256 + threadIdx.x;
    const int total = Bc * (Tc / 64 - 1) * 3 * C;
    if (g >= total) return;
    const int c = g % C;
    int r = g / C;
    const int j = r % 3;
    r /= 3;
    const int chunk = r % (Tc / 64 - 1) + 1;
    const int b = r / (Tc / 64 - 1);
    halo[((size_t)(b * 64 + chunk) * 3 + j) * C + c] =
        in[((size_t)b * Tc + chunk * 64 - 3 + j) * C + c];
}

// ---------------------------------------------------------------------------
// Depthwise causal conv1d (K=4) + SiLU (+ optional l2norm), IN PLACE.
// ---------------------------------------------------------------------------
template <int C, bool L2N>
__global__ void __launch_bounds__(256) conv_silu_inplace(
    float* __restrict__ buf, const float* __restrict__ w,
    const float* __restrict__ halo) {
    constexpr int CB = C / 256;
    const int bidx = blockIdx.x;
    const int cb = bidx % CB;
    const int tchunk = (bidx / CB) % (Tc / 64);
    const int b = bidx / (CB * (Tc / 64));
    const int c = cb * 256 + threadIdx.x;
    const int t0 = tchunk * 64;
    const float w0 = w[c * 4 + 0], w1 = w[c * 4 + 1], w2 = w[c * 4 + 2],
                w3 = w[c * 4 + 3];
    float xm3 = 0.f, xm2 = 0.f, xm1 = 0.f;
    if (tchunk > 0) {
        const float* hp = halo + (size_t)(b * 64 + tchunk) * 3 * C + c;
        xm3 = hp[0];
        xm2 = hp[C];
        xm1 = hp[2 * C];
    }
    float* p = buf + (size_t)b * Tc * C + c;
#pragma unroll 4
    for (int i = 0; i < 64; i++) {
        float xt = p[(size_t)(t0 + i) * C];
        float y = w0 * xm3 + w1 * xm2 + w2 * xm1 + w3 * xt;
        y = siluf(y);
        if (L2N) {
            float ss = y * y;
#pragma unroll
            for (int m = 1; m < 64; m <<= 1) ss += __shfl_xor(ss, m, 64);
            y *= rsqrtf(ss + 1e-6f);
        }
        p[(size_t)(t0 + i) * C] = y;
        xm3 = xm2;
        xm2 = xm1;
        xm1 = xt;
    }
}

// ---------------------------------------------------------------------------
// TM precompute: Gram via bf16 MFMA, f32 solve. T,M row-major [t][s].
// ---------------------------------------------------------------------------
__global__ void __launch_bounds__(256) tm_precompute(
    const float* __restrict__ kc, const float* __restrict__ qc,
    const float* __restrict__ g, const float* __restrict__ beta,
    float* __restrict__ tmT, float* __restrict__ tmM) {
    const int bid = blockIdx.x;
    const int ch = bid & (NCH - 1);
    const int bh = bid >> 6;
    const int b = bh >> 4, h = bh & 15;
    const int tid = threadIdx.x;
    const int t0 = ch * CC;

    __shared__ __align__(16) unsigned short kb16[CC][72];
    __shared__ __align__(16) unsigned short qb16[CC][72];
    __shared__ __align__(16) float AtL[CC][DKc + 4];  // A^T: AtL[s][t]
    __shared__ float cL[CC], betaL[CC];

    const size_t qk0 = (size_t)b * Tc * KDIMc + h * DKc;
    const size_t gb0 = (size_t)b * Tc * Hc + h;
    const size_t tile = (size_t)(bh * NCH + ch) * 4096;

#pragma unroll
    for (int i = 0; i < 4; i++) {
        int e = tid + i * 256;
        int r = e >> 4, c4 = (e & 15) << 2;
        float4 kv = *(const float4*)&kc[qk0 + (size_t)(t0 + r) * KDIMc + c4];
        float4 qv = *(const float4*)&qc[qk0 + (size_t)(t0 + r) * KDIMc + c4];
        *(uint2*)&kb16[r][c4] = make_uint2(pk2(kv.x, kv.y), pk2(kv.z, kv.w));
        *(uint2*)&qb16[r][c4] = make_uint2(pk2(qv.x, qv.y), pk2(qv.z, qv.w));
    }
    if (tid < 64) {
        float gv = g[gb0 + (size_t)(t0 + tid) * Hc];
        float cv = gv;
#pragma unroll
        for (int d = 1; d < 64; d <<= 1) {
            float nb = __shfl_up(cv, d, 64);
            if (tid >= d) cv += nb;
        }
        cL[tid] = cv;
        betaL[tid] = beta[gb0 + (size_t)(t0 + tid) * Hc];
    }
    __syncthreads();

    {
        const int w = tid >> 6, lane = tid & 63;
        const int fr = lane & 15, fk8 = (lane >> 4) << 3;
        const int rr = (lane >> 4) << 2;
        short8 ak0 = *(const short8*)&kb16[w * 16 + fr][fk8];
        short8 ak1 = *(const short8*)&kb16[w * 16 + fr][fk8 + 32];
        short8 aq0 = *(const short8*)&qb16[w * 16 + fr][fk8];
        short8 aq1 = *(const short8*)&qb16[w * 16 + fr][fk8 + 32];
#pragma unroll
        for (int j = 0; j < 4; j++) {
            short8 b0 = *(const short8*)&kb16[j * 16 + fr][fk8];
            short8 b1 = *(const short8*)&kb16[j * 16 + fr][fk8 + 32];
            f32x4 kk = (f32x4){0.f, 0.f, 0.f, 0.f};
            f32x4 qk = (f32x4){0.f, 0.f, 0.f, 0.f};
            kk = __builtin_amdgcn_mfma_f32_16x16x32_bf16(ak0, b0, kk, 0, 0, 0);
            kk = __builtin_amdgcn_mfma_f32_16x16x32_bf16(ak1, b1, kk, 0, 0, 0);
            qk = __builtin_amdgcn_mfma_f32_16x16x32_bf16(aq0, b0, qk, 0, 0, 0);
            qk = __builtin_amdgcn_mfma_f32_16x16x32_bf16(aq1, b1, qk, 0, 0, 0);
#pragma unroll
            for (int r = 0; r < 4; r++) {
                int t = w * 16 + rr + r, s = j * 16 + fr;
                float E = expf(cL[t] - cL[s]);
                AtL[s][t] = (s < t) ? betaL[t] * E * kk[r] : 0.f;
                tmM[tile + (size_t)t * 64 + s] =
                    (s <= t) ? 0.125f * E * qk[r] : 0.f;
            }
        }
    }
    __syncthreads();

    {
        const int w = tid >> 6, lane = tid & 63;
        float acc[16];
#pragma unroll
        for (int di = 0; di < 16; di++)
            acc[di] = (lane == w * 16 + di) ? 1.f : 0.f;
#pragma unroll 4
        for (int s = 0; s < 64; s++) {
            float a = AtL[s][lane];
#pragma unroll
            for (int di = 0; di < 16; di++) {
                float ds = __shfl(acc[di], s, 64);
                acc[di] -= a * ds;
            }
        }
#pragma unroll
        for (int p = 0; p < 4; p++) {
            float4 v4 = make_float4(acc[p * 4 + 0], acc[p * 4 + 1],
                                    acc[p * 4 + 2], acc[p * 4 + 3]);
            *(float4*)&tmT[tile + (size_t)lane * 64 + w * 16 + p * 4] = v4;
        }
    }
}

// ---------------------------------------------------------------------------
// Sequential chunk scan v5: all four matmuls (KS/QS, T*RHS, M*delta, and the
// S UPDATE) on MFMA. S master lives in f32 MFMA accumulators of waves 0-3
// (wave w = dk-strip w*16); bf16 S^T operand copy in LDS for readouts.
// ---------------------------------------------------------------------------
__global__ void __launch_bounds__(512, 2) delta_scan(
    const float* __restrict__ kc, const float* __restrict__ qc,
    float* vo, const float* __restrict__ g, const float* __restrict__ beta,
    const float* __restrict__ tmT, const float* __restrict__ tmM) {
    const int bid = blockIdx.x;
    const int sl = bid >> 5;   // 0..7
    const int bh = bid & 31;   // 0..31 -> XCD = bh%8
    const int b = bh >> 4, h = bh & 15;
    const int tid = threadIdx.x;

    __shared__ __align__(16) float VL[CC][20];
    __shared__ float gamL[CC], egL[CC], betaL[CC];
    __shared__ __align__(16) unsigned short kb16[CC][72];  // K rows
    __shared__ __align__(16) unsigned short kh16[CC][72];  // K^T: [dk][t]
    __shared__ __align__(16) unsigned short qb16[CC][72];
    __shared__ __align__(16) unsigned short Tb16[CC][72];
    __shared__ __align__(16) unsigned short Mb16[CC][72];
    __shared__ __align__(16) unsigned short STb16[16][72];  // S^T bf16 copy
    __shared__ __align__(16) unsigned short DTb16[16][72];  // RHS^T bf16
    __shared__ __align__(16) unsigned short D2b16[16][72];  // delta^T bf16
    __shared__ __align__(16) unsigned short egd16[16][72];  // (eg*delta)^T

    const size_t qk0 = (size_t)b * Tc * KDIMc + h * DKc;
    const size_t v0 = (size_t)b * Tc * VDIMc + h * DVc + sl * 16;
    const size_t gb0 = (size_t)b * Tc * Hc + h;
    const size_t tb0 = (size_t)(bh * NCH) * 4096;

    for (int i = tid; i < 16 * 72; i += 512) ((unsigned short*)STb16)[i] = 0;

    const int r0 = tid >> 4, c40 = (tid & 15) << 2;
    const int r1 = r0 + 32;
    const int wid = tid >> 6, lane = tid & 63;
    const int fr = lane & 15;
    const int fk8 = (lane >> 4) << 3;
    const int rr = (lane >> 4) << 2;

    f32x4 accS = (f32x4){0.f, 0.f, 0.f, 0.f};  // waves 0-3: S[w*16+rr+r][fr]

    float4 kv0, kv1, qv0, qv1, tv0, tv1, mv0, mv1, vv0;
    float gvr = 0.f, bvr = 0.f;

#define LOADREGS(CH)                                                          \
    {                                                                         \
        const size_t tK = qk0 + (size_t)(CH) * CC * KDIMc;                    \
        const size_t tile_ = tb0 + (size_t)(CH) * 4096;                       \
        kv0 = *(const float4*)&kc[tK + (size_t)r0 * KDIMc + c40];             \
        kv1 = *(const float4*)&kc[tK + (size_t)r1 * KDIMc + c40];             \
        qv0 = *(const float4*)&qc[tK + (size_t)r0 * KDIMc + c40];             \
        qv1 = *(const float4*)&qc[tK + (size_t)r1 * KDIMc + c40];             \
        tv0 = *(const float4*)&tmT[tile_ + (size_t)tid * 4];                  \
        tv1 = *(const float4*)&tmT[tile_ + (size_t)(tid + 512) * 4];          \
        mv0 = *(const float4*)&tmM[tile_ + (size_t)tid * 4];                  \
        mv1 = *(const float4*)&tmM[tile_ + (size_t)(tid + 512) * 4];          \
        if (tid < 256)                                                        \
            vv0 = *(const float4*)&vo[v0 +                                    \
                                      (size_t)((CH) * CC + (tid >> 2)) *     \
                                          VDIMc +                             \
                                      ((tid & 3) << 2)];                      \
        if (tid < 64) {                                                       \
            gvr = g[gb0 + (size_t)((CH) * CC + tid) * Hc];                    \
            bvr = beta[gb0 + (size_t)((CH) * CC + tid) * Hc];                 \
        }                                                                     \
    }

    LOADREGS(0);

#pragma unroll 1
    for (int ch = 0; ch < NCH; ch++) {
        __syncthreads();  // B0: prev chunk fully done (STb16 visible)

        // ---- stage regs -> LDS
        {
            *(uint2*)&kb16[r0][c40] = make_uint2(pk2(kv0.x, kv0.y), pk2(kv0.z, kv0.w));
            *(uint2*)&kb16[r1][c40] = make_uint2(pk2(kv1.x, kv1.y), pk2(kv1.z, kv1.w));
            *(uint2*)&qb16[r0][c40] = make_uint2(pk2(qv0.x, qv0.y), pk2(qv0.z, qv0.w));
            *(uint2*)&qb16[r1][c40] = make_uint2(pk2(qv1.x, qv1.y), pk2(qv1.z, qv1.w));
            *(uint2*)&Tb16[r0][c40] = make_uint2(pk2(tv0.x, tv0.y), pk2(tv0.z, tv0.w));
            *(uint2*)&Tb16[r1][c40] = make_uint2(pk2(tv1.x, tv1.y), pk2(tv1.z, tv1.w));
            *(uint2*)&Mb16[r0][c40] = make_uint2(pk2(mv0.x, mv0.y), pk2(mv0.z, mv0.w));
            *(uint2*)&Mb16[r1][c40] = make_uint2(pk2(mv1.x, mv1.y), pk2(mv1.z, mv1.w));
            float* kp0 = (float*)&kv0;
            float* kp1 = (float*)&kv1;
#pragma unroll
            for (int i = 0; i < 4; i++) {
                kh16[c40 + i][r0] = f2bf(kp0[i]);
                kh16[c40 + i][r1] = f2bf(kp1[i]);
            }
            if (tid < 256) *(float4*)&VL[tid >> 2][(tid & 3) << 2] = vv0;
            if (tid < 64) {
                float cv = gvr;
#pragma unroll
                for (int d = 1; d < 64; d <<= 1) {
                    float nb = __shfl_up(cv, d, 64);
                    if (tid >= d) cv += nb;
                }
                gamL[tid] = expf(cv);
                float cend = __shfl(cv, 63, 64);
                egL[tid] = expf(cend - cv);
                betaL[tid] = bvr;
            }
        }
        if (ch + 1 < NCH) LOADREGS(ch + 1);
        __syncthreads();  // B1: stage visible

        // ---- phase 1: KS (waves 0-3) and QS (waves 4-7) via MFMA
        f32x4 acc1 = (f32x4){0.f, 0.f, 0.f, 0.f};
        {
            short8 bs0 = *(const short8*)&STb16[fr][fk8];
            short8 bs1 = *(const short8*)&STb16[fr][fk8 + 32];
            if (wid < 4) {
                const int m0 = wid << 4;
                short8 a0 = *(const short8*)&kb16[m0 + fr][fk8];
                short8 a1 = *(const short8*)&kb16[m0 + fr][fk8 + 32];
                acc1 = __builtin_amdgcn_mfma_f32_16x16x32_bf16(a0, bs0, acc1, 0, 0, 0);
                acc1 = __builtin_amdgcn_mfma_f32_16x16x32_bf16(a1, bs1, acc1, 0, 0, 0);
#pragma unroll
                for (int r = 0; r < 4; r++) {
                    int t = m0 + rr + r;
                    float rhs = betaL[t] * (VL[t][fr] - gamL[t] * acc1[r]);
                    DTb16[fr][t] = f2bf(rhs);
                }
            } else {
                const int m0 = (wid - 4) << 4;
                short8 a0 = *(const short8*)&qb16[m0 + fr][fk8];
                short8 a1 = *(const short8*)&qb16[m0 + fr][fk8 + 32];
                acc1 = __builtin_amdgcn_mfma_f32_16x16x32_bf16(a0, bs0, acc1, 0, 0, 0);
                acc1 = __builtin_amdgcn_mfma_f32_16x16x32_bf16(a1, bs1, acc1, 0, 0, 0);
#pragma unroll
                for (int r = 0; r < 4; r++) {
                    int t = m0 + rr + r;
                    acc1[r] *= 0.125f * gamL[t];
                }
            }
        }
        __syncthreads();  // B2: RHS ready

        // ---- phase 2: delta = T * RHS (waves 0-3); write delta and eg*delta
        if (wid < 4) {
            const int m0 = wid << 4;
            short8 a0 = *(const short8*)&Tb16[m0 + fr][fk8];
            short8 a1 = *(const short8*)&Tb16[m0 + fr][fk8 + 32];
            short8 b0 = *(const short8*)&DTb16[fr][fk8];
            short8 b1 = *(const short8*)&DTb16[fr][fk8 + 32];
            f32x4 d = (f32x4){0.f, 0.f, 0.f, 0.f};
            d = __builtin_amdgcn_mfma_f32_16x16x32_bf16(a0, b0, d, 0, 0, 0);
            d = __builtin_amdgcn_mfma_f32_16x16x32_bf16(a1, b1, d, 0, 0, 0);
#pragma unroll
            for (int r = 0; r < 4; r++) {
                int t = m0 + rr + r;
                D2b16[fr][t] = f2bf(d[r]);
                egd16[fr][t] = f2bf(egL[t] * d[r]);
            }
        }
        __syncthreads();  // B3: delta ready

        // ---- phase 3 (waves 4-7): O = M*delta + scaledQS, store direct.
        //      phase 4 (waves 0-3): S = ge*S + K^T(eg*delta) via MFMA.
        if (wid >= 4) {
            const int m0 = (wid - 4) << 4;
            short8 a0 = *(const short8*)&Mb16[m0 + fr][fk8];
            short8 a1 = *(const short8*)&Mb16[m0 + fr][fk8 + 32];
            short8 b0 = *(const short8*)&D2b16[fr][fk8];
            short8 b1 = *(const short8*)&D2b16[fr][fk8 + 32];
            f32x4 o = acc1;  // 0.125*gam*QS
            o = __builtin_amdgcn_mfma_f32_16x16x32_bf16(a0, b0, o, 0, 0, 0);
            o = __builtin_amdgcn_mfma_f32_16x16x32_bf16(a1, b1, o, 0, 0, 0);
#pragma unroll
            for (int r = 0; r < 4; r++)
                vo[v0 + (size_t)(ch * CC + m0 + rr + r) * VDIMc + fr] = o[r];
        } else {
            const int m0 = wid << 4;
            const float ge = gamL[63];
            short8 a0 = *(const short8*)&kh16[m0 + fr][fk8];
            short8 a1 = *(const short8*)&kh16[m0 + fr][fk8 + 32];
            short8 b0 = *(const short8*)&egd16[fr][fk8];
            short8 b1 = *(const short8*)&egd16[fr][fk8 + 32];
#pragma unroll
            for (int r = 0; r < 4; r++) accS[r] *= ge;
            accS = __builtin_amdgcn_mfma_f32_16x16x32_bf16(a0, b0, accS, 0, 0, 0);
            accS = __builtin_amdgcn_mfma_f32_16x16x32_bf16(a1, b1, accS, 0, 0, 0);
#pragma unroll
            for (int r = 0; r < 4; r++)
                STb16[fr][m0 + rr + r] = f2bf(accS[r]);
        }
    }
#undef LOADREGS
}

// ---------------------------------------------------------------------------
// Workspace: same 235.9 MB layout; rfac aliases gbuf region? No - gbuf is
// live (g) until scan ends; rfac runs after scan when gbuf is dead. OK.
// obb aliases tm (dead after scan).
// ---------------------------------------------------------------------------
extern "C" void kernel_launch(void* const* d_in, const int* in_sizes, int n_in,
                              void* d_out, int out_size, void* d_ws,
                              size_t ws_size, hipStream_t stream) {
    const float* x = (const float*)d_in[0];
    const float* w_q = (const float*)d_in[1];
    const float* w_k = (const float*)d_in[2];
    const float* w_v = (const float*)d_in[3];
    const float* w_a = (const float*)d_in[4];
    const float* w_b = (const float*)d_in[5];
    const float* w_g = (const float*)d_in[6];
    const float* w_out = (const float*)d_in[7];
    const float* A_log = (const float*)d_in[8];
    const float* dt_bias = (const float*)d_in[9];
    const float* conv_q = (const float*)d_in[10];
    const float* conv_k = (const float*)d_in[11];
    const float* conv_v = (const float*)d_in[12];
    const float* norm_w = (const float*)d_in[13];

    float* ws = (float*)d_ws;
    const size_t M = Mrows;
    float* qb = ws;
    float* kb = qb + M * KDIMc;
    float* vb = kb + M * KDIMc;
    float* tm = vb + M * VDIMc;          // T (8.4M) + M (8.4M)
    float* gbuf = tm + M * VDIMc;
    float* bbuf = gbuf + M * Hc;
    float* xtra = bbuf + M * Hc;
    float* tmT = tm;
    float* tmM = tm + (size_t)Bc * Hc * NCH * 4096;
    float* halo = tm;                     // alias: dead before tm_precompute
    unsigned short* obb = (unsigned short*)tm;  // alias: after scan, tm dead
    float* rfac = gbuf;                   // alias: g dead after scan

    unsigned short* xb = (unsigned short*)xtra;
    unsigned short* wqT = xb + M * KDIMc;
    unsigned short* wkT = wqT + (size_t)KDIMc * Dc;
    unsigned short* wvT = wkT + (size_t)KDIMc * Dc;
    unsigned short* wgT = wvT + (size_t)VDIMc * Dc;
    unsigned short* woT = wgT + (size_t)VDIMc * Dc;

    // 0) conversions
    convert_bf16<<<dim3(M * Dc / 4 / 256), 256, 0, stream>>>(x, xb, M * Dc / 4);
    transp_bf16<<<dim3((KDIMc / 32) * (Dc / 32)), 256, 0, stream>>>(w_q, wqT,
                                                                    Dc, KDIMc);
    transp_bf16<<<dim3((KDIMc / 32) * (Dc / 32)), 256, 0, stream>>>(w_k, wkT,
                                                                    Dc, KDIMc);
    transp_bf16<<<dim3((VDIMc / 32) * (Dc / 32)), 256, 0, stream>>>(w_v, wvT,
                                                                    Dc, VDIMc);
    transp_bf16<<<dim3((VDIMc / 32) * (Dc / 32)), 256, 0, stream>>>(w_g, wgT,
                                                                    Dc, VDIMc);
    transp_bf16<<<dim3((Dc / 32) * (VDIMc / 32)), 256, 0, stream>>>(
        w_out, woT, VDIMc, Dc);

    // 1) q/k/v projections (bf16 MFMA)
    gemm_bf16<<<dim3((M / 128) * (KDIMc / 128)), 256, 0, stream>>>(
        xb, wqT, qb, M, KDIMc, Dc);
    gemm_bf16<<<dim3((M / 128) * (KDIMc / 128)), 256, 0, stream>>>(
        xb, wkT, kb, M, KDIMc, Dc);
    gemm_bf16<<<dim3((M / 128) * (VDIMc / 128)), 256, 0, stream>>>(
        xb, wvT, vb, M, VDIMc, Dc);

    // 2) a/b projections fused with activation -> g, beta
    ab_proj<<<dim3(M / 4), 256, 0, stream>>>(x, w_a, w_b, A_log, dt_bias, gbuf,
                                             bbuf);

    // 3) conv + silu (+ l2norm for q,k), in place with halo save
    {
        const int nqk = Bc * (Tc / 64 - 1) * 3 * KDIMc;
        const int nv = Bc * (Tc / 64 - 1) * 3 * VDIMc;
        save_halo<KDIMc><<<dim3((nqk + 255) / 256), 256, 0, stream>>>(qb, halo);
        conv_silu_inplace<KDIMc, true>
            <<<dim3(Bc * (Tc / 64) * (KDIMc / 256)), 256, 0, stream>>>(
                qb, conv_q, halo);
        save_halo<KDIMc><<<dim3((nqk + 255) / 256), 256, 0, stream>>>(kb, halo);
        conv_silu_inplace<KDIMc, true>
            <<<dim3(Bc * (Tc / 64) * (KDIMc / 256)), 256, 0, stream>>>(
                kb, conv_k, halo);
        save_halo<VDIMc><<<dim3((nv + 255) / 256), 256, 0, stream>>>(vb, halo);
        conv_silu_inplace<VDIMc, false>
            <<<dim3(Bc * (Tc / 64) * (VDIMc / 256)), 256, 0, stream>>>(
                vb, conv_v, halo);
    }

    // 4a) parallel precompute of T=(I+A)^{-1} and M (MFMA Gram)
    tm_precompute<<<dim3(Bc * Hc * NCH), 256, 0, stream>>>(kb, qb, gbuf, bbuf,
                                                           tmT, tmM);
    // 4b) sequential scan v5 (all-MFMA phases, register-resident S)
    delta_scan<<<dim3(Bc * Hc * 8), 512, 0, stream>>>(kb, qb, vb, gbuf, bbuf,
                                                      tmT, tmM);

    // 5) rms factors from o (=vb), then gate GEMM fused with rms epilogue
    rfac_kernel<<<dim3(M * Hc / 4), 256, 0, stream>>>(vb, rfac);
    gemm_gate_rms<<<dim3((M / 128) * (VDIMc / 128)), 256, 0, stream>>>(
        xb, wgT, vb, rfac, norm_w, obb, M, VDIMc, Dc);

    // 6) output projection (bf16 MFMA) -> d_out
    gemm_bf16<<<dim3((M / 128) * (Dc / 128)), 256, 0, stream>>>(
        obb, woT, (float*)d_out, M, Dc, VDIMc);
}

// Round 12
// 690.220 us; speedup vs baseline: 32.2303x; 1.1110x over previous
//
#include <hip/hip_runtime.h>
#include <hip/hip_bf16.h>
#include <math.h>

// Problem constants
#define Bc 2
#define Tc 4096
#define Dc 1024
#define Hc 16
#define DKc 64
#define DVc 128
#define KDIMc 1024   // H*DK
#define VDIMc 2048   // H*DV
#define Mrows (Bc*Tc) // 8192
#define CC 64        // scan chunk size
#define NCH (Tc/CC)  // 64 chunks

typedef short short8 __attribute__((ext_vector_type(8)));
typedef float f32x4 __attribute__((ext_vector_type(4)));

__device__ __forceinline__ float siluf(float x) {
    return x / (1.f + expf(-x));
}
__device__ __forceinline__ float dot4(float4 a, float4 b) {
    return a.x * b.x + a.y * b.y + a.z * b.z + a.w * b.w;
}
__device__ __forceinline__ unsigned short f2bf(float f) {
    unsigned int u = __float_as_uint(f);
    unsigned int r = (u + 0x7fffu + ((u >> 16) & 1u)) >> 16;
    return (unsigned short)r;
}
__device__ __forceinline__ unsigned int pk2(float a, float b) {
    return (unsigned)f2bf(a) | ((unsigned)f2bf(b) << 16);
}
// async global->LDS DMA, 16B per lane; lds base must be wave-uniform.
__device__ __forceinline__ void gload16(const unsigned short* g,
                                        unsigned short* l) {
    __builtin_amdgcn_global_load_lds(
        (const __attribute__((address_space(1))) unsigned int*)g,
        (__attribute__((address_space(3))) unsigned int*)l, 16, 0, 0);
}

// ---------------------------------------------------------------------------
// x (f32) -> bf16, straight elementwise. 4 elems/thread.
// ---------------------------------------------------------------------------
__global__ void __launch_bounds__(256) convert_bf16(
    const float* __restrict__ in, unsigned short* __restrict__ out, int n4) {
    int g = blockIdx.x * 256 + threadIdx.x;
    if (g >= n4) return;
    float4 v = *(const float4*)&in[(size_t)g * 4];
    *(uint2*)&out[(size_t)g * 4] = make_uint2(pk2(v.x, v.y), pk2(v.z, v.w));
}

// ---------------------------------------------------------------------------
// Transpose + convert: in f32 [K][N] -> out bf16 [N][K]. 32x32 LDS tiles.
// ---------------------------------------------------------------------------
__global__ void __launch_bounds__(256) transp_bf16(
    const float* __restrict__ in, unsigned short* __restrict__ out, int K,
    int N) {
    __shared__ float t[32][33];
    const int nbx = N >> 5;
    const int n0 = (blockIdx.x % nbx) << 5;
    const int k0 = (blockIdx.x / nbx) << 5;
    const int c = threadIdx.x & 31, r4 = (threadIdx.x >> 5) << 2;
#pragma unroll
    for (int i = 0; i < 4; i++)
        t[r4 + i][c] = in[(size_t)(k0 + r4 + i) * N + n0 + c];
    __syncthreads();
#pragma unroll
    for (int i = 0; i < 4; i++)
        out[(size_t)(n0 + r4 + i) * K + k0 + c] = f2bf(t[c][r4 + i]);
}

// ---------------------------------------------------------------------------
// Transpose f32 [Dc][16] -> [16][Dc] (for w_a / w_b). Grid = Dc/64.
// ---------------------------------------------------------------------------
__global__ void __launch_bounds__(256) transp_f32w(
    const float* __restrict__ in, float* __restrict__ out) {
    __shared__ float t[64][17];
    const int k0 = blockIdx.x * 64;
    const int r = threadIdx.x >> 2, c4 = (threadIdx.x & 3) << 2;
    float4 v = *(const float4*)&in[(size_t)(k0 + r) * 16 + c4];
    t[r][c4 + 0] = v.x;
    t[r][c4 + 1] = v.y;
    t[r][c4 + 2] = v.z;
    t[r][c4 + 3] = v.w;
    __syncthreads();
    const int n = threadIdx.x >> 4;
    const int kk = (threadIdx.x & 15) << 2;
    out[(size_t)n * Dc + k0 + kk + 0] = t[kk + 0][n];
    out[(size_t)n * Dc + k0 + kk + 1] = t[kk + 1][n];
    out[(size_t)n * Dc + k0 + kk + 2] = t[kk + 2][n];
    out[(size_t)n * Dc + k0 + kk + 3] = t[kk + 3][n];
}

// ---------------------------------------------------------------------------
// bf16 MFMA GEMM: C[M,N] f32 = A[M,K] bf16 (row-major) @ Bt[N,K] bf16.
// 128x128 tile, BK=32, 4 waves, global_load_lds staging.
// ---------------------------------------------------------------------------
__global__ void __launch_bounds__(256) gemm_bf16(
    const unsigned short* __restrict__ A, const unsigned short* __restrict__ Bt,
    float* __restrict__ C, int M, int N, int K) {
    __shared__ unsigned short As[128 * 32];
    __shared__ unsigned short Bs[128 * 32];
    const int tid = threadIdx.x;
    const int nbx = N >> 7;
    const int bx = blockIdx.x % nbx, by = blockIdx.x / nbx;
    const int m0 = by << 7, n0 = bx << 7;
    const int w = tid >> 6, lane = tid & 63;
    const int wr = (w >> 1) << 6, wc = (w & 1) << 6;
    const int fr = lane & 15, fk8 = (lane >> 4) << 3;
    const int grow = lane >> 2;
    const int gcol = (lane & 3) << 3;

    f32x4 acc[4][4];
#pragma unroll
    for (int i = 0; i < 4; i++)
#pragma unroll
        for (int j = 0; j < 4; j++)
            acc[i][j] = (f32x4){0.f, 0.f, 0.f, 0.f};

    const int nkt = K >> 5;
    for (int kt = 0; kt < nkt; kt++) {
        __syncthreads();
        {
            const size_t kb = (size_t)(kt << 5) + gcol;
#pragma unroll
            for (int r = 0; r < 2; r++) {
                const int rows = r * 64 + w * 16;
                gload16(&A[(size_t)(m0 + rows + grow) * K + kb],
                        &As[rows * 32]);
                gload16(&Bt[(size_t)(n0 + rows + grow) * K + kb],
                        &Bs[rows * 32]);
            }
        }
        __syncthreads();
        short8 af[4], bfr[4];
#pragma unroll
        for (int i = 0; i < 4; i++)
            af[i] = *(const short8*)&As[(wr + i * 16 + fr) * 32 + fk8];
#pragma unroll
        for (int j = 0; j < 4; j++)
            bfr[j] = *(const short8*)&Bs[(wc + j * 16 + fr) * 32 + fk8];
#pragma unroll
        for (int i = 0; i < 4; i++)
#pragma unroll
            for (int j = 0; j < 4; j++)
                acc[i][j] = __builtin_amdgcn_mfma_f32_16x16x32_bf16(
                    af[i], bfr[j], acc[i][j], 0, 0, 0);
    }
    const int cr = (lane >> 4) << 2;
#pragma unroll
    for (int i = 0; i < 4; i++)
#pragma unroll
        for (int j = 0; j < 4; j++) {
#pragma unroll
            for (int r = 0; r < 4; r++) {
                C[(size_t)(m0 + wr + i * 16 + cr + r) * N + n0 + wc + j * 16 +
                  fr] = acc[i][j][r];
            }
        }
}

// ---------------------------------------------------------------------------
// Gate GEMM fused with gated RMSNorm epilogue: obb = rms(o)*w*silu(x@w_g).
// ---------------------------------------------------------------------------
__global__ void __launch_bounds__(256) gemm_gate_rms(
    const unsigned short* __restrict__ A, const unsigned short* __restrict__ Bt,
    const float* __restrict__ o, const float* __restrict__ rfac,
    const float* __restrict__ norm_w, unsigned short* __restrict__ out,
    int M, int N, int K) {
    __shared__ unsigned short As[128 * 32];
    __shared__ unsigned short Bs[128 * 32];
    const int tid = threadIdx.x;
    const int nbx = N >> 7;
    const int bx = blockIdx.x % nbx, by = blockIdx.x / nbx;
    const int m0 = by << 7, n0 = bx << 7;
    const int h = n0 >> 7;
    const int w = tid >> 6, lane = tid & 63;
    const int wr = (w >> 1) << 6, wc = (w & 1) << 6;
    const int fr = lane & 15, fk8 = (lane >> 4) << 3;
    const int grow = lane >> 2;
    const int gcol = (lane & 3) << 3;

    f32x4 acc[4][4];
#pragma unroll
    for (int i = 0; i < 4; i++)
#pragma unroll
        for (int j = 0; j < 4; j++)
            acc[i][j] = (f32x4){0.f, 0.f, 0.f, 0.f};

    const int nkt = K >> 5;
    for (int kt = 0; kt < nkt; kt++) {
        __syncthreads();
        {
            const size_t kb = (size_t)(kt << 5) + gcol;
#pragma unroll
            for (int r = 0; r < 2; r++) {
                const int rows = r * 64 + w * 16;
                gload16(&A[(size_t)(m0 + rows + grow) * K + kb],
                        &As[rows * 32]);
                gload16(&Bt[(size_t)(n0 + rows + grow) * K + kb],
                        &Bs[rows * 32]);
            }
        }
        __syncthreads();
        short8 af[4], bfr[4];
#pragma unroll
        for (int i = 0; i < 4; i++)
            af[i] = *(const short8*)&As[(wr + i * 16 + fr) * 32 + fk8];
#pragma unroll
        for (int j = 0; j < 4; j++)
            bfr[j] = *(const short8*)&Bs[(wc + j * 16 + fr) * 32 + fk8];
#pragma unroll
        for (int i = 0; i < 4; i++)
#pragma unroll
            for (int j = 0; j < 4; j++)
                acc[i][j] = __builtin_amdgcn_mfma_f32_16x16x32_bf16(
                    af[i], bfr[j], acc[i][j], 0, 0, 0);
    }
    const int cr = (lane >> 4) << 2;
#pragma unroll
    for (int i = 0; i < 4; i++)
#pragma unroll
        for (int j = 0; j < 4; j++) {
            const int colh = wc + j * 16 + fr;
            const float nw = norm_w[colh];
#pragma unroll
            for (int r = 0; r < 4; r++) {
                const int row = m0 + wr + i * 16 + cr + r;
                float ov = o[(size_t)row * VDIMc + n0 + colh];
                float f = rfac[(size_t)row * Hc + h];
                float y = ov * f * nw * siluf(acc[i][j][r]);
                out[(size_t)row * VDIMc + n0 + colh] = f2bf(y);
            }
        }
}

// ---------------------------------------------------------------------------
// Per-(row,h) RMS factor: rf = rsqrt(mean(o^2)+eps). One wave per 128-row.
// ---------------------------------------------------------------------------
__global__ void __launch_bounds__(256) rfac_kernel(
    const float* __restrict__ o, float* __restrict__ rf) {
    const int row = blockIdx.x * 4 + (threadIdx.x >> 6);
    const int lane = threadIdx.x & 63;
    const size_t base = (size_t)row * DVc;
    float2 ov = *(const float2*)&o[base + lane * 2];
    float ss = ov.x * ov.x + ov.y * ov.y;
#pragma unroll
    for (int m = 1; m < 64; m <<= 1) ss += __shfl_xor(ss, m, 64);
    if (lane == 0) rf[row] = rsqrtf(ss * (1.f / 128.f) + 1e-5f);
}

// ---------------------------------------------------------------------------
// a/b projections v2: transposed f32 weights (float4 loads), one WAVE per
// 4 rows so each weight-float4 is amortized over 4 x-float4s.
// lane = (h<<2)|kg; block = 16 rows (4 waves). R11's ab_proj was load-issue
// bound at 176us (576 load instrs/thread, 512 scalar).
// ---------------------------------------------------------------------------
__global__ void __launch_bounds__(256) ab_proj(
    const float* __restrict__ x, const float* __restrict__ w_aT,
    const float* __restrict__ w_bT, const float* __restrict__ A_log,
    const float* __restrict__ dt_bias, float* __restrict__ g_out,
    float* __restrict__ beta_out) {
    const int wv = threadIdx.x >> 6;
    const int lane = threadIdx.x & 63;
    const int h = lane >> 2, kg = lane & 3;
    const int row0 = blockIdx.x * 16 + wv * 4;
    const float* wa = w_aT + (size_t)h * Dc + kg * 256;
    const float* wb = w_bT + (size_t)h * Dc + kg * 256;
    const float* xr = x + (size_t)row0 * Dc + kg * 256;
    float pa[4] = {0.f, 0.f, 0.f, 0.f}, pb[4] = {0.f, 0.f, 0.f, 0.f};
#pragma unroll 4
    for (int k = 0; k < 256; k += 4) {
        float4 a4 = *(const float4*)&wa[k];
        float4 b4 = *(const float4*)&wb[k];
#pragma unroll
        for (int r = 0; r < 4; r++) {
            float4 x4 = *(const float4*)&xr[(size_t)r * Dc + k];
            pa[r] += dot4(x4, a4);
            pb[r] += dot4(x4, b4);
        }
    }
#pragma unroll
    for (int r = 0; r < 4; r++) {
        pa[r] += __shfl_xor(pa[r], 1, 64);
        pa[r] += __shfl_xor(pa[r], 2, 64);
        pb[r] += __shfl_xor(pb[r], 1, 64);
        pb[r] += __shfl_xor(pb[r], 2, 64);
    }
    if (kg == 0) {
        const float el = expf(A_log[h]);
        const float db = dt_bias[h];
#pragma unroll
        for (int r = 0; r < 4; r++) {
            float arg = pa[r] + db;
            float sp = fmaxf(arg, 0.f) + log1pf(expf(-fabsf(arg)));
            g_out[(size_t)(row0 + r) * Hc + h] = -el * sp;
            beta_out[(size_t)(row0 + r) * Hc + h] =
                2.f / (1.f + expf(-pb[r]));
        }
    }
}

// ---------------------------------------------------------------------------
// Save 3-row halos at 64-step chunk boundaries (for in-place conv).
// ---------------------------------------------------------------------------
template <int C>
__global__ void __launch_bounds__(256) save_halo(
    const float* __restrict__ in, float* __restrict__ halo) {
    const int g = blockIdx.x * 256 + threadIdx.x;
    const int total = Bc * (Tc / 64 - 1) * 3 * C;
    if (g >= total) return;
    const int c = g % C;
    int r = g / C;
    const int j = r % 3;
    r /= 3;
    const int chunk = r % (Tc / 64 - 1) + 1;
    const int b = r / (Tc / 64 - 1);
    halo[((size_t)(b * 64 + chunk) * 3 + j) * C + c] =
        in[((size_t)b * Tc + chunk * 64 - 3 + j) * C + c];
}

// ---------------------------------------------------------------------------
// Depthwise causal conv1d (K=4) + SiLU (+ optional l2norm), IN PLACE.
// ---------------------------------------------------------------------------
template <int C, bool L2N>
__global__ void __launch_bounds__(256) conv_silu_inplace(
    float* __restrict__ buf, const float* __restrict__ w,
    const float* __restrict__ halo) {
    constexpr int CB = C / 256;
    const int bidx = blockIdx.x;
    const int cb = bidx % CB;
    const int tchunk = (bidx / CB) % (Tc / 64);
    const int b = bidx / (CB * (Tc / 64));
    const int c = cb * 256 + threadIdx.x;
    const int t0 = tchunk * 64;
    const float w0 = w[c * 4 + 0], w1 = w[c * 4 + 1], w2 = w[c * 4 + 2],
                w3 = w[c * 4 + 3];
    float xm3 = 0.f, xm2 = 0.f, xm1 = 0.f;
    if (tchunk > 0) {
        const float* hp = halo + (size_t)(b * 64 + tchunk) * 3 * C + c;
        xm3 = hp[0];
        xm2 = hp[C];
        xm1 = hp[2 * C];
    }
    float* p = buf + (size_t)b * Tc * C + c;
#pragma unroll 4
    for (int i = 0; i < 64; i++) {
        float xt = p[(size_t)(t0 + i) * C];
        float y = w0 * xm3 + w1 * xm2 + w2 * xm1 + w3 * xt;
        y = siluf(y);
        if (L2N) {
            float ss = y * y;
#pragma unroll
            for (int m = 1; m < 64; m <<= 1) ss += __shfl_xor(ss, m, 64);
            y *= rsqrtf(ss + 1e-6f);
        }
        p[(size_t)(t0 + i) * C] = y;
        xm3 = xm2;
        xm2 = xm1;
        xm1 = xt;
    }
}

// ---------------------------------------------------------------------------
// TM precompute: Gram via bf16 MFMA, f32 solve. T,M row-major [t][s].
// ---------------------------------------------------------------------------
__global__ void __launch_bounds__(256) tm_precompute(
    const float* __restrict__ kc, const float* __restrict__ qc,
    const float* __restrict__ g, const float* __restrict__ beta,
    float* __restrict__ tmT, float* __restrict__ tmM) {
    const int bid = blockIdx.x;
    const int ch = bid & (NCH - 1);
    const int bh = bid >> 6;
    const int b = bh >> 4, h = bh & 15;
    const int tid = threadIdx.x;
    const int t0 = ch * CC;

    __shared__ __align__(16) unsigned short kb16[CC][72];
    __shared__ __align__(16) unsigned short qb16[CC][72];
    __shared__ __align__(16) float AtL[CC][DKc + 4];  // A^T: AtL[s][t]
    __shared__ float cL[CC], betaL[CC];

    const size_t qk0 = (size_t)b * Tc * KDIMc + h * DKc;
    const size_t gb0 = (size_t)b * Tc * Hc + h;
    const size_t tile = (size_t)(bh * NCH + ch) * 4096;

#pragma unroll
    for (int i = 0; i < 4; i++) {
        int e = tid + i * 256;
        int r = e >> 4, c4 = (e & 15) << 2;
        float4 kv = *(const float4*)&kc[qk0 + (size_t)(t0 + r) * KDIMc + c4];
        float4 qv = *(const float4*)&qc[qk0 + (size_t)(t0 + r) * KDIMc + c4];
        *(uint2*)&kb16[r][c4] = make_uint2(pk2(kv.x, kv.y), pk2(kv.z, kv.w));
        *(uint2*)&qb16[r][c4] = make_uint2(pk2(qv.x, qv.y), pk2(qv.z, qv.w));
    }
    if (tid < 64) {
        float gv = g[gb0 + (size_t)(t0 + tid) * Hc];
        float cv = gv;
#pragma unroll
        for (int d = 1; d < 64; d <<= 1) {
            float nb = __shfl_up(cv, d, 64);
            if (tid >= d) cv += nb;
        }
        cL[tid] = cv;
        betaL[tid] = beta[gb0 + (size_t)(t0 + tid) * Hc];
    }
    __syncthreads();

    {
        const int w = tid >> 6, lane = tid & 63;
        const int fr = lane & 15, fk8 = (lane >> 4) << 3;
        const int rr = (lane >> 4) << 2;
        short8 ak0 = *(const short8*)&kb16[w * 16 + fr][fk8];
        short8 ak1 = *(const short8*)&kb16[w * 16 + fr][fk8 + 32];
        short8 aq0 = *(const short8*)&qb16[w * 16 + fr][fk8];
        short8 aq1 = *(const short8*)&qb16[w * 16 + fr][fk8 + 32];
#pragma unroll
        for (int j = 0; j < 4; j++) {
            short8 b0 = *(const short8*)&kb16[j * 16 + fr][fk8];
            short8 b1 = *(const short8*)&kb16[j * 16 + fr][fk8 + 32];
            f32x4 kk = (f32x4){0.f, 0.f, 0.f, 0.f};
            f32x4 qk = (f32x4){0.f, 0.f, 0.f, 0.f};
            kk = __builtin_amdgcn_mfma_f32_16x16x32_bf16(ak0, b0, kk, 0, 0, 0);
            kk = __builtin_amdgcn_mfma_f32_16x16x32_bf16(ak1, b1, kk, 0, 0, 0);
            qk = __builtin_amdgcn_mfma_f32_16x16x32_bf16(aq0, b0, qk, 0, 0, 0);
            qk = __builtin_amdgcn_mfma_f32_16x16x32_bf16(aq1, b1, qk, 0, 0, 0);
#pragma unroll
            for (int r = 0; r < 4; r++) {
                int t = w * 16 + rr + r, s = j * 16 + fr;
                float E = expf(cL[t] - cL[s]);
                AtL[s][t] = (s < t) ? betaL[t] * E * kk[r] : 0.f;
                tmM[tile + (size_t)t * 64 + s] =
                    (s <= t) ? 0.125f * E * qk[r] : 0.f;
            }
        }
    }
    __syncthreads();

    {
        const int w = tid >> 6, lane = tid & 63;
        float acc[16];
#pragma unroll
        for (int di = 0; di < 16; di++)
            acc[di] = (lane == w * 16 + di) ? 1.f : 0.f;
#pragma unroll 4
        for (int s = 0; s < 64; s++) {
            float a = AtL[s][lane];
#pragma unroll
            for (int di = 0; di < 16; di++) {
                float ds = __shfl(acc[di], s, 64);
                acc[di] -= a * ds;
            }
        }
#pragma unroll
        for (int p = 0; p < 4; p++) {
            float4 v4 = make_float4(acc[p * 4 + 0], acc[p * 4 + 1],
                                    acc[p * 4 + 2], acc[p * 4 + 3]);
            *(float4*)&tmT[tile + (size_t)lane * 64 + w * 16 + p * 4] = v4;
        }
    }
}

// ---------------------------------------------------------------------------
// Sequential chunk scan v5: all-MFMA phases, register-resident S.
// ---------------------------------------------------------------------------
__global__ void __launch_bounds__(512, 2) delta_scan(
    const float* __restrict__ kc, const float* __restrict__ qc,
    float* vo, const float* __restrict__ g, const float* __restrict__ beta,
    const float* __restrict__ tmT, const float* __restrict__ tmM) {
    const int bid = blockIdx.x;
    const int sl = bid >> 5;   // 0..7
    const int bh = bid & 31;   // 0..31 -> XCD = bh%8
    const int b = bh >> 4, h = bh & 15;
    const int tid = threadIdx.x;

    __shared__ __align__(16) float VL[CC][20];
    __shared__ float gamL[CC], egL[CC], betaL[CC];
    __shared__ __align__(16) unsigned short kb16[CC][72];  // K rows
    __shared__ __align__(16) unsigned short kh16[CC][72];  // K^T: [dk][t]
    __shared__ __align__(16) unsigned short qb16[CC][72];
    __shared__ __align__(16) unsigned short Tb16[CC][72];
    __shared__ __align__(16) unsigned short Mb16[CC][72];
    __shared__ __align__(16) unsigned short STb16[16][72];  // S^T bf16 copy
    __shared__ __align__(16) unsigned short DTb16[16][72];  // RHS^T bf16
    __shared__ __align__(16) unsigned short D2b16[16][72];  // delta^T bf16
    __shared__ __align__(16) unsigned short egd16[16][72];  // (eg*delta)^T

    const size_t qk0 = (size_t)b * Tc * KDIMc + h * DKc;
    const size_t v0 = (size_t)b * Tc * VDIMc + h * DVc + sl * 16;
    const size_t gb0 = (size_t)b * Tc * Hc + h;
    const size_t tb0 = (size_t)(bh * NCH) * 4096;

    for (int i = tid; i < 16 * 72; i += 512) ((unsigned short*)STb16)[i] = 0;

    const int r0 = tid >> 4, c40 = (tid & 15) << 2;
    const int r1 = r0 + 32;
    const int wid = tid >> 6, lane = tid & 63;
    const int fr = lane & 15;
    const int fk8 = (lane >> 4) << 3;
    const int rr = (lane >> 4) << 2;

    f32x4 accS = (f32x4){0.f, 0.f, 0.f, 0.f};  // waves 0-3: S[w*16+rr+r][fr]

    float4 kv0, kv1, qv0, qv1, tv0, tv1, mv0, mv1, vv0;
    float gvr = 0.f, bvr = 0.f;

#define LOADREGS(CH)                                                          \
    {                                                                         \
        const size_t tK = qk0 + (size_t)(CH) * CC * KDIMc;                    \
        const size_t tile_ = tb0 + (size_t)(CH) * 4096;                       \
        kv0 = *(const float4*)&kc[tK + (size_t)r0 * KDIMc + c40];             \
        kv1 = *(const float4*)&kc[tK + (size_t)r1 * KDIMc + c40];             \
        qv0 = *(const float4*)&qc[tK + (size_t)r0 * KDIMc + c40];             \
        qv1 = *(const float4*)&qc[tK + (size_t)r1 * KDIMc + c40];             \
        tv0 = *(const float4*)&tmT[tile_ + (size_t)tid * 4];                  \
        tv1 = *(const float4*)&tmT[tile_ + (size_t)(tid + 512) * 4];          \
        mv0 = *(const float4*)&tmM[tile_ + (size_t)tid * 4];                  \
        mv1 = *(const float4*)&tmM[tile_ + (size_t)(tid + 512) * 4];          \
        if (tid < 256)                                                        \
            vv0 = *(const float4*)&vo[v0 +                                    \
                                      (size_t)((CH) * CC + (tid >> 2)) *     \
                                          VDIMc +                             \
                                      ((tid & 3) << 2)];                      \
        if (tid < 64) {                                                       \
            gvr = g[gb0 + (size_t)((CH) * CC + tid) * Hc];                    \
            bvr = beta[gb0 + (size_t)((CH) * CC + tid) * Hc];                 \
        }                                                                     \
    }

    LOADREGS(0);

#pragma unroll 1
    for (int ch = 0; ch < NCH; ch++) {
        __syncthreads();  // B0: prev chunk fully done (STb16 visible)

        // ---- stage regs -> LDS
        {
            *(uint2*)&kb16[r0][c40] = make_uint2(pk2(kv0.x, kv0.y), pk2(kv0.z, kv0.w));
            *(uint2*)&kb16[r1][c40] = make_uint2(pk2(kv1.x, kv1.y), pk2(kv1.z, kv1.w));
            *(uint2*)&qb16[r0][c40] = make_uint2(pk2(qv0.x, qv0.y), pk2(qv0.z, qv0.w));
            *(uint2*)&qb16[r1][c40] = make_uint2(pk2(qv1.x, qv1.y), pk2(qv1.z, qv1.w));
            *(uint2*)&Tb16[r0][c40] = make_uint2(pk2(tv0.x, tv0.y), pk2(tv0.z, tv0.w));
            *(uint2*)&Tb16[r1][c40] = make_uint2(pk2(tv1.x, tv1.y), pk2(tv1.z, tv1.w));
            *(uint2*)&Mb16[r0][c40] = make_uint2(pk2(mv0.x, mv0.y), pk2(mv0.z, mv0.w));
            *(uint2*)&Mb16[r1][c40] = make_uint2(pk2(mv1.x, mv1.y), pk2(mv1.z, mv1.w));
            float* kp0 = (float*)&kv0;
            float* kp1 = (float*)&kv1;
#pragma unroll
            for (int i = 0; i < 4; i++) {
                kh16[c40 + i][r0] = f2bf(kp0[i]);
                kh16[c40 + i][r1] = f2bf(kp1[i]);
            }
            if (tid < 256) *(float4*)&VL[tid >> 2][(tid & 3) << 2] = vv0;
            if (tid < 64) {
                float cv = gvr;
#pragma unroll
                for (int d = 1; d < 64; d <<= 1) {
                    float nb = __shfl_up(cv, d, 64);
                    if (tid >= d) cv += nb;
                }
                gamL[tid] = expf(cv);
                float cend = __shfl(cv, 63, 64);
                egL[tid] = expf(cend - cv);
                betaL[tid] = bvr;
            }
        }
        if (ch + 1 < NCH) LOADREGS(ch + 1);
        __syncthreads();  // B1: stage visible

        // ---- phase 1: KS (waves 0-3) and QS (waves 4-7) via MFMA
        f32x4 acc1 = (f32x4){0.f, 0.f, 0.f, 0.f};
        {
            short8 bs0 = *(const short8*)&STb16[fr][fk8];
            short8 bs1 = *(const short8*)&STb16[fr][fk8 + 32];
            if (wid < 4) {
                const int m0 = wid << 4;
                short8 a0 = *(const short8*)&kb16[m0 + fr][fk8];
                short8 a1 = *(const short8*)&kb16[m0 + fr][fk8 + 32];
                acc1 = __builtin_amdgcn_mfma_f32_16x16x32_bf16(a0, bs0, acc1, 0, 0, 0);
                acc1 = __builtin_amdgcn_mfma_f32_16x16x32_bf16(a1, bs1, acc1, 0, 0, 0);
#pragma unroll
                for (int r = 0; r < 4; r++) {
                    int t = m0 + rr + r;
                    float rhs = betaL[t] * (VL[t][fr] - gamL[t] * acc1[r]);
                    DTb16[fr][t] = f2bf(rhs);
                }
            } else {
                const int m0 = (wid - 4) << 4;
                short8 a0 = *(const short8*)&qb16[m0 + fr][fk8];
                short8 a1 = *(const short8*)&qb16[m0 + fr][fk8 + 32];
                acc1 = __builtin_amdgcn_mfma_f32_16x16x32_bf16(a0, bs0, acc1, 0, 0, 0);
                acc1 = __builtin_amdgcn_mfma_f32_16x16x32_bf16(a1, bs1, acc1, 0, 0, 0);
#pragma unroll
                for (int r = 0; r < 4; r++) {
                    int t = m0 + rr + r;
                    acc1[r] *= 0.125f * gamL[t];
                }
            }
        }
        __syncthreads();  // B2: RHS ready

        // ---- phase 2: delta = T * RHS (waves 0-3); write delta and eg*delta
        if (wid < 4) {
            const int m0 = wid << 4;
            short8 a0 = *(const short8*)&Tb16[m0 + fr][fk8];
            short8 a1 = *(const short8*)&Tb16[m0 + fr][fk8 + 32];
            short8 b0 = *(const short8*)&DTb16[fr][fk8];
            short8 b1 = *(const short8*)&DTb16[fr][fk8 + 32];
            f32x4 d = (f32x4){0.f, 0.f, 0.f, 0.f};
            d = __builtin_amdgcn_mfma_f32_16x16x32_bf16(a0, b0, d, 0, 0, 0);
            d = __builtin_amdgcn_mfma_f32_16x16x32_bf16(a1, b1, d, 0, 0, 0);
#pragma unroll
            for (int r = 0; r < 4; r++) {
                int t = m0 + rr + r;
                D2b16[fr][t] = f2bf(d[r]);
                egd16[fr][t] = f2bf(egL[t] * d[r]);
            }
        }
        __syncthreads();  // B3: delta ready

        // ---- phase 3 (waves 4-7): O = M*delta + scaledQS, store direct.
        //      phase 4 (waves 0-3): S = ge*S + K^T(eg*delta) via MFMA.
        if (wid >= 4) {
            const int m0 = (wid - 4) << 4;
            short8 a0 = *(const short8*)&Mb16[m0 + fr][fk8];
            short8 a1 = *(const short8*)&Mb16[m0 + fr][fk8 + 32];
            short8 b0 = *(const short8*)&D2b16[fr][fk8];
            short8 b1 = *(const short8*)&D2b16[fr][fk8 + 32];
            f32x4 o = acc1;  // 0.125*gam*QS
            o = __builtin_amdgcn_mfma_f32_16x16x32_bf16(a0, b0, o, 0, 0, 0);
            o = __builtin_amdgcn_mfma_f32_16x16x32_bf16(a1, b1, o, 0, 0, 0);
#pragma unroll
            for (int r = 0; r < 4; r++)
                vo[v0 + (size_t)(ch * CC + m0 + rr + r) * VDIMc + fr] = o[r];
        } else {
            const int m0 = wid << 4;
            const float ge = gamL[63];
            short8 a0 = *(const short8*)&kh16[m0 + fr][fk8];
            short8 a1 = *(const short8*)&kh16[m0 + fr][fk8 + 32];
            short8 b0 = *(const short8*)&egd16[fr][fk8];
            short8 b1 = *(const short8*)&egd16[fr][fk8 + 32];
#pragma unroll
            for (int r = 0; r < 4; r++) accS[r] *= ge;
            accS = __builtin_amdgcn_mfma_f32_16x16x32_bf16(a0, b0, accS, 0, 0, 0);
            accS = __builtin_amdgcn_mfma_f32_16x16x32_bf16(a1, b1, accS, 0, 0, 0);
#pragma unroll
            for (int r = 0; r < 4; r++)
                STb16[fr][m0 + rr + r] = f2bf(accS[r]);
        }
    }
#undef LOADREGS
}

// ---------------------------------------------------------------------------
// Workspace: 236 MB layout + 2x16KB f32 transposed a/b weights appended.
// ---------------------------------------------------------------------------
extern "C" void kernel_launch(void* const* d_in, const int* in_sizes, int n_in,
                              void* d_out, int out_size, void* d_ws,
                              size_t ws_size, hipStream_t stream) {
    const float* x = (const float*)d_in[0];
    const float* w_q = (const float*)d_in[1];
    const float* w_k = (const float*)d_in[2];
    const float* w_v = (const float*)d_in[3];
    const float* w_a = (const float*)d_in[4];
    const float* w_b = (const float*)d_in[5];
    const float* w_g = (const float*)d_in[6];
    const float* w_out = (const float*)d_in[7];
    const float* A_log = (const float*)d_in[8];
    const float* dt_bias = (const float*)d_in[9];
    const float* conv_q = (const float*)d_in[10];
    const float* conv_k = (const float*)d_in[11];
    const float* conv_v = (const float*)d_in[12];
    const float* norm_w = (const float*)d_in[13];

    float* ws = (float*)d_ws;
    const size_t M = Mrows;
    float* qb = ws;
    float* kb = qb + M * KDIMc;
    float* vb = kb + M * KDIMc;
    float* tm = vb + M * VDIMc;          // T (8.4M) + M (8.4M)
    float* gbuf = tm + M * VDIMc;
    float* bbuf = gbuf + M * Hc;
    float* xtra = bbuf + M * Hc;
    float* tmT = tm;
    float* tmM = tm + (size_t)Bc * Hc * NCH * 4096;
    float* halo = tm;                     // alias: dead before tm_precompute
    unsigned short* obb = (unsigned short*)tm;  // alias: after scan, tm dead
    float* rfac = gbuf;                   // alias: g dead after scan

    unsigned short* xb = (unsigned short*)xtra;
    unsigned short* wqT = xb + M * KDIMc;
    unsigned short* wkT = wqT + (size_t)KDIMc * Dc;
    unsigned short* wvT = wkT + (size_t)KDIMc * Dc;
    unsigned short* wgT = wvT + (size_t)VDIMc * Dc;
    unsigned short* woT = wgT + (size_t)VDIMc * Dc;
    float* waT = (float*)(woT + (size_t)Dc * VDIMc);  // 16K floats
    float* wbT = waT + (size_t)16 * Dc;               // 16K floats

    // 0) conversions
    convert_bf16<<<dim3(M * Dc / 4 / 256), 256, 0, stream>>>(x, xb, M * Dc / 4);
    transp_bf16<<<dim3((KDIMc / 32) * (Dc / 32)), 256, 0, stream>>>(w_q, wqT,
                                                                    Dc, KDIMc);
    transp_bf16<<<dim3((KDIMc / 32) * (Dc / 32)), 256, 0, stream>>>(w_k, wkT,
                                                                    Dc, KDIMc);
    transp_bf16<<<dim3((VDIMc / 32) * (Dc / 32)), 256, 0, stream>>>(w_v, wvT,
                                                                    Dc, VDIMc);
    transp_bf16<<<dim3((VDIMc / 32) * (Dc / 32)), 256, 0, stream>>>(w_g, wgT,
                                                                    Dc, VDIMc);
    transp_bf16<<<dim3((Dc / 32) * (VDIMc / 32)), 256, 0, stream>>>(
        w_out, woT, VDIMc, Dc);
    transp_f32w<<<dim3(Dc / 64), 256, 0, stream>>>(w_a, waT);
    transp_f32w<<<dim3(Dc / 64), 256, 0, stream>>>(w_b, wbT);

    // 1) q/k/v projections (bf16 MFMA)
    gemm_bf16<<<dim3((M / 128) * (KDIMc / 128)), 256, 0, stream>>>(
        xb, wqT, qb, M, KDIMc, Dc);
    gemm_bf16<<<dim3((M / 128) * (KDIMc / 128)), 256, 0, stream>>>(
        xb, wkT, kb, M, KDIMc, Dc);
    gemm_bf16<<<dim3((M / 128) * (VDIMc / 128)), 256, 0, stream>>>(
        xb, wvT, vb, M, VDIMc, Dc);

    // 2) a/b projections (f32, transposed weights) -> g, beta
    ab_proj<<<dim3(M / 16), 256, 0, stream>>>(x, waT, wbT, A_log, dt_bias,
                                              gbuf, bbuf);

    // 3) conv + silu (+ l2norm for q,k), in place with halo save
    {
        const int nqk = Bc * (Tc / 64 - 1) * 3 * KDIMc;
        const int nv = Bc * (Tc / 64 - 1) * 3 * VDIMc;
        save_halo<KDIMc><<<dim3((nqk + 255) / 256), 256, 0, stream>>>(qb, halo);
        conv_silu_inplace<KDIMc, true>
            <<<dim3(Bc * (Tc / 64) * (KDIMc / 256)), 256, 0, stream>>>(
                qb, conv_q, halo);
        save_halo<KDIMc><<<dim3((nqk + 255) / 256), 256, 0, stream>>>(kb, halo);
        conv_silu_inplace<KDIMc, true>
            <<<dim3(Bc * (Tc / 64) * (KDIMc / 256)), 256, 0, stream>>>(
                kb, conv_k, halo);
        save_halo<VDIMc><<<dim3((nv + 255) / 256), 256, 0, stream>>>(vb, halo);
        conv_silu_inplace<VDIMc, false>
            <<<dim3(Bc * (Tc / 64) * (VDIMc / 256)), 256, 0, stream>>>(
                vb, conv_v, halo);
    }

    // 4a) parallel precompute of T=(I+A)^{-1} and M (MFMA Gram)
    tm_precompute<<<dim3(Bc * Hc * NCH), 256, 0, stream>>>(kb, qb, gbuf, bbuf,
                                                           tmT, tmM);
    // 4b) sequential scan v5 (all-MFMA phases, register-resident S)
    delta_scan<<<dim3(Bc * Hc * 8), 512, 0, stream>>>(kb, qb, vb, gbuf, bbuf,
                                                      tmT, tmM);

    // 5) rms factors from o (=vb), then gate GEMM fused with rms epilogue
    rfac_kernel<<<dim3(M * Hc / 4), 256, 0, stream>>>(vb, rfac);
    gemm_gate_rms<<<dim3((M / 128) * (VDIMc / 128)), 256, 0, stream>>>(
        xb, wgT, vb, rfac, norm_w, obb, M, VDIMc, Dc);

    // 6) output projection (bf16 MFMA) -> d_out
    gemm_bf16<<<dim3((M / 128) * (Dc / 128)), 256, 0, stream>>>(
        obb, woT, (float*)d_out, M, Dc, VDIMc);
}

// Round 13
// 653.566 us; speedup vs baseline: 34.0378x; 1.0561x over previous
//
#include <hip/hip_runtime.h>
#include <hip/hip_bf16.h>
#include <math.h>

// Problem constants
#define Bc 2
#define Tc 4096
#define Dc 1024
#define Hc 16
#define DKc 64
#define DVc 128
#define KDIMc 1024   // H*DK
#define VDIMc 2048   // H*DV
#define Mrows (Bc*Tc) // 8192
#define CC 64        // scan chunk size
#define NCH (Tc/CC)  // 64 chunks

typedef short short8 __attribute__((ext_vector_type(8)));
typedef float f32x4 __attribute__((ext_vector_type(4)));

__device__ __forceinline__ float siluf(float x) {
    return x / (1.f + expf(-x));
}
__device__ __forceinline__ float dot4(float4 a, float4 b) {
    return a.x * b.x + a.y * b.y + a.z * b.z + a.w * b.w;
}
__device__ __forceinline__ unsigned short f2bf(float f) {
    unsigned int u = __float_as_uint(f);
    unsigned int r = (u + 0x7fffu + ((u >> 16) & 1u)) >> 16;
    return (unsigned short)r;
}
__device__ __forceinline__ unsigned int pk2(float a, float b) {
    return (unsigned)f2bf(a) | ((unsigned)f2bf(b) << 16);
}
__device__ __forceinline__ float bf2f(unsigned short s) {
    unsigned int u = ((unsigned int)s) << 16;
    return __uint_as_float(u);
}
// async global->LDS DMA, 16B per lane; lds base must be wave-uniform.
__device__ __forceinline__ void gload16(const unsigned short* g,
                                        unsigned short* l) {
    __builtin_amdgcn_global_load_lds(
        (const __attribute__((address_space(1))) unsigned int*)g,
        (__attribute__((address_space(3))) unsigned int*)l, 16, 0, 0);
}

// ---------------------------------------------------------------------------
// x (f32) -> bf16, straight elementwise. 4 elems/thread.
// ---------------------------------------------------------------------------
__global__ void __launch_bounds__(256) convert_bf16(
    const float* __restrict__ in, unsigned short* __restrict__ out, int n4) {
    int g = blockIdx.x * 256 + threadIdx.x;
    if (g >= n4) return;
    float4 v = *(const float4*)&in[(size_t)g * 4];
    *(uint2*)&out[(size_t)g * 4] = make_uint2(pk2(v.x, v.y), pk2(v.z, v.w));
}

// ---------------------------------------------------------------------------
// Transpose + convert: in f32 [K][N] -> out bf16 [N][K]. 32x32 LDS tiles.
// ---------------------------------------------------------------------------
__global__ void __launch_bounds__(256) transp_bf16(
    const float* __restrict__ in, unsigned short* __restrict__ out, int K,
    int N) {
    __shared__ float t[32][33];
    const int nbx = N >> 5;
    const int n0 = (blockIdx.x % nbx) << 5;
    const int k0 = (blockIdx.x / nbx) << 5;
    const int c = threadIdx.x & 31, r4 = (threadIdx.x >> 5) << 2;
#pragma unroll
    for (int i = 0; i < 4; i++)
        t[r4 + i][c] = in[(size_t)(k0 + r4 + i) * N + n0 + c];
    __syncthreads();
#pragma unroll
    for (int i = 0; i < 4; i++)
        out[(size_t)(n0 + r4 + i) * K + k0 + c] = f2bf(t[c][r4 + i]);
}

// ---------------------------------------------------------------------------
// Transpose f32 [Dc][16] -> [16][Dc] (for w_a / w_b). Grid = Dc/64.
// ---------------------------------------------------------------------------
__global__ void __launch_bounds__(256) transp_f32w(
    const float* __restrict__ in, float* __restrict__ out) {
    __shared__ float t[64][17];
    const int k0 = blockIdx.x * 64;
    const int r = threadIdx.x >> 2, c4 = (threadIdx.x & 3) << 2;
    float4 v = *(const float4*)&in[(size_t)(k0 + r) * 16 + c4];
    t[r][c4 + 0] = v.x;
    t[r][c4 + 1] = v.y;
    t[r][c4 + 2] = v.z;
    t[r][c4 + 3] = v.w;
    __syncthreads();
    const int n = threadIdx.x >> 4;
    const int kk = (threadIdx.x & 15) << 2;
    out[(size_t)n * Dc + k0 + kk + 0] = t[kk + 0][n];
    out[(size_t)n * Dc + k0 + kk + 1] = t[kk + 1][n];
    out[(size_t)n * Dc + k0 + kk + 2] = t[kk + 2][n];
    out[(size_t)n * Dc + k0 + kk + 3] = t[kk + 3][n];
}

// ---------------------------------------------------------------------------
// Fused q/k/v projection GEMM: A[M,1024] bf16 @ BtAll[4096,1024] bf16
// (wqT|wkT|wvT contiguous). Epilogue routes by bx: 0-7 -> qb (N=1024),
// 8-15 -> kb (N=1024), 16-31 -> vb (N=2048).
// ---------------------------------------------------------------------------
__global__ void __launch_bounds__(256) gemm_qkv(
    const unsigned short* __restrict__ A, const unsigned short* __restrict__ Bt,
    float* __restrict__ qb, float* __restrict__ kb, float* __restrict__ vb) {
    __shared__ unsigned short As[128 * 32];
    __shared__ unsigned short Bs[128 * 32];
    const int tid = threadIdx.x;
    const int bx = blockIdx.x & 31, by = blockIdx.x >> 5;
    const int m0 = by << 7, n0 = bx << 7;
    const int K = Dc;
    const int w = tid >> 6, lane = tid & 63;
    const int wr = (w >> 1) << 6, wc = (w & 1) << 6;
    const int fr = lane & 15, fk8 = (lane >> 4) << 3;
    const int grow = lane >> 2;
    const int gcol = (lane & 3) << 3;

    f32x4 acc[4][4];
#pragma unroll
    for (int i = 0; i < 4; i++)
#pragma unroll
        for (int j = 0; j < 4; j++)
            acc[i][j] = (f32x4){0.f, 0.f, 0.f, 0.f};

    const int nkt = K >> 5;
    for (int kt = 0; kt < nkt; kt++) {
        __syncthreads();
        {
            const size_t kbase = (size_t)(kt << 5) + gcol;
#pragma unroll
            for (int r = 0; r < 2; r++) {
                const int rows = r * 64 + w * 16;
                gload16(&A[(size_t)(m0 + rows + grow) * K + kbase],
                        &As[rows * 32]);
                gload16(&Bt[(size_t)(n0 + rows + grow) * K + kbase],
                        &Bs[rows * 32]);
            }
        }
        __syncthreads();
        short8 af[4], bfr[4];
#pragma unroll
        for (int i = 0; i < 4; i++)
            af[i] = *(const short8*)&As[(wr + i * 16 + fr) * 32 + fk8];
#pragma unroll
        for (int j = 0; j < 4; j++)
            bfr[j] = *(const short8*)&Bs[(wc + j * 16 + fr) * 32 + fk8];
#pragma unroll
        for (int i = 0; i < 4; i++)
#pragma unroll
            for (int j = 0; j < 4; j++)
                acc[i][j] = __builtin_amdgcn_mfma_f32_16x16x32_bf16(
                    af[i], bfr[j], acc[i][j], 0, 0, 0);
    }
    float* Cb;
    int ncols, coloff;
    if (bx < 8) { Cb = qb; ncols = KDIMc; coloff = bx << 7; }
    else if (bx < 16) { Cb = kb; ncols = KDIMc; coloff = (bx - 8) << 7; }
    else { Cb = vb; ncols = VDIMc; coloff = (bx - 16) << 7; }
    const int cr = (lane >> 4) << 2;
#pragma unroll
    for (int i = 0; i < 4; i++)
#pragma unroll
        for (int j = 0; j < 4; j++) {
#pragma unroll
            for (int r = 0; r < 4; r++) {
                Cb[(size_t)(m0 + wr + i * 16 + cr + r) * ncols + coloff + wc +
                   j * 16 + fr] = acc[i][j][r];
            }
        }
}

// ---------------------------------------------------------------------------
// bf16 MFMA GEMM (generic): C f32 = A @ Bt. Used for output projection.
// ---------------------------------------------------------------------------
__global__ void __launch_bounds__(256) gemm_bf16(
    const unsigned short* __restrict__ A, const unsigned short* __restrict__ Bt,
    float* __restrict__ C, int M, int N, int K) {
    __shared__ unsigned short As[128 * 32];
    __shared__ unsigned short Bs[128 * 32];
    const int tid = threadIdx.x;
    const int nbx = N >> 7;
    const int bx = blockIdx.x % nbx, by = blockIdx.x / nbx;
    const int m0 = by << 7, n0 = bx << 7;
    const int w = tid >> 6, lane = tid & 63;
    const int wr = (w >> 1) << 6, wc = (w & 1) << 6;
    const int fr = lane & 15, fk8 = (lane >> 4) << 3;
    const int grow = lane >> 2;
    const int gcol = (lane & 3) << 3;

    f32x4 acc[4][4];
#pragma unroll
    for (int i = 0; i < 4; i++)
#pragma unroll
        for (int j = 0; j < 4; j++)
            acc[i][j] = (f32x4){0.f, 0.f, 0.f, 0.f};

    const int nkt = K >> 5;
    for (int kt = 0; kt < nkt; kt++) {
        __syncthreads();
        {
            const size_t kb = (size_t)(kt << 5) + gcol;
#pragma unroll
            for (int r = 0; r < 2; r++) {
                const int rows = r * 64 + w * 16;
                gload16(&A[(size_t)(m0 + rows + grow) * K + kb],
                        &As[rows * 32]);
                gload16(&Bt[(size_t)(n0 + rows + grow) * K + kb],
                        &Bs[rows * 32]);
            }
        }
        __syncthreads();
        short8 af[4], bfr[4];
#pragma unroll
        for (int i = 0; i < 4; i++)
            af[i] = *(const short8*)&As[(wr + i * 16 + fr) * 32 + fk8];
#pragma unroll
        for (int j = 0; j < 4; j++)
            bfr[j] = *(const short8*)&Bs[(wc + j * 16 + fr) * 32 + fk8];
#pragma unroll
        for (int i = 0; i < 4; i++)
#pragma unroll
            for (int j = 0; j < 4; j++)
                acc[i][j] = __builtin_amdgcn_mfma_f32_16x16x32_bf16(
                    af[i], bfr[j], acc[i][j], 0, 0, 0);
    }
    const int cr = (lane >> 4) << 2;
#pragma unroll
    for (int i = 0; i < 4; i++)
#pragma unroll
        for (int j = 0; j < 4; j++) {
#pragma unroll
            for (int r = 0; r < 4; r++) {
                C[(size_t)(m0 + wr + i * 16 + cr + r) * N + n0 + wc + j * 16 +
                  fr] = acc[i][j][r];
            }
        }
}

// ---------------------------------------------------------------------------
// Gate GEMM fused with gated RMSNorm epilogue: obb = rms(o)*w*silu(x@w_g).
// ---------------------------------------------------------------------------
__global__ void __launch_bounds__(256) gemm_gate_rms(
    const unsigned short* __restrict__ A, const unsigned short* __restrict__ Bt,
    const float* __restrict__ o, const float* __restrict__ rfac,
    const float* __restrict__ norm_w, unsigned short* __restrict__ out,
    int M, int N, int K) {
    __shared__ unsigned short As[128 * 32];
    __shared__ unsigned short Bs[128 * 32];
    const int tid = threadIdx.x;
    const int nbx = N >> 7;
    const int bx = blockIdx.x % nbx, by = blockIdx.x / nbx;
    const int m0 = by << 7, n0 = bx << 7;
    const int h = n0 >> 7;
    const int w = tid >> 6, lane = tid & 63;
    const int wr = (w >> 1) << 6, wc = (w & 1) << 6;
    const int fr = lane & 15, fk8 = (lane >> 4) << 3;
    const int grow = lane >> 2;
    const int gcol = (lane & 3) << 3;

    f32x4 acc[4][4];
#pragma unroll
    for (int i = 0; i < 4; i++)
#pragma unroll
        for (int j = 0; j < 4; j++)
            acc[i][j] = (f32x4){0.f, 0.f, 0.f, 0.f};

    const int nkt = K >> 5;
    for (int kt = 0; kt < nkt; kt++) {
        __syncthreads();
        {
            const size_t kb = (size_t)(kt << 5) + gcol;
#pragma unroll
            for (int r = 0; r < 2; r++) {
                const int rows = r * 64 + w * 16;
                gload16(&A[(size_t)(m0 + rows + grow) * K + kb],
                        &As[rows * 32]);
                gload16(&Bt[(size_t)(n0 + rows + grow) * K + kb],
                        &Bs[rows * 32]);
            }
        }
        __syncthreads();
        short8 af[4], bfr[4];
#pragma unroll
        for (int i = 0; i < 4; i++)
            af[i] = *(const short8*)&As[(wr + i * 16 + fr) * 32 + fk8];
#pragma unroll
        for (int j = 0; j < 4; j++)
            bfr[j] = *(const short8*)&Bs[(wc + j * 16 + fr) * 32 + fk8];
#pragma unroll
        for (int i = 0; i < 4; i++)
#pragma unroll
            for (int j = 0; j < 4; j++)
                acc[i][j] = __builtin_amdgcn_mfma_f32_16x16x32_bf16(
                    af[i], bfr[j], acc[i][j], 0, 0, 0);
    }
    const int cr = (lane >> 4) << 2;
#pragma unroll
    for (int i = 0; i < 4; i++)
#pragma unroll
        for (int j = 0; j < 4; j++) {
            const int colh = wc + j * 16 + fr;
            const float nw = norm_w[colh];
#pragma unroll
            for (int r = 0; r < 4; r++) {
                const int row = m0 + wr + i * 16 + cr + r;
                float ov = o[(size_t)row * VDIMc + n0 + colh];
                float f = rfac[(size_t)row * Hc + h];
                float y = ov * f * nw * siluf(acc[i][j][r]);
                out[(size_t)row * VDIMc + n0 + colh] = f2bf(y);
            }
        }
}

// ---------------------------------------------------------------------------
// Per-(row,h) RMS factor: rf = rsqrt(mean(o^2)+eps). One wave per 128-row.
// ---------------------------------------------------------------------------
__global__ void __launch_bounds__(256) rfac_kernel(
    const float* __restrict__ o, float* __restrict__ rf) {
    const int row = blockIdx.x * 4 + (threadIdx.x >> 6);
    const int lane = threadIdx.x & 63;
    const size_t base = (size_t)row * DVc;
    float2 ov = *(const float2*)&o[base + lane * 2];
    float ss = ov.x * ov.x + ov.y * ov.y;
#pragma unroll
    for (int m = 1; m < 64; m <<= 1) ss += __shfl_xor(ss, m, 64);
    if (lane == 0) rf[row] = rsqrtf(ss * (1.f / 128.f) + 1e-5f);
}

// ---------------------------------------------------------------------------
// a/b projections: transposed f32 weights, one wave per 4 rows.
// ---------------------------------------------------------------------------
__global__ void __launch_bounds__(256) ab_proj(
    const float* __restrict__ x, const float* __restrict__ w_aT,
    const float* __restrict__ w_bT, const float* __restrict__ A_log,
    const float* __restrict__ dt_bias, float* __restrict__ g_out,
    float* __restrict__ beta_out) {
    const int wv = threadIdx.x >> 6;
    const int lane = threadIdx.x & 63;
    const int h = lane >> 2, kg = lane & 3;
    const int row0 = blockIdx.x * 16 + wv * 4;
    const float* wa = w_aT + (size_t)h * Dc + kg * 256;
    const float* wb = w_bT + (size_t)h * Dc + kg * 256;
    const float* xr = x + (size_t)row0 * Dc + kg * 256;
    float pa[4] = {0.f, 0.f, 0.f, 0.f}, pb[4] = {0.f, 0.f, 0.f, 0.f};
#pragma unroll 4
    for (int k = 0; k < 256; k += 4) {
        float4 a4 = *(const float4*)&wa[k];
        float4 b4 = *(const float4*)&wb[k];
#pragma unroll
        for (int r = 0; r < 4; r++) {
            float4 x4 = *(const float4*)&xr[(size_t)r * Dc + k];
            pa[r] += dot4(x4, a4);
            pb[r] += dot4(x4, b4);
        }
    }
#pragma unroll
    for (int r = 0; r < 4; r++) {
        pa[r] += __shfl_xor(pa[r], 1, 64);
        pa[r] += __shfl_xor(pa[r], 2, 64);
        pb[r] += __shfl_xor(pb[r], 1, 64);
        pb[r] += __shfl_xor(pb[r], 2, 64);
    }
    if (kg == 0) {
        const float el = expf(A_log[h]);
        const float db = dt_bias[h];
#pragma unroll
        for (int r = 0; r < 4; r++) {
            float arg = pa[r] + db;
            float sp = fmaxf(arg, 0.f) + log1pf(expf(-fabsf(arg)));
            g_out[(size_t)(row0 + r) * Hc + h] = -el * sp;
            beta_out[(size_t)(row0 + r) * Hc + h] =
                2.f / (1.f + expf(-pb[r]));
        }
    }
}

// ---------------------------------------------------------------------------
// Save 3-row halos at 64-step chunk boundaries (for in-place v conv).
// ---------------------------------------------------------------------------
template <int C>
__global__ void __launch_bounds__(256) save_halo(
    const float* __restrict__ in, float* __restrict__ halo) {
    const int g = blockIdx.x * 256 + threadIdx.x;
    const int total = Bc * (Tc / 64 - 1) * 3 * C;
    if (g >= total) return;
    const int c = g % C;
    int r = g / C;
    const int j = r % 3;
    r /= 3;
    const int chunk = r % (Tc / 64 - 1) + 1;
    const int b = r / (Tc / 64 - 1);
    halo[((size_t)(b * 64 + chunk) * 3 + j) * C + c] =
        in[((size_t)b * Tc + chunk * 64 - 3 + j) * C + c];
}

// ---------------------------------------------------------------------------
// Depthwise causal conv1d + SiLU + l2norm, OUT-OF-PLACE f32 -> bf16.
// (no halo needed: input buffer is never overwritten)
// ---------------------------------------------------------------------------
template <int C, bool L2N>
__global__ void __launch_bounds__(256) conv_silu_bf16(
    const float* __restrict__ in, const float* __restrict__ w,
    unsigned short* __restrict__ out) {
    constexpr int CB = C / 256;
    const int bidx = blockIdx.x;
    const int cb = bidx % CB;
    const int tchunk = (bidx / CB) % (Tc / 64);
    const int b = bidx / (CB * (Tc / 64));
    const int c = cb * 256 + threadIdx.x;
    const int t0 = tchunk * 64;
    const float w0 = w[c * 4 + 0], w1 = w[c * 4 + 1], w2 = w[c * 4 + 2],
                w3 = w[c * 4 + 3];
    const float* src = in + (size_t)b * Tc * C + c;
    float xm3 = (t0 >= 3) ? src[(size_t)(t0 - 3) * C] : 0.f;
    float xm2 = (t0 >= 2) ? src[(size_t)(t0 - 2) * C] : 0.f;
    float xm1 = (t0 >= 1) ? src[(size_t)(t0 - 1) * C] : 0.f;
    unsigned short* dst = out + (size_t)b * Tc * C + c;
#pragma unroll 4
    for (int i = 0; i < 64; i++) {
        float xt = src[(size_t)(t0 + i) * C];
        float y = w0 * xm3 + w1 * xm2 + w2 * xm1 + w3 * xt;
        y = siluf(y);
        if (L2N) {
            float ss = y * y;
#pragma unroll
            for (int m = 1; m < 64; m <<= 1) ss += __shfl_xor(ss, m, 64);
            y *= rsqrtf(ss + 1e-6f);
        }
        dst[(size_t)(t0 + i) * C] = f2bf(y);
        xm3 = xm2;
        xm2 = xm1;
        xm1 = xt;
    }
}

// ---------------------------------------------------------------------------
// Depthwise causal conv1d (K=4) + SiLU, IN PLACE f32 (for v).
// ---------------------------------------------------------------------------
template <int C, bool L2N>
__global__ void __launch_bounds__(256) conv_silu_inplace(
    float* __restrict__ buf, const float* __restrict__ w,
    const float* __restrict__ halo) {
    constexpr int CB = C / 256;
    const int bidx = blockIdx.x;
    const int cb = bidx % CB;
    const int tchunk = (bidx / CB) % (Tc / 64);
    const int b = bidx / (CB * (Tc / 64));
    const int c = cb * 256 + threadIdx.x;
    const int t0 = tchunk * 64;
    const float w0 = w[c * 4 + 0], w1 = w[c * 4 + 1], w2 = w[c * 4 + 2],
                w3 = w[c * 4 + 3];
    float xm3 = 0.f, xm2 = 0.f, xm1 = 0.f;
    if (tchunk > 0) {
        const float* hp = halo + (size_t)(b * 64 + tchunk) * 3 * C + c;
        xm3 = hp[0];
        xm2 = hp[C];
        xm1 = hp[2 * C];
    }
    float* p = buf + (size_t)b * Tc * C + c;
#pragma unroll 4
    for (int i = 0; i < 64; i++) {
        float xt = p[(size_t)(t0 + i) * C];
        float y = w0 * xm3 + w1 * xm2 + w2 * xm1 + w3 * xt;
        y = siluf(y);
        if (L2N) {
            float ss = y * y;
#pragma unroll
            for (int m = 1; m < 64; m <<= 1) ss += __shfl_xor(ss, m, 64);
            y *= rsqrtf(ss + 1e-6f);
        }
        p[(size_t)(t0 + i) * C] = y;
        xm3 = xm2;
        xm2 = xm1;
        xm1 = xt;
    }
}

// ---------------------------------------------------------------------------
// TM precompute: Gram via bf16 MFMA (inputs already bf16), f32 solve.
// T,M stored bf16 row-major [t][s] (they're consumed as bf16 in the scan).
// ---------------------------------------------------------------------------
__global__ void __launch_bounds__(256) tm_precompute(
    const unsigned short* __restrict__ kc, const unsigned short* __restrict__ qc,
    const float* __restrict__ g, const float* __restrict__ beta,
    unsigned short* __restrict__ tmT, unsigned short* __restrict__ tmM) {
    const int bid = blockIdx.x;
    const int ch = bid & (NCH - 1);
    const int bh = bid >> 6;
    const int b = bh >> 4, h = bh & 15;
    const int tid = threadIdx.x;
    const int t0 = ch * CC;

    __shared__ __align__(16) unsigned short kb16[CC][72];
    __shared__ __align__(16) unsigned short qb16[CC][72];
    __shared__ __align__(16) float AtL[CC][DKc + 4];  // A^T: AtL[s][t]
    __shared__ float cL[CC], betaL[CC];

    const size_t qk0 = (size_t)b * Tc * KDIMc + h * DKc;
    const size_t gb0 = (size_t)b * Tc * Hc + h;
    const size_t tile = (size_t)(bh * NCH + ch) * 4096;

#pragma unroll
    for (int i = 0; i < 2; i++) {
        int e = tid + i * 256;
        int r = e >> 3, c8 = (e & 7) << 3;
        *(short8*)&kb16[r][c8] =
            *(const short8*)&kc[qk0 + (size_t)(t0 + r) * KDIMc + c8];
        *(short8*)&qb16[r][c8] =
            *(const short8*)&qc[qk0 + (size_t)(t0 + r) * KDIMc + c8];
    }
    if (tid < 64) {
        float gv = g[gb0 + (size_t)(t0 + tid) * Hc];
        float cv = gv;
#pragma unroll
        for (int d = 1; d < 64; d <<= 1) {
            float nb = __shfl_up(cv, d, 64);
            if (tid >= d) cv += nb;
        }
        cL[tid] = cv;
        betaL[tid] = beta[gb0 + (size_t)(t0 + tid) * Hc];
    }
    __syncthreads();

    {
        const int w = tid >> 6, lane = tid & 63;
        const int fr = lane & 15, fk8 = (lane >> 4) << 3;
        const int rr = (lane >> 4) << 2;
        short8 ak0 = *(const short8*)&kb16[w * 16 + fr][fk8];
        short8 ak1 = *(const short8*)&kb16[w * 16 + fr][fk8 + 32];
        short8 aq0 = *(const short8*)&qb16[w * 16 + fr][fk8];
        short8 aq1 = *(const short8*)&qb16[w * 16 + fr][fk8 + 32];
#pragma unroll
        for (int j = 0; j < 4; j++) {
            short8 b0 = *(const short8*)&kb16[j * 16 + fr][fk8];
            short8 b1 = *(const short8*)&kb16[j * 16 + fr][fk8 + 32];
            f32x4 kk = (f32x4){0.f, 0.f, 0.f, 0.f};
            f32x4 qk = (f32x4){0.f, 0.f, 0.f, 0.f};
            kk = __builtin_amdgcn_mfma_f32_16x16x32_bf16(ak0, b0, kk, 0, 0, 0);
            kk = __builtin_amdgcn_mfma_f32_16x16x32_bf16(ak1, b1, kk, 0, 0, 0);
            qk = __builtin_amdgcn_mfma_f32_16x16x32_bf16(aq0, b0, qk, 0, 0, 0);
            qk = __builtin_amdgcn_mfma_f32_16x16x32_bf16(aq1, b1, qk, 0, 0, 0);
#pragma unroll
            for (int r = 0; r < 4; r++) {
                int t = w * 16 + rr + r, s = j * 16 + fr;
                float E = expf(cL[t] - cL[s]);
                AtL[s][t] = (s < t) ? betaL[t] * E * kk[r] : 0.f;
                tmM[tile + (size_t)t * 64 + s] =
                    (s <= t) ? f2bf(0.125f * E * qk[r]) : (unsigned short)0;
            }
        }
    }
    __syncthreads();

    {
        const int w = tid >> 6, lane = tid & 63;
        float acc[16];
#pragma unroll
        for (int di = 0; di < 16; di++)
            acc[di] = (lane == w * 16 + di) ? 1.f : 0.f;
#pragma unroll 4
        for (int s = 0; s < 64; s++) {
            float a = AtL[s][lane];
#pragma unroll
            for (int di = 0; di < 16; di++) {
                float ds = __shfl(acc[di], s, 64);
                acc[di] -= a * ds;
            }
        }
        unsigned short tb[16];
#pragma unroll
        for (int di = 0; di < 16; di++) tb[di] = f2bf(acc[di]);
        *(uint4*)&tmT[tile + (size_t)lane * 64 + w * 16] = *(uint4*)&tb[0];
        *(uint4*)&tmT[tile + (size_t)lane * 64 + w * 16 + 8] = *(uint4*)&tb[8];
    }
}

// ---------------------------------------------------------------------------
// Sequential chunk scan v6: all-bf16 staging (pure short8 copies), all-MFMA
// phases, register-resident S. V path f32 (unchanged numerics).
// ---------------------------------------------------------------------------
__global__ void __launch_bounds__(512, 2) delta_scan(
    const unsigned short* __restrict__ kc, const unsigned short* __restrict__ qc,
    float* vo, const float* __restrict__ g, const float* __restrict__ beta,
    const unsigned short* __restrict__ tmT,
    const unsigned short* __restrict__ tmM) {
    const int bid = blockIdx.x;
    const int sl = bid >> 5;   // 0..7
    const int bh = bid & 31;   // 0..31 -> XCD = bh%8
    const int b = bh >> 4, h = bh & 15;
    const int tid = threadIdx.x;

    __shared__ __align__(16) float VL[CC][20];
    __shared__ float gamL[CC], egL[CC], betaL[CC];
    __shared__ __align__(16) unsigned short kb16[CC][72];  // K rows
    __shared__ __align__(16) unsigned short kh16[CC][72];  // K^T: [dk][t]
    __shared__ __align__(16) unsigned short qb16[CC][72];
    __shared__ __align__(16) unsigned short Tb16[CC][72];
    __shared__ __align__(16) unsigned short Mb16[CC][72];
    __shared__ __align__(16) unsigned short STb16[16][72];  // S^T bf16 copy
    __shared__ __align__(16) unsigned short DTb16[16][72];  // RHS^T bf16
    __shared__ __align__(16) unsigned short D2b16[16][72];  // delta^T bf16
    __shared__ __align__(16) unsigned short egd16[16][72];  // (eg*delta)^T

    const size_t qk0 = (size_t)b * Tc * KDIMc + h * DKc;
    const size_t v0 = (size_t)b * Tc * VDIMc + h * DVc + sl * 16;
    const size_t gb0 = (size_t)b * Tc * Hc + h;
    const size_t tb0 = (size_t)(bh * NCH) * 4096;

    for (int i = tid; i < 16 * 72; i += 512) ((unsigned short*)STb16)[i] = 0;

    const int r8 = tid >> 3, c8 = (tid & 7) << 3;  // bf16 staging coords
    const int wid = tid >> 6, lane = tid & 63;
    const int fr = lane & 15;
    const int fk8 = (lane >> 4) << 3;
    const int rr = (lane >> 4) << 2;

    f32x4 accS = (f32x4){0.f, 0.f, 0.f, 0.f};  // waves 0-3: S[w*16+rr+r][fr]

    short8 kv, qv, tv, mv;
    float4 vv0;
    float gvr = 0.f, bvr = 0.f;

#define LOADREGS(CH)                                                          \
    {                                                                         \
        const size_t tK = qk0 + (size_t)(CH) * CC * KDIMc;                    \
        const size_t tile_ = tb0 + (size_t)(CH) * 4096;                       \
        kv = *(const short8*)&kc[tK + (size_t)r8 * KDIMc + c8];               \
        qv = *(const short8*)&qc[tK + (size_t)r8 * KDIMc + c8];               \
        tv = *(const short8*)&tmT[tile_ + (size_t)tid * 8];                   \
        mv = *(const short8*)&tmM[tile_ + (size_t)tid * 8];                   \
        if (tid < 256)                                                        \
            vv0 = *(const float4*)&vo[v0 +                                    \
                                      (size_t)((CH) * CC + (tid >> 2)) *     \
                                          VDIMc +                             \
                                      ((tid & 3) << 2)];                      \
        if (tid < 64) {                                                       \
            gvr = g[gb0 + (size_t)((CH) * CC + tid) * Hc];                    \
            bvr = beta[gb0 + (size_t)((CH) * CC + tid) * Hc];                 \
        }                                                                     \
    }

    LOADREGS(0);

#pragma unroll 1
    for (int ch = 0; ch < NCH; ch++) {
        __syncthreads();  // B0: prev chunk fully done (STb16 visible)

        // ---- stage regs -> LDS (pure copies; no conversions)
        {
            *(short8*)&kb16[r8][c8] = kv;
            *(short8*)&qb16[r8][c8] = qv;
            *(short8*)&Tb16[r8][c8] = tv;
            *(short8*)&Mb16[r8][c8] = mv;
#pragma unroll
            for (int i = 0; i < 8; i++) kh16[c8 + i][r8] = kv[i];
            if (tid < 256) *(float4*)&VL[tid >> 2][(tid & 3) << 2] = vv0;
            if (tid < 64) {
                float cv = gvr;
#pragma unroll
                for (int d = 1; d < 64; d <<= 1) {
                    float nb = __shfl_up(cv, d, 64);
                    if (tid >= d) cv += nb;
                }
                gamL[tid] = expf(cv);
                float cend = __shfl(cv, 63, 64);
                egL[tid] = expf(cend - cv);
                betaL[tid] = bvr;
            }
        }
        if (ch + 1 < NCH) LOADREGS(ch + 1);
        __syncthreads();  // B1: stage visible

        // ---- phase 1: KS (waves 0-3) and QS (waves 4-7) via MFMA
        f32x4 acc1 = (f32x4){0.f, 0.f, 0.f, 0.f};
        {
            short8 bs0 = *(const short8*)&STb16[fr][fk8];
            short8 bs1 = *(const short8*)&STb16[fr][fk8 + 32];
            if (wid < 4) {
                const int m0 = wid << 4;
                short8 a0 = *(const short8*)&kb16[m0 + fr][fk8];
                short8 a1 = *(const short8*)&kb16[m0 + fr][fk8 + 32];
                acc1 = __builtin_amdgcn_mfma_f32_16x16x32_bf16(a0, bs0, acc1, 0, 0, 0);
                acc1 = __builtin_amdgcn_mfma_f32_16x16x32_bf16(a1, bs1, acc1, 0, 0, 0);
#pragma unroll
                for (int r = 0; r < 4; r++) {
                    int t = m0 + rr + r;
                    float rhs = betaL[t] * (VL[t][fr] - gamL[t] * acc1[r]);
                    DTb16[fr][t] = f2bf(rhs);
                }
            } else {
                const int m0 = (wid - 4) << 4;
                short8 a0 = *(const short8*)&qb16[m0 + fr][fk8];
                short8 a1 = *(const short8*)&qb16[m0 + fr][fk8 + 32];
                acc1 = __builtin_amdgcn_mfma_f32_16x16x32_bf16(a0, bs0, acc1, 0, 0, 0);
                acc1 = __builtin_amdgcn_mfma_f32_16x16x32_bf16(a1, bs1, acc1, 0, 0, 0);
#pragma unroll
                for (int r = 0; r < 4; r++) {
                    int t = m0 + rr + r;
                    acc1[r] *= 0.125f * gamL[t];
                }
            }
        }
        __syncthreads();  // B2: RHS ready

        // ---- phase 2: delta = T * RHS (waves 0-3); write delta and eg*delta
        if (wid < 4) {
            const int m0 = wid << 4;
            short8 a0 = *(const short8*)&Tb16[m0 + fr][fk8];
            short8 a1 = *(const short8*)&Tb16[m0 + fr][fk8 + 32];
            short8 b0 = *(const short8*)&DTb16[fr][fk8];
            short8 b1 = *(const short8*)&DTb16[fr][fk8 + 32];
            f32x4 d = (f32x4){0.f, 0.f, 0.f, 0.f};
            d = __builtin_amdgcn_mfma_f32_16x16x32_bf16(a0, b0, d, 0, 0, 0);
            d = __builtin_amdgcn_mfma_f32_16x16x32_bf16(a1, b1, d, 0, 0, 0);
#pragma unroll
            for (int r = 0; r < 4; r++) {
                int t = m0 + rr + r;
                D2b16[fr][t] = f2bf(d[r]);
                egd16[fr][t] = f2bf(egL[t] * d[r]);
            }
        }
        __syncthreads();  // B3: delta ready

        // ---- phase 3 (waves 4-7): O = M*delta + scaledQS, store direct.
        //      phase 4 (waves 0-3): S = ge*S + K^T(eg*delta) via MFMA.
        if (wid >= 4) {
            const int m0 = (wid - 4) << 4;
            short8 a0 = *(const short8*)&Mb16[m0 + fr][fk8];
            short8 a1 = *(const short8*)&Mb16[m0 + fr][fk8 + 32];
            short8 b0 = *(const short8*)&D2b16[fr][fk8];
            short8 b1 = *(const short8*)&D2b16[fr][fk8 + 32];
            f32x4 o = acc1;  // 0.125*gam*QS
            o = __builtin_amdgcn_mfma_f32_16x16x32_bf16(a0, b0, o, 0, 0, 0);
            o = __builtin_amdgcn_mfma_f32_16x16x32_bf16(a1, b1, o, 0, 0, 0);
#pragma unroll
            for (int r = 0; r < 4; r++)
                vo[v0 + (size_t)(ch * CC + m0 + rr + r) * VDIMc + fr] = o[r];
        } else {
            const int m0 = wid << 4;
            const float ge = gamL[63];
            short8 a0 = *(const short8*)&kh16[m0 + fr][fk8];
            short8 a1 = *(const short8*)&kh16[m0 + fr][fk8 + 32];
            short8 b0 = *(const short8*)&egd16[fr][fk8];
            short8 b1 = *(const short8*)&egd16[fr][fk8 + 32];
#pragma unroll
            for (int r = 0; r < 4; r++) accS[r] *= ge;
            accS = __builtin_amdgcn_mfma_f32_16x16x32_bf16(a0, b0, accS, 0, 0, 0);
            accS = __builtin_amdgcn_mfma_f32_16x16x32_bf16(a1, b1, accS, 0, 0, 0);
#pragma unroll
            for (int r = 0; r < 4; r++)
                STb16[fr][m0 + rr + r] = f2bf(accS[r]);
        }
    }
#undef LOADREGS
}

// ---------------------------------------------------------------------------
// Workspace (floats), 236 MB total (unchanged):
//   qb 8.39M | kb 8.39M | vb 16.78M | tm-region 16.78M | gbuf | bbuf | xtra
// tm-region as shorts (33.55M): tmT16 [0,8.39M) | tmM16 [8.39M,16.78M) |
//   qc16 [16.78M,25.17M) | kc16 [25.17M,33.55M).   halo aliases tm start
//   (dead before tm_precompute); obb aliases tm start (after scan).
// ---------------------------------------------------------------------------
extern "C" void kernel_launch(void* const* d_in, const int* in_sizes, int n_in,
                              void* d_out, int out_size, void* d_ws,
                              size_t ws_size, hipStream_t stream) {
    const float* x = (const float*)d_in[0];
    const float* w_q = (const float*)d_in[1];
    const float* w_k = (const float*)d_in[2];
    const float* w_v = (const float*)d_in[3];
    const float* w_a = (const float*)d_in[4];
    const float* w_b = (const float*)d_in[5];
    const float* w_g = (const float*)d_in[6];
    const float* w_out = (const float*)d_in[7];
    const float* A_log = (const float*)d_in[8];
    const float* dt_bias = (const float*)d_in[9];
    const float* conv_q = (const float*)d_in[10];
    const float* conv_k = (const float*)d_in[11];
    const float* conv_v = (const float*)d_in[12];
    const float* norm_w = (const float*)d_in[13];

    float* ws = (float*)d_ws;
    const size_t M = Mrows;
    float* qb = ws;
    float* kb = qb + M * KDIMc;
    float* vb = kb + M * KDIMc;
    float* tm = vb + M * VDIMc;          // 16.78M floats region
    float* gbuf = tm + M * VDIMc;
    float* bbuf = gbuf + M * Hc;
    float* xtra = bbuf + M * Hc;

    unsigned short* tmS = (unsigned short*)tm;
    unsigned short* tmT16 = tmS;
    unsigned short* tmM16 = tmS + (size_t)8388608;
    unsigned short* qc16 = tmS + (size_t)16777216;
    unsigned short* kc16 = tmS + (size_t)25165824;
    float* halo = tm;                     // dead before tm_precompute
    unsigned short* obb = tmS;            // after scan, tmT/tmM dead
    float* rfac = gbuf;                   // g dead after scan

    unsigned short* xb = (unsigned short*)xtra;
    unsigned short* wqT = xb + M * KDIMc;
    unsigned short* wkT = wqT + (size_t)KDIMc * Dc;
    unsigned short* wvT = wkT + (size_t)KDIMc * Dc;  // wqT|wkT|wvT contiguous
    unsigned short* wgT = wvT + (size_t)VDIMc * Dc;
    unsigned short* woT = wgT + (size_t)VDIMc * Dc;
    float* waT = (float*)(woT + (size_t)Dc * VDIMc);
    float* wbT = waT + (size_t)16 * Dc;

    // 0) conversions
    convert_bf16<<<dim3(M * Dc / 4 / 256), 256, 0, stream>>>(x, xb, M * Dc / 4);
    transp_bf16<<<dim3((KDIMc / 32) * (Dc / 32)), 256, 0, stream>>>(w_q, wqT,
                                                                    Dc, KDIMc);
    transp_bf16<<<dim3((KDIMc / 32) * (Dc / 32)), 256, 0, stream>>>(w_k, wkT,
                                                                    Dc, KDIMc);
    transp_bf16<<<dim3((VDIMc / 32) * (Dc / 32)), 256, 0, stream>>>(w_v, wvT,
                                                                    Dc, VDIMc);
    transp_bf16<<<dim3((VDIMc / 32) * (Dc / 32)), 256, 0, stream>>>(w_g, wgT,
                                                                    Dc, VDIMc);
    transp_bf16<<<dim3((Dc / 32) * (VDIMc / 32)), 256, 0, stream>>>(
        w_out, woT, VDIMc, Dc);
    transp_f32w<<<dim3(Dc / 64), 256, 0, stream>>>(w_a, waT);
    transp_f32w<<<dim3(Dc / 64), 256, 0, stream>>>(w_b, wbT);

    // 1) fused q/k/v projection (one GEMM, N=4096 concat)
    gemm_qkv<<<dim3((M / 128) * 32), 256, 0, stream>>>(xb, wqT, qb, kb, vb);

    // 2) a/b projections -> g, beta
    ab_proj<<<dim3(M / 16), 256, 0, stream>>>(x, waT, wbT, A_log, dt_bias,
                                              gbuf, bbuf);

    // 3) conv + silu: q,k out-of-place -> bf16 (+l2norm); v in-place f32
    conv_silu_bf16<KDIMc, true>
        <<<dim3(Bc * (Tc / 64) * (KDIMc / 256)), 256, 0, stream>>>(qb, conv_q,
                                                                   qc16);
    conv_silu_bf16<KDIMc, true>
        <<<dim3(Bc * (Tc / 64) * (KDIMc / 256)), 256, 0, stream>>>(kb, conv_k,
                                                                   kc16);
    {
        const int nv = Bc * (Tc / 64 - 1) * 3 * VDIMc;
        save_halo<VDIMc><<<dim3((nv + 255) / 256), 256, 0, stream>>>(vb, halo);
        conv_silu_inplace<VDIMc, false>
            <<<dim3(Bc * (Tc / 64) * (VDIMc / 256)), 256, 0, stream>>>(
                vb, conv_v, halo);
    }

    // 4a) parallel precompute of T=(I+A)^{-1} and M (bf16 out)
    tm_precompute<<<dim3(Bc * Hc * NCH), 256, 0, stream>>>(
        kc16, qc16, gbuf, bbuf, tmT16, tmM16);
    // 4b) sequential scan v6 (bf16 staging, all-MFMA)
    delta_scan<<<dim3(Bc * Hc * 8), 512, 0, stream>>>(kc16, qc16, vb, gbuf,
                                                      bbuf, tmT16, tmM16);

    // 5) rms factors from o (=vb), then gate GEMM fused with rms epilogue
    rfac_kernel<<<dim3(M * Hc / 4), 256, 0, stream>>>(vb, rfac);
    gemm_gate_rms<<<dim3((M / 128) * (VDIMc / 128)), 256, 0, stream>>>(
        xb, wgT, vb, rfac, norm_w, obb, M, VDIMc, Dc);

    // 6) output projection (bf16 MFMA) -> d_out
    gemm_bf16<<<dim3((M / 128) * (Dc / 128)), 256, 0, stream>>>(
        obb, woT, (float*)d_out, M, Dc, VDIMc);
}

// Round 14
// 608.845 us; speedup vs baseline: 36.5379x; 1.0735x over previous
//
#include <hip/hip_runtime.h>
#include <hip/hip_bf16.h>
#include <math.h>

// Problem constants
#define Bc 2
#define Tc 4096
#define Dc 1024
#define Hc 16
#define DKc 64
#define DVc 128
#define KDIMc 1024   // H*DK
#define VDIMc 2048   // H*DV
#define Mrows (Bc*Tc) // 8192
#define CC 64        // scan chunk size
#define NCH (Tc/CC)  // 64 chunks

typedef short short8 __attribute__((ext_vector_type(8)));
typedef float f32x4 __attribute__((ext_vector_type(4)));

__device__ __forceinline__ float siluf(float x) {
    return x / (1.f + expf(-x));
}
__device__ __forceinline__ float dot4(float4 a, float4 b) {
    return a.x * b.x + a.y * b.y + a.z * b.z + a.w * b.w;
}
__device__ __forceinline__ unsigned short f2bf(float f) {
    unsigned int u = __float_as_uint(f);
    unsigned int r = (u + 0x7fffu + ((u >> 16) & 1u)) >> 16;
    return (unsigned short)r;
}
__device__ __forceinline__ unsigned int pk2(float a, float b) {
    return (unsigned)f2bf(a) | ((unsigned)f2bf(b) << 16);
}
__device__ __forceinline__ float bf2f(unsigned short s) {
    unsigned int u = ((unsigned int)s) << 16;
    return __uint_as_float(u);
}
// async global->LDS DMA, 16B per lane; lds base must be wave-uniform.
__device__ __forceinline__ void gload16(const unsigned short* g,
                                        unsigned short* l) {
    __builtin_amdgcn_global_load_lds(
        (const __attribute__((address_space(1))) unsigned int*)g,
        (__attribute__((address_space(3))) unsigned int*)l, 16, 0, 0);
}

// ---------------------------------------------------------------------------
// x (f32) -> bf16, straight elementwise. 4 elems/thread.
// ---------------------------------------------------------------------------
__global__ void __launch_bounds__(256) convert_bf16(
    const float* __restrict__ in, unsigned short* __restrict__ out, int n4) {
    int g = blockIdx.x * 256 + threadIdx.x;
    if (g >= n4) return;
    float4 v = *(const float4*)&in[(size_t)g * 4];
    *(uint2*)&out[(size_t)g * 4] = make_uint2(pk2(v.x, v.y), pk2(v.z, v.w));
}

// ---------------------------------------------------------------------------
// Transpose + convert: in f32 [K][N] -> out bf16 [N][K]. 32x32 LDS tiles.
// ---------------------------------------------------------------------------
__global__ void __launch_bounds__(256) transp_bf16(
    const float* __restrict__ in, unsigned short* __restrict__ out, int K,
    int N) {
    __shared__ float t[32][33];
    const int nbx = N >> 5;
    const int n0 = (blockIdx.x % nbx) << 5;
    const int k0 = (blockIdx.x / nbx) << 5;
    const int c = threadIdx.x & 31, r4 = (threadIdx.x >> 5) << 2;
#pragma unroll
    for (int i = 0; i < 4; i++)
        t[r4 + i][c] = in[(size_t)(k0 + r4 + i) * N + n0 + c];
    __syncthreads();
#pragma unroll
    for (int i = 0; i < 4; i++)
        out[(size_t)(n0 + r4 + i) * K + k0 + c] = f2bf(t[c][r4 + i]);
}

// ---------------------------------------------------------------------------
// Transpose f32 [Dc][16] -> [16][Dc] (for w_a / w_b). Grid = Dc/64.
// ---------------------------------------------------------------------------
__global__ void __launch_bounds__(256) transp_f32w(
    const float* __restrict__ in, float* __restrict__ out) {
    __shared__ float t[64][17];
    const int k0 = blockIdx.x * 64;
    const int r = threadIdx.x >> 2, c4 = (threadIdx.x & 3) << 2;
    float4 v = *(const float4*)&in[(size_t)(k0 + r) * 16 + c4];
    t[r][c4 + 0] = v.x;
    t[r][c4 + 1] = v.y;
    t[r][c4 + 2] = v.z;
    t[r][c4 + 3] = v.w;
    __syncthreads();
    const int n = threadIdx.x >> 4;
    const int kk = (threadIdx.x & 15) << 2;
    out[(size_t)n * Dc + k0 + kk + 0] = t[kk + 0][n];
    out[(size_t)n * Dc + k0 + kk + 1] = t[kk + 1][n];
    out[(size_t)n * Dc + k0 + kk + 2] = t[kk + 2][n];
    out[(size_t)n * Dc + k0 + kk + 3] = t[kk + 3][n];
}

// ---------------------------------------------------------------------------
// BK=64 staging macro bodies shared by the GEMM kernels:
// split half-K LDS buffers keep the proven 64B row stride (DMA-legal,
// unchanged bank behavior) while halving barrier count per K.
// ---------------------------------------------------------------------------
#define GEMM_STAGE64(Ap, Bp, Kk)                                              \
    {                                                                         \
        const size_t kb0 = (size_t)(kt << 6) + gcol;                          \
        const size_t kb1 = kb0 + 32;                                          \
        _Pragma("unroll") for (int r = 0; r < 2; r++) {                       \
            const int rows = r * 64 + w * 16;                                 \
            gload16(&Ap[(size_t)(m0 + rows + grow) * Kk + kb0],               \
                    &As0[rows * 32]);                                         \
            gload16(&Ap[(size_t)(m0 + rows + grow) * Kk + kb1],               \
                    &As1[rows * 32]);                                         \
            gload16(&Bp[(size_t)(n0 + rows + grow) * Kk + kb0],               \
                    &Bs0[rows * 32]);                                         \
            gload16(&Bp[(size_t)(n0 + rows + grow) * Kk + kb1],               \
                    &Bs1[rows * 32]);                                         \
        }                                                                     \
    }

#define GEMM_MFMA64()                                                         \
    {                                                                         \
        short8 af[4], bfr[4];                                                 \
        _Pragma("unroll") for (int i = 0; i < 4; i++)                         \
            af[i] = *(const short8*)&As0[(wr + i * 16 + fr) * 32 + fk8];      \
        _Pragma("unroll") for (int j = 0; j < 4; j++)                         \
            bfr[j] = *(const short8*)&Bs0[(wc + j * 16 + fr) * 32 + fk8];     \
        _Pragma("unroll") for (int i = 0; i < 4; i++)                         \
            _Pragma("unroll") for (int j = 0; j < 4; j++)                     \
                acc[i][j] = __builtin_amdgcn_mfma_f32_16x16x32_bf16(          \
                    af[i], bfr[j], acc[i][j], 0, 0, 0);                       \
        _Pragma("unroll") for (int i = 0; i < 4; i++)                         \
            af[i] = *(const short8*)&As1[(wr + i * 16 + fr) * 32 + fk8];      \
        _Pragma("unroll") for (int j = 0; j < 4; j++)                         \
            bfr[j] = *(const short8*)&Bs1[(wc + j * 16 + fr) * 32 + fk8];     \
        _Pragma("unroll") for (int i = 0; i < 4; i++)                         \
            _Pragma("unroll") for (int j = 0; j < 4; j++)                     \
                acc[i][j] = __builtin_amdgcn_mfma_f32_16x16x32_bf16(          \
                    af[i], bfr[j], acc[i][j], 0, 0, 0);                       \
    }

// ---------------------------------------------------------------------------
// Fused q/k/v projection GEMM (BK=64): A[M,1024] @ BtAll[4096,1024].
// bx 0-7 -> qb (bf16 out), 8-15 -> kb (bf16 out), 16-31 -> vb (f32).
// q/k are consumed only by conv->bf16, so bf16 store here just moves the
// rounding one step earlier (pre-conv) and halves their HBM traffic.
// ---------------------------------------------------------------------------
__global__ void __launch_bounds__(256) gemm_qkv(
    const unsigned short* __restrict__ A, const unsigned short* __restrict__ Bt,
    unsigned short* __restrict__ q16, unsigned short* __restrict__ k16,
    float* __restrict__ vb) {
    __shared__ unsigned short As0[128 * 32], As1[128 * 32];
    __shared__ unsigned short Bs0[128 * 32], Bs1[128 * 32];
    const int tid = threadIdx.x;
    const int bx = blockIdx.x & 31, by = blockIdx.x >> 5;
    const int m0 = by << 7, n0 = bx << 7;
    const int K = Dc;
    const int w = tid >> 6, lane = tid & 63;
    const int wr = (w >> 1) << 6, wc = (w & 1) << 6;
    const int fr = lane & 15, fk8 = (lane >> 4) << 3;
    const int grow = lane >> 2;
    const int gcol = (lane & 3) << 3;

    f32x4 acc[4][4];
#pragma unroll
    for (int i = 0; i < 4; i++)
#pragma unroll
        for (int j = 0; j < 4; j++)
            acc[i][j] = (f32x4){0.f, 0.f, 0.f, 0.f};

    const int nkt = K >> 6;
    for (int kt = 0; kt < nkt; kt++) {
        __syncthreads();
        GEMM_STAGE64(A, Bt, K);
        __syncthreads();
        GEMM_MFMA64();
    }
    const int cr = (lane >> 4) << 2;
    if (bx < 16) {
        unsigned short* Cb = (bx < 8) ? q16 : k16;
        const int coloff = (bx & 7) << 7;
#pragma unroll
        for (int i = 0; i < 4; i++)
#pragma unroll
            for (int j = 0; j < 4; j++) {
#pragma unroll
                for (int r = 0; r < 4; r++) {
                    Cb[(size_t)(m0 + wr + i * 16 + cr + r) * KDIMc + coloff +
                       wc + j * 16 + fr] = f2bf(acc[i][j][r]);
                }
            }
    } else {
        const int coloff = (bx - 16) << 7;
#pragma unroll
        for (int i = 0; i < 4; i++)
#pragma unroll
            for (int j = 0; j < 4; j++) {
#pragma unroll
                for (int r = 0; r < 4; r++) {
                    vb[(size_t)(m0 + wr + i * 16 + cr + r) * VDIMc + coloff +
                       wc + j * 16 + fr] = acc[i][j][r];
                }
            }
    }
}

// ---------------------------------------------------------------------------
// bf16 MFMA GEMM (generic, BK=64): C f32 = A @ Bt. For output projection.
// ---------------------------------------------------------------------------
__global__ void __launch_bounds__(256) gemm_bf16(
    const unsigned short* __restrict__ A, const unsigned short* __restrict__ Bt,
    float* __restrict__ C, int M, int N, int K) {
    __shared__ unsigned short As0[128 * 32], As1[128 * 32];
    __shared__ unsigned short Bs0[128 * 32], Bs1[128 * 32];
    const int tid = threadIdx.x;
    const int nbx = N >> 7;
    const int bx = blockIdx.x % nbx, by = blockIdx.x / nbx;
    const int m0 = by << 7, n0 = bx << 7;
    const int w = tid >> 6, lane = tid & 63;
    const int wr = (w >> 1) << 6, wc = (w & 1) << 6;
    const int fr = lane & 15, fk8 = (lane >> 4) << 3;
    const int grow = lane >> 2;
    const int gcol = (lane & 3) << 3;

    f32x4 acc[4][4];
#pragma unroll
    for (int i = 0; i < 4; i++)
#pragma unroll
        for (int j = 0; j < 4; j++)
            acc[i][j] = (f32x4){0.f, 0.f, 0.f, 0.f};

    const int nkt = K >> 6;
    for (int kt = 0; kt < nkt; kt++) {
        __syncthreads();
        GEMM_STAGE64(A, Bt, K);
        __syncthreads();
        GEMM_MFMA64();
    }
    const int cr = (lane >> 4) << 2;
#pragma unroll
    for (int i = 0; i < 4; i++)
#pragma unroll
        for (int j = 0; j < 4; j++) {
#pragma unroll
            for (int r = 0; r < 4; r++) {
                C[(size_t)(m0 + wr + i * 16 + cr + r) * N + n0 + wc + j * 16 +
                  fr] = acc[i][j][r];
            }
        }
}

// ---------------------------------------------------------------------------
// Gate GEMM (BK=64) fused with gated RMSNorm epilogue.
// ---------------------------------------------------------------------------
__global__ void __launch_bounds__(256) gemm_gate_rms(
    const unsigned short* __restrict__ A, const unsigned short* __restrict__ Bt,
    const float* __restrict__ o, const float* __restrict__ rfac,
    const float* __restrict__ norm_w, unsigned short* __restrict__ out,
    int M, int N, int K) {
    __shared__ unsigned short As0[128 * 32], As1[128 * 32];
    __shared__ unsigned short Bs0[128 * 32], Bs1[128 * 32];
    const int tid = threadIdx.x;
    const int nbx = N >> 7;
    const int bx = blockIdx.x % nbx, by = blockIdx.x / nbx;
    const int m0 = by << 7, n0 = bx << 7;
    const int h = n0 >> 7;
    const int w = tid >> 6, lane = tid & 63;
    const int wr = (w >> 1) << 6, wc = (w & 1) << 6;
    const int fr = lane & 15, fk8 = (lane >> 4) << 3;
    const int grow = lane >> 2;
    const int gcol = (lane & 3) << 3;

    f32x4 acc[4][4];
#pragma unroll
    for (int i = 0; i < 4; i++)
#pragma unroll
        for (int j = 0; j < 4; j++)
            acc[i][j] = (f32x4){0.f, 0.f, 0.f, 0.f};

    const int nkt = K >> 6;
    for (int kt = 0; kt < nkt; kt++) {
        __syncthreads();
        GEMM_STAGE64(A, Bt, K);
        __syncthreads();
        GEMM_MFMA64();
    }
    const int cr = (lane >> 4) << 2;
#pragma unroll
    for (int i = 0; i < 4; i++)
#pragma unroll
        for (int j = 0; j < 4; j++) {
            const int colh = wc + j * 16 + fr;
            const float nw = norm_w[colh];
#pragma unroll
            for (int r = 0; r < 4; r++) {
                const int row = m0 + wr + i * 16 + cr + r;
                float ov = o[(size_t)row * VDIMc + n0 + colh];
                float f = rfac[(size_t)row * Hc + h];
                float y = ov * f * nw * siluf(acc[i][j][r]);
                out[(size_t)row * VDIMc + n0 + colh] = f2bf(y);
            }
        }
}

// ---------------------------------------------------------------------------
// Per-(row,h) RMS factor: rf = rsqrt(mean(o^2)+eps). One wave per 128-row.
// ---------------------------------------------------------------------------
__global__ void __launch_bounds__(256) rfac_kernel(
    const float* __restrict__ o, float* __restrict__ rf) {
    const int row = blockIdx.x * 4 + (threadIdx.x >> 6);
    const int lane = threadIdx.x & 63;
    const size_t base = (size_t)row * DVc;
    float2 ov = *(const float2*)&o[base + lane * 2];
    float ss = ov.x * ov.x + ov.y * ov.y;
#pragma unroll
    for (int m = 1; m < 64; m <<= 1) ss += __shfl_xor(ss, m, 64);
    if (lane == 0) rf[row] = rsqrtf(ss * (1.f / 128.f) + 1e-5f);
}

// ---------------------------------------------------------------------------
// a/b projections: transposed f32 weights, one wave per 4 rows.
// ---------------------------------------------------------------------------
__global__ void __launch_bounds__(256) ab_proj(
    const float* __restrict__ x, const float* __restrict__ w_aT,
    const float* __restrict__ w_bT, const float* __restrict__ A_log,
    const float* __restrict__ dt_bias, float* __restrict__ g_out,
    float* __restrict__ beta_out) {
    const int wv = threadIdx.x >> 6;
    const int lane = threadIdx.x & 63;
    const int h = lane >> 2, kg = lane & 3;
    const int row0 = blockIdx.x * 16 + wv * 4;
    const float* wa = w_aT + (size_t)h * Dc + kg * 256;
    const float* wb = w_bT + (size_t)h * Dc + kg * 256;
    const float* xr = x + (size_t)row0 * Dc + kg * 256;
    float pa[4] = {0.f, 0.f, 0.f, 0.f}, pb[4] = {0.f, 0.f, 0.f, 0.f};
#pragma unroll 4
    for (int k = 0; k < 256; k += 4) {
        float4 a4 = *(const float4*)&wa[k];
        float4 b4 = *(const float4*)&wb[k];
#pragma unroll
        for (int r = 0; r < 4; r++) {
            float4 x4 = *(const float4*)&xr[(size_t)r * Dc + k];
            pa[r] += dot4(x4, a4);
            pb[r] += dot4(x4, b4);
        }
    }
#pragma unroll
    for (int r = 0; r < 4; r++) {
        pa[r] += __shfl_xor(pa[r], 1, 64);
        pa[r] += __shfl_xor(pa[r], 2, 64);
        pb[r] += __shfl_xor(pb[r], 1, 64);
        pb[r] += __shfl_xor(pb[r], 2, 64);
    }
    if (kg == 0) {
        const float el = expf(A_log[h]);
        const float db = dt_bias[h];
#pragma unroll
        for (int r = 0; r < 4; r++) {
            float arg = pa[r] + db;
            float sp = fmaxf(arg, 0.f) + log1pf(expf(-fabsf(arg)));
            g_out[(size_t)(row0 + r) * Hc + h] = -el * sp;
            beta_out[(size_t)(row0 + r) * Hc + h] =
                2.f / (1.f + expf(-pb[r]));
        }
    }
}

// ---------------------------------------------------------------------------
// Save 3-row halos at 64-step chunk boundaries (for in-place v conv).
// ---------------------------------------------------------------------------
template <int C>
__global__ void __launch_bounds__(256) save_halo(
    const float* __restrict__ in, float* __restrict__ halo) {
    const int g = blockIdx.x * 256 + threadIdx.x;
    const int total = Bc * (Tc / 64 - 1) * 3 * C;
    if (g >= total) return;
    const int c = g % C;
    int r = g / C;
    const int j = r % 3;
    r /= 3;
    const int chunk = r % (Tc / 64 - 1) + 1;
    const int b = r / (Tc / 64 - 1);
    halo[((size_t)(b * 64 + chunk) * 3 + j) * C + c] =
        in[((size_t)b * Tc + chunk * 64 - 3 + j) * C + c];
}

// ---------------------------------------------------------------------------
// Depthwise causal conv1d + SiLU + l2norm, bf16 in -> bf16 out (q/k).
// Out-of-place; no halo needed.
// ---------------------------------------------------------------------------
template <int C, bool L2N>
__global__ void __launch_bounds__(256) conv_silu_b2b(
    const unsigned short* __restrict__ in, const float* __restrict__ w,
    unsigned short* __restrict__ out) {
    constexpr int CB = C / 256;
    const int bidx = blockIdx.x;
    const int cb = bidx % CB;
    const int tchunk = (bidx / CB) % (Tc / 64);
    const int b = bidx / (CB * (Tc / 64));
    const int c = cb * 256 + threadIdx.x;
    const int t0 = tchunk * 64;
    const float w0 = w[c * 4 + 0], w1 = w[c * 4 + 1], w2 = w[c * 4 + 2],
                w3 = w[c * 4 + 3];
    const unsigned short* src = in + (size_t)b * Tc * C + c;
    float xm3 = (t0 >= 3) ? bf2f(src[(size_t)(t0 - 3) * C]) : 0.f;
    float xm2 = (t0 >= 2) ? bf2f(src[(size_t)(t0 - 2) * C]) : 0.f;
    float xm1 = (t0 >= 1) ? bf2f(src[(size_t)(t0 - 1) * C]) : 0.f;
    unsigned short* dst = out + (size_t)b * Tc * C + c;
#pragma unroll 4
    for (int i = 0; i < 64; i++) {
        float xt = bf2f(src[(size_t)(t0 + i) * C]);
        float y = w0 * xm3 + w1 * xm2 + w2 * xm1 + w3 * xt;
        y = siluf(y);
        if (L2N) {
            float ss = y * y;
#pragma unroll
            for (int m = 1; m < 64; m <<= 1) ss += __shfl_xor(ss, m, 64);
            y *= rsqrtf(ss + 1e-6f);
        }
        dst[(size_t)(t0 + i) * C] = f2bf(y);
        xm3 = xm2;
        xm2 = xm1;
        xm1 = xt;
    }
}

// ---------------------------------------------------------------------------
// Depthwise causal conv1d (K=4) + SiLU, IN PLACE f32 (for v).
// ---------------------------------------------------------------------------
template <int C, bool L2N>
__global__ void __launch_bounds__(256) conv_silu_inplace(
    float* __restrict__ buf, const float* __restrict__ w,
    const float* __restrict__ halo) {
    constexpr int CB = C / 256;
    const int bidx = blockIdx.x;
    const int cb = bidx % CB;
    const int tchunk = (bidx / CB) % (Tc / 64);
    const int b = bidx / (CB * (Tc / 64));
    const int c = cb * 256 + threadIdx.x;
    const int t0 = tchunk * 64;
    const float w0 = w[c * 4 + 0], w1 = w[c * 4 + 1], w2 = w[c * 4 + 2],
                w3 = w[c * 4 + 3];
    float xm3 = 0.f, xm2 = 0.f, xm1 = 0.f;
    if (tchunk > 0) {
        const float* hp = halo + (size_t)(b * 64 + tchunk) * 3 * C + c;
        xm3 = hp[0];
        xm2 = hp[C];
        xm1 = hp[2 * C];
    }
    float* p = buf + (size_t)b * Tc * C + c;
#pragma unroll 4
    for (int i = 0; i < 64; i++) {
        float xt = p[(size_t)(t0 + i) * C];
        float y = w0 * xm3 + w1 * xm2 + w2 * xm1 + w3 * xt;
        y = siluf(y);
        if (L2N) {
            float ss = y * y;
#pragma unroll
            for (int m = 1; m < 64; m <<= 1) ss += __shfl_xor(ss, m, 64);
            y *= rsqrtf(ss + 1e-6f);
        }
        p[(size_t)(t0 + i) * C] = y;
        xm3 = xm2;
        xm2 = xm1;
        xm1 = xt;
    }
}

// ---------------------------------------------------------------------------
// TM precompute: Gram via bf16 MFMA (inputs already bf16), f32 solve.
// T,M stored bf16 row-major [t][s].
// ---------------------------------------------------------------------------
__global__ void __launch_bounds__(256) tm_precompute(
    const unsigned short* __restrict__ kc, const unsigned short* __restrict__ qc,
    const float* __restrict__ g, const float* __restrict__ beta,
    unsigned short* __restrict__ tmT, unsigned short* __restrict__ tmM) {
    const int bid = blockIdx.x;
    const int ch = bid & (NCH - 1);
    const int bh = bid >> 6;
    const int b = bh >> 4, h = bh & 15;
    const int tid = threadIdx.x;
    const int t0 = ch * CC;

    __shared__ __align__(16) unsigned short kb16[CC][72];
    __shared__ __align__(16) unsigned short qb16[CC][72];
    __shared__ __align__(16) float AtL[CC][DKc + 4];  // A^T: AtL[s][t]
    __shared__ float cL[CC], betaL[CC];

    const size_t qk0 = (size_t)b * Tc * KDIMc + h * DKc;
    const size_t gb0 = (size_t)b * Tc * Hc + h;
    const size_t tile = (size_t)(bh * NCH + ch) * 4096;

#pragma unroll
    for (int i = 0; i < 2; i++) {
        int e = tid + i * 256;
        int r = e >> 3, c8 = (e & 7) << 3;
        *(short8*)&kb16[r][c8] =
            *(const short8*)&kc[qk0 + (size_t)(t0 + r) * KDIMc + c8];
        *(short8*)&qb16[r][c8] =
            *(const short8*)&qc[qk0 + (size_t)(t0 + r) * KDIMc + c8];
    }
    if (tid < 64) {
        float gv = g[gb0 + (size_t)(t0 + tid) * Hc];
        float cv = gv;
#pragma unroll
        for (int d = 1; d < 64; d <<= 1) {
            float nb = __shfl_up(cv, d, 64);
            if (tid >= d) cv += nb;
        }
        cL[tid] = cv;
        betaL[tid] = beta[gb0 + (size_t)(t0 + tid) * Hc];
    }
    __syncthreads();

    {
        const int w = tid >> 6, lane = tid & 63;
        const int fr = lane & 15, fk8 = (lane >> 4) << 3;
        const int rr = (lane >> 4) << 2;
        short8 ak0 = *(const short8*)&kb16[w * 16 + fr][fk8];
        short8 ak1 = *(const short8*)&kb16[w * 16 + fr][fk8 + 32];
        short8 aq0 = *(const short8*)&qb16[w * 16 + fr][fk8];
        short8 aq1 = *(const short8*)&qb16[w * 16 + fr][fk8 + 32];
#pragma unroll
        for (int j = 0; j < 4; j++) {
            short8 b0 = *(const short8*)&kb16[j * 16 + fr][fk8];
            short8 b1 = *(const short8*)&kb16[j * 16 + fr][fk8 + 32];
            f32x4 kk = (f32x4){0.f, 0.f, 0.f, 0.f};
            f32x4 qk = (f32x4){0.f, 0.f, 0.f, 0.f};
            kk = __builtin_amdgcn_mfma_f32_16x16x32_bf16(ak0, b0, kk, 0, 0, 0);
            kk = __builtin_amdgcn_mfma_f32_16x16x32_bf16(ak1, b1, kk, 0, 0, 0);
            qk = __builtin_amdgcn_mfma_f32_16x16x32_bf16(aq0, b0, qk, 0, 0, 0);
            qk = __builtin_amdgcn_mfma_f32_16x16x32_bf16(aq1, b1, qk, 0, 0, 0);
#pragma unroll
            for (int r = 0; r < 4; r++) {
                int t = w * 16 + rr + r, s = j * 16 + fr;
                float E = expf(cL[t] - cL[s]);
                AtL[s][t] = (s < t) ? betaL[t] * E * kk[r] : 0.f;
                tmM[tile + (size_t)t * 64 + s] =
                    (s <= t) ? f2bf(0.125f * E * qk[r]) : (unsigned short)0;
            }
        }
    }
    __syncthreads();

    {
        const int w = tid >> 6, lane = tid & 63;
        float acc[16];
#pragma unroll
        for (int di = 0; di < 16; di++)
            acc[di] = (lane == w * 16 + di) ? 1.f : 0.f;
#pragma unroll 4
        for (int s = 0; s < 64; s++) {
            float a = AtL[s][lane];
#pragma unroll
            for (int di = 0; di < 16; di++) {
                float ds = __shfl(acc[di], s, 64);
                acc[di] -= a * ds;
            }
        }
        unsigned short tb[16];
#pragma unroll
        for (int di = 0; di < 16; di++) tb[di] = f2bf(acc[di]);
        *(uint4*)&tmT[tile + (size_t)lane * 64 + w * 16] = *(uint4*)&tb[0];
        *(uint4*)&tmT[tile + (size_t)lane * 64 + w * 16 + 8] = *(uint4*)&tb[8];
    }
}

// ---------------------------------------------------------------------------
// Sequential chunk scan v6: all-bf16 staging, all-MFMA phases, reg-resident S.
// ---------------------------------------------------------------------------
__global__ void __launch_bounds__(512, 2) delta_scan(
    const unsigned short* __restrict__ kc, const unsigned short* __restrict__ qc,
    float* vo, const float* __restrict__ g, const float* __restrict__ beta,
    const unsigned short* __restrict__ tmT,
    const unsigned short* __restrict__ tmM) {
    const int bid = blockIdx.x;
    const int sl = bid >> 5;   // 0..7
    const int bh = bid & 31;   // 0..31 -> XCD = bh%8
    const int b = bh >> 4, h = bh & 15;
    const int tid = threadIdx.x;

    __shared__ __align__(16) float VL[CC][20];
    __shared__ float gamL[CC], egL[CC], betaL[CC];
    __shared__ __align__(16) unsigned short kb16[CC][72];  // K rows
    __shared__ __align__(16) unsigned short kh16[CC][72];  // K^T: [dk][t]
    __shared__ __align__(16) unsigned short qb16[CC][72];
    __shared__ __align__(16) unsigned short Tb16[CC][72];
    __shared__ __align__(16) unsigned short Mb16[CC][72];
    __shared__ __align__(16) unsigned short STb16[16][72];  // S^T bf16 copy
    __shared__ __align__(16) unsigned short DTb16[16][72];  // RHS^T bf16
    __shared__ __align__(16) unsigned short D2b16[16][72];  // delta^T bf16
    __shared__ __align__(16) unsigned short egd16[16][72];  // (eg*delta)^T

    const size_t qk0 = (size_t)b * Tc * KDIMc + h * DKc;
    const size_t v0 = (size_t)b * Tc * VDIMc + h * DVc + sl * 16;
    const size_t gb0 = (size_t)b * Tc * Hc + h;
    const size_t tb0 = (size_t)(bh * NCH) * 4096;

    for (int i = tid; i < 16 * 72; i += 512) ((unsigned short*)STb16)[i] = 0;

    const int r8 = tid >> 3, c8 = (tid & 7) << 3;  // bf16 staging coords
    const int wid = tid >> 6, lane = tid & 63;
    const int fr = lane & 15;
    const int fk8 = (lane >> 4) << 3;
    const int rr = (lane >> 4) << 2;

    f32x4 accS = (f32x4){0.f, 0.f, 0.f, 0.f};  // waves 0-3: S[w*16+rr+r][fr]

    short8 kv, qv, tv, mv;
    float4 vv0;
    float gvr = 0.f, bvr = 0.f;

#define LOADREGS(CH)                                                          \
    {                                                                         \
        const size_t tK = qk0 + (size_t)(CH) * CC * KDIMc;                    \
        const size_t tile_ = tb0 + (size_t)(CH) * 4096;                       \
        kv = *(const short8*)&kc[tK + (size_t)r8 * KDIMc + c8];               \
        qv = *(const short8*)&qc[tK + (size_t)r8 * KDIMc + c8];               \
        tv = *(const short8*)&tmT[tile_ + (size_t)tid * 8];                   \
        mv = *(const short8*)&tmM[tile_ + (size_t)tid * 8];                   \
        if (tid < 256)                                                        \
            vv0 = *(const float4*)&vo[v0 +                                    \
                                      (size_t)((CH) * CC + (tid >> 2)) *     \
                                          VDIMc +                             \
                                      ((tid & 3) << 2)];                      \
        if (tid < 64) {                                                       \
            gvr = g[gb0 + (size_t)((CH) * CC + tid) * Hc];                    \
            bvr = beta[gb0 + (size_t)((CH) * CC + tid) * Hc];                 \
        }                                                                     \
    }

    LOADREGS(0);

#pragma unroll 1
    for (int ch = 0; ch < NCH; ch++) {
        __syncthreads();  // B0: prev chunk fully done (STb16 visible)

        // ---- stage regs -> LDS (pure copies; no conversions)
        {
            *(short8*)&kb16[r8][c8] = kv;
            *(short8*)&qb16[r8][c8] = qv;
            *(short8*)&Tb16[r8][c8] = tv;
            *(short8*)&Mb16[r8][c8] = mv;
#pragma unroll
            for (int i = 0; i < 8; i++) kh16[c8 + i][r8] = kv[i];
            if (tid < 256) *(float4*)&VL[tid >> 2][(tid & 3) << 2] = vv0;
            if (tid < 64) {
                float cv = gvr;
#pragma unroll
                for (int d = 1; d < 64; d <<= 1) {
                    float nb = __shfl_up(cv, d, 64);
                    if (tid >= d) cv += nb;
                }
                gamL[tid] = expf(cv);
                float cend = __shfl(cv, 63, 64);
                egL[tid] = expf(cend - cv);
                betaL[tid] = bvr;
            }
        }
        if (ch + 1 < NCH) LOADREGS(ch + 1);
        __syncthreads();  // B1: stage visible

        // ---- phase 1: KS (waves 0-3) and QS (waves 4-7) via MFMA
        f32x4 acc1 = (f32x4){0.f, 0.f, 0.f, 0.f};
        {
            short8 bs0 = *(const short8*)&STb16[fr][fk8];
            short8 bs1 = *(const short8*)&STb16[fr][fk8 + 32];
            if (wid < 4) {
                const int m0 = wid << 4;
                short8 a0 = *(const short8*)&kb16[m0 + fr][fk8];
                short8 a1 = *(const short8*)&kb16[m0 + fr][fk8 + 32];
                acc1 = __builtin_amdgcn_mfma_f32_16x16x32_bf16(a0, bs0, acc1, 0, 0, 0);
                acc1 = __builtin_amdgcn_mfma_f32_16x16x32_bf16(a1, bs1, acc1, 0, 0, 0);
#pragma unroll
                for (int r = 0; r < 4; r++) {
                    int t = m0 + rr + r;
                    float rhs = betaL[t] * (VL[t][fr] - gamL[t] * acc1[r]);
                    DTb16[fr][t] = f2bf(rhs);
                }
            } else {
                const int m0 = (wid - 4) << 4;
                short8 a0 = *(const short8*)&qb16[m0 + fr][fk8];
                short8 a1 = *(const short8*)&qb16[m0 + fr][fk8 + 32];
                acc1 = __builtin_amdgcn_mfma_f32_16x16x32_bf16(a0, bs0, acc1, 0, 0, 0);
                acc1 = __builtin_amdgcn_mfma_f32_16x16x32_bf16(a1, bs1, acc1, 0, 0, 0);
#pragma unroll
                for (int r = 0; r < 4; r++) {
                    int t = m0 + rr + r;
                    acc1[r] *= 0.125f * gamL[t];
                }
            }
        }
        __syncthreads();  // B2: RHS ready

        // ---- phase 2: delta = T * RHS (waves 0-3); write delta and eg*delta
        if (wid < 4) {
            const int m0 = wid << 4;
            short8 a0 = *(const short8*)&Tb16[m0 + fr][fk8];
            short8 a1 = *(const short8*)&Tb16[m0 + fr][fk8 + 32];
            short8 b0 = *(const short8*)&DTb16[fr][fk8];
            short8 b1 = *(const short8*)&DTb16[fr][fk8 + 32];
            f32x4 d = (f32x4){0.f, 0.f, 0.f, 0.f};
            d = __builtin_amdgcn_mfma_f32_16x16x32_bf16(a0, b0, d, 0, 0, 0);
            d = __builtin_amdgcn_mfma_f32_16x16x32_bf16(a1, b1, d, 0, 0, 0);
#pragma unroll
            for (int r = 0; r < 4; r++) {
                int t = m0 + rr + r;
                D2b16[fr][t] = f2bf(d[r]);
                egd16[fr][t] = f2bf(egL[t] * d[r]);
            }
        }
        __syncthreads();  // B3: delta ready

        // ---- phase 3 (waves 4-7): O = M*delta + scaledQS, store direct.
        //      phase 4 (waves 0-3): S = ge*S + K^T(eg*delta) via MFMA.
        if (wid >= 4) {
            const int m0 = (wid - 4) << 4;
            short8 a0 = *(const short8*)&Mb16[m0 + fr][fk8];
            short8 a1 = *(const short8*)&Mb16[m0 + fr][fk8 + 32];
            short8 b0 = *(const short8*)&D2b16[fr][fk8];
            short8 b1 = *(const short8*)&D2b16[fr][fk8 + 32];
            f32x4 o = acc1;  // 0.125*gam*QS
            o = __builtin_amdgcn_mfma_f32_16x16x32_bf16(a0, b0, o, 0, 0, 0);
            o = __builtin_amdgcn_mfma_f32_16x16x32_bf16(a1, b1, o, 0, 0, 0);
#pragma unroll
            for (int r = 0; r < 4; r++)
                vo[v0 + (size_t)(ch * CC + m0 + rr + r) * VDIMc + fr] = o[r];
        } else {
            const int m0 = wid << 4;
            const float ge = gamL[63];
            short8 a0 = *(const short8*)&kh16[m0 + fr][fk8];
            short8 a1 = *(const short8*)&kh16[m0 + fr][fk8 + 32];
            short8 b0 = *(const short8*)&egd16[fr][fk8];
            short8 b1 = *(const short8*)&egd16[fr][fk8 + 32];
#pragma unroll
            for (int r = 0; r < 4; r++) accS[r] *= ge;
            accS = __builtin_amdgcn_mfma_f32_16x16x32_bf16(a0, b0, accS, 0, 0, 0);
            accS = __builtin_amdgcn_mfma_f32_16x16x32_bf16(a1, b1, accS, 0, 0, 0);
#pragma unroll
            for (int r = 0; r < 4; r++)
                STb16[fr][m0 + rr + r] = f2bf(accS[r]);
        }
    }
#undef LOADREGS
}

// ---------------------------------------------------------------------------
// Workspace (floats), 236 MB total (unchanged):
//   qb 8.39M (holds q bf16) | kb 8.39M (k bf16) | vb 16.78M |
//   tm-region 16.78M | gbuf | bbuf | xtra
// tm-region as shorts: tmT16 | tmM16 | qc16 | kc16.  halo aliases tm start
// (dead before tm_precompute); obb aliases tm start (after scan).
// ---------------------------------------------------------------------------
extern "C" void kernel_launch(void* const* d_in, const int* in_sizes, int n_in,
                              void* d_out, int out_size, void* d_ws,
                              size_t ws_size, hipStream_t stream) {
    const float* x = (const float*)d_in[0];
    const float* w_q = (const float*)d_in[1];
    const float* w_k = (const float*)d_in[2];
    const float* w_v = (const float*)d_in[3];
    const float* w_a = (const float*)d_in[4];
    const float* w_b = (const float*)d_in[5];
    const float* w_g = (const float*)d_in[6];
    const float* w_out = (const float*)d_in[7];
    const float* A_log = (const float*)d_in[8];
    const float* dt_bias = (const float*)d_in[9];
    const float* conv_q = (const float*)d_in[10];
    const float* conv_k = (const float*)d_in[11];
    const float* conv_v = (const float*)d_in[12];
    const float* norm_w = (const float*)d_in[13];

    float* ws = (float*)d_ws;
    const size_t M = Mrows;
    float* qb = ws;
    float* kb = qb + M * KDIMc;
    float* vb = kb + M * KDIMc;
    float* tm = vb + M * VDIMc;          // 16.78M floats region
    float* gbuf = tm + M * VDIMc;
    float* bbuf = gbuf + M * Hc;
    float* xtra = bbuf + M * Hc;

    unsigned short* q16raw = (unsigned short*)qb;
    unsigned short* k16raw = (unsigned short*)kb;
    unsigned short* tmS = (unsigned short*)tm;
    unsigned short* tmT16 = tmS;
    unsigned short* tmM16 = tmS + (size_t)8388608;
    unsigned short* qc16 = tmS + (size_t)16777216;
    unsigned short* kc16 = tmS + (size_t)25165824;
    float* halo = tm;                     // dead before tm_precompute
    unsigned short* obb = tmS;            // after scan, tmT/tmM dead
    float* rfac = gbuf;                   // g dead after scan

    unsigned short* xb = (unsigned short*)xtra;
    unsigned short* wqT = xb + M * KDIMc;
    unsigned short* wkT = wqT + (size_t)KDIMc * Dc;
    unsigned short* wvT = wkT + (size_t)KDIMc * Dc;  // wqT|wkT|wvT contiguous
    unsigned short* wgT = wvT + (size_t)VDIMc * Dc;
    unsigned short* woT = wgT + (size_t)VDIMc * Dc;
    float* waT = (float*)(woT + (size_t)Dc * VDIMc);
    float* wbT = waT + (size_t)16 * Dc;

    // 0) conversions
    convert_bf16<<<dim3(M * Dc / 4 / 256), 256, 0, stream>>>(x, xb, M * Dc / 4);
    transp_bf16<<<dim3((KDIMc / 32) * (Dc / 32)), 256, 0, stream>>>(w_q, wqT,
                                                                    Dc, KDIMc);
    transp_bf16<<<dim3((KDIMc / 32) * (Dc / 32)), 256, 0, stream>>>(w_k, wkT,
                                                                    Dc, KDIMc);
    transp_bf16<<<dim3((VDIMc / 32) * (Dc / 32)), 256, 0, stream>>>(w_v, wvT,
                                                                    Dc, VDIMc);
    transp_bf16<<<dim3((VDIMc / 32) * (Dc / 32)), 256, 0, stream>>>(w_g, wgT,
                                                                    Dc, VDIMc);
    transp_bf16<<<dim3((Dc / 32) * (VDIMc / 32)), 256, 0, stream>>>(
        w_out, woT, VDIMc, Dc);
    transp_f32w<<<dim3(Dc / 64), 256, 0, stream>>>(w_a, waT);
    transp_f32w<<<dim3(Dc / 64), 256, 0, stream>>>(w_b, wbT);

    // 1) fused q/k/v projection (one GEMM, BK=64; q/k out bf16)
    gemm_qkv<<<dim3((M / 128) * 32), 256, 0, stream>>>(xb, wqT, q16raw, k16raw,
                                                       vb);

    // 2) a/b projections -> g, beta
    ab_proj<<<dim3(M / 16), 256, 0, stream>>>(x, waT, wbT, A_log, dt_bias,
                                              gbuf, bbuf);

    // 3) conv + silu: q,k bf16->bf16 (+l2norm); v in-place f32
    conv_silu_b2b<KDIMc, true>
        <<<dim3(Bc * (Tc / 64) * (KDIMc / 256)), 256, 0, stream>>>(
            q16raw, conv_q, qc16);
    conv_silu_b2b<KDIMc, true>
        <<<dim3(Bc * (Tc / 64) * (KDIMc / 256)), 256, 0, stream>>>(
            k16raw, conv_k, kc16);
    {
        const int nv = Bc * (Tc / 64 - 1) * 3 * VDIMc;
        save_halo<VDIMc><<<dim3((nv + 255) / 256), 256, 0, stream>>>(vb, halo);
        conv_silu_inplace<VDIMc, false>
            <<<dim3(Bc * (Tc / 64) * (VDIMc / 256)), 256, 0, stream>>>(
                vb, conv_v, halo);
    }

    // 4a) parallel precompute of T=(I+A)^{-1} and M (bf16 out)
    tm_precompute<<<dim3(Bc * Hc * NCH), 256, 0, stream>>>(
        kc16, qc16, gbuf, bbuf, tmT16, tmM16);
    // 4b) sequential scan v6 (bf16 staging, all-MFMA)
    delta_scan<<<dim3(Bc * Hc * 8), 512, 0, stream>>>(kc16, qc16, vb, gbuf,
                                                      bbuf, tmT16, tmM16);

    // 5) rms factors from o (=vb), then gate GEMM fused with rms epilogue
    rfac_kernel<<<dim3(M * Hc / 4), 256, 0, stream>>>(vb, rfac);
    gemm_gate_rms<<<dim3((M / 128) * (VDIMc / 128)), 256, 0, stream>>>(
        xb, wgT, vb, rfac, norm_w, obb, M, VDIMc, Dc);

    // 6) output projection (bf16 MFMA, BK=64) -> d_out
    gemm_bf16<<<dim3((M / 128) * (Dc / 128)), 256, 0, stream>>>(
        obb, woT, (float*)d_out, M, Dc, VDIMc);
}

// Round 15
// 604.085 us; speedup vs baseline: 36.8258x; 1.0079x over previous
//
#include <hip/hip_runtime.h>
#include <hip/hip_bf16.h>
#include <math.h>

// Problem constants
#define Bc 2
#define Tc 4096
#define Dc 1024
#define Hc 16
#define DKc 64
#define DVc 128
#define KDIMc 1024   // H*DK
#define VDIMc 2048   // H*DV
#define Mrows (Bc*Tc) // 8192
#define CC 64        // scan chunk size
#define NCH (Tc/CC)  // 64 chunks

typedef short short8 __attribute__((ext_vector_type(8)));
typedef float f32x4 __attribute__((ext_vector_type(4)));

__device__ __forceinline__ float siluf(float x) {
    return x / (1.f + expf(-x));
}
__device__ __forceinline__ float dot4(float4 a, float4 b) {
    return a.x * b.x + a.y * b.y + a.z * b.z + a.w * b.w;
}
__device__ __forceinline__ unsigned short f2bf(float f) {
    unsigned int u = __float_as_uint(f);
    unsigned int r = (u + 0x7fffu + ((u >> 16) & 1u)) >> 16;
    return (unsigned short)r;
}
__device__ __forceinline__ unsigned int pk2(float a, float b) {
    return (unsigned)f2bf(a) | ((unsigned)f2bf(b) << 16);
}
__device__ __forceinline__ float bf2f(unsigned short s) {
    unsigned int u = ((unsigned int)s) << 16;
    return __uint_as_float(u);
}
// async global->LDS DMA, 16B per lane; lds base must be wave-uniform.
__device__ __forceinline__ void gload16(const unsigned short* g,
                                        unsigned short* l) {
    __builtin_amdgcn_global_load_lds(
        (const __attribute__((address_space(1))) unsigned int*)g,
        (__attribute__((address_space(3))) unsigned int*)l, 16, 0, 0);
}

// ---------------------------------------------------------------------------
// x (f32) -> bf16, straight elementwise. 4 elems/thread.
// ---------------------------------------------------------------------------
__global__ void __launch_bounds__(256) convert_bf16(
    const float* __restrict__ in, unsigned short* __restrict__ out, int n4) {
    int g = blockIdx.x * 256 + threadIdx.x;
    if (g >= n4) return;
    float4 v = *(const float4*)&in[(size_t)g * 4];
    *(uint2*)&out[(size_t)g * 4] = make_uint2(pk2(v.x, v.y), pk2(v.z, v.w));
}

// ---------------------------------------------------------------------------
// Transpose + convert: in f32 [K][N] -> out bf16 [N][K]. 32x32 LDS tiles.
// ---------------------------------------------------------------------------
__global__ void __launch_bounds__(256) transp_bf16(
    const float* __restrict__ in, unsigned short* __restrict__ out, int K,
    int N) {
    __shared__ float t[32][33];
    const int nbx = N >> 5;
    const int n0 = (blockIdx.x % nbx) << 5;
    const int k0 = (blockIdx.x / nbx) << 5;
    const int c = threadIdx.x & 31, r4 = (threadIdx.x >> 5) << 2;
#pragma unroll
    for (int i = 0; i < 4; i++)
        t[r4 + i][c] = in[(size_t)(k0 + r4 + i) * N + n0 + c];
    __syncthreads();
#pragma unroll
    for (int i = 0; i < 4; i++)
        out[(size_t)(n0 + r4 + i) * K + k0 + c] = f2bf(t[c][r4 + i]);
}

// ---------------------------------------------------------------------------
// Transpose f32 [Dc][16] -> [16][Dc] (for w_a / w_b). Grid = Dc/64.
// ---------------------------------------------------------------------------
__global__ void __launch_bounds__(256) transp_f32w(
    const float* __restrict__ in, float* __restrict__ out) {
    __shared__ float t[64][17];
    const int k0 = blockIdx.x * 64;
    const int r = threadIdx.x >> 2, c4 = (threadIdx.x & 3) << 2;
    float4 v = *(const float4*)&in[(size_t)(k0 + r) * 16 + c4];
    t[r][c4 + 0] = v.x;
    t[r][c4 + 1] = v.y;
    t[r][c4 + 2] = v.z;
    t[r][c4 + 3] = v.w;
    __syncthreads();
    const int n = threadIdx.x >> 4;
    const int kk = (threadIdx.x & 15) << 2;
    out[(size_t)n * Dc + k0 + kk + 0] = t[kk + 0][n];
    out[(size_t)n * Dc + k0 + kk + 1] = t[kk + 1][n];
    out[(size_t)n * Dc + k0 + kk + 2] = t[kk + 2][n];
    out[(size_t)n * Dc + k0 + kk + 3] = t[kk + 3][n];
}

// ---------------------------------------------------------------------------
// bf16 tile transpose: in [B][T][KDIM] -> out [B][KDIM][T]. 64x64 tiles.
// Feeds delta_scan's kh16 (K^T) with a clean short8 copy, eliminating the
// 8-way LDS write conflict of the old in-kernel scatter transpose.
// ---------------------------------------------------------------------------
__global__ void __launch_bounds__(256) transp_k16(
    const unsigned short* __restrict__ in, unsigned short* __restrict__ out) {
    __shared__ unsigned short t[64][68];  // 136B rows (8B-aligned)
    const int bx = blockIdx.x & 63;          // t-block
    const int by = (blockIdx.x >> 6) & 15;   // c-block (KDIM/64)
    const int b = blockIdx.x >> 10;
    const int t0 = bx << 6, c0 = by << 6;
    {
        const int row = threadIdx.x >> 2, c16 = (threadIdx.x & 3) << 4;
        const unsigned short* src =
            &in[((size_t)b * Tc + t0 + row) * KDIMc + c0 + c16];
#pragma unroll
        for (int i = 0; i < 4; i++)
            *(uint2*)&t[row][c16 + i * 4] = *(const uint2*)&src[i * 4];
    }
    __syncthreads();
    {
        const int cc = threadIdx.x & 63, tp = (threadIdx.x >> 6) << 4;
        unsigned short v[16];
#pragma unroll
        for (int i = 0; i < 16; i++) v[i] = t[tp + i][cc];
        unsigned short* dst =
            &out[((size_t)b * KDIMc + c0 + cc) * Tc + t0 + tp];
        *(uint4*)&dst[0] = *(uint4*)&v[0];
        *(uint4*)&dst[8] = *(uint4*)&v[8];
    }
}

// ---------------------------------------------------------------------------
// GEMM building blocks, BK=64, DOUBLE-BUFFERED LDS (T3-minimum schedule):
// one barrier per K-step; stage of tile kt+1 is issued right after the
// barrier so the DMAs fly under the MFMAs.
// ---------------------------------------------------------------------------
#define GEMM_SHARED()                                                         \
    __shared__ unsigned short As[2][2][128 * 32];                             \
    __shared__ unsigned short Bs[2][2][128 * 32];

#define GEMM_STAGE64(Ap, Bp, Kk, D, KT)                                       \
    {                                                                         \
        const size_t kb0 = (size_t)((KT) << 6) + gcol;                        \
        const size_t kb1 = kb0 + 32;                                          \
        _Pragma("unroll") for (int r = 0; r < 2; r++) {                       \
            const int rows = r * 64 + w * 16;                                 \
            gload16(&Ap[(size_t)(m0 + rows + grow) * Kk + kb0],               \
                    &As[D][0][rows * 32]);                                    \
            gload16(&Ap[(size_t)(m0 + rows + grow) * Kk + kb1],               \
                    &As[D][1][rows * 32]);                                    \
            gload16(&Bp[(size_t)(n0 + rows + grow) * Kk + kb0],               \
                    &Bs[D][0][rows * 32]);                                    \
            gload16(&Bp[(size_t)(n0 + rows + grow) * Kk + kb1],               \
                    &Bs[D][1][rows * 32]);                                    \
        }                                                                     \
    }

#define GEMM_MFMA64(D)                                                        \
    {                                                                         \
        short8 af[4], bfr[4];                                                 \
        _Pragma("unroll") for (int i = 0; i < 4; i++)                         \
            af[i] = *(const short8*)&As[D][0][(wr + i * 16 + fr) * 32 + fk8]; \
        _Pragma("unroll") for (int j = 0; j < 4; j++)                         \
            bfr[j] = *(const short8*)&Bs[D][0][(wc + j * 16 + fr) * 32 + fk8];\
        _Pragma("unroll") for (int i = 0; i < 4; i++)                         \
            _Pragma("unroll") for (int j = 0; j < 4; j++)                     \
                acc[i][j] = __builtin_amdgcn_mfma_f32_16x16x32_bf16(          \
                    af[i], bfr[j], acc[i][j], 0, 0, 0);                       \
        _Pragma("unroll") for (int i = 0; i < 4; i++)                         \
            af[i] = *(const short8*)&As[D][1][(wr + i * 16 + fr) * 32 + fk8]; \
        _Pragma("unroll") for (int j = 0; j < 4; j++)                         \
            bfr[j] = *(const short8*)&Bs[D][1][(wc + j * 16 + fr) * 32 + fk8];\
        _Pragma("unroll") for (int i = 0; i < 4; i++)                         \
            _Pragma("unroll") for (int j = 0; j < 4; j++)                     \
                acc[i][j] = __builtin_amdgcn_mfma_f32_16x16x32_bf16(          \
                    af[i], bfr[j], acc[i][j], 0, 0, 0);                       \
    }

#define GEMM_KLOOP(Ap, Bp, Kk)                                                \
    {                                                                         \
        int cur = 0;                                                          \
        const int nkt = (Kk) >> 6;                                            \
        GEMM_STAGE64(Ap, Bp, Kk, 0, 0);                                       \
        for (int kt = 0; kt < nkt; kt++) {                                    \
            __syncthreads(); /* drains buf[cur] DMAs; prev reads done */      \
            if (kt + 1 < nkt) GEMM_STAGE64(Ap, Bp, Kk, cur ^ 1, kt + 1);      \
            GEMM_MFMA64(cur);                                                 \
            cur ^= 1;                                                         \
        }                                                                     \
    }

// ---------------------------------------------------------------------------
// Fused q/k/v projection GEMM: bx 0-7 -> q16, 8-15 -> k16, 16-31 -> vb f32.
// ---------------------------------------------------------------------------
__global__ void __launch_bounds__(256) gemm_qkv(
    const unsigned short* __restrict__ A, const unsigned short* __restrict__ Bt,
    unsigned short* __restrict__ q16, unsigned short* __restrict__ k16,
    float* __restrict__ vb) {
    GEMM_SHARED();
    const int tid = threadIdx.x;
    const int bx = blockIdx.x & 31, by = blockIdx.x >> 5;
    const int m0 = by << 7, n0 = bx << 7;
    const int w = tid >> 6, lane = tid & 63;
    const int wr = (w >> 1) << 6, wc = (w & 1) << 6;
    const int fr = lane & 15, fk8 = (lane >> 4) << 3;
    const int grow = lane >> 2;
    const int gcol = (lane & 3) << 3;

    f32x4 acc[4][4];
#pragma unroll
    for (int i = 0; i < 4; i++)
#pragma unroll
        for (int j = 0; j < 4; j++)
            acc[i][j] = (f32x4){0.f, 0.f, 0.f, 0.f};

    GEMM_KLOOP(A, Bt, Dc);

    const int cr = (lane >> 4) << 2;
    if (bx < 16) {
        unsigned short* Cb = (bx < 8) ? q16 : k16;
        const int coloff = (bx & 7) << 7;
#pragma unroll
        for (int i = 0; i < 4; i++)
#pragma unroll
            for (int j = 0; j < 4; j++) {
#pragma unroll
                for (int r = 0; r < 4; r++) {
                    Cb[(size_t)(m0 + wr + i * 16 + cr + r) * KDIMc + coloff +
                       wc + j * 16 + fr] = f2bf(acc[i][j][r]);
                }
            }
    } else {
        const int coloff = (bx - 16) << 7;
#pragma unroll
        for (int i = 0; i < 4; i++)
#pragma unroll
            for (int j = 0; j < 4; j++) {
#pragma unroll
                for (int r = 0; r < 4; r++) {
                    vb[(size_t)(m0 + wr + i * 16 + cr + r) * VDIMc + coloff +
                       wc + j * 16 + fr] = acc[i][j][r];
                }
            }
    }
}

// ---------------------------------------------------------------------------
// bf16 MFMA GEMM (generic): C f32 = A @ Bt. For output projection.
// ---------------------------------------------------------------------------
__global__ void __launch_bounds__(256) gemm_bf16(
    const unsigned short* __restrict__ A, const unsigned short* __restrict__ Bt,
    float* __restrict__ C, int M, int N, int K) {
    GEMM_SHARED();
    const int tid = threadIdx.x;
    const int nbx = N >> 7;
    const int bx = blockIdx.x % nbx, by = blockIdx.x / nbx;
    const int m0 = by << 7, n0 = bx << 7;
    const int w = tid >> 6, lane = tid & 63;
    const int wr = (w >> 1) << 6, wc = (w & 1) << 6;
    const int fr = lane & 15, fk8 = (lane >> 4) << 3;
    const int grow = lane >> 2;
    const int gcol = (lane & 3) << 3;

    f32x4 acc[4][4];
#pragma unroll
    for (int i = 0; i < 4; i++)
#pragma unroll
        for (int j = 0; j < 4; j++)
            acc[i][j] = (f32x4){0.f, 0.f, 0.f, 0.f};

    GEMM_KLOOP(A, Bt, K);

    const int cr = (lane >> 4) << 2;
#pragma unroll
    for (int i = 0; i < 4; i++)
#pragma unroll
        for (int j = 0; j < 4; j++) {
#pragma unroll
            for (int r = 0; r < 4; r++) {
                C[(size_t)(m0 + wr + i * 16 + cr + r) * N + n0 + wc + j * 16 +
                  fr] = acc[i][j][r];
            }
        }
}

// ---------------------------------------------------------------------------
// Gate GEMM fused with gated RMSNorm epilogue.
// ---------------------------------------------------------------------------
__global__ void __launch_bounds__(256) gemm_gate_rms(
    const unsigned short* __restrict__ A, const unsigned short* __restrict__ Bt,
    const float* __restrict__ o, const float* __restrict__ rfac,
    const float* __restrict__ norm_w, unsigned short* __restrict__ out,
    int M, int N, int K) {
    GEMM_SHARED();
    const int tid = threadIdx.x;
    const int nbx = N >> 7;
    const int bx = blockIdx.x % nbx, by = blockIdx.x / nbx;
    const int m0 = by << 7, n0 = bx << 7;
    const int h = n0 >> 7;
    const int w = tid >> 6, lane = tid & 63;
    const int wr = (w >> 1) << 6, wc = (w & 1) << 6;
    const int fr = lane & 15, fk8 = (lane >> 4) << 3;
    const int grow = lane >> 2;
    const int gcol = (lane & 3) << 3;

    f32x4 acc[4][4];
#pragma unroll
    for (int i = 0; i < 4; i++)
#pragma unroll
        for (int j = 0; j < 4; j++)
            acc[i][j] = (f32x4){0.f, 0.f, 0.f, 0.f};

    GEMM_KLOOP(A, Bt, K);

    const int cr = (lane >> 4) << 2;
#pragma unroll
    for (int i = 0; i < 4; i++)
#pragma unroll
        for (int j = 0; j < 4; j++) {
            const int colh = wc + j * 16 + fr;
            const float nw = norm_w[colh];
#pragma unroll
            for (int r = 0; r < 4; r++) {
                const int row = m0 + wr + i * 16 + cr + r;
                float ov = o[(size_t)row * VDIMc + n0 + colh];
                float f = rfac[(size_t)row * Hc + h];
                float y = ov * f * nw * siluf(acc[i][j][r]);
                out[(size_t)row * VDIMc + n0 + colh] = f2bf(y);
            }
        }
}

// ---------------------------------------------------------------------------
// Per-(row,h) RMS factor: rf = rsqrt(mean(o^2)+eps). One wave per 128-row.
// ---------------------------------------------------------------------------
__global__ void __launch_bounds__(256) rfac_kernel(
    const float* __restrict__ o, float* __restrict__ rf) {
    const int row = blockIdx.x * 4 + (threadIdx.x >> 6);
    const int lane = threadIdx.x & 63;
    const size_t base = (size_t)row * DVc;
    float2 ov = *(const float2*)&o[base + lane * 2];
    float ss = ov.x * ov.x + ov.y * ov.y;
#pragma unroll
    for (int m = 1; m < 64; m <<= 1) ss += __shfl_xor(ss, m, 64);
    if (lane == 0) rf[row] = rsqrtf(ss * (1.f / 128.f) + 1e-5f);
}

// ---------------------------------------------------------------------------
// a/b projections: transposed f32 weights, one wave per 4 rows.
// ---------------------------------------------------------------------------
__global__ void __launch_bounds__(256) ab_proj(
    const float* __restrict__ x, const float* __restrict__ w_aT,
    const float* __restrict__ w_bT, const float* __restrict__ A_log,
    const float* __restrict__ dt_bias, float* __restrict__ g_out,
    float* __restrict__ beta_out) {
    const int wv = threadIdx.x >> 6;
    const int lane = threadIdx.x & 63;
    const int h = lane >> 2, kg = lane & 3;
    const int row0 = blockIdx.x * 16 + wv * 4;
    const float* wa = w_aT + (size_t)h * Dc + kg * 256;
    const float* wb = w_bT + (size_t)h * Dc + kg * 256;
    const float* xr = x + (size_t)row0 * Dc + kg * 256;
    float pa[4] = {0.f, 0.f, 0.f, 0.f}, pb[4] = {0.f, 0.f, 0.f, 0.f};
#pragma unroll 4
    for (int k = 0; k < 256; k += 4) {
        float4 a4 = *(const float4*)&wa[k];
        float4 b4 = *(const float4*)&wb[k];
#pragma unroll
        for (int r = 0; r < 4; r++) {
            float4 x4 = *(const float4*)&xr[(size_t)r * Dc + k];
            pa[r] += dot4(x4, a4);
            pb[r] += dot4(x4, b4);
        }
    }
#pragma unroll
    for (int r = 0; r < 4; r++) {
        pa[r] += __shfl_xor(pa[r], 1, 64);
        pa[r] += __shfl_xor(pa[r], 2, 64);
        pb[r] += __shfl_xor(pb[r], 1, 64);
        pb[r] += __shfl_xor(pb[r], 2, 64);
    }
    if (kg == 0) {
        const float el = expf(A_log[h]);
        const float db = dt_bias[h];
#pragma unroll
        for (int r = 0; r < 4; r++) {
            float arg = pa[r] + db;
            float sp = fmaxf(arg, 0.f) + log1pf(expf(-fabsf(arg)));
            g_out[(size_t)(row0 + r) * Hc + h] = -el * sp;
            beta_out[(size_t)(row0 + r) * Hc + h] =
                2.f / (1.f + expf(-pb[r]));
        }
    }
}

// ---------------------------------------------------------------------------
// Save 3-row halos at 64-step chunk boundaries (for in-place v conv).
// ---------------------------------------------------------------------------
template <int C>
__global__ void __launch_bounds__(256) save_halo(
    const float* __restrict__ in, float* __restrict__ halo) {
    const int g = blockIdx.x * 256 + threadIdx.x;
    const int total = Bc * (Tc / 64 - 1) * 3 * C;
    if (g >= total) return;
    const int c = g % C;
    int r = g / C;
    const int j = r % 3;
    r /= 3;
    const int chunk = r % (Tc / 64 - 1) + 1;
    const int b = r / (Tc / 64 - 1);
    halo[((size_t)(b * 64 + chunk) * 3 + j) * C + c] =
        in[((size_t)b * Tc + chunk * 64 - 3 + j) * C + c];
}

// ---------------------------------------------------------------------------
// Depthwise causal conv1d + SiLU + l2norm, bf16 in -> bf16 out (q/k).
// ---------------------------------------------------------------------------
template <int C, bool L2N>
__global__ void __launch_bounds__(256) conv_silu_b2b(
    const unsigned short* __restrict__ in, const float* __restrict__ w,
    unsigned short* __restrict__ out) {
    constexpr int CB = C / 256;
    const int bidx = blockIdx.x;
    const int cb = bidx % CB;
    const int tchunk = (bidx / CB) % (Tc / 64);
    const int b = bidx / (CB * (Tc / 64));
    const int c = cb * 256 + threadIdx.x;
    const int t0 = tchunk * 64;
    const float w0 = w[c * 4 + 0], w1 = w[c * 4 + 1], w2 = w[c * 4 + 2],
                w3 = w[c * 4 + 3];
    const unsigned short* src = in + (size_t)b * Tc * C + c;
    float xm3 = (t0 >= 3) ? bf2f(src[(size_t)(t0 - 3) * C]) : 0.f;
    float xm2 = (t0 >= 2) ? bf2f(src[(size_t)(t0 - 2) * C]) : 0.f;
    float xm1 = (t0 >= 1) ? bf2f(src[(size_t)(t0 - 1) * C]) : 0.f;
    unsigned short* dst = out + (size_t)b * Tc * C + c;
#pragma unroll 4
    for (int i = 0; i < 64; i++) {
        float xt = bf2f(src[(size_t)(t0 + i) * C]);
        float y = w0 * xm3 + w1 * xm2 + w2 * xm1 + w3 * xt;
        y = siluf(y);
        if (L2N) {
            float ss = y * y;
#pragma unroll
            for (int m = 1; m < 64; m <<= 1) ss += __shfl_xor(ss, m, 64);
            y *= rsqrtf(ss + 1e-6f);
        }
        dst[(size_t)(t0 + i) * C] = f2bf(y);
        xm3 = xm2;
        xm2 = xm1;
        xm1 = xt;
    }
}

// ---------------------------------------------------------------------------
// Depthwise causal conv1d (K=4) + SiLU, IN PLACE f32 (for v).
// ---------------------------------------------------------------------------
template <int C, bool L2N>
__global__ void __launch_bounds__(256) conv_silu_inplace(
    float* __restrict__ buf, const float* __restrict__ w,
    const float* __restrict__ halo) {
    constexpr int CB = C / 256;
    const int bidx = blockIdx.x;
    const int cb = bidx % CB;
    const int tchunk = (bidx / CB) % (Tc / 64);
    const int b = bidx / (CB * (Tc / 64));
    const int c = cb * 256 + threadIdx.x;
    const int t0 = tchunk * 64;
    const float w0 = w[c * 4 + 0], w1 = w[c * 4 + 1], w2 = w[c * 4 + 2],
                w3 = w[c * 4 + 3];
    float xm3 = 0.f, xm2 = 0.f, xm1 = 0.f;
    if (tchunk > 0) {
        const float* hp = halo + (size_t)(b * 64 + tchunk) * 3 * C + c;
        xm3 = hp[0];
        xm2 = hp[C];
        xm1 = hp[2 * C];
    }
    float* p = buf + (size_t)b * Tc * C + c;
#pragma unroll 4
    for (int i = 0; i < 64; i++) {
        float xt = p[(size_t)(t0 + i) * C];
        float y = w0 * xm3 + w1 * xm2 + w2 * xm1 + w3 * xt;
        y = siluf(y);
        if (L2N) {
            float ss = y * y;
#pragma unroll
            for (int m = 1; m < 64; m <<= 1) ss += __shfl_xor(ss, m, 64);
            y *= rsqrtf(ss + 1e-6f);
        }
        p[(size_t)(t0 + i) * C] = y;
        xm3 = xm2;
        xm2 = xm1;
        xm1 = xt;
    }
}

// ---------------------------------------------------------------------------
// TM precompute: Gram via bf16 MFMA, f32 solve. T,M stored bf16 [t][s].
// ---------------------------------------------------------------------------
__global__ void __launch_bounds__(256) tm_precompute(
    const unsigned short* __restrict__ kc, const unsigned short* __restrict__ qc,
    const float* __restrict__ g, const float* __restrict__ beta,
    unsigned short* __restrict__ tmT, unsigned short* __restrict__ tmM) {
    const int bid = blockIdx.x;
    const int ch = bid & (NCH - 1);
    const int bh = bid >> 6;
    const int b = bh >> 4, h = bh & 15;
    const int tid = threadIdx.x;
    const int t0 = ch * CC;

    __shared__ __align__(16) unsigned short kb16[CC][72];
    __shared__ __align__(16) unsigned short qb16[CC][72];
    __shared__ __align__(16) float AtL[CC][DKc + 4];  // A^T: AtL[s][t]
    __shared__ float cL[CC], betaL[CC];

    const size_t qk0 = (size_t)b * Tc * KDIMc + h * DKc;
    const size_t gb0 = (size_t)b * Tc * Hc + h;
    const size_t tile = (size_t)(bh * NCH + ch) * 4096;

#pragma unroll
    for (int i = 0; i < 2; i++) {
        int e = tid + i * 256;
        int r = e >> 3, c8 = (e & 7) << 3;
        *(short8*)&kb16[r][c8] =
            *(const short8*)&kc[qk0 + (size_t)(t0 + r) * KDIMc + c8];
        *(short8*)&qb16[r][c8] =
            *(const short8*)&qc[qk0 + (size_t)(t0 + r) * KDIMc + c8];
    }
    if (tid < 64) {
        float gv = g[gb0 + (size_t)(t0 + tid) * Hc];
        float cv = gv;
#pragma unroll
        for (int d = 1; d < 64; d <<= 1) {
            float nb = __shfl_up(cv, d, 64);
            if (tid >= d) cv += nb;
        }
        cL[tid] = cv;
        betaL[tid] = beta[gb0 + (size_t)(t0 + tid) * Hc];
    }
    __syncthreads();

    {
        const int w = tid >> 6, lane = tid & 63;
        const int fr = lane & 15, fk8 = (lane >> 4) << 3;
        const int rr = (lane >> 4) << 2;
        short8 ak0 = *(const short8*)&kb16[w * 16 + fr][fk8];
        short8 ak1 = *(const short8*)&kb16[w * 16 + fr][fk8 + 32];
        short8 aq0 = *(const short8*)&qb16[w * 16 + fr][fk8];
        short8 aq1 = *(const short8*)&qb16[w * 16 + fr][fk8 + 32];
#pragma unroll
        for (int j = 0; j < 4; j++) {
            short8 b0 = *(const short8*)&kb16[j * 16 + fr][fk8];
            short8 b1 = *(const short8*)&kb16[j * 16 + fr][fk8 + 32];
            f32x4 kk = (f32x4){0.f, 0.f, 0.f, 0.f};
            f32x4 qk = (f32x4){0.f, 0.f, 0.f, 0.f};
            kk = __builtin_amdgcn_mfma_f32_16x16x32_bf16(ak0, b0, kk, 0, 0, 0);
            kk = __builtin_amdgcn_mfma_f32_16x16x32_bf16(ak1, b1, kk, 0, 0, 0);
            qk = __builtin_amdgcn_mfma_f32_16x16x32_bf16(aq0, b0, qk, 0, 0, 0);
            qk = __builtin_amdgcn_mfma_f32_16x16x32_bf16(aq1, b1, qk, 0, 0, 0);
#pragma unroll
            for (int r = 0; r < 4; r++) {
                int t = w * 16 + rr + r, s = j * 16 + fr;
                float E = expf(cL[t] - cL[s]);
                AtL[s][t] = (s < t) ? betaL[t] * E * kk[r] : 0.f;
                tmM[tile + (size_t)t * 64 + s] =
                    (s <= t) ? f2bf(0.125f * E * qk[r]) : (unsigned short)0;
            }
        }
    }
    __syncthreads();

    {
        const int w = tid >> 6, lane = tid & 63;
        float acc[16];
#pragma unroll
        for (int di = 0; di < 16; di++)
            acc[di] = (lane == w * 16 + di) ? 1.f : 0.f;
#pragma unroll 4
        for (int s = 0; s < 64; s++) {
            float a = AtL[s][lane];
#pragma unroll
            for (int di = 0; di < 16; di++) {
                float ds = __shfl(acc[di], s, 64);
                acc[di] -= a * ds;
            }
        }
        unsigned short tb[16];
#pragma unroll
        for (int di = 0; di < 16; di++) tb[di] = f2bf(acc[di]);
        *(uint4*)&tmT[tile + (size_t)lane * 64 + w * 16] = *(uint4*)&tb[0];
        *(uint4*)&tmT[tile + (size_t)lane * 64 + w * 16 + 8] = *(uint4*)&tb[8];
    }
}

// ---------------------------------------------------------------------------
// Sequential chunk scan v7: K^T staged from pre-transposed global (clean
// short8 copy -> no LDS write conflicts), all-bf16 staging, all-MFMA phases,
// register-resident S.
// ---------------------------------------------------------------------------
__global__ void __launch_bounds__(512, 2) delta_scan(
    const unsigned short* __restrict__ kc, const unsigned short* __restrict__ qc,
    const unsigned short* __restrict__ kcT,  // [B][KDIM][T]
    float* vo, const float* __restrict__ g, const float* __restrict__ beta,
    const unsigned short* __restrict__ tmT,
    const unsigned short* __restrict__ tmM) {
    const int bid = blockIdx.x;
    const int sl = bid >> 5;   // 0..7
    const int bh = bid & 31;   // 0..31 -> XCD = bh%8
    const int b = bh >> 4, h = bh & 15;
    const int tid = threadIdx.x;

    __shared__ __align__(16) float VL[CC][20];
    __shared__ float gamL[CC], egL[CC], betaL[CC];
    __shared__ __align__(16) unsigned short kb16[CC][72];  // K rows
    __shared__ __align__(16) unsigned short kh16[CC][72];  // K^T: [dk][t]
    __shared__ __align__(16) unsigned short qb16[CC][72];
    __shared__ __align__(16) unsigned short Tb16[CC][72];
    __shared__ __align__(16) unsigned short Mb16[CC][72];
    __shared__ __align__(16) unsigned short STb16[16][72];  // S^T bf16 copy
    __shared__ __align__(16) unsigned short DTb16[16][72];  // RHS^T bf16
    __shared__ __align__(16) unsigned short D2b16[16][72];  // delta^T bf16
    __shared__ __align__(16) unsigned short egd16[16][72];  // (eg*delta)^T

    const size_t qk0 = (size_t)b * Tc * KDIMc + h * DKc;
    const size_t kT0 = ((size_t)b * KDIMc + h * DKc) * Tc;
    const size_t v0 = (size_t)b * Tc * VDIMc + h * DVc + sl * 16;
    const size_t gb0 = (size_t)b * Tc * Hc + h;
    const size_t tb0 = (size_t)(bh * NCH) * 4096;

    for (int i = tid; i < 16 * 72; i += 512) ((unsigned short*)STb16)[i] = 0;

    const int r8 = tid >> 3, c8 = (tid & 7) << 3;  // bf16 staging coords
    const int wid = tid >> 6, lane = tid & 63;
    const int fr = lane & 15;
    const int fk8 = (lane >> 4) << 3;
    const int rr = (lane >> 4) << 2;

    f32x4 accS = (f32x4){0.f, 0.f, 0.f, 0.f};  // waves 0-3: S[w*16+rr+r][fr]

    short8 kv, kvT, qv, tv, mv;
    float4 vv0;
    float gvr = 0.f, bvr = 0.f;

#define LOADREGS(CH)                                                          \
    {                                                                         \
        const size_t tK = qk0 + (size_t)(CH) * CC * KDIMc;                    \
        const size_t tile_ = tb0 + (size_t)(CH) * 4096;                       \
        kv = *(const short8*)&kc[tK + (size_t)r8 * KDIMc + c8];               \
        kvT = *(const short8*)&kcT[kT0 + (size_t)r8 * Tc + (CH) * CC + c8];   \
        qv = *(const short8*)&qc[tK + (size_t)r8 * KDIMc + c8];               \
        tv = *(const short8*)&tmT[tile_ + (size_t)tid * 8];                   \
        mv = *(const short8*)&tmM[tile_ + (size_t)tid * 8];                   \
        if (tid < 256)                                                        \
            vv0 = *(const float4*)&vo[v0 +                                    \
                                      (size_t)((CH) * CC + (tid >> 2)) *     \
                                          VDIMc +                             \
                                      ((tid & 3) << 2)];                      \
        if (tid < 64) {                                                       \
            gvr = g[gb0 + (size_t)((CH) * CC + tid) * Hc];                    \
            bvr = beta[gb0 + (size_t)((CH) * CC + tid) * Hc];                 \
        }                                                                     \
    }

    LOADREGS(0);

#pragma unroll 1
    for (int ch = 0; ch < NCH; ch++) {
        __syncthreads();  // B0: prev chunk fully done (STb16 visible)

        // ---- stage regs -> LDS (pure short8 copies; no conversions)
        {
            *(short8*)&kb16[r8][c8] = kv;
            *(short8*)&kh16[r8][c8] = kvT;
            *(short8*)&qb16[r8][c8] = qv;
            *(short8*)&Tb16[r8][c8] = tv;
            *(short8*)&Mb16[r8][c8] = mv;
            if (tid < 256) *(float4*)&VL[tid >> 2][(tid & 3) << 2] = vv0;
            if (tid < 64) {
                float cv = gvr;
#pragma unroll
                for (int d = 1; d < 64; d <<= 1) {
                    float nb = __shfl_up(cv, d, 64);
                    if (tid >= d) cv += nb;
                }
                gamL[tid] = expf(cv);
                float cend = __shfl(cv, 63, 64);
                egL[tid] = expf(cend - cv);
                betaL[tid] = bvr;
            }
        }
        if (ch + 1 < NCH) LOADREGS(ch + 1);
        __syncthreads();  // B1: stage visible

        // ---- phase 1: KS (waves 0-3) and QS (waves 4-7) via MFMA
        f32x4 acc1 = (f32x4){0.f, 0.f, 0.f, 0.f};
        {
            short8 bs0 = *(const short8*)&STb16[fr][fk8];
            short8 bs1 = *(const short8*)&STb16[fr][fk8 + 32];
            if (wid < 4) {
                const int m0 = wid << 4;
                short8 a0 = *(const short8*)&kb16[m0 + fr][fk8];
                short8 a1 = *(const short8*)&kb16[m0 + fr][fk8 + 32];
                acc1 = __builtin_amdgcn_mfma_f32_16x16x32_bf16(a0, bs0, acc1, 0, 0, 0);
                acc1 = __builtin_amdgcn_mfma_f32_16x16x32_bf16(a1, bs1, acc1, 0, 0, 0);
#pragma unroll
                for (int r = 0; r < 4; r++) {
                    int t = m0 + rr + r;
                    float rhs = betaL[t] * (VL[t][fr] - gamL[t] * acc1[r]);
                    DTb16[fr][t] = f2bf(rhs);
                }
            } else {
                const int m0 = (wid - 4) << 4;
                short8 a0 = *(const short8*)&qb16[m0 + fr][fk8];
                short8 a1 = *(const short8*)&qb16[m0 + fr][fk8 + 32];
                acc1 = __builtin_amdgcn_mfma_f32_16x16x32_bf16(a0, bs0, acc1, 0, 0, 0);
                acc1 = __builtin_amdgcn_mfma_f32_16x16x32_bf16(a1, bs1, acc1, 0, 0, 0);
#pragma unroll
                for (int r = 0; r < 4; r++) {
                    int t = m0 + rr + r;
                    acc1[r] *= 0.125f * gamL[t];
                }
            }
        }
        __syncthreads();  // B2: RHS ready

        // ---- phase 2: delta = T * RHS (waves 0-3); write delta and eg*delta
        if (wid < 4) {
            const int m0 = wid << 4;
            short8 a0 = *(const short8*)&Tb16[m0 + fr][fk8];
            short8 a1 = *(const short8*)&Tb16[m0 + fr][fk8 + 32];
            short8 b0 = *(const short8*)&DTb16[fr][fk8];
            short8 b1 = *(const short8*)&DTb16[fr][fk8 + 32];
            f32x4 d = (f32x4){0.f, 0.f, 0.f, 0.f};
            d = __builtin_amdgcn_mfma_f32_16x16x32_bf16(a0, b0, d, 0, 0, 0);
            d = __builtin_amdgcn_mfma_f32_16x16x32_bf16(a1, b1, d, 0, 0, 0);
#pragma unroll
            for (int r = 0; r < 4; r++) {
                int t = m0 + rr + r;
                D2b16[fr][t] = f2bf(d[r]);
                egd16[fr][t] = f2bf(egL[t] * d[r]);
            }
        }
        __syncthreads();  // B3: delta ready

        // ---- phase 3 (waves 4-7): O = M*delta + scaledQS, store direct.
        //      phase 4 (waves 0-3): S = ge*S + K^T(eg*delta) via MFMA.
        if (wid >= 4) {
            const int m0 = (wid - 4) << 4;
            short8 a0 = *(const short8*)&Mb16[m0 + fr][fk8];
            short8 a1 = *(const short8*)&Mb16[m0 + fr][fk8 + 32];
            short8 b0 = *(const short8*)&D2b16[fr][fk8];
            short8 b1 = *(const short8*)&D2b16[fr][fk8 + 32];
            f32x4 o = acc1;  // 0.125*gam*QS
            o = __builtin_amdgcn_mfma_f32_16x16x32_bf16(a0, b0, o, 0, 0, 0);
            o = __builtin_amdgcn_mfma_f32_16x16x32_bf16(a1, b1, o, 0, 0, 0);
#pragma unroll
            for (int r = 0; r < 4; r++)
                vo[v0 + (size_t)(ch * CC + m0 + rr + r) * VDIMc + fr] = o[r];
        } else {
            const int m0 = wid << 4;
            const float ge = gamL[63];
            short8 a0 = *(const short8*)&kh16[m0 + fr][fk8];
            short8 a1 = *(const short8*)&kh16[m0 + fr][fk8 + 32];
            short8 b0 = *(const short8*)&egd16[fr][fk8];
            short8 b1 = *(const short8*)&egd16[fr][fk8 + 32];
#pragma unroll
            for (int r = 0; r < 4; r++) accS[r] *= ge;
            accS = __builtin_amdgcn_mfma_f32_16x16x32_bf16(a0, b0, accS, 0, 0, 0);
            accS = __builtin_amdgcn_mfma_f32_16x16x32_bf16(a1, b1, accS, 0, 0, 0);
#pragma unroll
            for (int r = 0; r < 4; r++)
                STb16[fr][m0 + rr + r] = f2bf(accS[r]);
        }
    }
#undef LOADREGS
}

// ---------------------------------------------------------------------------
// Workspace (floats), 236 MB (unchanged):
//   qb 8.39M (q16raw, then kcT16) | kb 8.39M (k16raw) | vb 16.78M |
//   tm-region 16.78M (tmT16|tmM16|qc16|kc16 as shorts) | gbuf | bbuf | xtra
// halo aliases tm start (dead before tm_precompute); obb aliases tm start
// (after scan); kcT16 aliases qb (q16raw dead after conv_q); rfac = gbuf.
// ---------------------------------------------------------------------------
extern "C" void kernel_launch(void* const* d_in, const int* in_sizes, int n_in,
                              void* d_out, int out_size, void* d_ws,
                              size_t ws_size, hipStream_t stream) {
    const float* x = (const float*)d_in[0];
    const float* w_q = (const float*)d_in[1];
    const float* w_k = (const float*)d_in[2];
    const float* w_v = (const float*)d_in[3];
    const float* w_a = (const float*)d_in[4];
    const float* w_b = (const float*)d_in[5];
    const float* w_g = (const float*)d_in[6];
    const float* w_out = (const float*)d_in[7];
    const float* A_log = (const float*)d_in[8];
    const float* dt_bias = (const float*)d_in[9];
    const float* conv_q = (const float*)d_in[10];
    const float* conv_k = (const float*)d_in[11];
    const float* conv_v = (const float*)d_in[12];
    const float* norm_w = (const float*)d_in[13];

    float* ws = (float*)d_ws;
    const size_t M = Mrows;
    float* qb = ws;
    float* kb = qb + M * KDIMc;
    float* vb = kb + M * KDIMc;
    float* tm = vb + M * VDIMc;          // 16.78M floats region
    float* gbuf = tm + M * VDIMc;
    float* bbuf = gbuf + M * Hc;
    float* xtra = bbuf + M * Hc;

    unsigned short* q16raw = (unsigned short*)qb;
    unsigned short* k16raw = (unsigned short*)kb;
    unsigned short* kcT16 = (unsigned short*)qb;  // alias: after conv_q
    unsigned short* tmS = (unsigned short*)tm;
    unsigned short* tmT16 = tmS;
    unsigned short* tmM16 = tmS + (size_t)8388608;
    unsigned short* qc16 = tmS + (size_t)16777216;
    unsigned short* kc16 = tmS + (size_t)25165824;
    float* halo = tm;                     // dead before tm_precompute
    unsigned short* obb = tmS;            // after scan, tmT/tmM dead
    float* rfac = gbuf;                   // g dead after scan

    unsigned short* xb = (unsigned short*)xtra;
    unsigned short* wqT = xb + M * KDIMc;
    unsigned short* wkT = wqT + (size_t)KDIMc * Dc;
    unsigned short* wvT = wkT + (size_t)KDIMc * Dc;  // wqT|wkT|wvT contiguous
    unsigned short* wgT = wvT + (size_t)VDIMc * Dc;
    unsigned short* woT = wgT + (size_t)VDIMc * Dc;
    float* waT = (float*)(woT + (size_t)Dc * VDIMc);
    float* wbT = waT + (size_t)16 * Dc;

    // 0) conversions
    convert_bf16<<<dim3(M * Dc / 4 / 256), 256, 0, stream>>>(x, xb, M * Dc / 4);
    transp_bf16<<<dim3((KDIMc / 32) * (Dc / 32)), 256, 0, stream>>>(w_q, wqT,
                                                                    Dc, KDIMc);
    transp_bf16<<<dim3((KDIMc / 32) * (Dc / 32)), 256, 0, stream>>>(w_k, wkT,
                                                                    Dc, KDIMc);
    transp_bf16<<<dim3((VDIMc / 32) * (Dc / 32)), 256, 0, stream>>>(w_v, wvT,
                                                                    Dc, VDIMc);
    transp_bf16<<<dim3((VDIMc / 32) * (Dc / 32)), 256, 0, stream>>>(w_g, wgT,
                                                                    Dc, VDIMc);
    transp_bf16<<<dim3((Dc / 32) * (VDIMc / 32)), 256, 0, stream>>>(
        w_out, woT, VDIMc, Dc);
    transp_f32w<<<dim3(Dc / 64), 256, 0, stream>>>(w_a, waT);
    transp_f32w<<<dim3(Dc / 64), 256, 0, stream>>>(w_b, wbT);

    // 1) fused q/k/v projection (one GEMM, BK=64 dbuf; q/k out bf16)
    gemm_qkv<<<dim3((M / 128) * 32), 256, 0, stream>>>(xb, wqT, q16raw, k16raw,
                                                       vb);

    // 2) a/b projections -> g, beta
    ab_proj<<<dim3(M / 16), 256, 0, stream>>>(x, waT, wbT, A_log, dt_bias,
                                              gbuf, bbuf);

    // 3) conv + silu: q,k bf16->bf16 (+l2norm); v in-place f32
    conv_silu_b2b<KDIMc, true>
        <<<dim3(Bc * (Tc / 64) * (KDIMc / 256)), 256, 0, stream>>>(
            q16raw, conv_q, qc16);
    conv_silu_b2b<KDIMc, true>
        <<<dim3(Bc * (Tc / 64) * (KDIMc / 256)), 256, 0, stream>>>(
            k16raw, conv_k, kc16);
    // kcT16 = kc16 transposed to [B][KDIM][T] (aliases qb; conv_q done above)
    transp_k16<<<dim3(Bc * 16 * 64), 256, 0, stream>>>(kc16, kcT16);
    {
        const int nv = Bc * (Tc / 64 - 1) * 3 * VDIMc;
        save_halo<VDIMc><<<dim3((nv + 255) / 256), 256, 0, stream>>>(vb, halo);
        conv_silu_inplace<VDIMc, false>
            <<<dim3(Bc * (Tc / 64) * (VDIMc / 256)), 256, 0, stream>>>(
                vb, conv_v, halo);
    }

    // 4a) parallel precompute of T=(I+A)^{-1} and M (bf16 out)
    tm_precompute<<<dim3(Bc * Hc * NCH), 256, 0, stream>>>(
        kc16, qc16, gbuf, bbuf, tmT16, tmM16);
    // 4b) sequential scan v7 (conflict-free K^T staging)
    delta_scan<<<dim3(Bc * Hc * 8), 512, 0, stream>>>(
        kc16, qc16, kcT16, vb, gbuf, bbuf, tmT16, tmM16);

    // 5) rms factors from o (=vb), then gate GEMM fused with rms epilogue
    rfac_kernel<<<dim3(M * Hc / 4), 256, 0, stream>>>(vb, rfac);
    gemm_gate_rms<<<dim3((M / 128) * (VDIMc / 128)), 256, 0, stream>>>(
        xb, wgT, vb, rfac, norm_w, obb, M, VDIMc, Dc);

    // 6) output projection (bf16 MFMA, BK=64 dbuf) -> d_out
    gemm_bf16<<<dim3((M / 128) * (Dc / 128)), 256, 0, stream>>>(
        obb, woT, (float*)d_out, M, Dc, VDIMc);
}